// Round 2
// baseline (4064.404 us; speedup 1.0000x reference)
//
#include <hip/hip_runtime.h>
#include <hip/hip_bf16.h>

// ---------------- constants ----------------
#define NN 50000
#define MM 400000
#define BB 1000
#define FF 39
#define EE 11
#define GG 200
#define PP 128

// ---------------- helpers ----------------
__device__ __forceinline__ float bf2f(unsigned short u) {
  return __uint_as_float(((unsigned int)u) << 16);
}
__device__ __forceinline__ float leakyf(float x) { return x > 0.f ? x : 0.01f * x; }
__device__ __forceinline__ float eluf(float x)   { return x > 0.f ? x : (expf(x) - 1.f); }
__device__ __forceinline__ float sigmf(float x)  { return 1.f / (1.f + expf(-x)); }
__device__ __forceinline__ unsigned int encf(float x) {
  unsigned int b = __float_as_uint(x);
  return (b & 0x80000000u) ? ~b : (b | 0x80000000u);
}
__device__ __forceinline__ float decf(unsigned int k) {
  return __uint_as_float((k & 0x80000000u) ? (k & 0x7FFFFFFFu) : ~k);
}

// ---------------- runtime dtype detection ----------------
// node_feats ~ N(0,1). If buffer is bf16-packed, bits[14:8] of each 32-bit
// word are a bf16 exponent field -> in [60,64] w.p. ~0.99. If native f32,
// those are mantissa bits -> uniform (p ~ 0.04). Vote over 2048 words.
__global__ __launch_bounds__(256) void detect_dtype(const unsigned int* __restrict__ w,
                                                    int* __restrict__ flag) {
  __shared__ int cnt[256];
  int c = 0;
  for (int i = threadIdx.x; i < 2048; i += 256) {
    unsigned int e = (w[i] >> 8) & 0x7F;
    c += (e >= 60 && e <= 64) ? 1 : 0;
  }
  cnt[threadIdx.x] = c;
  __syncthreads();
  for (int s = 128; s; s >>= 1) {
    if (threadIdx.x < s) cnt[threadIdx.x] += cnt[threadIdx.x + s];
    __syncthreads();
  }
  if (threadIdx.x == 0) *flag = (cnt[0] >= 1024) ? 1 : 0;  // 1 = bf16 inputs
}

// ---------------- batched conversion to f32 ----------------
struct CvtJob { const void* s; float* d; int n; int pad; };
struct CvtJobs32 { CvtJob j[32]; };

__global__ __launch_bounds__(256) void cvt_any(CvtJobs32 jobs, const int* __restrict__ flag) {
  CvtJob job = jobs.j[blockIdx.y];
  int isbf = *flag;
  if (isbf) {
    const unsigned short* s = (const unsigned short*)job.s;
    for (int i = blockIdx.x * 256 + threadIdx.x; i < job.n; i += gridDim.x * 256)
      job.d[i] = bf2f(s[i]);
  } else {
    const float* s = (const float*)job.s;
    for (int i = blockIdx.x * 256 + threadIdx.x; i < job.n; i += gridDim.x * 256)
      job.d[i] = s[i];
  }
}

// ---------------- generic tiled GEMM: C = act(mask(A@W + b)) ----------------
#define Bb 64
#define Bn 64
#define Bk 16
__global__ __launch_bounds__(256) void gemm_kernel(
    const float* __restrict__ A, const float* __restrict__ W,
    const float* __restrict__ bias, const float* __restrict__ rowmask,
    float* __restrict__ Cf, void* __restrict__ Oout, const int* __restrict__ oflag,
    int Mr, int Nc, int K, int act)
{
  __shared__ float As[Bk][Bb + 1];
  __shared__ float Ws[Bk][Bn];
  int row0 = blockIdx.x * Bb, col0 = blockIdx.y * Bn;
  int tid = threadIdx.x;
  int ty = tid >> 4, tx = tid & 15;
  float acc[4][4] = {};
  for (int k0 = 0; k0 < K; k0 += Bk) {
    for (int l = tid; l < Bb * Bk; l += 256) {
      int m = l >> 4, kk = l & 15;
      int r = row0 + m, k = k0 + kk;
      As[kk][m] = (r < Mr && k < K) ? A[(size_t)r * K + k] : 0.f;
    }
    for (int l = tid; l < Bk * Bn; l += 256) {
      int kk = l >> 6, nn = l & 63;
      int k = k0 + kk, c = col0 + nn;
      Ws[kk][nn] = (k < K && c < Nc) ? W[(size_t)k * Nc + c] : 0.f;
    }
    __syncthreads();
#pragma unroll
    for (int kk = 0; kk < Bk; ++kk) {
      float av[4], bv[4];
#pragma unroll
      for (int i = 0; i < 4; ++i) av[i] = As[kk][ty * 4 + i];
#pragma unroll
      for (int j = 0; j < 4; ++j) bv[j] = Ws[kk][tx * 4 + j];
#pragma unroll
      for (int i = 0; i < 4; ++i)
#pragma unroll
        for (int j = 0; j < 4; ++j) acc[i][j] += av[i] * bv[j];
    }
    __syncthreads();
  }
  int isbf = (oflag != nullptr) ? *oflag : 0;
#pragma unroll
  for (int i = 0; i < 4; ++i) {
    int r = row0 + ty * 4 + i;
    if (r >= Mr) continue;
    bool valid = (rowmask == nullptr) || (rowmask[r] > 0.f);
#pragma unroll
    for (int j = 0; j < 4; ++j) {
      int c = col0 + tx * 4 + j;
      if (c >= Nc) continue;
      float v = valid ? (acc[i][j] + (bias ? bias[c] : 0.f)) : 0.f;
      if (act == 1) v = leakyf(v);
      else if (act == 2) v = eluf(v);
      else if (act == 3) v = fmaxf(v, 0.f);
      size_t idx = (size_t)r * Nc + c;
      if (Oout) {
        if (isbf) ((__hip_bfloat16*)Oout)[idx] = __float2bfloat16(v);
        else      ((float*)Oout)[idx] = v;
      } else {
        Cf[idx] = v;
      }
    }
  }
}

// ---------------- fused GRU: out = [relu](GRUCell(x, h)) ----------------
__global__ __launch_bounds__(256) void gru_kernel(
    const float* __restrict__ X, const float* __restrict__ H,
    const float* __restrict__ Wih, const float* __restrict__ Whh,
    const float* __restrict__ bih, const float* __restrict__ bhh,
    float* __restrict__ Out, int R, int relu_out)
{
  __shared__ float xs[Bk][Bb + 1];
  __shared__ float hs[Bk][Bb + 1];
  __shared__ float ws[6][Bk][Bn];
  int row0 = blockIdx.x * Bb, col0 = blockIdx.y * Bn;
  int tid = threadIdx.x;
  int ty = tid >> 4, tx = tid & 15;
  float acc[6][4][4] = {};
  for (int k0 = 0; k0 < GG; k0 += Bk) {
    for (int l = tid; l < Bb * Bk; l += 256) {
      int m = l >> 4, kk = l & 15;
      int r = row0 + m, k = k0 + kk;
      bool ok = (r < R && k < GG);
      xs[kk][m] = ok ? X[(size_t)r * GG + k] : 0.f;
      hs[kk][m] = ok ? H[(size_t)r * GG + k] : 0.f;
    }
#pragma unroll
    for (int z6 = 0; z6 < 6; ++z6) {
      const float* Wp = (z6 < 3) ? Wih : Whh;
      int coff = (z6 % 3) * GG + col0;
      for (int l = tid; l < Bk * Bn; l += 256) {
        int kk = l >> 6, nn = l & 63;
        int k = k0 + kk;
        bool ok = (k < GG && col0 + nn < GG);
        ws[z6][kk][nn] = ok ? Wp[(size_t)k * 600 + coff + nn] : 0.f;
      }
    }
    __syncthreads();
#pragma unroll
    for (int kk = 0; kk < Bk; ++kk) {
      float xv[4], hv[4];
#pragma unroll
      for (int i = 0; i < 4; ++i) { xv[i] = xs[kk][ty * 4 + i]; hv[i] = hs[kk][ty * 4 + i]; }
#pragma unroll
      for (int z6 = 0; z6 < 6; ++z6) {
        float wv[4];
#pragma unroll
        for (int j = 0; j < 4; ++j) wv[j] = ws[z6][kk][tx * 4 + j];
#pragma unroll
        for (int i = 0; i < 4; ++i) {
          float a = (z6 < 3) ? xv[i] : hv[i];
#pragma unroll
          for (int j = 0; j < 4; ++j) acc[z6][i][j] += a * wv[j];
        }
      }
    }
    __syncthreads();
  }
#pragma unroll
  for (int i = 0; i < 4; ++i) {
    int r = row0 + ty * 4 + i;
    if (r >= R) continue;
#pragma unroll
    for (int j = 0; j < 4; ++j) {
      int c = col0 + tx * 4 + j;
      if (c >= GG) continue;
      float rr = sigmf(acc[0][i][j] + bih[c]       + acc[3][i][j] + bhh[c]);
      float zz = sigmf(acc[1][i][j] + bih[200 + c] + acc[4][i][j] + bhh[200 + c]);
      float nn = tanhf(acc[2][i][j] + bih[400 + c] + rr * (acc[5][i][j] + bhh[400 + c]));
      float hval = H[(size_t)r * GG + c];
      float o = (1.f - zz) * nn + zz * hval;
      if (relu_out) o = fmaxf(o, 0.f);
      Out[(size_t)r * GG + c] = o;
    }
  }
}

// ---------------- per-node dot(s): o1 = X·w1, o2 = X·w2 ----------------
__global__ __launch_bounds__(256) void node_dot2(
    const float* __restrict__ X, const float* __restrict__ w1, const float* __restrict__ w2,
    float* __restrict__ o1, float* __restrict__ o2, int N)
{
  int v = (blockIdx.x * 256 + threadIdx.x) >> 6;
  int lane = threadIdx.x & 63;
  if (v >= N) return;
  float d1 = 0.f, d2 = 0.f;
  for (int k = lane; k < GG; k += 64) {
    float x = X[(size_t)v * GG + k];
    d1 += x * w1[k];
    if (w2) d2 += x * w2[k];
  }
  for (int off = 32; off; off >>= 1) {
    d1 += __shfl_down(d1, off);
    if (w2) d2 += __shfl_down(d2, off);
  }
  if (lane == 0) { o1[v] = d1; if (w2) o2[v] = d2; }
}

// ---------------- layer-1 edge pass 1: logits + atomic max ----------------
__global__ __launch_bounds__(256) void edge_pass1(
    const float* __restrict__ Xe, const float* __restrict__ xa,
    const float* __restrict__ pe1w_e, const float* __restrict__ pe1b,
    const float* __restrict__ pe2w_e, const float* __restrict__ pe2b,
    const float* __restrict__ alpha,
    const int* __restrict__ src, const int* __restrict__ dst,
    float* __restrict__ logit, unsigned int* __restrict__ mmax, int M)
{
  int e = (blockIdx.x * 256 + threadIdx.x) >> 6;
  int lane = threadIdx.x & 63;
  if (e >= M) return;
  int s = src[e], d = dst[e];
  float xe[EE];
#pragma unroll
  for (int j = 0; j < EE; ++j) xe[j] = Xe[(size_t)e * EE + j];
  float beta = 0.f;
  for (int k = lane; k < GG; k += 64) {
    float acc = xa[(size_t)s * GG + k] + pe1b[k];
#pragma unroll
    for (int j = 0; j < EE; ++j) acc += xe[j] * pe1w_e[j * GG + k];
    acc = leakyf(acc);
    beta += acc * pe2w_e[k];
  }
  for (int off = 32; off; off >>= 1) beta += __shfl_down(beta, off);
  if (lane == 0) {
    float l = leakyf(alpha[d] + beta + pe2b[0]);
    logit[e] = l;
    atomicMax(&mmax[d], encf(l));
  }
}

// ---------------- layer-1 edge pass 2: scatter e*he1 ----------------
__global__ __launch_bounds__(256) void edge_pass2(
    const float* __restrict__ Xe, const float* __restrict__ xa,
    const float* __restrict__ pe1w_e, const float* __restrict__ pe1b,
    const int* __restrict__ src, const int* __restrict__ dst,
    const float* __restrict__ logit, const unsigned int* __restrict__ mmax,
    float* __restrict__ S, float* __restrict__ ssum, int M)
{
  int e = (blockIdx.x * 256 + threadIdx.x) >> 6;
  int lane = threadIdx.x & 63;
  if (e >= M) return;
  int s = src[e], d = dst[e];
  float xe[EE];
#pragma unroll
  for (int j = 0; j < EE; ++j) xe[j] = Xe[(size_t)e * EE + j];
  float w = expf(fminf(logit[e] - decf(mmax[d]), 0.f));
  for (int k = lane; k < GG; k += 64) {
    float acc = xa[(size_t)s * GG + k] + pe1b[k];
#pragma unroll
    for (int j = 0; j < EE; ++j) acc += xe[j] * pe1w_e[j * GG + k];
    acc = leakyf(acc);
    atomicAdd(&S[(size_t)d * GG + k], w * acc);
  }
  if (lane == 0) atomicAdd(&ssum[d], w);
}

// ---------------- divide S by segment sum (guard empty) ----------------
__global__ __launch_bounds__(256) void divnorm_kernel(
    float* __restrict__ S, const float* __restrict__ ssum, int total)
{
  int i = blockIdx.x * 256 + threadIdx.x;
  if (i >= total) return;
  float s = ssum[i / GG];
  S[i] = (s > 0.f) ? S[i] / s : 0.f;
}

// ---------------- layer-2 logits (thread per edge) ----------------
__global__ __launch_bounds__(256) void l2_logit(
    const float* __restrict__ gd, const float* __restrict__ gs, const float* __restrict__ lpeb,
    const int* __restrict__ src, const int* __restrict__ dst,
    float* __restrict__ logit, unsigned int* __restrict__ mmax, int M)
{
  int e = blockIdx.x * 256 + threadIdx.x;
  if (e >= M) return;
  float l = leakyf(gd[dst[e]] + gs[src[e]] + lpeb[0]);
  logit[e] = l;
  atomicMax(&mmax[dst[e]], encf(l));
}

// ---------------- layer-2 scatter: S2 += e * hv_proj[src] ----------------
__global__ __launch_bounds__(256) void l2_scatter(
    const float* __restrict__ hvp,
    const int* __restrict__ src, const int* __restrict__ dst,
    const float* __restrict__ logit, const unsigned int* __restrict__ mmax,
    float* __restrict__ S2, float* __restrict__ s2, int M)
{
  int e = (blockIdx.x * 256 + threadIdx.x) >> 6;
  int lane = threadIdx.x & 63;
  if (e >= M) return;
  int s = src[e], d = dst[e];
  float w = expf(fminf(logit[e] - decf(mmax[d]), 0.f));
  for (int k = lane; k < GG; k += 64)
    atomicAdd(&S2[(size_t)d * GG + k], w * hvp[(size_t)s * GG + k]);
  if (lane == 0) atomicAdd(&s2[d], w);
}

// ---------------- c2 = elu(S2 / s2) with empty guard (in place) ----------------
__global__ __launch_bounds__(256) void c2elu_kernel(
    float* __restrict__ S2, const float* __restrict__ s2, int total)
{
  int i = blockIdx.x * 256 + threadIdx.x;
  if (i >= total) return;
  float s = s2[i / GG];
  S2[i] = (s > 0.f) ? eluf(S2[i] / s) : 0.f;
}

// ---------------- per-graph sum (50 contiguous nodes/graph) ----------------
__global__ __launch_bounds__(256) void graph_sum(
    const float* __restrict__ h, float* __restrict__ g)
{
  int b = blockIdx.x, k = threadIdx.x;
  if (k < GG) {
    float a = 0.f;
    for (int i = 0; i < 50; ++i) a += h[((size_t)b * 50 + i) * GG + k];
    g[(size_t)b * GG + k] = a;
  }
}

// ---------------- readout attention ----------------
__global__ __launch_bounds__(256) void attn_kernel(
    const float* __restrict__ g, const float* __restrict__ h2,
    const float* __restrict__ w1, const float* __restrict__ dh,
    const float* __restrict__ rb, float* __restrict__ weighted)
{
  int b = blockIdx.x;
  __shared__ float red[256];
  __shared__ float zs[50];
  __shared__ float as_[50];
  __shared__ float dgs;
  int tid = threadIdx.x;
  float p = 0.f;
  if (tid < GG) p = fmaxf(g[(size_t)b * GG + tid], 0.f) * w1[tid];
  red[tid] = p;
  __syncthreads();
  for (int s = 128; s; s >>= 1) { if (tid < s) red[tid] += red[tid + s]; __syncthreads(); }
  if (tid == 0) dgs = red[0];
  __syncthreads();
  if (tid < 50) zs[tid] = leakyf(dgs + dh[b * 50 + tid] + rb[0]);
  __syncthreads();
  if (tid == 0) {
    float m = -1e30f;
    for (int i = 0; i < 50; ++i) m = fmaxf(m, zs[i]);
    float s = 0.f;
    for (int i = 0; i < 50; ++i) { float e = expf(zs[i] - m); as_[i] = e; s += e; }
    float inv = 1.f / s;
    for (int i = 0; i < 50; ++i) as_[i] *= inv;
  }
  __syncthreads();
  if (tid < GG) {
    float a = 0.f;
    for (int i = 0; i < 50; ++i) a += as_[i] * h2[((size_t)b * 50 + i) * GG + tid];
    weighted[(size_t)b * GG + tid] = a;
  }
}

// ---------------- host ----------------
extern "C" void kernel_launch(void* const* d_in, const int* in_sizes, int n_in,
                              void* d_out, int out_size, void* d_ws, size_t ws_size,
                              hipStream_t stream)
{
  (void)n_in; (void)out_size; (void)ws_size;
  const int N = NN, M = MM, B = BB, F = FF, G = GG, P = PP;
  float* ws = (float*)d_ws;
  size_t off = 0;
  auto alloc = [&](size_t n) { size_t o = off; off += (n + 63) & ~(size_t)63; return o; };

  size_t o_flag = alloc(16);
  // converted weights
  size_t o_pn_w = alloc(F * G), o_pn_b = alloc(G);
  size_t o_pe1_w = alloc((F + EE) * G), o_pe1_b = alloc(G);
  size_t o_pe2_w = alloc(2 * G), o_pe2_b = alloc(1);
  size_t o_et_w = alloc(G * G), o_et_b = alloc(G);
  size_t o_g0_wih = alloc(G * 3 * G), o_g0_whh = alloc(G * 3 * G);
  size_t o_g0_bih = alloc(3 * G), o_g0_bhh = alloc(3 * G);
  size_t o_lpe_w = alloc(2 * G), o_lpe_b = alloc(1);
  size_t o_lpn_w = alloc(G * G), o_lpn_b = alloc(G);
  size_t o_g1_wih = alloc(G * 3 * G), o_g1_whh = alloc(G * 3 * G);
  size_t o_g1_bih = alloc(3 * G), o_g1_bhh = alloc(3 * G);
  size_t o_rl_w = alloc(2 * 2 * G), o_rl_b = alloc(2);
  size_t o_rp_w = alloc(2 * G * G), o_rp_b = alloc(2 * G);
  size_t o_rg_wih = alloc(2 * G * 3 * G), o_rg_whh = alloc(2 * G * 3 * G);
  size_t o_rg_bih = alloc(2 * 3 * G), o_rg_bhh = alloc(2 * 3 * G);
  size_t o_t_w = alloc(G * P), o_t_b = alloc(P);
  // fp32 inputs
  size_t o_Xn = alloc((size_t)N * F);
  size_t o_Xe = alloc((size_t)M * EE);
  // big buffers [N,G]
  size_t o_B1 = alloc((size_t)N * G);
  size_t o_B2 = alloc((size_t)N * G);
  size_t o_B3 = alloc((size_t)N * G);
  // small vectors
  size_t o_alpha = alloc(N), o_ssum = alloc(N), o_mmax = alloc(N), o_logit = alloc(M);
  size_t o_gd = alloc(N), o_gs = alloc(N), o_dh = alloc(N);
  size_t o_gv0 = alloc((size_t)B * G), o_gwt = alloc((size_t)B * G), o_grep = alloc((size_t)B * G);
  size_t o_gv1 = alloc((size_t)B * G), o_gv2 = alloc((size_t)B * G);

  int* flag = (int*)(ws + o_flag);

  // ---- conversion jobs ----
  CvtJobs32 jobs;
  int ji = 0;
  auto push = [&](int idx, size_t dsto) {
    jobs.j[ji].s = d_in[idx];
    jobs.j[ji].d = ws + dsto;
    jobs.j[ji].n = in_sizes[idx];
    jobs.j[ji].pad = 0;
    ++ji;
  };
  push(0, o_Xn);
  push(1, o_Xe);
  push(2, o_pn_w);  push(3, o_pn_b);
  push(4, o_pe1_w); push(5, o_pe1_b);
  push(6, o_pe2_w); push(7, o_pe2_b);
  push(8, o_et_w);  push(9, o_et_b);
  push(10, o_g0_wih); push(11, o_g0_whh); push(12, o_g0_bih); push(13, o_g0_bhh);
  push(14, o_lpe_w);  push(15, o_lpe_b);
  push(16, o_lpn_w);  push(17, o_lpn_b);
  push(18, o_g1_wih); push(19, o_g1_whh); push(20, o_g1_bih); push(21, o_g1_bhh);
  push(22, o_rl_w);   push(23, o_rl_b);
  push(24, o_rp_w);   push(25, o_rp_b);
  push(26, o_rg_wih); push(27, o_rg_whh); push(28, o_rg_bih); push(29, o_rg_bhh);
  push(30, o_t_w);    push(31, o_t_b);

  const int* src = (const int*)d_in[32];
  const int* dst = (const int*)d_in[33];

  dim3 blk(256);
  detect_dtype<<<dim3(1), blk, 0, stream>>>((const unsigned int*)d_in[0], flag);
  cvt_any<<<dim3(512, 32), blk, 0, stream>>>(jobs, flag);

  dim3 gNG((N + Bb - 1) / Bb, (G + Bn - 1) / Bn);

  // hv_new = leaky(Xn@pn_w + pn_b) -> B1
  gemm_kernel<<<gNG, blk, 0, stream>>>(ws + o_Xn, ws + o_pn_w, ws + o_pn_b, nullptr,
                                       ws + o_B1, nullptr, nullptr, N, G, F, 1);
  // xa = Xn @ pe1_w[:39] -> B2 (bias folded into edge passes)
  gemm_kernel<<<gNG, blk, 0, stream>>>(ws + o_Xn, ws + o_pe1_w, nullptr, nullptr,
                                       ws + o_B2, nullptr, nullptr, N, G, F, 0);
  // alpha = hv_new · pe2_w[:200]
  node_dot2<<<dim3((N + 3) / 4), blk, 0, stream>>>(ws + o_B1, ws + o_pe2_w, nullptr,
                                                   ws + o_alpha, nullptr, N);
  hipMemsetAsync(ws + o_mmax, 0, (size_t)N * 4, stream);
  hipMemsetAsync(ws + o_ssum, 0, (size_t)N * 4, stream);
  hipMemsetAsync(ws + o_B3, 0, (size_t)N * G * 4, stream);

  edge_pass1<<<dim3((M + 3) / 4), blk, 0, stream>>>(
      ws + o_Xe, ws + o_B2, ws + o_pe1_w + (size_t)F * G, ws + o_pe1_b,
      ws + o_pe2_w + G, ws + o_pe2_b, ws + o_alpha, src, dst,
      ws + o_logit, (unsigned int*)(ws + o_mmax), M);
  edge_pass2<<<dim3((M + 3) / 4), blk, 0, stream>>>(
      ws + o_Xe, ws + o_B2, ws + o_pe1_w + (size_t)F * G, ws + o_pe1_b,
      src, dst, ws + o_logit, (const unsigned int*)(ws + o_mmax),
      ws + o_B3, ws + o_ssum, M);
  divnorm_kernel<<<dim3((N * G + 255) / 256), blk, 0, stream>>>(ws + o_B3, ws + o_ssum, N * G);
  // c = elu(mask(B3@et_w + et_b)) -> B2
  gemm_kernel<<<gNG, blk, 0, stream>>>(ws + o_B3, ws + o_et_w, ws + o_et_b, ws + o_ssum,
                                       ws + o_B2, nullptr, nullptr, N, G, G, 2);
  // h = relu(GRU0(x=B2, h=B1)) -> B3
  gru_kernel<<<gNG, blk, 0, stream>>>(ws + o_B2, ws + o_B1, ws + o_g0_wih, ws + o_g0_whh,
                                      ws + o_g0_bih, ws + o_g0_bhh, ws + o_B3, N, 1);

  // ---- layer 2 ----
  node_dot2<<<dim3((N + 3) / 4), blk, 0, stream>>>(ws + o_B3, ws + o_lpe_w, ws + o_lpe_w + G,
                                                   ws + o_gd, ws + o_gs, N);
  // hv_proj = h@lpn_w + lpn_b -> B1
  gemm_kernel<<<gNG, blk, 0, stream>>>(ws + o_B3, ws + o_lpn_w, ws + o_lpn_b, nullptr,
                                       ws + o_B1, nullptr, nullptr, N, G, G, 0);
  hipMemsetAsync(ws + o_mmax, 0, (size_t)N * 4, stream);
  hipMemsetAsync(ws + o_ssum, 0, (size_t)N * 4, stream);
  hipMemsetAsync(ws + o_B2, 0, (size_t)N * G * 4, stream);
  l2_logit<<<dim3((M + 255) / 256), blk, 0, stream>>>(ws + o_gd, ws + o_gs, ws + o_lpe_b,
                                                      src, dst, ws + o_logit,
                                                      (unsigned int*)(ws + o_mmax), M);
  l2_scatter<<<dim3((M + 3) / 4), blk, 0, stream>>>(ws + o_B1, src, dst, ws + o_logit,
                                                    (const unsigned int*)(ws + o_mmax),
                                                    ws + o_B2, ws + o_ssum, M);
  c2elu_kernel<<<dim3((N * G + 255) / 256), blk, 0, stream>>>(ws + o_B2, ws + o_ssum, N * G);
  // h2 = relu(GRU1(x=B2, h=B3)) -> B1
  gru_kernel<<<gNG, blk, 0, stream>>>(ws + o_B2, ws + o_B3, ws + o_g1_wih, ws + o_g1_whh,
                                      ws + o_g1_bih, ws + o_g1_bhh, ws + o_B1, N, 1);

  // ---- readout ----
  graph_sum<<<dim3(B), blk, 0, stream>>>(ws + o_B1, ws + o_gv0);
  dim3 gBG((B + Bb - 1) / Bb, (G + Bn - 1) / Bn);
  size_t gcur = o_gv0, gnext = o_gv1;
  for (int t = 0; t < 2; ++t) {
    node_dot2<<<dim3((N + 3) / 4), blk, 0, stream>>>(ws + o_B1, ws + o_rl_w + t * 2 * G + G,
                                                     nullptr, ws + o_dh, nullptr, N);
    attn_kernel<<<dim3(B), blk, 0, stream>>>(ws + gcur, ws + o_B1, ws + o_rl_w + t * 2 * G,
                                             ws + o_dh, ws + o_rl_b + t, ws + o_gwt);
    gemm_kernel<<<gBG, blk, 0, stream>>>(ws + o_gwt, ws + o_rp_w + (size_t)t * G * G,
                                         ws + o_rp_b + t * G, nullptr,
                                         ws + o_grep, nullptr, nullptr, B, G, G, 2);
    gru_kernel<<<gBG, blk, 0, stream>>>(ws + o_grep, ws + gcur,
                                        ws + o_rg_wih + (size_t)t * G * 3 * G,
                                        ws + o_rg_whh + (size_t)t * G * 3 * G,
                                        ws + o_rg_bih + t * 3 * G, ws + o_rg_bhh + t * 3 * G,
                                        ws + gnext, B, 0);
    gcur = gnext;
    gnext = o_gv2;
  }
  // out = g @ t_w + t_b (dtype per detected flag)
  dim3 gOut((B + Bb - 1) / Bb, (P + Bn - 1) / Bn);
  gemm_kernel<<<gOut, blk, 0, stream>>>(ws + gcur, ws + o_t_w, ws + o_t_b, nullptr,
                                        nullptr, d_out, flag, B, P, G, 0);
}

// Round 3
// 1984.006 us; speedup vs baseline: 2.0486x; 2.0486x over previous
//
#include <hip/hip_runtime.h>
#include <hip/hip_bf16.h>

// ---------------- constants ----------------
#define NN 50000
#define MM 400000
#define BB 1000
#define FF 39
#define EE 11
#define GG 200
#define PP 128

typedef __attribute__((ext_vector_type(8))) short bf16x8;
typedef __attribute__((ext_vector_type(4))) float f32x4;

// ---------------- helpers ----------------
__device__ __forceinline__ float bf2f(unsigned short u) {
  return __uint_as_float(((unsigned int)u) << 16);
}
__device__ __forceinline__ unsigned short f2bf(float x) {
  union { __hip_bfloat16 b; unsigned short u; } v;
  v.b = __float2bfloat16(x);
  return v.u;
}
__device__ __forceinline__ float leakyf(float x) { return x > 0.f ? x : 0.01f * x; }
__device__ __forceinline__ float eluf(float x)   { return x > 0.f ? x : (expf(x) - 1.f); }
__device__ __forceinline__ float sigmf(float x)  { return 1.f / (1.f + expf(-x)); }
__device__ __forceinline__ unsigned int encf(float x) {
  unsigned int b = __float_as_uint(x);
  return (b & 0x80000000u) ? ~b : (b | 0x80000000u);
}
__device__ __forceinline__ float decf(unsigned int k) {
  return __uint_as_float((k & 0x80000000u) ? (k & 0x7FFFFFFFu) : ~k);
}

// ---------------- runtime dtype detection ----------------
__global__ __launch_bounds__(256) void detect_dtype(const unsigned int* __restrict__ w,
                                                    int* __restrict__ flag) {
  __shared__ int cnt[256];
  int c = 0;
  for (int i = threadIdx.x; i < 2048; i += 256) {
    unsigned int e = (w[i] >> 8) & 0x7F;
    c += (e >= 60 && e <= 64) ? 1 : 0;
  }
  cnt[threadIdx.x] = c;
  __syncthreads();
  for (int s = 128; s; s >>= 1) {
    if (threadIdx.x < s) cnt[threadIdx.x] += cnt[threadIdx.x + s];
    __syncthreads();
  }
  if (threadIdx.x == 0) *flag = (cnt[0] >= 1024) ? 1 : 0;  // 1 = bf16 inputs
}

// ---------------- batched conversion to f32 ----------------
struct CvtJob { const void* s; float* d; int n; int pad; };
struct CvtJobs32 { CvtJob j[32]; };

__global__ __launch_bounds__(256) void cvt_any(CvtJobs32 jobs, const int* __restrict__ flag) {
  CvtJob job = jobs.j[blockIdx.y];
  int isbf = *flag;
  if (isbf) {
    const unsigned short* s = (const unsigned short*)job.s;
    for (int i = blockIdx.x * 256 + threadIdx.x; i < job.n; i += gridDim.x * 256)
      job.d[i] = bf2f(s[i]);
  } else {
    const float* s = (const float*)job.s;
    for (int i = blockIdx.x * 256 + threadIdx.x; i < job.n; i += gridDim.x * 256)
      job.d[i] = s[i];
  }
}

// ---------------- weight transpose+cvt: W f32 [K][N] -> Wt bf16 [N][K] ----------------
struct TJob { const float* s; unsigned short* d; int K; int N; };
struct TJobs10 { TJob j[10]; };

__global__ __launch_bounds__(256) void transpose_bf16(TJobs10 jobs) {
  TJob job = jobs.j[blockIdx.y];
  int total = job.K * job.N;
  for (int idx = blockIdx.x * 256 + threadIdx.x; idx < total; idx += gridDim.x * 256) {
    int n = idx / job.K, k = idx - n * job.K;
    job.d[idx] = f2bf(job.s[(size_t)k * job.N + n]);
  }
}

// ================= MFMA GEMM: C = act(mask(A@W + b)) =================
// A: f32 [Mr][K] (cvt to bf16 at staging); Wt: bf16 [Nc][K] (pre-transposed)
// tile: 128 rows x 64 cols, K-step 32, 4 waves (each: 32 rows x 64 cols)
#define LDP 40  // padded LDS row stride in bf16 units (conflict-free, 16B-aligned)
__global__ __launch_bounds__(256) void mfma_gemm(
    const float* __restrict__ A, const unsigned short* __restrict__ Wt,
    const float* __restrict__ bias, const float* __restrict__ rowmask,
    float* __restrict__ C, int Mr, int Nc, int K, int act)
{
  __shared__ short As[128 * LDP];
  __shared__ short Bs[64 * LDP];
  int tid = threadIdx.x;
  int w = tid >> 6, lane = tid & 63, quad = lane >> 4, l15 = lane & 15;
  int row0 = blockIdx.x * 128, col0 = blockIdx.y * 64;

  f32x4 zero4 = {0.f, 0.f, 0.f, 0.f};
  f32x4 acc[2][4];
#pragma unroll
  for (int r = 0; r < 2; ++r)
#pragma unroll
    for (int c = 0; c < 4; ++c) acc[r][c] = zero4;

  for (int k0 = 0; k0 < K; k0 += 32) {
    // stage A: thread -> (row, half): 16 f32 -> bf16
    {
      int row = tid >> 1, half = tid & 1;
      int r = row0 + row;
      short tmp[16];
      const float* ap = A + (size_t)r * K + k0 + half * 16;
      if (r < Mr && k0 + half * 16 + 16 <= K) {
#pragma unroll
        for (int j = 0; j < 16; ++j) tmp[j] = (short)f2bf(ap[j]);
      } else if (r < Mr) {
#pragma unroll
        for (int j = 0; j < 16; ++j) {
          int k = k0 + half * 16 + j;
          tmp[j] = (k < K) ? (short)f2bf(ap[j]) : (short)0;
        }
      } else {
#pragma unroll
        for (int j = 0; j < 16; ++j) tmp[j] = 0;
      }
      *(bf16x8*)&As[row * LDP + half * 16]     = *(bf16x8*)&tmp[0];
      *(bf16x8*)&As[row * LDP + half * 16 + 8] = *(bf16x8*)&tmp[8];
    }
    // stage B: thread -> (col, seg): 8 bf16 contiguous
    {
      int col = tid & 63, seg = tid >> 6;
      int n = col0 + col, k = k0 + seg * 8;
      short t8[8];
      const unsigned short* wp = Wt + (size_t)n * K + k;
      if (n < Nc && k + 8 <= K) {
        *(bf16x8*)&t8[0] = *(const bf16x8*)wp;
      } else {
#pragma unroll
        for (int j = 0; j < 8; ++j)
          t8[j] = (n < Nc && k + j < K) ? (short)wp[j] : (short)0;
      }
      *(bf16x8*)&Bs[col * LDP + seg * 8] = *(bf16x8*)&t8[0];
    }
    __syncthreads();
    bf16x8 a[2], b[4];
#pragma unroll
    for (int r = 0; r < 2; ++r)
      a[r] = *(const bf16x8*)&As[(w * 32 + r * 16 + l15) * LDP + quad * 8];
#pragma unroll
    for (int c = 0; c < 4; ++c)
      b[c] = *(const bf16x8*)&Bs[(c * 16 + l15) * LDP + quad * 8];
#pragma unroll
    for (int r = 0; r < 2; ++r)
#pragma unroll
      for (int c = 0; c < 4; ++c)
        acc[r][c] = __builtin_amdgcn_mfma_f32_16x16x32_bf16(a[r], b[c], acc[r][c], 0, 0, 0);
    __syncthreads();
  }
  // epilogue: C/D layout col=lane&15, row=quad*4+reg
#pragma unroll
  for (int r = 0; r < 2; ++r) {
#pragma unroll
    for (int c = 0; c < 4; ++c) {
      int col = col0 + c * 16 + l15;
      if (col >= Nc) continue;
#pragma unroll
      for (int i = 0; i < 4; ++i) {
        int row = row0 + w * 32 + r * 16 + quad * 4 + i;
        if (row >= Mr) continue;
        bool valid = (rowmask == nullptr) || (rowmask[row] > 0.f);
        float v = valid ? (acc[r][c][i] + (bias ? bias[col] : 0.f)) : 0.f;
        if (act == 1) v = leakyf(v);
        else if (act == 2) v = eluf(v);
        C[(size_t)row * Nc + col] = v;
      }
    }
  }
}

// ================= fused MFMA GRU =================
// X,H: f32 [R][200]; WtIH/WtHH: bf16 [600][200] (pre-transposed)
// tile: 128 rows x 32 gate-cols x 6 gates; 4 waves (32 rows each)
__global__ __launch_bounds__(256) void mfma_gru(
    const float* __restrict__ X, const float* __restrict__ H,
    const unsigned short* __restrict__ WtIH, const unsigned short* __restrict__ WtHH,
    const float* __restrict__ bih, const float* __restrict__ bhh,
    float* __restrict__ Out, int R, int relu_out)
{
  __shared__ short Xs[128 * LDP];
  __shared__ short Hs[128 * LDP];
  __shared__ short Ws[192 * LDP];
  int tid = threadIdx.x;
  int w = tid >> 6, lane = tid & 63, quad = lane >> 4, l15 = lane & 15;
  int row0 = blockIdx.x * 128, col0 = blockIdx.y * 32;

  f32x4 zero4 = {0.f, 0.f, 0.f, 0.f};
  f32x4 acc[6][2][2];
#pragma unroll
  for (int g = 0; g < 6; ++g)
#pragma unroll
    for (int r = 0; r < 2; ++r)
#pragma unroll
      for (int c = 0; c < 2; ++c) acc[g][r][c] = zero4;

  for (int k0 = 0; k0 < GG; k0 += 32) {
    // stage X and H
    {
      int row = tid >> 1, half = tid & 1;
      int r = row0 + row;
      short tx[16], th[16];
      const float* xp = X + (size_t)r * GG + k0 + half * 16;
      const float* hp = H + (size_t)r * GG + k0 + half * 16;
      if (r < R && k0 + half * 16 + 16 <= GG) {
#pragma unroll
        for (int j = 0; j < 16; ++j) { tx[j] = (short)f2bf(xp[j]); th[j] = (short)f2bf(hp[j]); }
      } else if (r < R) {
#pragma unroll
        for (int j = 0; j < 16; ++j) {
          int k = k0 + half * 16 + j;
          tx[j] = (k < GG) ? (short)f2bf(xp[j]) : (short)0;
          th[j] = (k < GG) ? (short)f2bf(hp[j]) : (short)0;
        }
      } else {
#pragma unroll
        for (int j = 0; j < 16; ++j) { tx[j] = 0; th[j] = 0; }
      }
      *(bf16x8*)&Xs[row * LDP + half * 16]     = *(bf16x8*)&tx[0];
      *(bf16x8*)&Xs[row * LDP + half * 16 + 8] = *(bf16x8*)&tx[8];
      *(bf16x8*)&Hs[row * LDP + half * 16]     = *(bf16x8*)&th[0];
      *(bf16x8*)&Hs[row * LDP + half * 16 + 8] = *(bf16x8*)&th[8];
    }
    // stage W: 6 gates x 32 cols x 4 segs = 768 tasks
    for (int task = tid; task < 768; task += 256) {
      int rw = task >> 2, seg = task & 3;
      int g = rw >> 5, cc = rw & 31;
      int n = col0 + cc, k = k0 + seg * 8;
      const unsigned short* wp = (g < 3)
          ? WtIH + (size_t)(g * GG + n) * GG + k
          : WtHH + (size_t)((g - 3) * GG + n) * GG + k;
      short t8[8];
      if (n < GG && k + 8 <= GG) {
        *(bf16x8*)&t8[0] = *(const bf16x8*)wp;
      } else {
#pragma unroll
        for (int j = 0; j < 8; ++j)
          t8[j] = (n < GG && k + j < GG) ? (short)wp[j] : (short)0;
      }
      *(bf16x8*)&Ws[rw * LDP + seg * 8] = *(bf16x8*)&t8[0];
    }
    __syncthreads();
    bf16x8 ax[2], ah[2];
#pragma unroll
    for (int r = 0; r < 2; ++r) {
      ax[r] = *(const bf16x8*)&Xs[(w * 32 + r * 16 + l15) * LDP + quad * 8];
      ah[r] = *(const bf16x8*)&Hs[(w * 32 + r * 16 + l15) * LDP + quad * 8];
    }
#pragma unroll
    for (int g = 0; g < 6; ++g) {
      bf16x8 b[2];
#pragma unroll
      for (int c = 0; c < 2; ++c)
        b[c] = *(const bf16x8*)&Ws[(g * 32 + c * 16 + l15) * LDP + quad * 8];
#pragma unroll
      for (int r = 0; r < 2; ++r)
#pragma unroll
        for (int c = 0; c < 2; ++c)
          acc[g][r][c] = __builtin_amdgcn_mfma_f32_16x16x32_bf16(
              (g < 3) ? ax[r] : ah[r], b[c], acc[g][r][c], 0, 0, 0);
    }
    __syncthreads();
  }
  // epilogue
#pragma unroll
  for (int r = 0; r < 2; ++r) {
#pragma unroll
    for (int c = 0; c < 2; ++c) {
      int col = col0 + c * 16 + l15;
      if (col >= GG) continue;
      float br = bih[col],       bhr = bhh[col];
      float bz = bih[200 + col], bhz = bhh[200 + col];
      float bn = bih[400 + col], bhn = bhh[400 + col];
#pragma unroll
      for (int i = 0; i < 4; ++i) {
        int row = row0 + w * 32 + r * 16 + quad * 4 + i;
        if (row >= R) continue;
        float rr = sigmf(acc[0][r][c][i] + br + acc[3][r][c][i] + bhr);
        float zz = sigmf(acc[1][r][c][i] + bz + acc[4][r][c][i] + bhz);
        float nn = tanhf(acc[2][r][c][i] + bn + rr * (acc[5][r][c][i] + bhn));
        float hval = H[(size_t)row * GG + col];
        float o = (1.f - zz) * nn + zz * hval;
        if (relu_out) o = fmaxf(o, 0.f);
        Out[(size_t)row * GG + col] = o;
      }
    }
  }
}

// ---------------- fp32 tiled GEMM (small shapes) ----------------
#define Bb 64
#define Bn 64
#define Bk 16
__global__ __launch_bounds__(256) void gemm_kernel(
    const float* __restrict__ A, const float* __restrict__ W,
    const float* __restrict__ bias, const float* __restrict__ rowmask,
    float* __restrict__ Cf, void* __restrict__ Oout, const int* __restrict__ oflag,
    int Mr, int Nc, int K, int act)
{
  __shared__ float As[Bk][Bb + 1];
  __shared__ float Ws[Bk][Bn];
  int row0 = blockIdx.x * Bb, col0 = blockIdx.y * Bn;
  int tid = threadIdx.x;
  int ty = tid >> 4, tx = tid & 15;
  float acc[4][4] = {};
  for (int k0 = 0; k0 < K; k0 += Bk) {
    for (int l = tid; l < Bb * Bk; l += 256) {
      int m = l >> 4, kk = l & 15;
      int r = row0 + m, k = k0 + kk;
      As[kk][m] = (r < Mr && k < K) ? A[(size_t)r * K + k] : 0.f;
    }
    for (int l = tid; l < Bk * Bn; l += 256) {
      int kk = l >> 6, nn = l & 63;
      int k = k0 + kk, c = col0 + nn;
      Ws[kk][nn] = (k < K && c < Nc) ? W[(size_t)k * Nc + c] : 0.f;
    }
    __syncthreads();
#pragma unroll
    for (int kk = 0; kk < Bk; ++kk) {
      float av[4], bv[4];
#pragma unroll
      for (int i = 0; i < 4; ++i) av[i] = As[kk][ty * 4 + i];
#pragma unroll
      for (int j = 0; j < 4; ++j) bv[j] = Ws[kk][tx * 4 + j];
#pragma unroll
      for (int i = 0; i < 4; ++i)
#pragma unroll
        for (int j = 0; j < 4; ++j) acc[i][j] += av[i] * bv[j];
    }
    __syncthreads();
  }
  int isbf = (oflag != nullptr) ? *oflag : 0;
#pragma unroll
  for (int i = 0; i < 4; ++i) {
    int r = row0 + ty * 4 + i;
    if (r >= Mr) continue;
    bool valid = (rowmask == nullptr) || (rowmask[r] > 0.f);
#pragma unroll
    for (int j = 0; j < 4; ++j) {
      int c = col0 + tx * 4 + j;
      if (c >= Nc) continue;
      float v = valid ? (acc[i][j] + (bias ? bias[c] : 0.f)) : 0.f;
      if (act == 1) v = leakyf(v);
      else if (act == 2) v = eluf(v);
      else if (act == 3) v = fmaxf(v, 0.f);
      size_t idx = (size_t)r * Nc + c;
      if (Oout) {
        if (isbf) ((__hip_bfloat16*)Oout)[idx] = __float2bfloat16(v);
        else      ((float*)Oout)[idx] = v;
      } else {
        Cf[idx] = v;
      }
    }
  }
}

// ---------------- per-node dot(s) ----------------
__global__ __launch_bounds__(256) void node_dot2(
    const float* __restrict__ X, const float* __restrict__ w1, const float* __restrict__ w2,
    float* __restrict__ o1, float* __restrict__ o2, int N)
{
  int v = (blockIdx.x * 256 + threadIdx.x) >> 6;
  int lane = threadIdx.x & 63;
  if (v >= N) return;
  float d1 = 0.f, d2 = 0.f;
  for (int k = lane; k < GG; k += 64) {
    float x = X[(size_t)v * GG + k];
    d1 += x * w1[k];
    if (w2) d2 += x * w2[k];
  }
  for (int off = 32; off; off >>= 1) {
    d1 += __shfl_down(d1, off);
    if (w2) d2 += __shfl_down(d2, off);
  }
  if (lane == 0) { o1[v] = d1; if (w2) o2[v] = d2; }
}

// ---------------- layer-1 edge pass 1 ----------------
__global__ __launch_bounds__(256) void edge_pass1(
    const float* __restrict__ Xe, const float* __restrict__ xa,
    const float* __restrict__ pe1w_e, const float* __restrict__ pe1b,
    const float* __restrict__ pe2w_e, const float* __restrict__ pe2b,
    const float* __restrict__ alpha,
    const int* __restrict__ src, const int* __restrict__ dst,
    float* __restrict__ logit, unsigned int* __restrict__ mmax, int M)
{
  int e = (blockIdx.x * 256 + threadIdx.x) >> 6;
  int lane = threadIdx.x & 63;
  if (e >= M) return;
  int s = src[e], d = dst[e];
  float xe[EE];
#pragma unroll
  for (int j = 0; j < EE; ++j) xe[j] = Xe[(size_t)e * EE + j];
  float beta = 0.f;
  for (int k = lane; k < GG; k += 64) {
    float acc = xa[(size_t)s * GG + k] + pe1b[k];
#pragma unroll
    for (int j = 0; j < EE; ++j) acc += xe[j] * pe1w_e[j * GG + k];
    acc = leakyf(acc);
    beta += acc * pe2w_e[k];
  }
  for (int off = 32; off; off >>= 1) beta += __shfl_down(beta, off);
  if (lane == 0) {
    float l = leakyf(alpha[d] + beta + pe2b[0]);
    logit[e] = l;
    atomicMax(&mmax[d], encf(l));
  }
}

// ---------------- layer-1 edge pass 2 ----------------
__global__ __launch_bounds__(256) void edge_pass2(
    const float* __restrict__ Xe, const float* __restrict__ xa,
    const float* __restrict__ pe1w_e, const float* __restrict__ pe1b,
    const int* __restrict__ src, const int* __restrict__ dst,
    const float* __restrict__ logit, const unsigned int* __restrict__ mmax,
    float* __restrict__ S, float* __restrict__ ssum, int M)
{
  int e = (blockIdx.x * 256 + threadIdx.x) >> 6;
  int lane = threadIdx.x & 63;
  if (e >= M) return;
  int s = src[e], d = dst[e];
  float xe[EE];
#pragma unroll
  for (int j = 0; j < EE; ++j) xe[j] = Xe[(size_t)e * EE + j];
  float w = expf(fminf(logit[e] - decf(mmax[d]), 0.f));
  for (int k = lane; k < GG; k += 64) {
    float acc = xa[(size_t)s * GG + k] + pe1b[k];
#pragma unroll
    for (int j = 0; j < EE; ++j) acc += xe[j] * pe1w_e[j * GG + k];
    acc = leakyf(acc);
    atomicAdd(&S[(size_t)d * GG + k], w * acc);
  }
  if (lane == 0) atomicAdd(&ssum[d], w);
}

__global__ __launch_bounds__(256) void divnorm_kernel(
    float* __restrict__ S, const float* __restrict__ ssum, int total)
{
  int i = blockIdx.x * 256 + threadIdx.x;
  if (i >= total) return;
  float s = ssum[i / GG];
  S[i] = (s > 0.f) ? S[i] / s : 0.f;
}

__global__ __launch_bounds__(256) void l2_logit(
    const float* __restrict__ gd, const float* __restrict__ gs, const float* __restrict__ lpeb,
    const int* __restrict__ src, const int* __restrict__ dst,
    float* __restrict__ logit, unsigned int* __restrict__ mmax, int M)
{
  int e = blockIdx.x * 256 + threadIdx.x;
  if (e >= M) return;
  float l = leakyf(gd[dst[e]] + gs[src[e]] + lpeb[0]);
  logit[e] = l;
  atomicMax(&mmax[dst[e]], encf(l));
}

__global__ __launch_bounds__(256) void l2_scatter(
    const float* __restrict__ hvp,
    const int* __restrict__ src, const int* __restrict__ dst,
    const float* __restrict__ logit, const unsigned int* __restrict__ mmax,
    float* __restrict__ S2, float* __restrict__ s2, int M)
{
  int e = (blockIdx.x * 256 + threadIdx.x) >> 6;
  int lane = threadIdx.x & 63;
  if (e >= M) return;
  int s = src[e], d = dst[e];
  float w = expf(fminf(logit[e] - decf(mmax[d]), 0.f));
  for (int k = lane; k < GG; k += 64)
    atomicAdd(&S2[(size_t)d * GG + k], w * hvp[(size_t)s * GG + k]);
  if (lane == 0) atomicAdd(&s2[d], w);
}

__global__ __launch_bounds__(256) void c2elu_kernel(
    float* __restrict__ S2, const float* __restrict__ s2, int total)
{
  int i = blockIdx.x * 256 + threadIdx.x;
  if (i >= total) return;
  float s = s2[i / GG];
  S2[i] = (s > 0.f) ? eluf(S2[i] / s) : 0.f;
}

__global__ __launch_bounds__(256) void graph_sum(
    const float* __restrict__ h, float* __restrict__ g)
{
  int b = blockIdx.x, k = threadIdx.x;
  if (k < GG) {
    float a = 0.f;
    for (int i = 0; i < 50; ++i) a += h[((size_t)b * 50 + i) * GG + k];
    g[(size_t)b * GG + k] = a;
  }
}

__global__ __launch_bounds__(256) void attn_kernel(
    const float* __restrict__ g, const float* __restrict__ h2,
    const float* __restrict__ w1, const float* __restrict__ dh,
    const float* __restrict__ rb, float* __restrict__ weighted)
{
  int b = blockIdx.x;
  __shared__ float red[256];
  __shared__ float zs[50];
  __shared__ float as_[50];
  __shared__ float dgs;
  int tid = threadIdx.x;
  float p = 0.f;
  if (tid < GG) p = fmaxf(g[(size_t)b * GG + tid], 0.f) * w1[tid];
  red[tid] = p;
  __syncthreads();
  for (int s = 128; s; s >>= 1) { if (tid < s) red[tid] += red[tid + s]; __syncthreads(); }
  if (tid == 0) dgs = red[0];
  __syncthreads();
  if (tid < 50) zs[tid] = leakyf(dgs + dh[b * 50 + tid] + rb[0]);
  __syncthreads();
  if (tid == 0) {
    float m = -1e30f;
    for (int i = 0; i < 50; ++i) m = fmaxf(m, zs[i]);
    float s = 0.f;
    for (int i = 0; i < 50; ++i) { float e = expf(zs[i] - m); as_[i] = e; s += e; }
    float inv = 1.f / s;
    for (int i = 0; i < 50; ++i) as_[i] *= inv;
  }
  __syncthreads();
  if (tid < GG) {
    float a = 0.f;
    for (int i = 0; i < 50; ++i) a += as_[i] * h2[((size_t)b * 50 + i) * GG + tid];
    weighted[(size_t)b * GG + tid] = a;
  }
}

// ---------------- host ----------------
extern "C" void kernel_launch(void* const* d_in, const int* in_sizes, int n_in,
                              void* d_out, int out_size, void* d_ws, size_t ws_size,
                              hipStream_t stream)
{
  (void)n_in; (void)out_size; (void)ws_size;
  const int N = NN, M = MM, B = BB, F = FF, G = GG, P = PP;
  float* ws = (float*)d_ws;
  size_t off = 0;
  auto alloc = [&](size_t n) { size_t o = off; off += (n + 63) & ~(size_t)63; return o; };

  size_t o_flag = alloc(16);
  size_t o_pn_w = alloc(F * G), o_pn_b = alloc(G);
  size_t o_pe1_w = alloc((F + EE) * G), o_pe1_b = alloc(G);
  size_t o_pe2_w = alloc(2 * G), o_pe2_b = alloc(1);
  size_t o_et_w = alloc(G * G), o_et_b = alloc(G);
  size_t o_g0_wih = alloc(G * 3 * G), o_g0_whh = alloc(G * 3 * G);
  size_t o_g0_bih = alloc(3 * G), o_g0_bhh = alloc(3 * G);
  size_t o_lpe_w = alloc(2 * G), o_lpe_b = alloc(1);
  size_t o_lpn_w = alloc(G * G), o_lpn_b = alloc(G);
  size_t o_g1_wih = alloc(G * 3 * G), o_g1_whh = alloc(G * 3 * G);
  size_t o_g1_bih = alloc(3 * G), o_g1_bhh = alloc(3 * G);
  size_t o_rl_w = alloc(2 * 2 * G), o_rl_b = alloc(2);
  size_t o_rp_w = alloc(2 * G * G), o_rp_b = alloc(2 * G);
  size_t o_rg_wih = alloc(2 * G * 3 * G), o_rg_whh = alloc(2 * G * 3 * G);
  size_t o_rg_bih = alloc(2 * 3 * G), o_rg_bhh = alloc(2 * 3 * G);
  size_t o_t_w = alloc(G * P), o_t_b = alloc(P);
  size_t o_Xn = alloc((size_t)N * F);
  size_t o_Xe = alloc((size_t)M * EE);
  size_t o_B1 = alloc((size_t)N * G);
  size_t o_B2 = alloc((size_t)N * G);
  size_t o_B3 = alloc((size_t)N * G);
  size_t o_alpha = alloc(N), o_ssum = alloc(N), o_mmax = alloc(N), o_logit = alloc(M);
  size_t o_gd = alloc(N), o_gs = alloc(N), o_dh = alloc(N);
  size_t o_gv0 = alloc((size_t)B * G), o_gwt = alloc((size_t)B * G), o_grep = alloc((size_t)B * G);
  size_t o_gv1 = alloc((size_t)B * G), o_gv2 = alloc((size_t)B * G);
  // bf16 transposed weights (ushort, counted in float units = n/2)
  size_t o_etT  = alloc(G * G / 2), o_lpnT = alloc(G * G / 2);
  size_t o_g0ihT = alloc(G * 3 * G / 2), o_g0hhT = alloc(G * 3 * G / 2);
  size_t o_g1ihT = alloc(G * 3 * G / 2), o_g1hhT = alloc(G * 3 * G / 2);
  size_t o_rg0ihT = alloc(G * 3 * G / 2), o_rg0hhT = alloc(G * 3 * G / 2);
  size_t o_rg1ihT = alloc(G * 3 * G / 2), o_rg1hhT = alloc(G * 3 * G / 2);

  int* flag = (int*)(ws + o_flag);

  CvtJobs32 jobs;
  int ji = 0;
  auto push = [&](int idx, size_t dsto) {
    jobs.j[ji].s = d_in[idx];
    jobs.j[ji].d = ws + dsto;
    jobs.j[ji].n = in_sizes[idx];
    jobs.j[ji].pad = 0;
    ++ji;
  };
  push(0, o_Xn);
  push(1, o_Xe);
  push(2, o_pn_w);  push(3, o_pn_b);
  push(4, o_pe1_w); push(5, o_pe1_b);
  push(6, o_pe2_w); push(7, o_pe2_b);
  push(8, o_et_w);  push(9, o_et_b);
  push(10, o_g0_wih); push(11, o_g0_whh); push(12, o_g0_bih); push(13, o_g0_bhh);
  push(14, o_lpe_w);  push(15, o_lpe_b);
  push(16, o_lpn_w);  push(17, o_lpn_b);
  push(18, o_g1_wih); push(19, o_g1_whh); push(20, o_g1_bih); push(21, o_g1_bhh);
  push(22, o_rl_w);   push(23, o_rl_b);
  push(24, o_rp_w);   push(25, o_rp_b);
  push(26, o_rg_wih); push(27, o_rg_whh); push(28, o_rg_bih); push(29, o_rg_bhh);
  push(30, o_t_w);    push(31, o_t_b);

  const int* src = (const int*)d_in[32];
  const int* dst = (const int*)d_in[33];

  dim3 blk(256);
  detect_dtype<<<dim3(1), blk, 0, stream>>>((const unsigned int*)d_in[0], flag);
  cvt_any<<<dim3(512, 32), blk, 0, stream>>>(jobs, flag);

  // transpose weights to bf16 [N][K]
  TJobs10 tj;
  auto tpush = [&](int slot, size_t srcO, size_t dstO, int K, int Nc) {
    tj.j[slot].s = ws + srcO;
    tj.j[slot].d = (unsigned short*)(ws + dstO);
    tj.j[slot].K = K; tj.j[slot].N = Nc;
  };
  tpush(0, o_et_w,  o_etT,  G, G);
  tpush(1, o_lpn_w, o_lpnT, G, G);
  tpush(2, o_g0_wih, o_g0ihT, G, 3 * G);
  tpush(3, o_g0_whh, o_g0hhT, G, 3 * G);
  tpush(4, o_g1_wih, o_g1ihT, G, 3 * G);
  tpush(5, o_g1_whh, o_g1hhT, G, 3 * G);
  tpush(6, o_rg_wih, o_rg0ihT, G, 3 * G);
  tpush(7, o_rg_whh, o_rg0hhT, G, 3 * G);
  tpush(8, o_rg_wih + (size_t)G * 3 * G, o_rg1ihT, G, 3 * G);
  tpush(9, o_rg_whh + (size_t)G * 3 * G, o_rg1hhT, G, 3 * G);
  transpose_bf16<<<dim3(128, 10), blk, 0, stream>>>(tj);

  dim3 gNG((N + Bb - 1) / Bb, (G + Bn - 1) / Bn);
  dim3 gMF((N + 127) / 128, (G + 63) / 64);
  dim3 gGRU((N + 127) / 128, (G + 31) / 32);
  dim3 gGRUb((B + 127) / 128, (G + 31) / 32);

  // hv_new = leaky(Xn@pn_w + pn_b) -> B1
  gemm_kernel<<<gNG, blk, 0, stream>>>(ws + o_Xn, ws + o_pn_w, ws + o_pn_b, nullptr,
                                       ws + o_B1, nullptr, nullptr, N, G, F, 1);
  // xa = Xn @ pe1_w[:39] -> B2
  gemm_kernel<<<gNG, blk, 0, stream>>>(ws + o_Xn, ws + o_pe1_w, nullptr, nullptr,
                                       ws + o_B2, nullptr, nullptr, N, G, F, 0);
  node_dot2<<<dim3((N + 3) / 4), blk, 0, stream>>>(ws + o_B1, ws + o_pe2_w, nullptr,
                                                   ws + o_alpha, nullptr, N);
  hipMemsetAsync(ws + o_mmax, 0, (size_t)N * 4, stream);
  hipMemsetAsync(ws + o_ssum, 0, (size_t)N * 4, stream);
  hipMemsetAsync(ws + o_B3, 0, (size_t)N * G * 4, stream);

  edge_pass1<<<dim3((M + 3) / 4), blk, 0, stream>>>(
      ws + o_Xe, ws + o_B2, ws + o_pe1_w + (size_t)F * G, ws + o_pe1_b,
      ws + o_pe2_w + G, ws + o_pe2_b, ws + o_alpha, src, dst,
      ws + o_logit, (unsigned int*)(ws + o_mmax), M);
  edge_pass2<<<dim3((M + 3) / 4), blk, 0, stream>>>(
      ws + o_Xe, ws + o_B2, ws + o_pe1_w + (size_t)F * G, ws + o_pe1_b,
      src, dst, ws + o_logit, (const unsigned int*)(ws + o_mmax),
      ws + o_B3, ws + o_ssum, M);
  divnorm_kernel<<<dim3((N * G + 255) / 256), blk, 0, stream>>>(ws + o_B3, ws + o_ssum, N * G);
  // c = elu(mask(B3@et_w + et_b)) -> B2   [MFMA]
  mfma_gemm<<<gMF, blk, 0, stream>>>(ws + o_B3, (const unsigned short*)(ws + o_etT),
                                     ws + o_et_b, ws + o_ssum, ws + o_B2, N, G, G, 2);
  // h = relu(GRU0(x=B2, h=B1)) -> B3   [MFMA]
  mfma_gru<<<gGRU, blk, 0, stream>>>(ws + o_B2, ws + o_B1,
                                     (const unsigned short*)(ws + o_g0ihT),
                                     (const unsigned short*)(ws + o_g0hhT),
                                     ws + o_g0_bih, ws + o_g0_bhh, ws + o_B3, N, 1);

  // ---- layer 2 ----
  node_dot2<<<dim3((N + 3) / 4), blk, 0, stream>>>(ws + o_B3, ws + o_lpe_w, ws + o_lpe_w + G,
                                                   ws + o_gd, ws + o_gs, N);
  // hv_proj = h@lpn_w + lpn_b -> B1   [MFMA]
  mfma_gemm<<<gMF, blk, 0, stream>>>(ws + o_B3, (const unsigned short*)(ws + o_lpnT),
                                     ws + o_lpn_b, nullptr, ws + o_B1, N, G, G, 0);
  hipMemsetAsync(ws + o_mmax, 0, (size_t)N * 4, stream);
  hipMemsetAsync(ws + o_ssum, 0, (size_t)N * 4, stream);
  hipMemsetAsync(ws + o_B2, 0, (size_t)N * G * 4, stream);
  l2_logit<<<dim3((M + 255) / 256), blk, 0, stream>>>(ws + o_gd, ws + o_gs, ws + o_lpe_b,
                                                      src, dst, ws + o_logit,
                                                      (unsigned int*)(ws + o_mmax), M);
  l2_scatter<<<dim3((M + 3) / 4), blk, 0, stream>>>(ws + o_B1, src, dst, ws + o_logit,
                                                    (const unsigned int*)(ws + o_mmax),
                                                    ws + o_B2, ws + o_ssum, M);
  c2elu_kernel<<<dim3((N * G + 255) / 256), blk, 0, stream>>>(ws + o_B2, ws + o_ssum, N * G);
  // h2 = relu(GRU1(x=B2, h=B3)) -> B1   [MFMA]
  mfma_gru<<<gGRU, blk, 0, stream>>>(ws + o_B2, ws + o_B3,
                                     (const unsigned short*)(ws + o_g1ihT),
                                     (const unsigned short*)(ws + o_g1hhT),
                                     ws + o_g1_bih, ws + o_g1_bhh, ws + o_B1, N, 1);

  // ---- readout ----
  graph_sum<<<dim3(B), blk, 0, stream>>>(ws + o_B1, ws + o_gv0);
  dim3 gBG((B + Bb - 1) / Bb, (G + Bn - 1) / Bn);
  size_t gcur = o_gv0, gnext = o_gv1;
  for (int t = 0; t < 2; ++t) {
    node_dot2<<<dim3((N + 3) / 4), blk, 0, stream>>>(ws + o_B1, ws + o_rl_w + t * 2 * G + G,
                                                     nullptr, ws + o_dh, nullptr, N);
    attn_kernel<<<dim3(B), blk, 0, stream>>>(ws + gcur, ws + o_B1, ws + o_rl_w + t * 2 * G,
                                             ws + o_dh, ws + o_rl_b + t, ws + o_gwt);
    gemm_kernel<<<gBG, blk, 0, stream>>>(ws + o_gwt, ws + o_rp_w + (size_t)t * G * G,
                                         ws + o_rp_b + t * G, nullptr,
                                         ws + o_grep, nullptr, nullptr, B, G, G, 2);
    mfma_gru<<<gGRUb, blk, 0, stream>>>(ws + o_grep, ws + gcur,
                                        (const unsigned short*)(ws + (t == 0 ? o_rg0ihT : o_rg1ihT)),
                                        (const unsigned short*)(ws + (t == 0 ? o_rg0hhT : o_rg1hhT)),
                                        ws + o_rg_bih + t * 3 * G, ws + o_rg_bhh + t * 3 * G,
                                        ws + gnext, B, 0);
    gcur = gnext;
    gnext = o_gv2;
  }
  dim3 gOut((B + Bb - 1) / Bb, (P + Bn - 1) / Bn);
  gemm_kernel<<<gOut, blk, 0, stream>>>(ws + gcur, ws + o_t_w, ws + o_t_b, nullptr,
                                        nullptr, d_out, flag, B, P, G, 0);
}

// Round 4
// 1341.344 us; speedup vs baseline: 3.0301x; 1.4791x over previous
//
#include <hip/hip_runtime.h>
#include <hip/hip_bf16.h>

// ---------------- constants ----------------
#define NN 50000
#define MM 400000
#define BB 1000
#define FF 39
#define EE 11
#define GG 200
#define PP 128

typedef __attribute__((ext_vector_type(8))) short bf16x8;
typedef __attribute__((ext_vector_type(4))) float f32x4;

// ---------------- helpers ----------------
__device__ __forceinline__ float bf2f(unsigned short u) {
  return __uint_as_float(((unsigned int)u) << 16);
}
__device__ __forceinline__ unsigned short f2bf(float x) {
  union { __hip_bfloat16 b; unsigned short u; } v;
  v.b = __float2bfloat16(x);
  return v.u;
}
__device__ __forceinline__ float leakyf(float x) { return x > 0.f ? x : 0.01f * x; }
__device__ __forceinline__ float eluf(float x)   { return x > 0.f ? x : (expf(x) - 1.f); }
__device__ __forceinline__ float sigmf(float x)  { return 1.f / (1.f + expf(-x)); }

// ---------------- runtime dtype detection ----------------
__global__ __launch_bounds__(256) void detect_dtype(const unsigned int* __restrict__ w,
                                                    int* __restrict__ flag) {
  __shared__ int cnt[256];
  int c = 0;
  for (int i = threadIdx.x; i < 2048; i += 256) {
    unsigned int e = (w[i] >> 8) & 0x7F;
    c += (e >= 60 && e <= 64) ? 1 : 0;
  }
  cnt[threadIdx.x] = c;
  __syncthreads();
  for (int s = 128; s; s >>= 1) {
    if (threadIdx.x < s) cnt[threadIdx.x] += cnt[threadIdx.x + s];
    __syncthreads();
  }
  if (threadIdx.x == 0) *flag = (cnt[0] >= 1024) ? 1 : 0;  // 1 = bf16 inputs
}

// ---------------- batched conversion to f32 ----------------
struct CvtJob { const void* s; float* d; int n; int pad; };
struct CvtJobs32 { CvtJob j[32]; };

__global__ __launch_bounds__(256) void cvt_any(CvtJobs32 jobs, const int* __restrict__ flag) {
  CvtJob job = jobs.j[blockIdx.y];
  int isbf = *flag;
  if (isbf) {
    const unsigned short* s = (const unsigned short*)job.s;
    for (int i = blockIdx.x * 256 + threadIdx.x; i < job.n; i += gridDim.x * 256)
      job.d[i] = bf2f(s[i]);
  } else {
    const float* s = (const float*)job.s;
    for (int i = blockIdx.x * 256 + threadIdx.x; i < job.n; i += gridDim.x * 256)
      job.d[i] = s[i];
  }
}

// ---------------- weight transpose+cvt: W f32 [K][N] -> Wt bf16 [N][K] ----------------
struct TJob { const float* s; unsigned short* d; int K; int N; };
struct TJobs12 { TJob j[12]; };

__global__ __launch_bounds__(256) void transpose_bf16(TJobs12 jobs) {
  TJob job = jobs.j[blockIdx.y];
  int total = job.K * job.N;
  for (int idx = blockIdx.x * 256 + threadIdx.x; idx < total; idx += gridDim.x * 256) {
    int n = idx / job.K, k = idx - n * job.K;
    job.d[idx] = f2bf(job.s[(size_t)k * job.N + n]);
  }
}

// ---------------- CSR build ----------------
__global__ __launch_bounds__(256) void hist_kernel(const int* __restrict__ dst,
                                                   int* __restrict__ cnt, int M) {
  int e = blockIdx.x * 256 + threadIdx.x;
  if (e < M) atomicAdd(&cnt[dst[e]], 1);
}

#define SCHUNK 2048
__global__ __launch_bounds__(256) void scan1_kernel(const int* __restrict__ cnt,
                                                    int* __restrict__ incl,
                                                    int* __restrict__ bsum, int n) {
  __shared__ int lds[256];
  int b = blockIdx.x, tid = threadIdx.x;
  int base = b * SCHUNK + tid * 8;
  int v[8], s = 0;
#pragma unroll
  for (int j = 0; j < 8; ++j) { int i = base + j; v[j] = (i < n) ? cnt[i] : 0; s += v[j]; }
  lds[tid] = s;
  __syncthreads();
  for (int o = 1; o < 256; o <<= 1) {
    int t = (tid >= o) ? lds[tid - o] : 0;
    __syncthreads();
    lds[tid] += t;
    __syncthreads();
  }
  int run = lds[tid] - s;
#pragma unroll
  for (int j = 0; j < 8; ++j) {
    run += v[j];
    int i = base + j;
    if (i < n) incl[i] = run;
  }
  if (tid == 255) bsum[b] = lds[255];
}

__global__ void scan2_kernel(int* __restrict__ bsum, int nb) {
  if (threadIdx.x == 0 && blockIdx.x == 0) {
    int run = 0;
    for (int i = 0; i < nb; ++i) { int t = bsum[i]; bsum[i] = run; run += t; }
  }
}

__global__ __launch_bounds__(256) void scan3_kernel(const int* __restrict__ incl,
                                                    const int* __restrict__ cnt,
                                                    const int* __restrict__ bsum,
                                                    int* __restrict__ offA,
                                                    int* __restrict__ cur, int n) {
  int i = blockIdx.x * 256 + threadIdx.x;
  if (i >= n) return;
  int o = incl[i] - cnt[i] + bsum[i / SCHUNK];
  offA[i] = o;
  cur[i] = o;
}

__global__ __launch_bounds__(256) void fill_kernel(const int* __restrict__ dst,
                                                   int* __restrict__ cur,
                                                   int* __restrict__ elist, int M) {
  int e = blockIdx.x * 256 + threadIdx.x;
  if (e >= M) return;
  int pos = atomicAdd(&cur[dst[e]], 1);
  elist[pos] = e;
}

// ---------------- layer-1 fused aggregation: one wave per node ----------------
// Online softmax over incident edges; he1 computed once per edge, reused for
// both the logit dot and the weighted accumulation. No atomics, no logit array.
__global__ __launch_bounds__(256) void l1_agg(
    const float* __restrict__ Xe, const float* __restrict__ xa,
    const float* __restrict__ pe1w_e /*[11][200]*/, const float* __restrict__ pe1b,
    const float* __restrict__ pe2w_e /*pe2w[200:400]*/, const float* __restrict__ pe2b,
    const float* __restrict__ alpha, const int* __restrict__ srcA,
    const int* __restrict__ offA, const int* __restrict__ cntA, const int* __restrict__ elist,
    float* __restrict__ S, float* __restrict__ ssumOut, int N)
{
  int v = (blockIdx.x * 256 + threadIdx.x) >> 6;
  int lane = threadIdx.x & 63;
  if (v >= N) return;
  int begin = offA[v], cnt = cntA[v];
  int k0 = lane, k1 = lane + 64, k2 = lane + 128;
  bool v3 = lane < 8;
  int k3 = v3 ? lane + 192 : 0;
  float b0 = pe1b[k0], b1 = pe1b[k1], b2 = pe1b[k2], b3 = pe1b[k3];
  float p0 = pe2w_e[k0], p1 = pe2w_e[k1], p2 = pe2w_e[k2];
  float p3 = v3 ? pe2w_e[k3] : 0.f;
  float w0[EE], w1[EE], w2[EE], w3[EE];
#pragma unroll
  for (int j = 0; j < EE; ++j) {
    w0[j] = pe1w_e[j * GG + k0];
    w1[j] = pe1w_e[j * GG + k1];
    w2[j] = pe1w_e[j * GG + k2];
    w3[j] = pe1w_e[j * GG + k3];
  }
  float alv = alpha[v] + pe2b[0];
  float m = -1e30f, ss = 0.f;
  float a0 = 0.f, a1 = 0.f, a2 = 0.f, a3 = 0.f;
  for (int t = 0; t < cnt; ++t) {
    int e = elist[begin + t];
    int s = srcA[e];
    const float* xep = Xe + (size_t)e * EE;
    float xe[EE];
#pragma unroll
    for (int j = 0; j < EE; ++j) xe[j] = xep[j];
    const float* xap = xa + (size_t)s * GG;
    float h0 = xap[k0] + b0, h1 = xap[k1] + b1, h2 = xap[k2] + b2, h3 = xap[k3] + b3;
#pragma unroll
    for (int j = 0; j < EE; ++j) {
      h0 += xe[j] * w0[j];
      h1 += xe[j] * w1[j];
      h2 += xe[j] * w2[j];
      h3 += xe[j] * w3[j];
    }
    h0 = leakyf(h0); h1 = leakyf(h1); h2 = leakyf(h2); h3 = leakyf(h3);
    float bp = h0 * p0 + h1 * p1 + h2 * p2 + h3 * p3;  // p3=0 masks invalid lane
    for (int o = 32; o; o >>= 1) bp += __shfl_down(bp, o);
    bp = __shfl(bp, 0);
    float l = leakyf(alv + bp);
    if (l > m) {
      float sc = expf(m - l);
      ss *= sc; a0 *= sc; a1 *= sc; a2 *= sc; a3 *= sc;
      m = l;
    }
    float w = expf(l - m);
    ss += w;
    a0 += w * h0; a1 += w * h1; a2 += w * h2; a3 += w * h3;
  }
  float inv = (cnt > 0) ? 1.f / ss : 0.f;
  float* sp = S + (size_t)v * GG;
  sp[k0] = a0 * inv; sp[k1] = a1 * inv; sp[k2] = a2 * inv;
  if (v3) sp[k3] = a3 * inv;
  if (lane == 0) ssumOut[v] = (cnt > 0) ? ss : 0.f;
}

// ---------------- layer-2 fused aggregation: one wave per node ----------------
__global__ __launch_bounds__(256) void l2_agg(
    const float* __restrict__ hvp, const float* __restrict__ gd, const float* __restrict__ gs,
    const float* __restrict__ lpeb, const int* __restrict__ srcA,
    const int* __restrict__ offA, const int* __restrict__ cntA, const int* __restrict__ elist,
    float* __restrict__ S2, int N)
{
  int v = (blockIdx.x * 256 + threadIdx.x) >> 6;
  int lane = threadIdx.x & 63;
  if (v >= N) return;
  int begin = offA[v], cnt = cntA[v];
  int k0 = lane, k1 = lane + 64, k2 = lane + 128;
  bool v3 = lane < 8;
  int k3 = v3 ? lane + 192 : 0;
  float gdv = gd[v] + lpeb[0];
  float m = -1e30f, ss = 0.f;
  float a0 = 0.f, a1 = 0.f, a2 = 0.f, a3 = 0.f;
  for (int t = 0; t < cnt; ++t) {
    int e = elist[begin + t];
    int s = srcA[e];
    float l = leakyf(gdv + gs[s]);
    if (l > m) {
      float sc = expf(m - l);
      ss *= sc; a0 *= sc; a1 *= sc; a2 *= sc; a3 *= sc;
      m = l;
    }
    float w = expf(l - m);
    ss += w;
    const float* hp = hvp + (size_t)s * GG;
    a0 += w * hp[k0]; a1 += w * hp[k1]; a2 += w * hp[k2]; a3 += w * hp[k3];
  }
  float inv = (cnt > 0) ? 1.f / ss : 0.f;
  float* sp = S2 + (size_t)v * GG;
  sp[k0] = (cnt > 0) ? eluf(a0 * inv) : 0.f;
  sp[k1] = (cnt > 0) ? eluf(a1 * inv) : 0.f;
  sp[k2] = (cnt > 0) ? eluf(a2 * inv) : 0.f;
  if (v3) sp[k3] = (cnt > 0) ? eluf(a3 * inv) : 0.f;
}

// ================= MFMA GEMM: C = act(mask(A@W + b)) =================
#define LDP 40
__global__ __launch_bounds__(256) void mfma_gemm(
    const float* __restrict__ A, const unsigned short* __restrict__ Wt,
    const float* __restrict__ bias, const float* __restrict__ rowmask,
    float* __restrict__ C, int Mr, int Nc, int K, int act)
{
  __shared__ short As[128 * LDP];
  __shared__ short Bs[64 * LDP];
  int tid = threadIdx.x;
  int w = tid >> 6, lane = tid & 63, quad = lane >> 4, l15 = lane & 15;
  int row0 = blockIdx.x * 128, col0 = blockIdx.y * 64;

  f32x4 zero4 = {0.f, 0.f, 0.f, 0.f};
  f32x4 acc[2][4];
#pragma unroll
  for (int r = 0; r < 2; ++r)
#pragma unroll
    for (int c = 0; c < 4; ++c) acc[r][c] = zero4;

  for (int k0 = 0; k0 < K; k0 += 32) {
    {
      int row = tid >> 1, half = tid & 1;
      int r = row0 + row;
      short tmp[16];
      const float* ap = A + (size_t)r * K + k0 + half * 16;
      if (r < Mr && k0 + half * 16 + 16 <= K) {
#pragma unroll
        for (int j = 0; j < 16; ++j) tmp[j] = (short)f2bf(ap[j]);
      } else if (r < Mr) {
#pragma unroll
        for (int j = 0; j < 16; ++j) {
          int k = k0 + half * 16 + j;
          tmp[j] = (k < K) ? (short)f2bf(ap[j]) : (short)0;
        }
      } else {
#pragma unroll
        for (int j = 0; j < 16; ++j) tmp[j] = 0;
      }
      *(bf16x8*)&As[row * LDP + half * 16]     = *(bf16x8*)&tmp[0];
      *(bf16x8*)&As[row * LDP + half * 16 + 8] = *(bf16x8*)&tmp[8];
    }
    {
      int col = tid & 63, seg = tid >> 6;
      int n = col0 + col, k = k0 + seg * 8;
      short t8[8];
      const unsigned short* wp = Wt + (size_t)n * K + k;
      if (n < Nc && k + 8 <= K) {
        *(bf16x8*)&t8[0] = *(const bf16x8*)wp;
      } else {
#pragma unroll
        for (int j = 0; j < 8; ++j)
          t8[j] = (n < Nc && k + j < K) ? (short)wp[j] : (short)0;
      }
      *(bf16x8*)&Bs[col * LDP + seg * 8] = *(bf16x8*)&t8[0];
    }
    __syncthreads();
    bf16x8 a[2], b[4];
#pragma unroll
    for (int r = 0; r < 2; ++r)
      a[r] = *(const bf16x8*)&As[(w * 32 + r * 16 + l15) * LDP + quad * 8];
#pragma unroll
    for (int c = 0; c < 4; ++c)
      b[c] = *(const bf16x8*)&Bs[(c * 16 + l15) * LDP + quad * 8];
#pragma unroll
    for (int r = 0; r < 2; ++r)
#pragma unroll
      for (int c = 0; c < 4; ++c)
        acc[r][c] = __builtin_amdgcn_mfma_f32_16x16x32_bf16(a[r], b[c], acc[r][c], 0, 0, 0);
    __syncthreads();
  }
#pragma unroll
  for (int r = 0; r < 2; ++r) {
#pragma unroll
    for (int c = 0; c < 4; ++c) {
      int col = col0 + c * 16 + l15;
      if (col >= Nc) continue;
#pragma unroll
      for (int i = 0; i < 4; ++i) {
        int row = row0 + w * 32 + r * 16 + quad * 4 + i;
        if (row >= Mr) continue;
        bool valid = (rowmask == nullptr) || (rowmask[row] > 0.f);
        float v = valid ? (acc[r][c][i] + (bias ? bias[col] : 0.f)) : 0.f;
        if (act == 1) v = leakyf(v);
        else if (act == 2) v = eluf(v);
        C[(size_t)row * Nc + col] = v;
      }
    }
  }
}

// ================= fused MFMA GRU =================
__global__ __launch_bounds__(256) void mfma_gru(
    const float* __restrict__ X, const float* __restrict__ H,
    const unsigned short* __restrict__ WtIH, const unsigned short* __restrict__ WtHH,
    const float* __restrict__ bih, const float* __restrict__ bhh,
    float* __restrict__ Out, int R, int relu_out)
{
  __shared__ short Xs[128 * LDP];
  __shared__ short Hs[128 * LDP];
  __shared__ short Ws[192 * LDP];
  int tid = threadIdx.x;
  int w = tid >> 6, lane = tid & 63, quad = lane >> 4, l15 = lane & 15;
  int row0 = blockIdx.x * 128, col0 = blockIdx.y * 32;

  f32x4 zero4 = {0.f, 0.f, 0.f, 0.f};
  f32x4 acc[6][2][2];
#pragma unroll
  for (int g = 0; g < 6; ++g)
#pragma unroll
    for (int r = 0; r < 2; ++r)
#pragma unroll
      for (int c = 0; c < 2; ++c) acc[g][r][c] = zero4;

  for (int k0 = 0; k0 < GG; k0 += 32) {
    {
      int row = tid >> 1, half = tid & 1;
      int r = row0 + row;
      short tx[16], th[16];
      const float* xp = X + (size_t)r * GG + k0 + half * 16;
      const float* hp = H + (size_t)r * GG + k0 + half * 16;
      if (r < R && k0 + half * 16 + 16 <= GG) {
#pragma unroll
        for (int j = 0; j < 16; ++j) { tx[j] = (short)f2bf(xp[j]); th[j] = (short)f2bf(hp[j]); }
      } else if (r < R) {
#pragma unroll
        for (int j = 0; j < 16; ++j) {
          int k = k0 + half * 16 + j;
          tx[j] = (k < GG) ? (short)f2bf(xp[j]) : (short)0;
          th[j] = (k < GG) ? (short)f2bf(hp[j]) : (short)0;
        }
      } else {
#pragma unroll
        for (int j = 0; j < 16; ++j) { tx[j] = 0; th[j] = 0; }
      }
      *(bf16x8*)&Xs[row * LDP + half * 16]     = *(bf16x8*)&tx[0];
      *(bf16x8*)&Xs[row * LDP + half * 16 + 8] = *(bf16x8*)&tx[8];
      *(bf16x8*)&Hs[row * LDP + half * 16]     = *(bf16x8*)&th[0];
      *(bf16x8*)&Hs[row * LDP + half * 16 + 8] = *(bf16x8*)&th[8];
    }
    for (int task = tid; task < 768; task += 256) {
      int rw = task >> 2, seg = task & 3;
      int g = rw >> 5, cc = rw & 31;
      int n = col0 + cc, k = k0 + seg * 8;
      const unsigned short* wp = (g < 3)
          ? WtIH + (size_t)(g * GG + n) * GG + k
          : WtHH + (size_t)((g - 3) * GG + n) * GG + k;
      short t8[8];
      if (n < GG && k + 8 <= GG) {
        *(bf16x8*)&t8[0] = *(const bf16x8*)wp;
      } else {
#pragma unroll
        for (int j = 0; j < 8; ++j)
          t8[j] = (n < GG && k + j < GG) ? (short)wp[j] : (short)0;
      }
      *(bf16x8*)&Ws[rw * LDP + seg * 8] = *(bf16x8*)&t8[0];
    }
    __syncthreads();
    bf16x8 ax[2], ah[2];
#pragma unroll
    for (int r = 0; r < 2; ++r) {
      ax[r] = *(const bf16x8*)&Xs[(w * 32 + r * 16 + l15) * LDP + quad * 8];
      ah[r] = *(const bf16x8*)&Hs[(w * 32 + r * 16 + l15) * LDP + quad * 8];
    }
#pragma unroll
    for (int g = 0; g < 6; ++g) {
      bf16x8 b[2];
#pragma unroll
      for (int c = 0; c < 2; ++c)
        b[c] = *(const bf16x8*)&Ws[(g * 32 + c * 16 + l15) * LDP + quad * 8];
#pragma unroll
      for (int r = 0; r < 2; ++r)
#pragma unroll
        for (int c = 0; c < 2; ++c)
          acc[g][r][c] = __builtin_amdgcn_mfma_f32_16x16x32_bf16(
              (g < 3) ? ax[r] : ah[r], b[c], acc[g][r][c], 0, 0, 0);
    }
    __syncthreads();
  }
#pragma unroll
  for (int r = 0; r < 2; ++r) {
#pragma unroll
    for (int c = 0; c < 2; ++c) {
      int col = col0 + c * 16 + l15;
      if (col >= GG) continue;
      float br = bih[col],       bhr = bhh[col];
      float bz = bih[200 + col], bhz = bhh[200 + col];
      float bn = bih[400 + col], bhn = bhh[400 + col];
#pragma unroll
      for (int i = 0; i < 4; ++i) {
        int row = row0 + w * 32 + r * 16 + quad * 4 + i;
        if (row >= R) continue;
        float rr = sigmf(acc[0][r][c][i] + br + acc[3][r][c][i] + bhr);
        float zz = sigmf(acc[1][r][c][i] + bz + acc[4][r][c][i] + bhz);
        float nn = tanhf(acc[2][r][c][i] + bn + rr * (acc[5][r][c][i] + bhn));
        float hval = H[(size_t)row * GG + col];
        float o = (1.f - zz) * nn + zz * hval;
        if (relu_out) o = fmaxf(o, 0.f);
        Out[(size_t)row * GG + col] = o;
      }
    }
  }
}

// ---------------- fp32 tiled GEMM (small shapes) ----------------
#define Bb 64
#define Bn 64
#define Bk 16
__global__ __launch_bounds__(256) void gemm_kernel(
    const float* __restrict__ A, const float* __restrict__ W,
    const float* __restrict__ bias, const float* __restrict__ rowmask,
    float* __restrict__ Cf, void* __restrict__ Oout, const int* __restrict__ oflag,
    int Mr, int Nc, int K, int act)
{
  __shared__ float As[Bk][Bb + 1];
  __shared__ float Ws[Bk][Bn];
  int row0 = blockIdx.x * Bb, col0 = blockIdx.y * Bn;
  int tid = threadIdx.x;
  int ty = tid >> 4, tx = tid & 15;
  float acc[4][4] = {};
  for (int k0 = 0; k0 < K; k0 += Bk) {
    for (int l = tid; l < Bb * Bk; l += 256) {
      int m = l >> 4, kk = l & 15;
      int r = row0 + m, k = k0 + kk;
      As[kk][m] = (r < Mr && k < K) ? A[(size_t)r * K + k] : 0.f;
    }
    for (int l = tid; l < Bk * Bn; l += 256) {
      int kk = l >> 6, nn = l & 63;
      int k = k0 + kk, c = col0 + nn;
      Ws[kk][nn] = (k < K && c < Nc) ? W[(size_t)k * Nc + c] : 0.f;
    }
    __syncthreads();
#pragma unroll
    for (int kk = 0; kk < Bk; ++kk) {
      float av[4], bv[4];
#pragma unroll
      for (int i = 0; i < 4; ++i) av[i] = As[kk][ty * 4 + i];
#pragma unroll
      for (int j = 0; j < 4; ++j) bv[j] = Ws[kk][tx * 4 + j];
#pragma unroll
      for (int i = 0; i < 4; ++i)
#pragma unroll
        for (int j = 0; j < 4; ++j) acc[i][j] += av[i] * bv[j];
    }
    __syncthreads();
  }
  int isbf = (oflag != nullptr) ? *oflag : 0;
#pragma unroll
  for (int i = 0; i < 4; ++i) {
    int r = row0 + ty * 4 + i;
    if (r >= Mr) continue;
    bool valid = (rowmask == nullptr) || (rowmask[r] > 0.f);
#pragma unroll
    for (int j = 0; j < 4; ++j) {
      int c = col0 + tx * 4 + j;
      if (c >= Nc) continue;
      float v = valid ? (acc[i][j] + (bias ? bias[c] : 0.f)) : 0.f;
      if (act == 1) v = leakyf(v);
      else if (act == 2) v = eluf(v);
      else if (act == 3) v = fmaxf(v, 0.f);
      size_t idx = (size_t)r * Nc + c;
      if (Oout) {
        if (isbf) ((__hip_bfloat16*)Oout)[idx] = __float2bfloat16(v);
        else      ((float*)Oout)[idx] = v;
      } else {
        Cf[idx] = v;
      }
    }
  }
}

// ---------------- per-node dot(s) ----------------
__global__ __launch_bounds__(256) void node_dot2(
    const float* __restrict__ X, const float* __restrict__ w1, const float* __restrict__ w2,
    float* __restrict__ o1, float* __restrict__ o2, int N)
{
  int v = (blockIdx.x * 256 + threadIdx.x) >> 6;
  int lane = threadIdx.x & 63;
  if (v >= N) return;
  float d1 = 0.f, d2 = 0.f;
  for (int k = lane; k < GG; k += 64) {
    float x = X[(size_t)v * GG + k];
    d1 += x * w1[k];
    if (w2) d2 += x * w2[k];
  }
  for (int off = 32; off; off >>= 1) {
    d1 += __shfl_down(d1, off);
    if (w2) d2 += __shfl_down(d2, off);
  }
  if (lane == 0) { o1[v] = d1; if (w2) o2[v] = d2; }
}

__global__ __launch_bounds__(256) void graph_sum(
    const float* __restrict__ h, float* __restrict__ g)
{
  int b = blockIdx.x, k = threadIdx.x;
  if (k < GG) {
    float a = 0.f;
    for (int i = 0; i < 50; ++i) a += h[((size_t)b * 50 + i) * GG + k];
    g[(size_t)b * GG + k] = a;
  }
}

__global__ __launch_bounds__(256) void attn_kernel(
    const float* __restrict__ g, const float* __restrict__ h2,
    const float* __restrict__ w1, const float* __restrict__ dh,
    const float* __restrict__ rb, float* __restrict__ weighted)
{
  int b = blockIdx.x;
  __shared__ float red[256];
  __shared__ float zs[50];
  __shared__ float as_[50];
  __shared__ float dgs;
  int tid = threadIdx.x;
  float p = 0.f;
  if (tid < GG) p = fmaxf(g[(size_t)b * GG + tid], 0.f) * w1[tid];
  red[tid] = p;
  __syncthreads();
  for (int s = 128; s; s >>= 1) { if (tid < s) red[tid] += red[tid + s]; __syncthreads(); }
  if (tid == 0) dgs = red[0];
  __syncthreads();
  if (tid < 50) zs[tid] = leakyf(dgs + dh[b * 50 + tid] + rb[0]);
  __syncthreads();
  if (tid == 0) {
    float m = -1e30f;
    for (int i = 0; i < 50; ++i) m = fmaxf(m, zs[i]);
    float s = 0.f;
    for (int i = 0; i < 50; ++i) { float e = expf(zs[i] - m); as_[i] = e; s += e; }
    float inv = 1.f / s;
    for (int i = 0; i < 50; ++i) as_[i] *= inv;
  }
  __syncthreads();
  if (tid < GG) {
    float a = 0.f;
    for (int i = 0; i < 50; ++i) a += as_[i] * h2[((size_t)b * 50 + i) * GG + tid];
    weighted[(size_t)b * GG + tid] = a;
  }
}

// ---------------- host ----------------
extern "C" void kernel_launch(void* const* d_in, const int* in_sizes, int n_in,
                              void* d_out, int out_size, void* d_ws, size_t ws_size,
                              hipStream_t stream)
{
  (void)n_in; (void)out_size; (void)ws_size;
  const int N = NN, M = MM, B = BB, F = FF, G = GG, P = PP;
  float* ws = (float*)d_ws;
  size_t off = 0;
  auto alloc = [&](size_t n) { size_t o = off; off += (n + 63) & ~(size_t)63; return o; };

  size_t o_flag = alloc(16);
  size_t o_pn_w = alloc(F * G), o_pn_b = alloc(G);
  size_t o_pe1_w = alloc((F + EE) * G), o_pe1_b = alloc(G);
  size_t o_pe2_w = alloc(2 * G), o_pe2_b = alloc(1);
  size_t o_et_w = alloc(G * G), o_et_b = alloc(G);
  size_t o_g0_wih = alloc(G * 3 * G), o_g0_whh = alloc(G * 3 * G);
  size_t o_g0_bih = alloc(3 * G), o_g0_bhh = alloc(3 * G);
  size_t o_lpe_w = alloc(2 * G), o_lpe_b = alloc(1);
  size_t o_lpn_w = alloc(G * G), o_lpn_b = alloc(G);
  size_t o_g1_wih = alloc(G * 3 * G), o_g1_whh = alloc(G * 3 * G);
  size_t o_g1_bih = alloc(3 * G), o_g1_bhh = alloc(3 * G);
  size_t o_rl_w = alloc(2 * 2 * G), o_rl_b = alloc(2);
  size_t o_rp_w = alloc(2 * G * G), o_rp_b = alloc(2 * G);
  size_t o_rg_wih = alloc(2 * G * 3 * G), o_rg_whh = alloc(2 * G * 3 * G);
  size_t o_rg_bih = alloc(2 * 3 * G), o_rg_bhh = alloc(2 * 3 * G);
  size_t o_t_w = alloc(G * P), o_t_b = alloc(P);
  size_t o_Xn = alloc((size_t)N * F);
  size_t o_Xe = alloc((size_t)M * EE);
  size_t o_B1 = alloc((size_t)N * G);
  size_t o_B2 = alloc((size_t)N * G);
  size_t o_B3 = alloc((size_t)N * G);
  size_t o_alpha = alloc(N), o_ssum = alloc(N);
  size_t o_gd = alloc(N), o_gs = alloc(N), o_dh = alloc(N);
  size_t o_gv0 = alloc((size_t)B * G), o_gwt = alloc((size_t)B * G), o_grep = alloc((size_t)B * G);
  size_t o_gv1 = alloc((size_t)B * G), o_gv2 = alloc((size_t)B * G);
  // bf16 transposed weights (float-unit sized: n/2)
  size_t o_etT  = alloc(G * G / 2), o_lpnT = alloc(G * G / 2);
  size_t o_g0ihT = alloc(G * 3 * G / 2), o_g0hhT = alloc(G * 3 * G / 2);
  size_t o_g1ihT = alloc(G * 3 * G / 2), o_g1hhT = alloc(G * 3 * G / 2);
  size_t o_rg0ihT = alloc(G * 3 * G / 2), o_rg0hhT = alloc(G * 3 * G / 2);
  size_t o_rg1ihT = alloc(G * 3 * G / 2), o_rg1hhT = alloc(G * 3 * G / 2);
  size_t o_pnT = alloc(G * F / 2 + 64), o_pe1T = alloc(G * F / 2 + 64);
  // CSR (ints stored in float-sized slots)
  size_t o_cnt = alloc(N), o_off = alloc(N), o_cur = alloc(N);
  size_t o_elist = alloc(M), o_bsum = alloc(64), o_incl = alloc(N);

  int* flag = (int*)(ws + o_flag);
  int* cntA = (int*)(ws + o_cnt);
  int* offA = (int*)(ws + o_off);
  int* curA = (int*)(ws + o_cur);
  int* elist = (int*)(ws + o_elist);
  int* bsum = (int*)(ws + o_bsum);
  int* incl = (int*)(ws + o_incl);

  CvtJobs32 jobs;
  int ji = 0;
  auto push = [&](int idx, size_t dsto) {
    jobs.j[ji].s = d_in[idx];
    jobs.j[ji].d = ws + dsto;
    jobs.j[ji].n = in_sizes[idx];
    jobs.j[ji].pad = 0;
    ++ji;
  };
  push(0, o_Xn);
  push(1, o_Xe);
  push(2, o_pn_w);  push(3, o_pn_b);
  push(4, o_pe1_w); push(5, o_pe1_b);
  push(6, o_pe2_w); push(7, o_pe2_b);
  push(8, o_et_w);  push(9, o_et_b);
  push(10, o_g0_wih); push(11, o_g0_whh); push(12, o_g0_bih); push(13, o_g0_bhh);
  push(14, o_lpe_w);  push(15, o_lpe_b);
  push(16, o_lpn_w);  push(17, o_lpn_b);
  push(18, o_g1_wih); push(19, o_g1_whh); push(20, o_g1_bih); push(21, o_g1_bhh);
  push(22, o_rl_w);   push(23, o_rl_b);
  push(24, o_rp_w);   push(25, o_rp_b);
  push(26, o_rg_wih); push(27, o_rg_whh); push(28, o_rg_bih); push(29, o_rg_bhh);
  push(30, o_t_w);    push(31, o_t_b);

  const int* src = (const int*)d_in[32];
  const int* dst = (const int*)d_in[33];

  dim3 blk(256);
  detect_dtype<<<dim3(1), blk, 0, stream>>>((const unsigned int*)d_in[0], flag);
  cvt_any<<<dim3(512, 32), blk, 0, stream>>>(jobs, flag);

  // ---- CSR build (by dst) ----
  hipMemsetAsync(cntA, 0, (size_t)N * 4, stream);
  hist_kernel<<<dim3((M + 255) / 256), blk, 0, stream>>>(dst, cntA, M);
  int nscb = (N + SCHUNK - 1) / SCHUNK;
  scan1_kernel<<<dim3(nscb), blk, 0, stream>>>(cntA, incl, bsum, N);
  scan2_kernel<<<dim3(1), dim3(64), 0, stream>>>(bsum, nscb);
  scan3_kernel<<<dim3((N + 255) / 256), blk, 0, stream>>>(incl, cntA, bsum, offA, curA, N);
  fill_kernel<<<dim3((M + 255) / 256), blk, 0, stream>>>(dst, curA, elist, M);

  // ---- weight transposes ----
  TJobs12 tj;
  auto tpush = [&](int slot, size_t srcO, size_t dstO, int K, int Nc) {
    tj.j[slot].s = ws + srcO;
    tj.j[slot].d = (unsigned short*)(ws + dstO);
    tj.j[slot].K = K; tj.j[slot].N = Nc;
  };
  tpush(0, o_et_w,  o_etT,  G, G);
  tpush(1, o_lpn_w, o_lpnT, G, G);
  tpush(2, o_g0_wih, o_g0ihT, G, 3 * G);
  tpush(3, o_g0_whh, o_g0hhT, G, 3 * G);
  tpush(4, o_g1_wih, o_g1ihT, G, 3 * G);
  tpush(5, o_g1_whh, o_g1hhT, G, 3 * G);
  tpush(6, o_rg_wih, o_rg0ihT, G, 3 * G);
  tpush(7, o_rg_whh, o_rg0hhT, G, 3 * G);
  tpush(8, o_rg_wih + (size_t)G * 3 * G, o_rg1ihT, G, 3 * G);
  tpush(9, o_rg_whh + (size_t)G * 3 * G, o_rg1hhT, G, 3 * G);
  tpush(10, o_pn_w,  o_pnT,  F, G);
  tpush(11, o_pe1_w, o_pe1T, F, G);  // only first 39 rows of pe1_w (node part)
  transpose_bf16<<<dim3(128, 12), blk, 0, stream>>>(tj);

  dim3 gMF((N + 127) / 128, (G + 63) / 64);
  dim3 gGRU((N + 127) / 128, (G + 31) / 32);
  dim3 gGRUb((B + 127) / 128, (G + 31) / 32);
  dim3 gWave((N + 3) / 4);

  // hv_new = leaky(Xn@pn_w + pn_b) -> B1   [MFMA]
  mfma_gemm<<<gMF, blk, 0, stream>>>(ws + o_Xn, (const unsigned short*)(ws + o_pnT),
                                     ws + o_pn_b, nullptr, ws + o_B1, N, G, F, 1);
  // xa = Xn @ pe1_w[:39] -> B2   [MFMA]
  mfma_gemm<<<gMF, blk, 0, stream>>>(ws + o_Xn, (const unsigned short*)(ws + o_pe1T),
                                     nullptr, nullptr, ws + o_B2, N, G, F, 0);
  node_dot2<<<gWave, blk, 0, stream>>>(ws + o_B1, ws + o_pe2_w, nullptr,
                                       ws + o_alpha, nullptr, N);
  // fused layer-1 aggregation -> B3 (normalized), ssum
  l1_agg<<<gWave, blk, 0, stream>>>(ws + o_Xe, ws + o_B2,
                                    ws + o_pe1_w + (size_t)F * G, ws + o_pe1_b,
                                    ws + o_pe2_w + G, ws + o_pe2_b, ws + o_alpha,
                                    src, offA, cntA, elist,
                                    ws + o_B3, ws + o_ssum, N);
  // c = elu(mask(B3@et_w + et_b)) -> B2   [MFMA]
  mfma_gemm<<<gMF, blk, 0, stream>>>(ws + o_B3, (const unsigned short*)(ws + o_etT),
                                     ws + o_et_b, ws + o_ssum, ws + o_B2, N, G, G, 2);
  // h = relu(GRU0(x=B2, h=B1)) -> B3   [MFMA]
  mfma_gru<<<gGRU, blk, 0, stream>>>(ws + o_B2, ws + o_B1,
                                     (const unsigned short*)(ws + o_g0ihT),
                                     (const unsigned short*)(ws + o_g0hhT),
                                     ws + o_g0_bih, ws + o_g0_bhh, ws + o_B3, N, 1);

  // ---- layer 2 ----
  node_dot2<<<gWave, blk, 0, stream>>>(ws + o_B3, ws + o_lpe_w, ws + o_lpe_w + G,
                                       ws + o_gd, ws + o_gs, N);
  // hv_proj = h@lpn_w + lpn_b -> B1   [MFMA]
  mfma_gemm<<<gMF, blk, 0, stream>>>(ws + o_B3, (const unsigned short*)(ws + o_lpnT),
                                     ws + o_lpn_b, nullptr, ws + o_B1, N, G, G, 0);
  // fused layer-2 aggregation -> B2 = elu(normalized sum)
  l2_agg<<<gWave, blk, 0, stream>>>(ws + o_B1, ws + o_gd, ws + o_gs, ws + o_lpe_b,
                                    src, offA, cntA, elist, ws + o_B2, N);
  // h2 = relu(GRU1(x=B2, h=B3)) -> B1   [MFMA]
  mfma_gru<<<gGRU, blk, 0, stream>>>(ws + o_B2, ws + o_B3,
                                     (const unsigned short*)(ws + o_g1ihT),
                                     (const unsigned short*)(ws + o_g1hhT),
                                     ws + o_g1_bih, ws + o_g1_bhh, ws + o_B1, N, 1);

  // ---- readout ----
  graph_sum<<<dim3(B), blk, 0, stream>>>(ws + o_B1, ws + o_gv0);
  dim3 gBG((B + Bb - 1) / Bb, (G + Bn - 1) / Bn);
  size_t gcur = o_gv0, gnext = o_gv1;
  for (int t = 0; t < 2; ++t) {
    node_dot2<<<gWave, blk, 0, stream>>>(ws + o_B1, ws + o_rl_w + t * 2 * G + G,
                                         nullptr, ws + o_dh, nullptr, N);
    attn_kernel<<<dim3(B), blk, 0, stream>>>(ws + gcur, ws + o_B1, ws + o_rl_w + t * 2 * G,
                                             ws + o_dh, ws + o_rl_b + t, ws + o_gwt);
    gemm_kernel<<<gBG, blk, 0, stream>>>(ws + o_gwt, ws + o_rp_w + (size_t)t * G * G,
                                         ws + o_rp_b + t * G, nullptr,
                                         ws + o_grep, nullptr, nullptr, B, G, G, 2);
    mfma_gru<<<gGRUb, blk, 0, stream>>>(ws + o_grep, ws + gcur,
                                        (const unsigned short*)(ws + (t == 0 ? o_rg0ihT : o_rg1ihT)),
                                        (const unsigned short*)(ws + (t == 0 ? o_rg0hhT : o_rg1hhT)),
                                        ws + o_rg_bih + t * 3 * G, ws + o_rg_bhh + t * 3 * G,
                                        ws + gnext, B, 0);
    gcur = gnext;
    gnext = o_gv2;
  }
  dim3 gOut((B + Bb - 1) / Bb, (P + Bn - 1) / Bn);
  gemm_kernel<<<gOut, blk, 0, stream>>>(ws + gcur, ws + o_t_w, ws + o_t_b, nullptr,
                                        nullptr, d_out, flag, B, P, G, 0);
}

// Round 5
// 1189.669 us; speedup vs baseline: 3.4164x; 1.1275x over previous
//
#include <hip/hip_runtime.h>
#include <hip/hip_bf16.h>

// ---------------- constants ----------------
#define NN 50000
#define MM 400000
#define BB 1000
#define FF 39
#define EE 11
#define GG 200
#define PP 128

typedef __attribute__((ext_vector_type(8))) short bf16x8;
typedef __attribute__((ext_vector_type(4))) float f32x4;

// ---------------- helpers ----------------
__device__ __forceinline__ float bf2f(unsigned short u) {
  return __uint_as_float(((unsigned int)u) << 16);
}
__device__ __forceinline__ unsigned short f2bf(float x) {
  union { __hip_bfloat16 b; unsigned short u; } v;
  v.b = __float2bfloat16(x);
  return v.u;
}
__device__ __forceinline__ float leakyf(float x) { return x > 0.f ? x : 0.01f * x; }
__device__ __forceinline__ float eluf(float x)   { return x > 0.f ? x : (expf(x) - 1.f); }
__device__ __forceinline__ float sigmf(float x)  { return 1.f / (1.f + expf(-x)); }
// swizzled LDS index (shorts): row stride 32 shorts (64B), 16B segs xor'd so
// both staging writes and 16-lane fragment reads are bank-uniform.
__device__ __forceinline__ int sw(int row, int seg) {
  return row * 32 + ((seg ^ ((row >> 1) & 3)) << 3);
}

// ---------------- runtime dtype detection ----------------
__global__ __launch_bounds__(256) void detect_dtype(const unsigned int* __restrict__ w,
                                                    int* __restrict__ flag) {
  __shared__ int cnt[256];
  int c = 0;
  for (int i = threadIdx.x; i < 2048; i += 256) {
    unsigned int e = (w[i] >> 8) & 0x7F;
    c += (e >= 60 && e <= 64) ? 1 : 0;
  }
  cnt[threadIdx.x] = c;
  __syncthreads();
  for (int s = 128; s; s >>= 1) {
    if (threadIdx.x < s) cnt[threadIdx.x] += cnt[threadIdx.x + s];
    __syncthreads();
  }
  if (threadIdx.x == 0) *flag = (cnt[0] >= 1024) ? 1 : 0;  // 1 = bf16 inputs
}

// ---------------- batched conversion to f32 ----------------
struct CvtJob { const void* s; float* d; int n; int pad; };
struct CvtJobs32 { CvtJob j[32]; };

__global__ __launch_bounds__(256) void cvt_any(CvtJobs32 jobs, const int* __restrict__ flag) {
  CvtJob job = jobs.j[blockIdx.y];
  int isbf = *flag;
  if (isbf) {
    const unsigned short* s = (const unsigned short*)job.s;
    for (int i = blockIdx.x * 256 + threadIdx.x; i < job.n; i += gridDim.x * 256)
      job.d[i] = bf2f(s[i]);
  } else {
    const float* s = (const float*)job.s;
    for (int i = blockIdx.x * 256 + threadIdx.x; i < job.n; i += gridDim.x * 256)
      job.d[i] = s[i];
  }
}

// ---------------- weight transpose+cvt: W f32 [K][N] -> Wt bf16 [N][K] ----------------
struct TJob { const float* s; unsigned short* d; int K; int N; };
struct TJobs12 { TJob j[12]; };

__global__ __launch_bounds__(256) void transpose_bf16(TJobs12 jobs) {
  TJob job = jobs.j[blockIdx.y];
  int total = job.K * job.N;
  for (int idx = blockIdx.x * 256 + threadIdx.x; idx < total; idx += gridDim.x * 256) {
    int n = idx / job.K, k = idx - n * job.K;
    job.d[idx] = f2bf(job.s[(size_t)k * job.N + n]);
  }
}

// ---------------- CSR build ----------------
__global__ __launch_bounds__(256) void hist_kernel(const int* __restrict__ dst,
                                                   int* __restrict__ cnt, int M) {
  int e = blockIdx.x * 256 + threadIdx.x;
  if (e < M) atomicAdd(&cnt[dst[e]], 1);
}

#define SCHUNK 2048
__global__ __launch_bounds__(256) void scan1_kernel(const int* __restrict__ cnt,
                                                    int* __restrict__ incl,
                                                    int* __restrict__ bsum, int n) {
  __shared__ int lds[256];
  int b = blockIdx.x, tid = threadIdx.x;
  int base = b * SCHUNK + tid * 8;
  int v[8], s = 0;
#pragma unroll
  for (int j = 0; j < 8; ++j) { int i = base + j; v[j] = (i < n) ? cnt[i] : 0; s += v[j]; }
  lds[tid] = s;
  __syncthreads();
  for (int o = 1; o < 256; o <<= 1) {
    int t = (tid >= o) ? lds[tid - o] : 0;
    __syncthreads();
    lds[tid] += t;
    __syncthreads();
  }
  int run = lds[tid] - s;
#pragma unroll
  for (int j = 0; j < 8; ++j) {
    run += v[j];
    int i = base + j;
    if (i < n) incl[i] = run;
  }
  if (tid == 255) bsum[b] = lds[255];
}

__global__ void scan2_kernel(int* __restrict__ bsum, int nb) {
  if (threadIdx.x == 0 && blockIdx.x == 0) {
    int run = 0;
    for (int i = 0; i < nb; ++i) { int t = bsum[i]; bsum[i] = run; run += t; }
  }
}

__global__ __launch_bounds__(256) void scan3_kernel(const int* __restrict__ incl,
                                                    const int* __restrict__ cnt,
                                                    const int* __restrict__ bsum,
                                                    int* __restrict__ offA,
                                                    int* __restrict__ cur, int n) {
  int i = blockIdx.x * 256 + threadIdx.x;
  if (i >= n) return;
  int o = incl[i] - cnt[i] + bsum[i / SCHUNK];
  offA[i] = o;
  cur[i] = o;
}

__global__ __launch_bounds__(256) void fill_kernel(const int* __restrict__ dst,
                                                   int* __restrict__ cur,
                                                   int* __restrict__ elist, int M) {
  int e = blockIdx.x * 256 + threadIdx.x;
  if (e >= M) return;
  int pos = atomicAdd(&cur[dst[e]], 1);
  elist[pos] = e;
}

// ---------------- layer-1 fused aggregation (xa table in bf16) ----------------
__global__ __launch_bounds__(256) void l1_agg(
    const float* __restrict__ Xe, const unsigned short* __restrict__ xa,
    const float* __restrict__ pe1w_e, const float* __restrict__ pe1b,
    const float* __restrict__ pe2w_e, const float* __restrict__ pe2b,
    const float* __restrict__ alpha, const int* __restrict__ srcA,
    const int* __restrict__ offA, const int* __restrict__ cntA, const int* __restrict__ elist,
    float* __restrict__ S, float* __restrict__ ssumOut, int N)
{
  int v = (blockIdx.x * 256 + threadIdx.x) >> 6;
  int lane = threadIdx.x & 63;
  if (v >= N) return;
  int begin = offA[v], cnt = cntA[v];
  int k0 = lane, k1 = lane + 64, k2 = lane + 128;
  bool v3 = lane < 8;
  int k3 = v3 ? lane + 192 : 0;
  float b0 = pe1b[k0], b1 = pe1b[k1], b2 = pe1b[k2], b3 = pe1b[k3];
  float p0 = pe2w_e[k0], p1 = pe2w_e[k1], p2 = pe2w_e[k2];
  float p3 = v3 ? pe2w_e[k3] : 0.f;
  float w0[EE], w1[EE], w2[EE], w3[EE];
#pragma unroll
  for (int j = 0; j < EE; ++j) {
    w0[j] = pe1w_e[j * GG + k0];
    w1[j] = pe1w_e[j * GG + k1];
    w2[j] = pe1w_e[j * GG + k2];
    w3[j] = pe1w_e[j * GG + k3];
  }
  float alv = alpha[v] + pe2b[0];
  float m = -1e30f, ss = 0.f;
  float a0 = 0.f, a1 = 0.f, a2 = 0.f, a3 = 0.f;
  for (int t = 0; t < cnt; ++t) {
    int e = elist[begin + t];
    int s = srcA[e];
    const float* xep = Xe + (size_t)e * EE;
    float xe[EE];
#pragma unroll
    for (int j = 0; j < EE; ++j) xe[j] = xep[j];
    const unsigned short* xap = xa + (size_t)s * GG;
    float h0 = bf2f(xap[k0]) + b0, h1 = bf2f(xap[k1]) + b1;
    float h2 = bf2f(xap[k2]) + b2, h3 = bf2f(xap[k3]) + b3;
#pragma unroll
    for (int j = 0; j < EE; ++j) {
      h0 += xe[j] * w0[j];
      h1 += xe[j] * w1[j];
      h2 += xe[j] * w2[j];
      h3 += xe[j] * w3[j];
    }
    h0 = leakyf(h0); h1 = leakyf(h1); h2 = leakyf(h2); h3 = leakyf(h3);
    float bp = h0 * p0 + h1 * p1 + h2 * p2 + h3 * p3;
    for (int o = 32; o; o >>= 1) bp += __shfl_down(bp, o);
    bp = __shfl(bp, 0);
    float l = leakyf(alv + bp);
    if (l > m) {
      float sc = expf(m - l);
      ss *= sc; a0 *= sc; a1 *= sc; a2 *= sc; a3 *= sc;
      m = l;
    }
    float w = expf(l - m);
    ss += w;
    a0 += w * h0; a1 += w * h1; a2 += w * h2; a3 += w * h3;
  }
  float inv = (cnt > 0) ? 1.f / ss : 0.f;
  float* sp = S + (size_t)v * GG;
  sp[k0] = a0 * inv; sp[k1] = a1 * inv; sp[k2] = a2 * inv;
  if (v3) sp[k3] = a3 * inv;
  if (lane == 0) ssumOut[v] = (cnt > 0) ? ss : 0.f;
}

// ---------------- layer-2 fused aggregation (hvp table in bf16) ----------------
__global__ __launch_bounds__(256) void l2_agg(
    const unsigned short* __restrict__ hvp, const float* __restrict__ gd,
    const float* __restrict__ gs, const float* __restrict__ lpeb,
    const int* __restrict__ srcA,
    const int* __restrict__ offA, const int* __restrict__ cntA, const int* __restrict__ elist,
    float* __restrict__ S2, int N)
{
  int v = (blockIdx.x * 256 + threadIdx.x) >> 6;
  int lane = threadIdx.x & 63;
  if (v >= N) return;
  int begin = offA[v], cnt = cntA[v];
  int k0 = lane, k1 = lane + 64, k2 = lane + 128;
  bool v3 = lane < 8;
  int k3 = v3 ? lane + 192 : 0;
  float gdv = gd[v] + lpeb[0];
  float m = -1e30f, ss = 0.f;
  float a0 = 0.f, a1 = 0.f, a2 = 0.f, a3 = 0.f;
  for (int t = 0; t < cnt; ++t) {
    int e = elist[begin + t];
    int s = srcA[e];
    float l = leakyf(gdv + gs[s]);
    if (l > m) {
      float sc = expf(m - l);
      ss *= sc; a0 *= sc; a1 *= sc; a2 *= sc; a3 *= sc;
      m = l;
    }
    float w = expf(l - m);
    ss += w;
    const unsigned short* hp = hvp + (size_t)s * GG;
    a0 += w * bf2f(hp[k0]); a1 += w * bf2f(hp[k1]);
    a2 += w * bf2f(hp[k2]); a3 += w * bf2f(hp[k3]);
  }
  float inv = (cnt > 0) ? 1.f / ss : 0.f;
  float* sp = S2 + (size_t)v * GG;
  sp[k0] = (cnt > 0) ? eluf(a0 * inv) : 0.f;
  sp[k1] = (cnt > 0) ? eluf(a1 * inv) : 0.f;
  sp[k2] = (cnt > 0) ? eluf(a2 * inv) : 0.f;
  if (v3) sp[k3] = (cnt > 0) ? eluf(a3 * inv) : 0.f;
}

// ================= MFMA GEMM: C = act(mask(A@W + b)) =================
// 1D grid, XCD-aware: blocks sharing a row-tile are congruent mod 8
// (same XCD) and dispatch-adjacent -> row-tile served from that XCD's L2.
__global__ __launch_bounds__(256) void mfma_gemm(
    const float* __restrict__ A, const unsigned short* __restrict__ Wt,
    const float* __restrict__ bias, const float* __restrict__ rowmask,
    float* __restrict__ Cf, unsigned short* __restrict__ Cb,
    int Mr, int Nc, int K, int act)
{
  __shared__ __attribute__((aligned(16))) short As[128 * 32];
  __shared__ __attribute__((aligned(16))) short Bs[64 * 32];
  int ncol = (Nc + 63) >> 6;
  int nrowt = (Mr + 127) >> 7;
  int per = 8 * ncol;
  int grp = blockIdx.x / per, rem = blockIdx.x % per;
  int rowt = grp * 8 + (rem & 7), colt = rem >> 3;
  if (rowt >= nrowt) return;
  int row0 = rowt * 128, col0 = colt * 64;
  int tid = threadIdx.x;
  int w = tid >> 6, lane = tid & 63, quad = lane >> 4, l15 = lane & 15;

  f32x4 zero4 = {0.f, 0.f, 0.f, 0.f};
  f32x4 acc[2][4];
#pragma unroll
  for (int r = 0; r < 2; ++r)
#pragma unroll
    for (int c = 0; c < 4; ++c) acc[r][c] = zero4;

  for (int k0 = 0; k0 < K; k0 += 32) {
    {
      int row = tid >> 1, half = tid & 1;
      int r = row0 + row;
      short tmp[16];
      const float* ap = A + (size_t)r * K + k0 + half * 16;
      if (r < Mr && k0 + half * 16 + 16 <= K) {
#pragma unroll
        for (int j = 0; j < 16; ++j) tmp[j] = (short)f2bf(ap[j]);
      } else if (r < Mr) {
#pragma unroll
        for (int j = 0; j < 16; ++j) {
          int k = k0 + half * 16 + j;
          tmp[j] = (k < K) ? (short)f2bf(ap[j]) : (short)0;
        }
      } else {
#pragma unroll
        for (int j = 0; j < 16; ++j) tmp[j] = 0;
      }
      *(bf16x8*)&As[sw(row, 2 * half)]     = *(bf16x8*)&tmp[0];
      *(bf16x8*)&As[sw(row, 2 * half + 1)] = *(bf16x8*)&tmp[8];
    }
    {
      int col = tid & 63, seg = tid >> 6;
      int n = col0 + col, k = k0 + seg * 8;
      short t8[8];
      const unsigned short* wp = Wt + (size_t)n * K + k;
      if (n < Nc && k + 8 <= K) {
        *(bf16x8*)&t8[0] = *(const bf16x8*)wp;
      } else {
#pragma unroll
        for (int j = 0; j < 8; ++j)
          t8[j] = (n < Nc && k + j < K) ? (short)wp[j] : (short)0;
      }
      *(bf16x8*)&Bs[sw(col, seg)] = *(bf16x8*)&t8[0];
    }
    __syncthreads();
    bf16x8 a[2], b[4];
#pragma unroll
    for (int r = 0; r < 2; ++r)
      a[r] = *(const bf16x8*)&As[sw(w * 32 + r * 16 + l15, quad)];
#pragma unroll
    for (int c = 0; c < 4; ++c)
      b[c] = *(const bf16x8*)&Bs[sw(c * 16 + l15, quad)];
#pragma unroll
    for (int r = 0; r < 2; ++r)
#pragma unroll
      for (int c = 0; c < 4; ++c)
        acc[r][c] = __builtin_amdgcn_mfma_f32_16x16x32_bf16(a[r], b[c], acc[r][c], 0, 0, 0);
    __syncthreads();
  }
#pragma unroll
  for (int r = 0; r < 2; ++r) {
#pragma unroll
    for (int c = 0; c < 4; ++c) {
      int col = col0 + c * 16 + l15;
      if (col >= Nc) continue;
#pragma unroll
      for (int i = 0; i < 4; ++i) {
        int row = row0 + w * 32 + r * 16 + quad * 4 + i;
        if (row >= Mr) continue;
        bool valid = (rowmask == nullptr) || (rowmask[row] > 0.f);
        float v = valid ? (acc[r][c][i] + (bias ? bias[col] : 0.f)) : 0.f;
        if (act == 1) v = leakyf(v);
        else if (act == 2) v = eluf(v);
        if (Cb) Cb[(size_t)row * Nc + col] = f2bf(v);
        else    Cf[(size_t)row * Nc + col] = v;
      }
    }
  }
}

// ================= fused MFMA GRU =================
__global__ __launch_bounds__(256) void mfma_gru(
    const float* __restrict__ X, const float* __restrict__ H,
    const unsigned short* __restrict__ WtIH, const unsigned short* __restrict__ WtHH,
    const float* __restrict__ bih, const float* __restrict__ bhh,
    float* __restrict__ Out, int R, int relu_out)
{
  __shared__ __attribute__((aligned(16))) short Xs[128 * 32];
  __shared__ __attribute__((aligned(16))) short Hs[128 * 32];
  __shared__ __attribute__((aligned(16))) short Ws[192 * 32];
  int nrowt = (R + 127) >> 7;
  int grp = blockIdx.x / 56, rem = blockIdx.x % 56;
  int rowt = grp * 8 + (rem & 7), colt = rem >> 3;
  if (rowt >= nrowt) return;
  int row0 = rowt * 128, col0 = colt * 32;
  int tid = threadIdx.x;
  int w = tid >> 6, lane = tid & 63, quad = lane >> 4, l15 = lane & 15;

  f32x4 zero4 = {0.f, 0.f, 0.f, 0.f};
  f32x4 acc[6][2][2];
#pragma unroll
  for (int g = 0; g < 6; ++g)
#pragma unroll
    for (int r = 0; r < 2; ++r)
#pragma unroll
      for (int c = 0; c < 2; ++c) acc[g][r][c] = zero4;

  for (int k0 = 0; k0 < GG; k0 += 32) {
    {
      int row = tid >> 1, half = tid & 1;
      int r = row0 + row;
      short tx[16], th[16];
      const float* xp = X + (size_t)r * GG + k0 + half * 16;
      const float* hp = H + (size_t)r * GG + k0 + half * 16;
      if (r < R && k0 + half * 16 + 16 <= GG) {
#pragma unroll
        for (int j = 0; j < 16; ++j) { tx[j] = (short)f2bf(xp[j]); th[j] = (short)f2bf(hp[j]); }
      } else if (r < R) {
#pragma unroll
        for (int j = 0; j < 16; ++j) {
          int k = k0 + half * 16 + j;
          tx[j] = (k < GG) ? (short)f2bf(xp[j]) : (short)0;
          th[j] = (k < GG) ? (short)f2bf(hp[j]) : (short)0;
        }
      } else {
#pragma unroll
        for (int j = 0; j < 16; ++j) { tx[j] = 0; th[j] = 0; }
      }
      *(bf16x8*)&Xs[sw(row, 2 * half)]     = *(bf16x8*)&tx[0];
      *(bf16x8*)&Xs[sw(row, 2 * half + 1)] = *(bf16x8*)&tx[8];
      *(bf16x8*)&Hs[sw(row, 2 * half)]     = *(bf16x8*)&th[0];
      *(bf16x8*)&Hs[sw(row, 2 * half + 1)] = *(bf16x8*)&th[8];
    }
    for (int task = tid; task < 768; task += 256) {
      int rw = task >> 2, seg = task & 3;
      int g = rw >> 5, cc = rw & 31;
      int n = col0 + cc, k = k0 + seg * 8;
      const unsigned short* wp = (g < 3)
          ? WtIH + (size_t)(g * GG + n) * GG + k
          : WtHH + (size_t)((g - 3) * GG + n) * GG + k;
      short t8[8];
      if (n < GG && k + 8 <= GG) {
        *(bf16x8*)&t8[0] = *(const bf16x8*)wp;
      } else {
#pragma unroll
        for (int j = 0; j < 8; ++j)
          t8[j] = (n < GG && k + j < GG) ? (short)wp[j] : (short)0;
      }
      *(bf16x8*)&Ws[sw(rw, seg)] = *(bf16x8*)&t8[0];
    }
    __syncthreads();
    bf16x8 ax[2], ah[2];
#pragma unroll
    for (int r = 0; r < 2; ++r) {
      ax[r] = *(const bf16x8*)&Xs[sw(w * 32 + r * 16 + l15, quad)];
      ah[r] = *(const bf16x8*)&Hs[sw(w * 32 + r * 16 + l15, quad)];
    }
#pragma unroll
    for (int g = 0; g < 6; ++g) {
      bf16x8 b[2];
#pragma unroll
      for (int c = 0; c < 2; ++c)
        b[c] = *(const bf16x8*)&Ws[sw(g * 32 + c * 16 + l15, quad)];
#pragma unroll
      for (int r = 0; r < 2; ++r)
#pragma unroll
        for (int c = 0; c < 2; ++c)
          acc[g][r][c] = __builtin_amdgcn_mfma_f32_16x16x32_bf16(
              (g < 3) ? ax[r] : ah[r], b[c], acc[g][r][c], 0, 0, 0);
    }
    __syncthreads();
  }
#pragma unroll
  for (int r = 0; r < 2; ++r) {
#pragma unroll
    for (int c = 0; c < 2; ++c) {
      int col = col0 + c * 16 + l15;
      if (col >= GG) continue;
      float br = bih[col],       bhr = bhh[col];
      float bz = bih[200 + col], bhz = bhh[200 + col];
      float bn = bih[400 + col], bhn = bhh[400 + col];
#pragma unroll
      for (int i = 0; i < 4; ++i) {
        int row = row0 + w * 32 + r * 16 + quad * 4 + i;
        if (row >= R) continue;
        float rr = sigmf(acc[0][r][c][i] + br + acc[3][r][c][i] + bhr);
        float zz = sigmf(acc[1][r][c][i] + bz + acc[4][r][c][i] + bhz);
        float nn = tanhf(acc[2][r][c][i] + bn + rr * (acc[5][r][c][i] + bhn));
        float hval = H[(size_t)row * GG + col];
        float o = (1.f - zz) * nn + zz * hval;
        if (relu_out) o = fmaxf(o, 0.f);
        Out[(size_t)row * GG + col] = o;
      }
    }
  }
}

// ---------------- fp32 tiled GEMM (small shapes) ----------------
#define Bb 64
#define Bn 64
#define Bk 16
__global__ __launch_bounds__(256) void gemm_kernel(
    const float* __restrict__ A, const float* __restrict__ W,
    const float* __restrict__ bias, const float* __restrict__ rowmask,
    float* __restrict__ Cf, void* __restrict__ Oout, const int* __restrict__ oflag,
    int Mr, int Nc, int K, int act)
{
  __shared__ float As[Bk][Bb + 1];
  __shared__ float Ws[Bk][Bn];
  int row0 = blockIdx.x * Bb, col0 = blockIdx.y * Bn;
  int tid = threadIdx.x;
  int ty = tid >> 4, tx = tid & 15;
  float acc[4][4] = {};
  for (int k0 = 0; k0 < K; k0 += Bk) {
    for (int l = tid; l < Bb * Bk; l += 256) {
      int m = l >> 4, kk = l & 15;
      int r = row0 + m, k = k0 + kk;
      As[kk][m] = (r < Mr && k < K) ? A[(size_t)r * K + k] : 0.f;
    }
    for (int l = tid; l < Bk * Bn; l += 256) {
      int kk = l >> 6, nn = l & 63;
      int k = k0 + kk, c = col0 + nn;
      Ws[kk][nn] = (k < K && c < Nc) ? W[(size_t)k * Nc + c] : 0.f;
    }
    __syncthreads();
#pragma unroll
    for (int kk = 0; kk < Bk; ++kk) {
      float av[4], bv[4];
#pragma unroll
      for (int i = 0; i < 4; ++i) av[i] = As[kk][ty * 4 + i];
#pragma unroll
      for (int j = 0; j < 4; ++j) bv[j] = Ws[kk][tx * 4 + j];
#pragma unroll
      for (int i = 0; i < 4; ++i)
#pragma unroll
        for (int j = 0; j < 4; ++j) acc[i][j] += av[i] * bv[j];
    }
    __syncthreads();
  }
  int isbf = (oflag != nullptr) ? *oflag : 0;
#pragma unroll
  for (int i = 0; i < 4; ++i) {
    int r = row0 + ty * 4 + i;
    if (r >= Mr) continue;
    bool valid = (rowmask == nullptr) || (rowmask[r] > 0.f);
#pragma unroll
    for (int j = 0; j < 4; ++j) {
      int c = col0 + tx * 4 + j;
      if (c >= Nc) continue;
      float v = valid ? (acc[i][j] + (bias ? bias[c] : 0.f)) : 0.f;
      if (act == 1) v = leakyf(v);
      else if (act == 2) v = eluf(v);
      else if (act == 3) v = fmaxf(v, 0.f);
      size_t idx = (size_t)r * Nc + c;
      if (Oout) {
        if (isbf) ((__hip_bfloat16*)Oout)[idx] = __float2bfloat16(v);
        else      ((float*)Oout)[idx] = v;
      } else {
        Cf[idx] = v;
      }
    }
  }
}

// ---------------- per-node dot(s) ----------------
__global__ __launch_bounds__(256) void node_dot2(
    const float* __restrict__ X, const float* __restrict__ w1, const float* __restrict__ w2,
    float* __restrict__ o1, float* __restrict__ o2, int N)
{
  int v = (blockIdx.x * 256 + threadIdx.x) >> 6;
  int lane = threadIdx.x & 63;
  if (v >= N) return;
  float d1 = 0.f, d2 = 0.f;
  for (int k = lane; k < GG; k += 64) {
    float x = X[(size_t)v * GG + k];
    d1 += x * w1[k];
    if (w2) d2 += x * w2[k];
  }
  for (int off = 32; off; off >>= 1) {
    d1 += __shfl_down(d1, off);
    if (w2) d2 += __shfl_down(d2, off);
  }
  if (lane == 0) { o1[v] = d1; if (w2) o2[v] = d2; }
}

__global__ __launch_bounds__(256) void graph_sum(
    const float* __restrict__ h, float* __restrict__ g)
{
  int b = blockIdx.x, k = threadIdx.x;
  if (k < GG) {
    float a = 0.f;
    for (int i = 0; i < 50; ++i) a += h[((size_t)b * 50 + i) * GG + k];
    g[(size_t)b * GG + k] = a;
  }
}

__global__ __launch_bounds__(256) void attn_kernel(
    const float* __restrict__ g, const float* __restrict__ h2,
    const float* __restrict__ w1, const float* __restrict__ dh,
    const float* __restrict__ rb, float* __restrict__ weighted)
{
  int b = blockIdx.x;
  __shared__ float red[256];
  __shared__ float zs[50];
  __shared__ float as_[50];
  __shared__ float dgs;
  int tid = threadIdx.x;
  float p = 0.f;
  if (tid < GG) p = fmaxf(g[(size_t)b * GG + tid], 0.f) * w1[tid];
  red[tid] = p;
  __syncthreads();
  for (int s = 128; s; s >>= 1) { if (tid < s) red[tid] += red[tid + s]; __syncthreads(); }
  if (tid == 0) dgs = red[0];
  __syncthreads();
  if (tid < 50) zs[tid] = leakyf(dgs + dh[b * 50 + tid] + rb[0]);
  __syncthreads();
  if (tid == 0) {
    float m = -1e30f;
    for (int i = 0; i < 50; ++i) m = fmaxf(m, zs[i]);
    float s = 0.f;
    for (int i = 0; i < 50; ++i) { float e = expf(zs[i] - m); as_[i] = e; s += e; }
    float inv = 1.f / s;
    for (int i = 0; i < 50; ++i) as_[i] *= inv;
  }
  __syncthreads();
  if (tid < GG) {
    float a = 0.f;
    for (int i = 0; i < 50; ++i) a += as_[i] * h2[((size_t)b * 50 + i) * GG + tid];
    weighted[(size_t)b * GG + tid] = a;
  }
}

// ---------------- host ----------------
static inline int gemm_grid(int Mr, int Nc) {
  int nrow = (Mr + 127) / 128, ncol = (Nc + 63) / 64;
  return ((nrow + 7) / 8) * 8 * ncol;
}
static inline int gru_grid(int R) {
  int nrow = (R + 127) / 128;
  return ((nrow + 7) / 8) * 56;
}

extern "C" void kernel_launch(void* const* d_in, const int* in_sizes, int n_in,
                              void* d_out, int out_size, void* d_ws, size_t ws_size,
                              hipStream_t stream)
{
  (void)n_in; (void)out_size; (void)ws_size;
  const int N = NN, M = MM, B = BB, F = FF, G = GG, P = PP;
  float* ws = (float*)d_ws;
  size_t off = 0;
  auto alloc = [&](size_t n) { size_t o = off; off += (n + 63) & ~(size_t)63; return o; };

  size_t o_flag = alloc(16);
  size_t o_pn_w = alloc(F * G), o_pn_b = alloc(G);
  size_t o_pe1_w = alloc((F + EE) * G), o_pe1_b = alloc(G);
  size_t o_pe2_w = alloc(2 * G), o_pe2_b = alloc(1);
  size_t o_et_w = alloc(G * G), o_et_b = alloc(G);
  size_t o_g0_wih = alloc(G * 3 * G), o_g0_whh = alloc(G * 3 * G);
  size_t o_g0_bih = alloc(3 * G), o_g0_bhh = alloc(3 * G);
  size_t o_lpe_w = alloc(2 * G), o_lpe_b = alloc(1);
  size_t o_lpn_w = alloc(G * G), o_lpn_b = alloc(G);
  size_t o_g1_wih = alloc(G * 3 * G), o_g1_whh = alloc(G * 3 * G);
  size_t o_g1_bih = alloc(3 * G), o_g1_bhh = alloc(3 * G);
  size_t o_rl_w = alloc(2 * 2 * G), o_rl_b = alloc(2);
  size_t o_rp_w = alloc(2 * G * G), o_rp_b = alloc(2 * G);
  size_t o_rg_wih = alloc(2 * G * 3 * G), o_rg_whh = alloc(2 * G * 3 * G);
  size_t o_rg_bih = alloc(2 * 3 * G), o_rg_bhh = alloc(2 * 3 * G);
  size_t o_t_w = alloc(G * P), o_t_b = alloc(P);
  size_t o_Xn = alloc((size_t)N * F);
  size_t o_Xe = alloc((size_t)M * EE);
  size_t o_B1 = alloc((size_t)N * G);
  size_t o_B2 = alloc((size_t)N * G);
  size_t o_B3 = alloc((size_t)N * G);
  size_t o_alpha = alloc(N), o_ssum = alloc(N);
  size_t o_gd = alloc(N), o_gs = alloc(N), o_dh = alloc(N);
  size_t o_gv0 = alloc((size_t)B * G), o_gwt = alloc((size_t)B * G), o_grep = alloc((size_t)B * G);
  size_t o_gv1 = alloc((size_t)B * G), o_gv2 = alloc((size_t)B * G);
  size_t o_etT  = alloc(G * G / 2), o_lpnT = alloc(G * G / 2);
  size_t o_g0ihT = alloc(G * 3 * G / 2), o_g0hhT = alloc(G * 3 * G / 2);
  size_t o_g1ihT = alloc(G * 3 * G / 2), o_g1hhT = alloc(G * 3 * G / 2);
  size_t o_rg0ihT = alloc(G * 3 * G / 2), o_rg0hhT = alloc(G * 3 * G / 2);
  size_t o_rg1ihT = alloc(G * 3 * G / 2), o_rg1hhT = alloc(G * 3 * G / 2);
  size_t o_pnT = alloc(G * F / 2 + 64), o_pe1T = alloc(G * F / 2 + 64);
  size_t o_cnt = alloc(N), o_off = alloc(N), o_cur = alloc(N);
  size_t o_elist = alloc(M), o_bsum = alloc(64), o_incl = alloc(N);

  int* flag = (int*)(ws + o_flag);
  int* cntA = (int*)(ws + o_cnt);
  int* offA = (int*)(ws + o_off);
  int* curA = (int*)(ws + o_cur);
  int* elist = (int*)(ws + o_elist);
  int* bsum = (int*)(ws + o_bsum);
  int* incl = (int*)(ws + o_incl);

  CvtJobs32 jobs;
  int ji = 0;
  auto push = [&](int idx, size_t dsto) {
    jobs.j[ji].s = d_in[idx];
    jobs.j[ji].d = ws + dsto;
    jobs.j[ji].n = in_sizes[idx];
    jobs.j[ji].pad = 0;
    ++ji;
  };
  push(0, o_Xn);
  push(1, o_Xe);
  push(2, o_pn_w);  push(3, o_pn_b);
  push(4, o_pe1_w); push(5, o_pe1_b);
  push(6, o_pe2_w); push(7, o_pe2_b);
  push(8, o_et_w);  push(9, o_et_b);
  push(10, o_g0_wih); push(11, o_g0_whh); push(12, o_g0_bih); push(13, o_g0_bhh);
  push(14, o_lpe_w);  push(15, o_lpe_b);
  push(16, o_lpn_w);  push(17, o_lpn_b);
  push(18, o_g1_wih); push(19, o_g1_whh); push(20, o_g1_bih); push(21, o_g1_bhh);
  push(22, o_rl_w);   push(23, o_rl_b);
  push(24, o_rp_w);   push(25, o_rp_b);
  push(26, o_rg_wih); push(27, o_rg_whh); push(28, o_rg_bih); push(29, o_rg_bhh);
  push(30, o_t_w);    push(31, o_t_b);

  const int* src = (const int*)d_in[32];
  const int* dst = (const int*)d_in[33];

  dim3 blk(256);
  detect_dtype<<<dim3(1), blk, 0, stream>>>((const unsigned int*)d_in[0], flag);
  cvt_any<<<dim3(512, 32), blk, 0, stream>>>(jobs, flag);

  // ---- CSR build (by dst) ----
  hipMemsetAsync(cntA, 0, (size_t)N * 4, stream);
  hist_kernel<<<dim3((M + 255) / 256), blk, 0, stream>>>(dst, cntA, M);
  int nscb = (N + SCHUNK - 1) / SCHUNK;
  scan1_kernel<<<dim3(nscb), blk, 0, stream>>>(cntA, incl, bsum, N);
  scan2_kernel<<<dim3(1), dim3(64), 0, stream>>>(bsum, nscb);
  scan3_kernel<<<dim3((N + 255) / 256), blk, 0, stream>>>(incl, cntA, bsum, offA, curA, N);
  fill_kernel<<<dim3((M + 255) / 256), blk, 0, stream>>>(dst, curA, elist, M);

  // ---- weight transposes ----
  TJobs12 tj;
  auto tpush = [&](int slot, size_t srcO, size_t dstO, int K, int Nc) {
    tj.j[slot].s = ws + srcO;
    tj.j[slot].d = (unsigned short*)(ws + dstO);
    tj.j[slot].K = K; tj.j[slot].N = Nc;
  };
  tpush(0, o_et_w,  o_etT,  G, G);
  tpush(1, o_lpn_w, o_lpnT, G, G);
  tpush(2, o_g0_wih, o_g0ihT, G, 3 * G);
  tpush(3, o_g0_whh, o_g0hhT, G, 3 * G);
  tpush(4, o_g1_wih, o_g1ihT, G, 3 * G);
  tpush(5, o_g1_whh, o_g1hhT, G, 3 * G);
  tpush(6, o_rg_wih, o_rg0ihT, G, 3 * G);
  tpush(7, o_rg_whh, o_rg0hhT, G, 3 * G);
  tpush(8, o_rg_wih + (size_t)G * 3 * G, o_rg1ihT, G, 3 * G);
  tpush(9, o_rg_whh + (size_t)G * 3 * G, o_rg1hhT, G, 3 * G);
  tpush(10, o_pn_w,  o_pnT,  F, G);
  tpush(11, o_pe1_w, o_pe1T, F, G);
  transpose_bf16<<<dim3(128, 12), blk, 0, stream>>>(tj);

  dim3 gWave((N + 3) / 4);

  // hv_new = leaky(Xn@pn_w + pn_b) -> B1 (f32)
  mfma_gemm<<<dim3(gemm_grid(N, G)), blk, 0, stream>>>(
      ws + o_Xn, (const unsigned short*)(ws + o_pnT), ws + o_pn_b, nullptr,
      ws + o_B1, nullptr, N, G, F, 1);
  // xa = Xn @ pe1_w[:39] -> B2 (bf16 table for l1_agg)
  mfma_gemm<<<dim3(gemm_grid(N, G)), blk, 0, stream>>>(
      ws + o_Xn, (const unsigned short*)(ws + o_pe1T), nullptr, nullptr,
      nullptr, (unsigned short*)(ws + o_B2), N, G, F, 0);
  node_dot2<<<gWave, blk, 0, stream>>>(ws + o_B1, ws + o_pe2_w, nullptr,
                                       ws + o_alpha, nullptr, N);
  l1_agg<<<gWave, blk, 0, stream>>>(ws + o_Xe, (const unsigned short*)(ws + o_B2),
                                    ws + o_pe1_w + (size_t)F * G, ws + o_pe1_b,
                                    ws + o_pe2_w + G, ws + o_pe2_b, ws + o_alpha,
                                    src, offA, cntA, elist,
                                    ws + o_B3, ws + o_ssum, N);
  // c = elu(mask(B3@et_w + et_b)) -> B2 (f32)
  mfma_gemm<<<dim3(gemm_grid(N, G)), blk, 0, stream>>>(
      ws + o_B3, (const unsigned short*)(ws + o_etT), ws + o_et_b, ws + o_ssum,
      ws + o_B2, nullptr, N, G, G, 2);
  // h = relu(GRU0(x=B2, h=B1)) -> B3
  mfma_gru<<<dim3(gru_grid(N)), blk, 0, stream>>>(
      ws + o_B2, ws + o_B1,
      (const unsigned short*)(ws + o_g0ihT), (const unsigned short*)(ws + o_g0hhT),
      ws + o_g0_bih, ws + o_g0_bhh, ws + o_B3, N, 1);

  // ---- layer 2 ----
  node_dot2<<<gWave, blk, 0, stream>>>(ws + o_B3, ws + o_lpe_w, ws + o_lpe_w + G,
                                       ws + o_gd, ws + o_gs, N);
  // hv_proj = h@lpn_w + lpn_b -> B1 (bf16 table for l2_agg)
  mfma_gemm<<<dim3(gemm_grid(N, G)), blk, 0, stream>>>(
      ws + o_B3, (const unsigned short*)(ws + o_lpnT), ws + o_lpn_b, nullptr,
      nullptr, (unsigned short*)(ws + o_B1), N, G, G, 0);
  l2_agg<<<gWave, blk, 0, stream>>>((const unsigned short*)(ws + o_B1),
                                    ws + o_gd, ws + o_gs, ws + o_lpe_b,
                                    src, offA, cntA, elist, ws + o_B2, N);
  // h2 = relu(GRU1(x=B2, h=B3)) -> B1 (f32)
  mfma_gru<<<dim3(gru_grid(N)), blk, 0, stream>>>(
      ws + o_B2, ws + o_B3,
      (const unsigned short*)(ws + o_g1ihT), (const unsigned short*)(ws + o_g1hhT),
      ws + o_g1_bih, ws + o_g1_bhh, ws + o_B1, N, 1);

  // ---- readout ----
  graph_sum<<<dim3(B), blk, 0, stream>>>(ws + o_B1, ws + o_gv0);
  dim3 gBG((B + Bb - 1) / Bb, (G + Bn - 1) / Bn);
  size_t gcur = o_gv0, gnext = o_gv1;
  for (int t = 0; t < 2; ++t) {
    node_dot2<<<gWave, blk, 0, stream>>>(ws + o_B1, ws + o_rl_w + t * 2 * G + G,
                                         nullptr, ws + o_dh, nullptr, N);
    attn_kernel<<<dim3(B), blk, 0, stream>>>(ws + gcur, ws + o_B1, ws + o_rl_w + t * 2 * G,
                                             ws + o_dh, ws + o_rl_b + t, ws + o_gwt);
    gemm_kernel<<<gBG, blk, 0, stream>>>(ws + o_gwt, ws + o_rp_w + (size_t)t * G * G,
                                         ws + o_rp_b + t * G, nullptr,
                                         ws + o_grep, nullptr, nullptr, B, G, G, 2);
    mfma_gru<<<dim3(gru_grid(B)), blk, 0, stream>>>(
        ws + o_grep, ws + gcur,
        (const unsigned short*)(ws + (t == 0 ? o_rg0ihT : o_rg1ihT)),
        (const unsigned short*)(ws + (t == 0 ? o_rg0hhT : o_rg1hhT)),
        ws + o_rg_bih + t * 3 * G, ws + o_rg_bhh + t * 3 * G,
        ws + gnext, B, 0);
    gcur = gnext;
    gnext = o_gv2;
  }
  dim3 gOut((B + Bb - 1) / Bb, (P + Bn - 1) / Bn);
  gemm_kernel<<<gOut, blk, 0, stream>>>(ws + gcur, ws + o_t_w, ws + o_t_b, nullptr,
                                        nullptr, d_out, flag, B, P, G, 0);
}

// Round 6
// 1050.629 us; speedup vs baseline: 3.8685x; 1.1323x over previous
//
#include <hip/hip_runtime.h>
#include <hip/hip_bf16.h>

// ---------------- constants ----------------
#define NN 50000
#define MM 400000
#define BB 1000
#define FF 39
#define EE 11
#define GG 200
#define PP 128

typedef __attribute__((ext_vector_type(8))) short bf16x8;
typedef __attribute__((ext_vector_type(4))) float f32x4;

// ---------------- helpers ----------------
__device__ __forceinline__ float bf2f(unsigned short u) {
  return __uint_as_float(((unsigned int)u) << 16);
}
__device__ __forceinline__ unsigned short f2bf(float x) {
  union { __hip_bfloat16 b; unsigned short u; } v;
  v.b = __float2bfloat16(x);
  return v.u;
}
__device__ __forceinline__ float leakyf(float x) { return x > 0.f ? x : 0.01f * x; }
__device__ __forceinline__ float eluf(float x)   { return x > 0.f ? x : (expf(x) - 1.f); }
__device__ __forceinline__ float sigmf(float x)  { return 1.f / (1.f + expf(-x)); }
__device__ __forceinline__ int sw(int row, int seg) {
  return row * 32 + ((seg ^ ((row >> 1) & 3)) << 3);
}
template <typename T> __device__ __forceinline__ float ldv(const T* p);
template <> __device__ __forceinline__ float ldv<float>(const float* p) { return *p; }
template <> __device__ __forceinline__ float ldv<unsigned short>(const unsigned short* p) { return bf2f(*p); }

// stage 16 elements (f32->bf16 cvt or bf16 copy) into tmp[16]
template <typename T>
__device__ __forceinline__ void stage16(const T* ap, int kbase, int K, bool rowok, short* tmp) {
  if (rowok && kbase + 16 <= K) {
    if constexpr (sizeof(T) == 2) {
      *(bf16x8*)&tmp[0] = *(const bf16x8*)(ap);
      *(bf16x8*)&tmp[8] = *(const bf16x8*)(ap + 8);
    } else {
#pragma unroll
      for (int j = 0; j < 16; ++j) tmp[j] = (short)f2bf(ap[j]);
    }
  } else if (rowok) {
#pragma unroll
    for (int j = 0; j < 16; ++j) {
      if (kbase + j < K) {
        if constexpr (sizeof(T) == 2) tmp[j] = (short)ap[j];
        else tmp[j] = (short)f2bf(ap[j]);
      } else tmp[j] = 0;
    }
  } else {
#pragma unroll
    for (int j = 0; j < 16; ++j) tmp[j] = 0;
  }
}

// ---------------- runtime dtype detection ----------------
__global__ __launch_bounds__(256) void detect_dtype(const unsigned int* __restrict__ w,
                                                    int* __restrict__ flag) {
  __shared__ int cnt[256];
  int c = 0;
  for (int i = threadIdx.x; i < 2048; i += 256) {
    unsigned int e = (w[i] >> 8) & 0x7F;
    c += (e >= 60 && e <= 64) ? 1 : 0;
  }
  cnt[threadIdx.x] = c;
  __syncthreads();
  for (int s = 128; s; s >>= 1) {
    if (threadIdx.x < s) cnt[threadIdx.x] += cnt[threadIdx.x + s];
    __syncthreads();
  }
  if (threadIdx.x == 0) *flag = (cnt[0] >= 1024) ? 1 : 0;
}

// ---------------- batched conversion to f32 ----------------
struct CvtJob { const void* s; float* d; int n; int pad; };
struct CvtJobs32 { CvtJob j[32]; };

__global__ __launch_bounds__(256) void cvt_any(CvtJobs32 jobs, const int* __restrict__ flag) {
  CvtJob job = jobs.j[blockIdx.y];
  int isbf = *flag;
  if (isbf) {
    const unsigned short* s = (const unsigned short*)job.s;
    for (int i = blockIdx.x * 256 + threadIdx.x; i < job.n; i += gridDim.x * 256)
      job.d[i] = bf2f(s[i]);
  } else {
    const float* s = (const float*)job.s;
    for (int i = blockIdx.x * 256 + threadIdx.x; i < job.n; i += gridDim.x * 256)
      job.d[i] = s[i];
  }
}

// ---------------- weight transpose+cvt ----------------
struct TJob { const float* s; unsigned short* d; int K; int N; };
struct TJobs12 { TJob j[12]; };

__global__ __launch_bounds__(256) void transpose_bf16(TJobs12 jobs) {
  TJob job = jobs.j[blockIdx.y];
  int total = job.K * job.N;
  for (int idx = blockIdx.x * 256 + threadIdx.x; idx < total; idx += gridDim.x * 256) {
    int n = idx / job.K, k = idx - n * job.K;
    job.d[idx] = f2bf(job.s[(size_t)k * job.N + n]);
  }
}

// ---------------- CSR build ----------------
__global__ __launch_bounds__(256) void hist_kernel(const int* __restrict__ dst,
                                                   int* __restrict__ cnt, int M) {
  int e = blockIdx.x * 256 + threadIdx.x;
  if (e < M) atomicAdd(&cnt[dst[e]], 1);
}

#define SCHUNK 2048
__global__ __launch_bounds__(256) void scan1_kernel(const int* __restrict__ cnt,
                                                    int* __restrict__ incl,
                                                    int* __restrict__ bsum, int n) {
  __shared__ int lds[256];
  int b = blockIdx.x, tid = threadIdx.x;
  int base = b * SCHUNK + tid * 8;
  int v[8], s = 0;
#pragma unroll
  for (int j = 0; j < 8; ++j) { int i = base + j; v[j] = (i < n) ? cnt[i] : 0; s += v[j]; }
  lds[tid] = s;
  __syncthreads();
  for (int o = 1; o < 256; o <<= 1) {
    int t = (tid >= o) ? lds[tid - o] : 0;
    __syncthreads();
    lds[tid] += t;
    __syncthreads();
  }
  int run = lds[tid] - s;
#pragma unroll
  for (int j = 0; j < 8; ++j) {
    run += v[j];
    int i = base + j;
    if (i < n) incl[i] = run;
  }
  if (tid == 255) bsum[b] = lds[255];
}

__global__ void scan2_kernel(int* __restrict__ bsum, int nb) {
  if (threadIdx.x == 0 && blockIdx.x == 0) {
    int run = 0;
    for (int i = 0; i < nb; ++i) { int t = bsum[i]; bsum[i] = run; run += t; }
  }
}

__global__ __launch_bounds__(256) void scan3_kernel(const int* __restrict__ incl,
                                                    const int* __restrict__ cnt,
                                                    const int* __restrict__ bsum,
                                                    int* __restrict__ offA,
                                                    int* __restrict__ cur, int n) {
  int i = blockIdx.x * 256 + threadIdx.x;
  if (i >= n) return;
  int o = incl[i] - cnt[i] + bsum[i / SCHUNK];
  offA[i] = o;
  cur[i] = o;
}

__global__ __launch_bounds__(256) void fill_kernel(const int* __restrict__ dst,
                                                   int* __restrict__ cur,
                                                   int* __restrict__ elist, int M) {
  int e = blockIdx.x * 256 + threadIdx.x;
  if (e >= M) return;
  int pos = atomicAdd(&cur[dst[e]], 1);
  elist[pos] = e;
}

// ---------------- layer-1 fused aggregation (no-max softmax, unroll x2) ----------------
__global__ __launch_bounds__(256) void l1_agg(
    const float* __restrict__ Xe, const unsigned short* __restrict__ xa,
    const float* __restrict__ pe1w_e, const float* __restrict__ pe1b,
    const float* __restrict__ pe2w_e, const float* __restrict__ pe2b,
    const float* __restrict__ alpha, const int* __restrict__ srcA,
    const int* __restrict__ offA, const int* __restrict__ cntA, const int* __restrict__ elist,
    unsigned short* __restrict__ S, float* __restrict__ ssumOut, int N)
{
  int v = (blockIdx.x * 256 + threadIdx.x) >> 6;
  int lane = threadIdx.x & 63;
  if (v >= N) return;
  int begin = offA[v], cnt = cntA[v];
  int k0 = lane, k1 = lane + 64, k2 = lane + 128;
  bool v3 = lane < 8;
  int k3 = v3 ? lane + 192 : 0;
  float b0 = pe1b[k0], b1 = pe1b[k1], b2 = pe1b[k2], b3 = pe1b[k3];
  float p0 = pe2w_e[k0], p1 = pe2w_e[k1], p2 = pe2w_e[k2];
  float p3 = v3 ? pe2w_e[k3] : 0.f;
  float pw0[EE], pw1[EE], pw2[EE], pw3[EE];
#pragma unroll
  for (int j = 0; j < EE; ++j) {
    pw0[j] = pe1w_e[j * GG + k0];
    pw1[j] = pe1w_e[j * GG + k1];
    pw2[j] = pe1w_e[j * GG + k2];
    pw3[j] = pe1w_e[j * GG + k3];
  }
  float alv = alpha[v] + pe2b[0];
  float ss = 0.f;
  float a0 = 0.f, a1 = 0.f, a2 = 0.f, a3 = 0.f;
  int t = 0;
  for (; t + 2 <= cnt; t += 2) {
    int e0 = elist[begin + t], e1 = elist[begin + t + 1];
    int s0 = srcA[e0], s1 = srcA[e1];
    const float* xp0 = Xe + (size_t)e0 * EE;
    const float* xp1 = Xe + (size_t)e1 * EE;
    const unsigned short* g0 = xa + (size_t)s0 * GG;
    const unsigned short* g1 = xa + (size_t)s1 * GG;
    float h00 = bf2f(g0[k0]) + b0, h01 = bf2f(g0[k1]) + b1;
    float h02 = bf2f(g0[k2]) + b2, h03 = bf2f(g0[k3]) + b3;
    float h10 = bf2f(g1[k0]) + b0, h11 = bf2f(g1[k1]) + b1;
    float h12 = bf2f(g1[k2]) + b2, h13 = bf2f(g1[k3]) + b3;
#pragma unroll
    for (int j = 0; j < EE; ++j) {
      float x0 = xp0[j], x1 = xp1[j];
      h00 += x0 * pw0[j]; h01 += x0 * pw1[j]; h02 += x0 * pw2[j]; h03 += x0 * pw3[j];
      h10 += x1 * pw0[j]; h11 += x1 * pw1[j]; h12 += x1 * pw2[j]; h13 += x1 * pw3[j];
    }
    h00 = leakyf(h00); h01 = leakyf(h01); h02 = leakyf(h02); h03 = leakyf(h03);
    h10 = leakyf(h10); h11 = leakyf(h11); h12 = leakyf(h12); h13 = leakyf(h13);
    float bp0 = h00 * p0 + h01 * p1 + h02 * p2 + h03 * p3;
    float bp1 = h10 * p0 + h11 * p1 + h12 * p2 + h13 * p3;
#pragma unroll
    for (int o = 32; o; o >>= 1) {
      bp0 += __shfl_down(bp0, o);
      bp1 += __shfl_down(bp1, o);
    }
    bp0 = __shfl(bp0, 0);
    bp1 = __shfl(bp1, 0);
    float w0 = expf(fminf(leakyf(alv + bp0), 60.f));
    float w1 = expf(fminf(leakyf(alv + bp1), 60.f));
    ss += w0 + w1;
    a0 += w0 * h00 + w1 * h10;
    a1 += w0 * h01 + w1 * h11;
    a2 += w0 * h02 + w1 * h12;
    a3 += w0 * h03 + w1 * h13;
  }
  if (t < cnt) {
    int e0 = elist[begin + t];
    int s0 = srcA[e0];
    const float* xp0 = Xe + (size_t)e0 * EE;
    const unsigned short* g0 = xa + (size_t)s0 * GG;
    float h00 = bf2f(g0[k0]) + b0, h01 = bf2f(g0[k1]) + b1;
    float h02 = bf2f(g0[k2]) + b2, h03 = bf2f(g0[k3]) + b3;
#pragma unroll
    for (int j = 0; j < EE; ++j) {
      float x0 = xp0[j];
      h00 += x0 * pw0[j]; h01 += x0 * pw1[j]; h02 += x0 * pw2[j]; h03 += x0 * pw3[j];
    }
    h00 = leakyf(h00); h01 = leakyf(h01); h02 = leakyf(h02); h03 = leakyf(h03);
    float bp0 = h00 * p0 + h01 * p1 + h02 * p2 + h03 * p3;
#pragma unroll
    for (int o = 32; o; o >>= 1) bp0 += __shfl_down(bp0, o);
    bp0 = __shfl(bp0, 0);
    float w0 = expf(fminf(leakyf(alv + bp0), 60.f));
    ss += w0;
    a0 += w0 * h00; a1 += w0 * h01; a2 += w0 * h02; a3 += w0 * h03;
  }
  float inv = (cnt > 0) ? 1.f / ss : 0.f;
  unsigned short* sp = S + (size_t)v * GG;
  sp[k0] = f2bf(a0 * inv); sp[k1] = f2bf(a1 * inv); sp[k2] = f2bf(a2 * inv);
  if (v3) sp[k3] = f2bf(a3 * inv);
  if (lane == 0) ssumOut[v] = (cnt > 0) ? ss : 0.f;
}

// ---------------- layer-2 fused aggregation (no-max softmax, unroll x4) ----------------
__global__ __launch_bounds__(256) void l2_agg(
    const unsigned short* __restrict__ hvp, const float* __restrict__ gd,
    const float* __restrict__ gs, const float* __restrict__ lpeb,
    const int* __restrict__ srcA,
    const int* __restrict__ offA, const int* __restrict__ cntA, const int* __restrict__ elist,
    unsigned short* __restrict__ S2, int N)
{
  int v = (blockIdx.x * 256 + threadIdx.x) >> 6;
  int lane = threadIdx.x & 63;
  if (v >= N) return;
  int begin = offA[v], cnt = cntA[v];
  int k0 = lane, k1 = lane + 64, k2 = lane + 128;
  bool v3 = lane < 8;
  int k3 = v3 ? lane + 192 : 0;
  float gdv = gd[v] + lpeb[0];
  float ss = 0.f;
  float a0 = 0.f, a1 = 0.f, a2 = 0.f, a3 = 0.f;
  int t = 0;
  for (; t + 4 <= cnt; t += 4) {
    int e0 = elist[begin + t],     e1 = elist[begin + t + 1];
    int e2 = elist[begin + t + 2], e3 = elist[begin + t + 3];
    int s0 = srcA[e0], s1 = srcA[e1], s2 = srcA[e2], s3 = srcA[e3];
    float w0 = expf(fminf(leakyf(gdv + gs[s0]), 60.f));
    float w1 = expf(fminf(leakyf(gdv + gs[s1]), 60.f));
    float w2 = expf(fminf(leakyf(gdv + gs[s2]), 60.f));
    float w3 = expf(fminf(leakyf(gdv + gs[s3]), 60.f));
    const unsigned short* hp0 = hvp + (size_t)s0 * GG;
    const unsigned short* hp1 = hvp + (size_t)s1 * GG;
    const unsigned short* hp2 = hvp + (size_t)s2 * GG;
    const unsigned short* hp3 = hvp + (size_t)s3 * GG;
    ss += w0 + w1 + w2 + w3;
    a0 += w0 * bf2f(hp0[k0]) + w1 * bf2f(hp1[k0]) + w2 * bf2f(hp2[k0]) + w3 * bf2f(hp3[k0]);
    a1 += w0 * bf2f(hp0[k1]) + w1 * bf2f(hp1[k1]) + w2 * bf2f(hp2[k1]) + w3 * bf2f(hp3[k1]);
    a2 += w0 * bf2f(hp0[k2]) + w1 * bf2f(hp1[k2]) + w2 * bf2f(hp2[k2]) + w3 * bf2f(hp3[k2]);
    a3 += w0 * bf2f(hp0[k3]) + w1 * bf2f(hp1[k3]) + w2 * bf2f(hp2[k3]) + w3 * bf2f(hp3[k3]);
  }
  for (; t < cnt; ++t) {
    int e = elist[begin + t];
    int s = srcA[e];
    float w = expf(fminf(leakyf(gdv + gs[s]), 60.f));
    const unsigned short* hp = hvp + (size_t)s * GG;
    ss += w;
    a0 += w * bf2f(hp[k0]); a1 += w * bf2f(hp[k1]);
    a2 += w * bf2f(hp[k2]); a3 += w * bf2f(hp[k3]);
  }
  float inv = (cnt > 0) ? 1.f / ss : 0.f;
  unsigned short* sp = S2 + (size_t)v * GG;
  sp[k0] = f2bf((cnt > 0) ? eluf(a0 * inv) : 0.f);
  sp[k1] = f2bf((cnt > 0) ? eluf(a1 * inv) : 0.f);
  sp[k2] = f2bf((cnt > 0) ? eluf(a2 * inv) : 0.f);
  if (v3) sp[k3] = f2bf((cnt > 0) ? eluf(a3 * inv) : 0.f);
}

// ================= MFMA GEMM: Cb = act(mask(A@W + b)) (bf16 out) =================
template <typename TA>
__global__ __launch_bounds__(256) void mfma_gemm(
    const TA* __restrict__ A, const unsigned short* __restrict__ Wt,
    const float* __restrict__ bias, const float* __restrict__ rowmask,
    unsigned short* __restrict__ Cb, int Mr, int Nc, int K, int act)
{
  __shared__ __attribute__((aligned(16))) short As[128 * 32];
  __shared__ __attribute__((aligned(16))) short Bs[64 * 32];
  int ncol = (Nc + 63) >> 6;
  int nrowt = (Mr + 127) >> 7;
  int per = 8 * ncol;
  int grp = blockIdx.x / per, rem = blockIdx.x % per;
  int rowt = grp * 8 + (rem & 7), colt = rem >> 3;
  if (rowt >= nrowt) return;
  int row0 = rowt * 128, col0 = colt * 64;
  int tid = threadIdx.x;
  int w = tid >> 6, lane = tid & 63, quad = lane >> 4, l15 = lane & 15;

  f32x4 zero4 = {0.f, 0.f, 0.f, 0.f};
  f32x4 acc[2][4];
#pragma unroll
  for (int r = 0; r < 2; ++r)
#pragma unroll
    for (int c = 0; c < 4; ++c) acc[r][c] = zero4;

  for (int k0 = 0; k0 < K; k0 += 32) {
    {
      int row = tid >> 1, half = tid & 1;
      int r = row0 + row;
      short tmp[16];
      stage16<TA>(A + (size_t)r * K + k0 + half * 16, k0 + half * 16, K, r < Mr, tmp);
      *(bf16x8*)&As[sw(row, 2 * half)]     = *(bf16x8*)&tmp[0];
      *(bf16x8*)&As[sw(row, 2 * half + 1)] = *(bf16x8*)&tmp[8];
    }
    {
      int col = tid & 63, seg = tid >> 6;
      int n = col0 + col, k = k0 + seg * 8;
      short t8[8];
      const unsigned short* wp = Wt + (size_t)n * K + k;
      if (n < Nc && k + 8 <= K) {
        *(bf16x8*)&t8[0] = *(const bf16x8*)wp;
      } else {
#pragma unroll
        for (int j = 0; j < 8; ++j)
          t8[j] = (n < Nc && k + j < K) ? (short)wp[j] : (short)0;
      }
      *(bf16x8*)&Bs[sw(col, seg)] = *(bf16x8*)&t8[0];
    }
    __syncthreads();
    bf16x8 a[2], b[4];
#pragma unroll
    for (int r = 0; r < 2; ++r)
      a[r] = *(const bf16x8*)&As[sw(w * 32 + r * 16 + l15, quad)];
#pragma unroll
    for (int c = 0; c < 4; ++c)
      b[c] = *(const bf16x8*)&Bs[sw(c * 16 + l15, quad)];
#pragma unroll
    for (int r = 0; r < 2; ++r)
#pragma unroll
      for (int c = 0; c < 4; ++c)
        acc[r][c] = __builtin_amdgcn_mfma_f32_16x16x32_bf16(a[r], b[c], acc[r][c], 0, 0, 0);
    __syncthreads();
  }
#pragma unroll
  for (int r = 0; r < 2; ++r) {
#pragma unroll
    for (int c = 0; c < 4; ++c) {
      int col = col0 + c * 16 + l15;
      if (col >= Nc) continue;
#pragma unroll
      for (int i = 0; i < 4; ++i) {
        int row = row0 + w * 32 + r * 16 + quad * 4 + i;
        if (row >= Mr) continue;
        bool valid = (rowmask == nullptr) || (rowmask[row] > 0.f);
        float v = valid ? (acc[r][c][i] + (bias ? bias[col] : 0.f)) : 0.f;
        if (act == 1) v = leakyf(v);
        else if (act == 2) v = eluf(v);
        Cb[(size_t)row * Nc + col] = f2bf(v);
      }
    }
  }
}

// ================= fused MFMA GRU =================
template <typename TI, typename TO>
__global__ __launch_bounds__(256) void mfma_gru(
    const TI* __restrict__ X, const TI* __restrict__ H,
    const unsigned short* __restrict__ WtIH, const unsigned short* __restrict__ WtHH,
    const float* __restrict__ bih, const float* __restrict__ bhh,
    TO* __restrict__ Out, int R, int relu_out)
{
  __shared__ __attribute__((aligned(16))) short Xs[128 * 32];
  __shared__ __attribute__((aligned(16))) short Hs[128 * 32];
  __shared__ __attribute__((aligned(16))) short Ws[192 * 32];
  int nrowt = (R + 127) >> 7;
  int grp = blockIdx.x / 56, rem = blockIdx.x % 56;
  int rowt = grp * 8 + (rem & 7), colt = rem >> 3;
  if (rowt >= nrowt) return;
  int row0 = rowt * 128, col0 = colt * 32;
  int tid = threadIdx.x;
  int w = tid >> 6, lane = tid & 63, quad = lane >> 4, l15 = lane & 15;

  f32x4 zero4 = {0.f, 0.f, 0.f, 0.f};
  f32x4 acc[6][2][2];
#pragma unroll
  for (int g = 0; g < 6; ++g)
#pragma unroll
    for (int r = 0; r < 2; ++r)
#pragma unroll
      for (int c = 0; c < 2; ++c) acc[g][r][c] = zero4;

  for (int k0 = 0; k0 < GG; k0 += 32) {
    {
      int row = tid >> 1, half = tid & 1;
      int r = row0 + row;
      short tx[16], th[16];
      stage16<TI>(X + (size_t)r * GG + k0 + half * 16, k0 + half * 16, GG, r < R, tx);
      stage16<TI>(H + (size_t)r * GG + k0 + half * 16, k0 + half * 16, GG, r < R, th);
      *(bf16x8*)&Xs[sw(row, 2 * half)]     = *(bf16x8*)&tx[0];
      *(bf16x8*)&Xs[sw(row, 2 * half + 1)] = *(bf16x8*)&tx[8];
      *(bf16x8*)&Hs[sw(row, 2 * half)]     = *(bf16x8*)&th[0];
      *(bf16x8*)&Hs[sw(row, 2 * half + 1)] = *(bf16x8*)&th[8];
    }
    for (int task = tid; task < 768; task += 256) {
      int rw = task >> 2, seg = task & 3;
      int g = rw >> 5, cc = rw & 31;
      int n = col0 + cc, k = k0 + seg * 8;
      const unsigned short* wp = (g < 3)
          ? WtIH + (size_t)(g * GG + n) * GG + k
          : WtHH + (size_t)((g - 3) * GG + n) * GG + k;
      short t8[8];
      if (n < GG && k + 8 <= GG) {
        *(bf16x8*)&t8[0] = *(const bf16x8*)wp;
      } else {
#pragma unroll
        for (int j = 0; j < 8; ++j)
          t8[j] = (n < GG && k + j < GG) ? (short)wp[j] : (short)0;
      }
      *(bf16x8*)&Ws[sw(rw, seg)] = *(bf16x8*)&t8[0];
    }
    __syncthreads();
    bf16x8 ax[2], ah[2];
#pragma unroll
    for (int r = 0; r < 2; ++r) {
      ax[r] = *(const bf16x8*)&Xs[sw(w * 32 + r * 16 + l15, quad)];
      ah[r] = *(const bf16x8*)&Hs[sw(w * 32 + r * 16 + l15, quad)];
    }
#pragma unroll
    for (int g = 0; g < 6; ++g) {
      bf16x8 b[2];
#pragma unroll
      for (int c = 0; c < 2; ++c)
        b[c] = *(const bf16x8*)&Ws[sw(g * 32 + c * 16 + l15, quad)];
#pragma unroll
      for (int r = 0; r < 2; ++r)
#pragma unroll
        for (int c = 0; c < 2; ++c)
          acc[g][r][c] = __builtin_amdgcn_mfma_f32_16x16x32_bf16(
              (g < 3) ? ax[r] : ah[r], b[c], acc[g][r][c], 0, 0, 0);
    }
    __syncthreads();
  }
#pragma unroll
  for (int r = 0; r < 2; ++r) {
#pragma unroll
    for (int c = 0; c < 2; ++c) {
      int col = col0 + c * 16 + l15;
      if (col >= GG) continue;
      float br = bih[col],       bhr = bhh[col];
      float bz = bih[200 + col], bhz = bhh[200 + col];
      float bn = bih[400 + col], bhn = bhh[400 + col];
#pragma unroll
      for (int i = 0; i < 4; ++i) {
        int row = row0 + w * 32 + r * 16 + quad * 4 + i;
        if (row >= R) continue;
        float rr = sigmf(acc[0][r][c][i] + br + acc[3][r][c][i] + bhr);
        float zz = sigmf(acc[1][r][c][i] + bz + acc[4][r][c][i] + bhz);
        float nn = tanhf(acc[2][r][c][i] + bn + rr * (acc[5][r][c][i] + bhn));
        float hval = ldv<TI>(H + (size_t)row * GG + col);
        float o = (1.f - zz) * nn + zz * hval;
        if (relu_out) o = fmaxf(o, 0.f);
        if constexpr (sizeof(TO) == 2) Out[(size_t)row * GG + col] = f2bf(o);
        else Out[(size_t)row * GG + col] = o;
      }
    }
  }
}

// ---------------- fp32 tiled GEMM (small readout shapes) ----------------
#define Bb 64
#define Bn 64
#define Bk 16
__global__ __launch_bounds__(256) void gemm_kernel(
    const float* __restrict__ A, const float* __restrict__ W,
    const float* __restrict__ bias, const float* __restrict__ rowmask,
    float* __restrict__ Cf, void* __restrict__ Oout, const int* __restrict__ oflag,
    int Mr, int Nc, int K, int act)
{
  __shared__ float As[Bk][Bb + 1];
  __shared__ float Ws[Bk][Bn];
  int row0 = blockIdx.x * Bb, col0 = blockIdx.y * Bn;
  int tid = threadIdx.x;
  int ty = tid >> 4, tx = tid & 15;
  float acc[4][4] = {};
  for (int k0 = 0; k0 < K; k0 += Bk) {
    for (int l = tid; l < Bb * Bk; l += 256) {
      int m = l >> 4, kk = l & 15;
      int r = row0 + m, k = k0 + kk;
      As[kk][m] = (r < Mr && k < K) ? A[(size_t)r * K + k] : 0.f;
    }
    for (int l = tid; l < Bk * Bn; l += 256) {
      int kk = l >> 6, nn = l & 63;
      int k = k0 + kk, c = col0 + nn;
      Ws[kk][nn] = (k < K && c < Nc) ? W[(size_t)k * Nc + c] : 0.f;
    }
    __syncthreads();
#pragma unroll
    for (int kk = 0; kk < Bk; ++kk) {
      float av[4], bv[4];
#pragma unroll
      for (int i = 0; i < 4; ++i) av[i] = As[kk][ty * 4 + i];
#pragma unroll
      for (int j = 0; j < 4; ++j) bv[j] = Ws[kk][tx * 4 + j];
#pragma unroll
      for (int i = 0; i < 4; ++i)
#pragma unroll
        for (int j = 0; j < 4; ++j) acc[i][j] += av[i] * bv[j];
    }
    __syncthreads();
  }
  int isbf = (oflag != nullptr) ? *oflag : 0;
#pragma unroll
  for (int i = 0; i < 4; ++i) {
    int r = row0 + ty * 4 + i;
    if (r >= Mr) continue;
    bool valid = (rowmask == nullptr) || (rowmask[r] > 0.f);
#pragma unroll
    for (int j = 0; j < 4; ++j) {
      int c = col0 + tx * 4 + j;
      if (c >= Nc) continue;
      float v = valid ? (acc[i][j] + (bias ? bias[c] : 0.f)) : 0.f;
      if (act == 1) v = leakyf(v);
      else if (act == 2) v = eluf(v);
      else if (act == 3) v = fmaxf(v, 0.f);
      size_t idx = (size_t)r * Nc + c;
      if (Oout) {
        if (isbf) ((__hip_bfloat16*)Oout)[idx] = __float2bfloat16(v);
        else      ((float*)Oout)[idx] = v;
      } else {
        Cf[idx] = v;
      }
    }
  }
}

// ---------------- per-node dot(s), bf16 input ----------------
__global__ __launch_bounds__(256) void node_dot2(
    const unsigned short* __restrict__ X, const float* __restrict__ w1,
    const float* __restrict__ w2,
    float* __restrict__ o1, float* __restrict__ o2, int N)
{
  int v = (blockIdx.x * 256 + threadIdx.x) >> 6;
  int lane = threadIdx.x & 63;
  if (v >= N) return;
  float d1 = 0.f, d2 = 0.f;
  for (int k = lane; k < GG; k += 64) {
    float x = bf2f(X[(size_t)v * GG + k]);
    d1 += x * w1[k];
    if (w2) d2 += x * w2[k];
  }
  for (int off = 32; off; off >>= 1) {
    d1 += __shfl_down(d1, off);
    if (w2) d2 += __shfl_down(d2, off);
  }
  if (lane == 0) { o1[v] = d1; if (w2) o2[v] = d2; }
}

__global__ __launch_bounds__(256) void graph_sum(
    const unsigned short* __restrict__ h, float* __restrict__ g)
{
  int b = blockIdx.x, k = threadIdx.x;
  if (k < GG) {
    float a = 0.f;
    for (int i = 0; i < 50; ++i) a += bf2f(h[((size_t)b * 50 + i) * GG + k]);
    g[(size_t)b * GG + k] = a;
  }
}

__global__ __launch_bounds__(256) void attn_kernel(
    const float* __restrict__ g, const unsigned short* __restrict__ h2,
    const float* __restrict__ w1, const float* __restrict__ dh,
    const float* __restrict__ rb, float* __restrict__ weighted)
{
  int b = blockIdx.x;
  __shared__ float red[256];
  __shared__ float zs[50];
  __shared__ float as_[50];
  __shared__ float dgs;
  int tid = threadIdx.x;
  float p = 0.f;
  if (tid < GG) p = fmaxf(g[(size_t)b * GG + tid], 0.f) * w1[tid];
  red[tid] = p;
  __syncthreads();
  for (int s = 128; s; s >>= 1) { if (tid < s) red[tid] += red[tid + s]; __syncthreads(); }
  if (tid == 0) dgs = red[0];
  __syncthreads();
  if (tid < 50) zs[tid] = leakyf(dgs + dh[b * 50 + tid] + rb[0]);
  __syncthreads();
  if (tid == 0) {
    float m = -1e30f;
    for (int i = 0; i < 50; ++i) m = fmaxf(m, zs[i]);
    float s = 0.f;
    for (int i = 0; i < 50; ++i) { float e = expf(zs[i] - m); as_[i] = e; s += e; }
    float inv = 1.f / s;
    for (int i = 0; i < 50; ++i) as_[i] *= inv;
  }
  __syncthreads();
  if (tid < GG) {
    float a = 0.f;
    for (int i = 0; i < 50; ++i) a += as_[i] * bf2f(h2[((size_t)b * 50 + i) * GG + tid]);
    weighted[(size_t)b * GG + tid] = a;
  }
}

// ---------------- host ----------------
static inline int gemm_grid(int Mr, int Nc) {
  int nrow = (Mr + 127) / 128, ncol = (Nc + 63) / 64;
  return ((nrow + 7) / 8) * 8 * ncol;
}
static inline int gru_grid(int R) {
  int nrow = (R + 127) / 128;
  return ((nrow + 7) / 8) * 56;
}

extern "C" void kernel_launch(void* const* d_in, const int* in_sizes, int n_in,
                              void* d_out, int out_size, void* d_ws, size_t ws_size,
                              hipStream_t stream)
{
  (void)n_in; (void)out_size; (void)ws_size;
  const int N = NN, M = MM, B = BB, F = FF, G = GG, P = PP;
  float* ws = (float*)d_ws;
  size_t off = 0;
  auto alloc = [&](size_t n) { size_t o = off; off += (n + 63) & ~(size_t)63; return o; };

  size_t o_flag = alloc(16);
  size_t o_pn_w = alloc(F * G), o_pn_b = alloc(G);
  size_t o_pe1_w = alloc((F + EE) * G), o_pe1_b = alloc(G);
  size_t o_pe2_w = alloc(2 * G), o_pe2_b = alloc(1);
  size_t o_et_w = alloc(G * G), o_et_b = alloc(G);
  size_t o_g0_wih = alloc(G * 3 * G), o_g0_whh = alloc(G * 3 * G);
  size_t o_g0_bih = alloc(3 * G), o_g0_bhh = alloc(3 * G);
  size_t o_lpe_w = alloc(2 * G), o_lpe_b = alloc(1);
  size_t o_lpn_w = alloc(G * G), o_lpn_b = alloc(G);
  size_t o_g1_wih = alloc(G * 3 * G), o_g1_whh = alloc(G * 3 * G);
  size_t o_g1_bih = alloc(3 * G), o_g1_bhh = alloc(3 * G);
  size_t o_rl_w = alloc(2 * 2 * G), o_rl_b = alloc(2);
  size_t o_rp_w = alloc(2 * G * G), o_rp_b = alloc(2 * G);
  size_t o_rg_wih = alloc(2 * G * 3 * G), o_rg_whh = alloc(2 * G * 3 * G);
  size_t o_rg_bih = alloc(2 * 3 * G), o_rg_bhh = alloc(2 * 3 * G);
  size_t o_t_w = alloc(G * P), o_t_b = alloc(P);
  size_t o_Xn = alloc((size_t)N * F);
  size_t o_Xe = alloc((size_t)M * EE);
  size_t o_B1 = alloc((size_t)N * G);  // used as bf16 (half occupancy)
  size_t o_B2 = alloc((size_t)N * G);
  size_t o_B3 = alloc((size_t)N * G);
  size_t o_alpha = alloc(N), o_ssum = alloc(N);
  size_t o_gd = alloc(N), o_gs = alloc(N), o_dh = alloc(N);
  size_t o_gv0 = alloc((size_t)B * G), o_gwt = alloc((size_t)B * G), o_grep = alloc((size_t)B * G);
  size_t o_gv1 = alloc((size_t)B * G), o_gv2 = alloc((size_t)B * G);
  size_t o_etT  = alloc(G * G / 2), o_lpnT = alloc(G * G / 2);
  size_t o_g0ihT = alloc(G * 3 * G / 2), o_g0hhT = alloc(G * 3 * G / 2);
  size_t o_g1ihT = alloc(G * 3 * G / 2), o_g1hhT = alloc(G * 3 * G / 2);
  size_t o_rg0ihT = alloc(G * 3 * G / 2), o_rg0hhT = alloc(G * 3 * G / 2);
  size_t o_rg1ihT = alloc(G * 3 * G / 2), o_rg1hhT = alloc(G * 3 * G / 2);
  size_t o_pnT = alloc(G * F / 2 + 64), o_pe1T = alloc(G * F / 2 + 64);
  size_t o_cnt = alloc(N), o_off = alloc(N), o_cur = alloc(N);
  size_t o_elist = alloc(M), o_bsum = alloc(64), o_incl = alloc(N);

  int* flag = (int*)(ws + o_flag);
  int* cntA = (int*)(ws + o_cnt);
  int* offA = (int*)(ws + o_off);
  int* curA = (int*)(ws + o_cur);
  int* elist = (int*)(ws + o_elist);
  int* bsum = (int*)(ws + o_bsum);
  int* incl = (int*)(ws + o_incl);
  unsigned short* B1b = (unsigned short*)(ws + o_B1);
  unsigned short* B2b = (unsigned short*)(ws + o_B2);
  unsigned short* B3b = (unsigned short*)(ws + o_B3);

  CvtJobs32 jobs;
  int ji = 0;
  auto push = [&](int idx, size_t dsto) {
    jobs.j[ji].s = d_in[idx];
    jobs.j[ji].d = ws + dsto;
    jobs.j[ji].n = in_sizes[idx];
    jobs.j[ji].pad = 0;
    ++ji;
  };
  push(0, o_Xn);
  push(1, o_Xe);
  push(2, o_pn_w);  push(3, o_pn_b);
  push(4, o_pe1_w); push(5, o_pe1_b);
  push(6, o_pe2_w); push(7, o_pe2_b);
  push(8, o_et_w);  push(9, o_et_b);
  push(10, o_g0_wih); push(11, o_g0_whh); push(12, o_g0_bih); push(13, o_g0_bhh);
  push(14, o_lpe_w);  push(15, o_lpe_b);
  push(16, o_lpn_w);  push(17, o_lpn_b);
  push(18, o_g1_wih); push(19, o_g1_whh); push(20, o_g1_bih); push(21, o_g1_bhh);
  push(22, o_rl_w);   push(23, o_rl_b);
  push(24, o_rp_w);   push(25, o_rp_b);
  push(26, o_rg_wih); push(27, o_rg_whh); push(28, o_rg_bih); push(29, o_rg_bhh);
  push(30, o_t_w);    push(31, o_t_b);

  const int* src = (const int*)d_in[32];
  const int* dst = (const int*)d_in[33];

  dim3 blk(256);
  detect_dtype<<<dim3(1), blk, 0, stream>>>((const unsigned int*)d_in[0], flag);
  cvt_any<<<dim3(512, 32), blk, 0, stream>>>(jobs, flag);

  // ---- CSR build (by dst) ----
  hipMemsetAsync(cntA, 0, (size_t)N * 4, stream);
  hist_kernel<<<dim3((M + 255) / 256), blk, 0, stream>>>(dst, cntA, M);
  int nscb = (N + SCHUNK - 1) / SCHUNK;
  scan1_kernel<<<dim3(nscb), blk, 0, stream>>>(cntA, incl, bsum, N);
  scan2_kernel<<<dim3(1), dim3(64), 0, stream>>>(bsum, nscb);
  scan3_kernel<<<dim3((N + 255) / 256), blk, 0, stream>>>(incl, cntA, bsum, offA, curA, N);
  fill_kernel<<<dim3((M + 255) / 256), blk, 0, stream>>>(dst, curA, elist, M);

  // ---- weight transposes ----
  TJobs12 tj;
  auto tpush = [&](int slot, size_t srcO, size_t dstO, int K, int Nc) {
    tj.j[slot].s = ws + srcO;
    tj.j[slot].d = (unsigned short*)(ws + dstO);
    tj.j[slot].K = K; tj.j[slot].N = Nc;
  };
  tpush(0, o_et_w,  o_etT,  G, G);
  tpush(1, o_lpn_w, o_lpnT, G, G);
  tpush(2, o_g0_wih, o_g0ihT, G, 3 * G);
  tpush(3, o_g0_whh, o_g0hhT, G, 3 * G);
  tpush(4, o_g1_wih, o_g1ihT, G, 3 * G);
  tpush(5, o_g1_whh, o_g1hhT, G, 3 * G);
  tpush(6, o_rg_wih, o_rg0ihT, G, 3 * G);
  tpush(7, o_rg_whh, o_rg0hhT, G, 3 * G);
  tpush(8, o_rg_wih + (size_t)G * 3 * G, o_rg1ihT, G, 3 * G);
  tpush(9, o_rg_whh + (size_t)G * 3 * G, o_rg1hhT, G, 3 * G);
  tpush(10, o_pn_w,  o_pnT,  F, G);
  tpush(11, o_pe1_w, o_pe1T, F, G);
  transpose_bf16<<<dim3(128, 12), blk, 0, stream>>>(tj);

  dim3 gWave((N + 3) / 4);

  // hv_new = leaky(Xn@pn_w + pn_b) -> B1 bf16
  mfma_gemm<float><<<dim3(gemm_grid(N, G)), blk, 0, stream>>>(
      ws + o_Xn, (const unsigned short*)(ws + o_pnT), ws + o_pn_b, nullptr,
      B1b, N, G, F, 1);
  // xa = Xn @ pe1_w[:39] -> B2 bf16
  mfma_gemm<float><<<dim3(gemm_grid(N, G)), blk, 0, stream>>>(
      ws + o_Xn, (const unsigned short*)(ws + o_pe1T), nullptr, nullptr,
      B2b, N, G, F, 0);
  node_dot2<<<gWave, blk, 0, stream>>>(B1b, ws + o_pe2_w, nullptr,
                                       ws + o_alpha, nullptr, N);
  l1_agg<<<gWave, blk, 0, stream>>>(ws + o_Xe, B2b,
                                    ws + o_pe1_w + (size_t)F * G, ws + o_pe1_b,
                                    ws + o_pe2_w + G, ws + o_pe2_b, ws + o_alpha,
                                    src, offA, cntA, elist,
                                    B3b, ws + o_ssum, N);
  // c = elu(mask(B3@et_w + et_b)) -> B2 bf16
  mfma_gemm<unsigned short><<<dim3(gemm_grid(N, G)), blk, 0, stream>>>(
      B3b, (const unsigned short*)(ws + o_etT), ws + o_et_b, ws + o_ssum,
      B2b, N, G, G, 2);
  // h = relu(GRU0(x=B2, h=B1)) -> B3 bf16
  mfma_gru<unsigned short, unsigned short><<<dim3(gru_grid(N)), blk, 0, stream>>>(
      B2b, B1b,
      (const unsigned short*)(ws + o_g0ihT), (const unsigned short*)(ws + o_g0hhT),
      ws + o_g0_bih, ws + o_g0_bhh, B3b, N, 1);

  // ---- layer 2 ----
  node_dot2<<<gWave, blk, 0, stream>>>(B3b, ws + o_lpe_w, ws + o_lpe_w + G,
                                       ws + o_gd, ws + o_gs, N);
  // hv_proj = h@lpn_w + lpn_b -> B1 bf16
  mfma_gemm<unsigned short><<<dim3(gemm_grid(N, G)), blk, 0, stream>>>(
      B3b, (const unsigned short*)(ws + o_lpnT), ws + o_lpn_b, nullptr,
      B1b, N, G, G, 0);
  l2_agg<<<gWave, blk, 0, stream>>>(B1b, ws + o_gd, ws + o_gs, ws + o_lpe_b,
                                    src, offA, cntA, elist, B2b, N);
  // h2 = relu(GRU1(x=B2, h=B3)) -> B1 bf16
  mfma_gru<unsigned short, unsigned short><<<dim3(gru_grid(N)), blk, 0, stream>>>(
      B2b, B3b,
      (const unsigned short*)(ws + o_g1ihT), (const unsigned short*)(ws + o_g1hhT),
      ws + o_g1_bih, ws + o_g1_bhh, B1b, N, 1);

  // ---- readout ----
  graph_sum<<<dim3(B), blk, 0, stream>>>(B1b, ws + o_gv0);
  dim3 gBG((B + Bb - 1) / Bb, (G + Bn - 1) / Bn);
  size_t gcur = o_gv0, gnext = o_gv1;
  for (int t = 0; t < 2; ++t) {
    node_dot2<<<gWave, blk, 0, stream>>>(B1b, ws + o_rl_w + t * 2 * G + G,
                                         nullptr, ws + o_dh, nullptr, N);
    attn_kernel<<<dim3(B), blk, 0, stream>>>(ws + gcur, B1b, ws + o_rl_w + t * 2 * G,
                                             ws + o_dh, ws + o_rl_b + t, ws + o_gwt);
    gemm_kernel<<<gBG, blk, 0, stream>>>(ws + o_gwt, ws + o_rp_w + (size_t)t * G * G,
                                         ws + o_rp_b + t * G, nullptr,
                                         ws + o_grep, nullptr, nullptr, B, G, G, 2);
    mfma_gru<float, float><<<dim3(gru_grid(B)), blk, 0, stream>>>(
        ws + o_grep, ws + gcur,
        (const unsigned short*)(ws + (t == 0 ? o_rg0ihT : o_rg1ihT)),
        (const unsigned short*)(ws + (t == 0 ? o_rg0hhT : o_rg1hhT)),
        ws + o_rg_bih + t * 3 * G, ws + o_rg_bhh + t * 3 * G,
        ws + gnext, B, 0);
    gcur = gnext;
    gnext = o_gv2;
  }
  dim3 gOut((B + Bb - 1) / Bb, (P + Bn - 1) / Bn);
  gemm_kernel<<<gOut, blk, 0, stream>>>(ws + gcur, ws + o_t_w, ws + o_t_b, nullptr,
                                        nullptr, d_out, flag, B, P, G, 0);
}

// Round 7
// 996.854 us; speedup vs baseline: 4.0772x; 1.0539x over previous
//
#include <hip/hip_runtime.h>
#include <hip/hip_bf16.h>

// ---------------- constants ----------------
#define NN 50000
#define MM 400000
#define BB 1000
#define FF 39
#define EE 11
#define GG 200
#define PP 128

typedef __attribute__((ext_vector_type(8))) short bf16x8;
typedef __attribute__((ext_vector_type(4))) float f32x4;
struct us4 { unsigned short x, y, z, w; };

// ---------------- helpers ----------------
__device__ __forceinline__ float bf2f(unsigned short u) {
  return __uint_as_float(((unsigned int)u) << 16);
}
__device__ __forceinline__ unsigned short f2bf(float x) {
  union { __hip_bfloat16 b; unsigned short u; } v;
  v.b = __float2bfloat16(x);
  return v.u;
}
__device__ __forceinline__ float leakyf(float x) { return x > 0.f ? x : 0.01f * x; }
__device__ __forceinline__ float eluf(float x)   { return x > 0.f ? x : (expf(x) - 1.f); }
__device__ __forceinline__ float sigmf(float x)  { return 1.f / (1.f + expf(-x)); }
__device__ __forceinline__ int sw(int row, int seg) {
  return row * 32 + ((seg ^ ((row >> 1) & 3)) << 3);
}
template <typename T> __device__ __forceinline__ float ldv(const T* p);
template <> __device__ __forceinline__ float ldv<float>(const float* p) { return *p; }
template <> __device__ __forceinline__ float ldv<unsigned short>(const unsigned short* p) { return bf2f(*p); }

template <typename T>
__device__ __forceinline__ void stage16(const T* ap, int kbase, int K, bool rowok, short* tmp) {
  if (rowok && kbase + 16 <= K) {
    if constexpr (sizeof(T) == 2) {
      *(bf16x8*)&tmp[0] = *(const bf16x8*)(ap);
      *(bf16x8*)&tmp[8] = *(const bf16x8*)(ap + 8);
    } else {
#pragma unroll
      for (int j = 0; j < 16; ++j) tmp[j] = (short)f2bf(ap[j]);
    }
  } else if (rowok) {
#pragma unroll
    for (int j = 0; j < 16; ++j) {
      if (kbase + j < K) {
        if constexpr (sizeof(T) == 2) tmp[j] = (short)ap[j];
        else tmp[j] = (short)f2bf(ap[j]);
      } else tmp[j] = 0;
    }
  } else {
#pragma unroll
    for (int j = 0; j < 16; ++j) tmp[j] = 0;
  }
}

// ---------------- runtime dtype detection ----------------
__global__ __launch_bounds__(256) void detect_dtype(const unsigned int* __restrict__ w,
                                                    int* __restrict__ flag) {
  __shared__ int cnt[256];
  int c = 0;
  for (int i = threadIdx.x; i < 2048; i += 256) {
    unsigned int e = (w[i] >> 8) & 0x7F;
    c += (e >= 60 && e <= 64) ? 1 : 0;
  }
  cnt[threadIdx.x] = c;
  __syncthreads();
  for (int s = 128; s; s >>= 1) {
    if (threadIdx.x < s) cnt[threadIdx.x] += cnt[threadIdx.x + s];
    __syncthreads();
  }
  if (threadIdx.x == 0) *flag = (cnt[0] >= 1024) ? 1 : 0;
}

// ---------------- batched conversion to f32 ----------------
struct CvtJob { const void* s; float* d; int n; int pad; };
struct CvtJobs32 { CvtJob j[32]; };

__global__ __launch_bounds__(256) void cvt_any(CvtJobs32 jobs, const int* __restrict__ flag) {
  CvtJob job = jobs.j[blockIdx.y];
  int isbf = *flag;
  if (isbf) {
    const unsigned short* s = (const unsigned short*)job.s;
    for (int i = blockIdx.x * 256 + threadIdx.x; i < job.n; i += gridDim.x * 256)
      job.d[i] = bf2f(s[i]);
  } else {
    const float* s = (const float*)job.s;
    for (int i = blockIdx.x * 256 + threadIdx.x; i < job.n; i += gridDim.x * 256)
      job.d[i] = s[i];
  }
}

// ---------------- weight transpose+cvt ----------------
struct TJob { const float* s; unsigned short* d; int K; int N; };
struct TJobs12 { TJob j[12]; };

__global__ __launch_bounds__(256) void transpose_bf16(TJobs12 jobs) {
  TJob job = jobs.j[blockIdx.y];
  int total = job.K * job.N;
  for (int idx = blockIdx.x * 256 + threadIdx.x; idx < total; idx += gridDim.x * 256) {
    int n = idx / job.K, k = idx - n * job.K;
    job.d[idx] = f2bf(job.s[(size_t)k * job.N + n]);
  }
}

// ---------------- CSR build ----------------
__global__ __launch_bounds__(256) void hist_kernel(const int* __restrict__ dst,
                                                   int* __restrict__ cnt, int M) {
  int e = blockIdx.x * 256 + threadIdx.x;
  if (e < M) atomicAdd(&cnt[dst[e]], 1);
}

#define SCHUNK 2048
__global__ __launch_bounds__(256) void scan1_kernel(const int* __restrict__ cnt,
                                                    int* __restrict__ incl,
                                                    int* __restrict__ bsum, int n) {
  __shared__ int lds[256];
  int b = blockIdx.x, tid = threadIdx.x;
  int base = b * SCHUNK + tid * 8;
  int v[8], s = 0;
#pragma unroll
  for (int j = 0; j < 8; ++j) { int i = base + j; v[j] = (i < n) ? cnt[i] : 0; s += v[j]; }
  lds[tid] = s;
  __syncthreads();
  for (int o = 1; o < 256; o <<= 1) {
    int t = (tid >= o) ? lds[tid - o] : 0;
    __syncthreads();
    lds[tid] += t;
    __syncthreads();
  }
  int run = lds[tid] - s;
#pragma unroll
  for (int j = 0; j < 8; ++j) {
    run += v[j];
    int i = base + j;
    if (i < n) incl[i] = run;
  }
  if (tid == 255) bsum[b] = lds[255];
}

__global__ void scan2_kernel(int* __restrict__ bsum, int nb) {
  if (threadIdx.x == 0 && blockIdx.x == 0) {
    int run = 0;
    for (int i = 0; i < nb; ++i) { int t = bsum[i]; bsum[i] = run; run += t; }
  }
}

__global__ __launch_bounds__(256) void scan3_kernel(const int* __restrict__ incl,
                                                    const int* __restrict__ cnt,
                                                    const int* __restrict__ bsum,
                                                    int* __restrict__ offA,
                                                    int* __restrict__ cur, int n) {
  int i = blockIdx.x * 256 + threadIdx.x;
  if (i >= n) return;
  int o = incl[i] - cnt[i] + bsum[i / SCHUNK];
  offA[i] = o;
  cur[i] = o;
}

__global__ __launch_bounds__(256) void fill_kernel(const int* __restrict__ dst,
                                                   int* __restrict__ cur,
                                                   int* __restrict__ elist, int M) {
  int e = blockIdx.x * 256 + threadIdx.x;
  if (e >= M) return;
  int pos = atomicAdd(&cur[dst[e]], 1);
  elist[pos] = e;
}

// ---------------- layer-1 fused aggregation ----------------
// lane L<50 owns channels 4L..4L+3: one ushort4 gather per edge.
// e/s/Xe are wave-uniform -> readfirstlane -> scalar loads (SMEM pipe).
// alpha (hv_new . pe2w[:200]) computed inline from own row.
__global__ __launch_bounds__(256) void l1_agg(
    const float* __restrict__ Xe, const unsigned short* __restrict__ xa,
    const unsigned short* __restrict__ hvnew,
    const float* __restrict__ pe1w_e, const float* __restrict__ pe1b,
    const float* __restrict__ pe2w_n, const float* __restrict__ pe2w_e,
    const float* __restrict__ pe2b, const int* __restrict__ srcA,
    const int* __restrict__ offA, const int* __restrict__ cntA, const int* __restrict__ elist,
    unsigned short* __restrict__ S, float* __restrict__ ssumOut, int N)
{
  int v = (blockIdx.x * 256 + threadIdx.x) >> 6;
  int lane = threadIdx.x & 63;
  if (v >= N) return;
  int begin = offA[v], cnt = cntA[v];
  bool act = lane < 50;
  int kb = act ? 4 * lane : 0;
  float b[4], p[4], pn[4];
  float pw[EE][4];
#pragma unroll
  for (int j = 0; j < 4; ++j) {
    b[j]  = pe1b[kb + j];
    p[j]  = act ? pe2w_e[kb + j] : 0.f;
    pn[j] = act ? pe2w_n[kb + j] : 0.f;
  }
#pragma unroll
  for (int jj = 0; jj < EE; ++jj)
#pragma unroll
    for (int j = 0; j < 4; ++j) pw[jj][j] = pe1w_e[jj * GG + kb + j];

  // alpha = hv_new[v] . pe2w_n
  us4 hv = *(const us4*)(hvnew + (size_t)v * GG + kb);
  float da = bf2f(hv.x) * pn[0] + bf2f(hv.y) * pn[1] + bf2f(hv.z) * pn[2] + bf2f(hv.w) * pn[3];
#pragma unroll
  for (int o = 32; o; o >>= 1) da += __shfl_down(da, o);
  float alv = __shfl(da, 0) + pe2b[0];

  float ss = 0.f;
  float a0 = 0.f, a1 = 0.f, a2 = 0.f, a3 = 0.f;
  int t = 0;
  for (; t + 2 <= cnt; t += 2) {
    int e0 = __builtin_amdgcn_readfirstlane(elist[begin + t]);
    int e1 = __builtin_amdgcn_readfirstlane(elist[begin + t + 1]);
    int s0 = __builtin_amdgcn_readfirstlane(srcA[e0]);
    int s1 = __builtin_amdgcn_readfirstlane(srcA[e1]);
    us4 g0 = *(const us4*)(xa + (size_t)s0 * GG + kb);
    us4 g1 = *(const us4*)(xa + (size_t)s1 * GG + kb);
    const float* xp0 = Xe + (size_t)e0 * EE;
    const float* xp1 = Xe + (size_t)e1 * EE;
    float h00 = bf2f(g0.x) + b[0], h01 = bf2f(g0.y) + b[1];
    float h02 = bf2f(g0.z) + b[2], h03 = bf2f(g0.w) + b[3];
    float h10 = bf2f(g1.x) + b[0], h11 = bf2f(g1.y) + b[1];
    float h12 = bf2f(g1.z) + b[2], h13 = bf2f(g1.w) + b[3];
#pragma unroll
    for (int jj = 0; jj < EE; ++jj) {
      float x0 = xp0[jj], x1 = xp1[jj];
      h00 += x0 * pw[jj][0]; h01 += x0 * pw[jj][1];
      h02 += x0 * pw[jj][2]; h03 += x0 * pw[jj][3];
      h10 += x1 * pw[jj][0]; h11 += x1 * pw[jj][1];
      h12 += x1 * pw[jj][2]; h13 += x1 * pw[jj][3];
    }
    h00 = leakyf(h00); h01 = leakyf(h01); h02 = leakyf(h02); h03 = leakyf(h03);
    h10 = leakyf(h10); h11 = leakyf(h11); h12 = leakyf(h12); h13 = leakyf(h13);
    float bp0 = h00 * p[0] + h01 * p[1] + h02 * p[2] + h03 * p[3];
    float bp1 = h10 * p[0] + h11 * p[1] + h12 * p[2] + h13 * p[3];
#pragma unroll
    for (int o = 32; o; o >>= 1) {
      bp0 += __shfl_down(bp0, o);
      bp1 += __shfl_down(bp1, o);
    }
    bp0 = __shfl(bp0, 0);
    bp1 = __shfl(bp1, 0);
    float w0 = expf(fminf(leakyf(alv + bp0), 60.f));
    float w1 = expf(fminf(leakyf(alv + bp1), 60.f));
    ss += w0 + w1;
    a0 += w0 * h00 + w1 * h10;
    a1 += w0 * h01 + w1 * h11;
    a2 += w0 * h02 + w1 * h12;
    a3 += w0 * h03 + w1 * h13;
  }
  if (t < cnt) {
    int e0 = __builtin_amdgcn_readfirstlane(elist[begin + t]);
    int s0 = __builtin_amdgcn_readfirstlane(srcA[e0]);
    us4 g0 = *(const us4*)(xa + (size_t)s0 * GG + kb);
    const float* xp0 = Xe + (size_t)e0 * EE;
    float h00 = bf2f(g0.x) + b[0], h01 = bf2f(g0.y) + b[1];
    float h02 = bf2f(g0.z) + b[2], h03 = bf2f(g0.w) + b[3];
#pragma unroll
    for (int jj = 0; jj < EE; ++jj) {
      float x0 = xp0[jj];
      h00 += x0 * pw[jj][0]; h01 += x0 * pw[jj][1];
      h02 += x0 * pw[jj][2]; h03 += x0 * pw[jj][3];
    }
    h00 = leakyf(h00); h01 = leakyf(h01); h02 = leakyf(h02); h03 = leakyf(h03);
    float bp0 = h00 * p[0] + h01 * p[1] + h02 * p[2] + h03 * p[3];
#pragma unroll
    for (int o = 32; o; o >>= 1) bp0 += __shfl_down(bp0, o);
    bp0 = __shfl(bp0, 0);
    float w0 = expf(fminf(leakyf(alv + bp0), 60.f));
    ss += w0;
    a0 += w0 * h00; a1 += w0 * h01; a2 += w0 * h02; a3 += w0 * h03;
  }
  float inv = (cnt > 0) ? 1.f / ss : 0.f;
  if (act) {
    us4 o4;
    o4.x = f2bf(a0 * inv); o4.y = f2bf(a1 * inv);
    o4.z = f2bf(a2 * inv); o4.w = f2bf(a3 * inv);
    *(us4*)(S + (size_t)v * GG + kb) = o4;
  }
  if (lane == 0) ssumOut[v] = (cnt > 0) ? ss : 0.f;
}

// ---------------- layer-2 fused aggregation ----------------
__global__ __launch_bounds__(256) void l2_agg(
    const unsigned short* __restrict__ hvp, const float* __restrict__ gd,
    const float* __restrict__ gs, const float* __restrict__ lpeb,
    const int* __restrict__ srcA,
    const int* __restrict__ offA, const int* __restrict__ cntA, const int* __restrict__ elist,
    unsigned short* __restrict__ S2, int N)
{
  int v = (blockIdx.x * 256 + threadIdx.x) >> 6;
  int lane = threadIdx.x & 63;
  if (v >= N) return;
  int begin = offA[v], cnt = cntA[v];
  bool act = lane < 50;
  int kb = act ? 4 * lane : 0;
  float gdv = gd[v] + lpeb[0];
  float ss = 0.f;
  float a0 = 0.f, a1 = 0.f, a2 = 0.f, a3 = 0.f;
  int t = 0;
  for (; t + 4 <= cnt; t += 4) {
    int e0 = __builtin_amdgcn_readfirstlane(elist[begin + t]);
    int e1 = __builtin_amdgcn_readfirstlane(elist[begin + t + 1]);
    int e2 = __builtin_amdgcn_readfirstlane(elist[begin + t + 2]);
    int e3 = __builtin_amdgcn_readfirstlane(elist[begin + t + 3]);
    int s0 = __builtin_amdgcn_readfirstlane(srcA[e0]);
    int s1 = __builtin_amdgcn_readfirstlane(srcA[e1]);
    int s2 = __builtin_amdgcn_readfirstlane(srcA[e2]);
    int s3 = __builtin_amdgcn_readfirstlane(srcA[e3]);
    us4 g0 = *(const us4*)(hvp + (size_t)s0 * GG + kb);
    us4 g1 = *(const us4*)(hvp + (size_t)s1 * GG + kb);
    us4 g2 = *(const us4*)(hvp + (size_t)s2 * GG + kb);
    us4 g3 = *(const us4*)(hvp + (size_t)s3 * GG + kb);
    float w0 = expf(fminf(leakyf(gdv + gs[s0]), 60.f));
    float w1 = expf(fminf(leakyf(gdv + gs[s1]), 60.f));
    float w2 = expf(fminf(leakyf(gdv + gs[s2]), 60.f));
    float w3 = expf(fminf(leakyf(gdv + gs[s3]), 60.f));
    ss += w0 + w1 + w2 + w3;
    a0 += w0 * bf2f(g0.x) + w1 * bf2f(g1.x) + w2 * bf2f(g2.x) + w3 * bf2f(g3.x);
    a1 += w0 * bf2f(g0.y) + w1 * bf2f(g1.y) + w2 * bf2f(g2.y) + w3 * bf2f(g3.y);
    a2 += w0 * bf2f(g0.z) + w1 * bf2f(g1.z) + w2 * bf2f(g2.z) + w3 * bf2f(g3.z);
    a3 += w0 * bf2f(g0.w) + w1 * bf2f(g1.w) + w2 * bf2f(g2.w) + w3 * bf2f(g3.w);
  }
  for (; t < cnt; ++t) {
    int e = __builtin_amdgcn_readfirstlane(elist[begin + t]);
    int s = __builtin_amdgcn_readfirstlane(srcA[e]);
    us4 g = *(const us4*)(hvp + (size_t)s * GG + kb);
    float w = expf(fminf(leakyf(gdv + gs[s]), 60.f));
    ss += w;
    a0 += w * bf2f(g.x); a1 += w * bf2f(g.y);
    a2 += w * bf2f(g.z); a3 += w * bf2f(g.w);
  }
  float inv = (cnt > 0) ? 1.f / ss : 0.f;
  if (act) {
    us4 o4;
    o4.x = f2bf((cnt > 0) ? eluf(a0 * inv) : 0.f);
    o4.y = f2bf((cnt > 0) ? eluf(a1 * inv) : 0.f);
    o4.z = f2bf((cnt > 0) ? eluf(a2 * inv) : 0.f);
    o4.w = f2bf((cnt > 0) ? eluf(a3 * inv) : 0.f);
    *(us4*)(S2 + (size_t)v * GG + kb) = o4;
  }
}

// ================= MFMA GEMM (bf16 out) =================
template <typename TA>
__global__ __launch_bounds__(256) void mfma_gemm(
    const TA* __restrict__ A, const unsigned short* __restrict__ Wt,
    const float* __restrict__ bias, const float* __restrict__ rowmask,
    unsigned short* __restrict__ Cb, int Mr, int Nc, int K, int act)
{
  __shared__ __attribute__((aligned(16))) short As[128 * 32];
  __shared__ __attribute__((aligned(16))) short Bs[64 * 32];
  int ncol = (Nc + 63) >> 6;
  int nrowt = (Mr + 127) >> 7;
  int per = 8 * ncol;
  int grp = blockIdx.x / per, rem = blockIdx.x % per;
  int rowt = grp * 8 + (rem & 7), colt = rem >> 3;
  if (rowt >= nrowt) return;
  int row0 = rowt * 128, col0 = colt * 64;
  int tid = threadIdx.x;
  int w = tid >> 6, lane = tid & 63, quad = lane >> 4, l15 = lane & 15;

  f32x4 zero4 = {0.f, 0.f, 0.f, 0.f};
  f32x4 acc[2][4];
#pragma unroll
  for (int r = 0; r < 2; ++r)
#pragma unroll
    for (int c = 0; c < 4; ++c) acc[r][c] = zero4;

  for (int k0 = 0; k0 < K; k0 += 32) {
    {
      int row = tid >> 1, half = tid & 1;
      int r = row0 + row;
      short tmp[16];
      stage16<TA>(A + (size_t)r * K + k0 + half * 16, k0 + half * 16, K, r < Mr, tmp);
      *(bf16x8*)&As[sw(row, 2 * half)]     = *(bf16x8*)&tmp[0];
      *(bf16x8*)&As[sw(row, 2 * half + 1)] = *(bf16x8*)&tmp[8];
    }
    {
      int col = tid & 63, seg = tid >> 6;
      int n = col0 + col, k = k0 + seg * 8;
      short t8[8];
      const unsigned short* wp = Wt + (size_t)n * K + k;
      if (n < Nc && k + 8 <= K) {
        *(bf16x8*)&t8[0] = *(const bf16x8*)wp;
      } else {
#pragma unroll
        for (int j = 0; j < 8; ++j)
          t8[j] = (n < Nc && k + j < K) ? (short)wp[j] : (short)0;
      }
      *(bf16x8*)&Bs[sw(col, seg)] = *(bf16x8*)&t8[0];
    }
    __syncthreads();
    bf16x8 a[2], b[4];
#pragma unroll
    for (int r = 0; r < 2; ++r)
      a[r] = *(const bf16x8*)&As[sw(w * 32 + r * 16 + l15, quad)];
#pragma unroll
    for (int c = 0; c < 4; ++c)
      b[c] = *(const bf16x8*)&Bs[sw(c * 16 + l15, quad)];
#pragma unroll
    for (int r = 0; r < 2; ++r)
#pragma unroll
      for (int c = 0; c < 4; ++c)
        acc[r][c] = __builtin_amdgcn_mfma_f32_16x16x32_bf16(a[r], b[c], acc[r][c], 0, 0, 0);
    __syncthreads();
  }
#pragma unroll
  for (int r = 0; r < 2; ++r) {
#pragma unroll
    for (int c = 0; c < 4; ++c) {
      int col = col0 + c * 16 + l15;
      if (col >= Nc) continue;
#pragma unroll
      for (int i = 0; i < 4; ++i) {
        int row = row0 + w * 32 + r * 16 + quad * 4 + i;
        if (row >= Mr) continue;
        bool valid = (rowmask == nullptr) || (rowmask[row] > 0.f);
        float v = valid ? (acc[r][c][i] + (bias ? bias[col] : 0.f)) : 0.f;
        if (act == 1) v = leakyf(v);
        else if (act == 2) v = eluf(v);
        Cb[(size_t)row * Nc + col] = f2bf(v);
      }
    }
  }
}

// ================= fused MFMA GRU =================
template <typename TI, typename TO>
__global__ __launch_bounds__(256) void mfma_gru(
    const TI* __restrict__ X, const TI* __restrict__ H,
    const unsigned short* __restrict__ WtIH, const unsigned short* __restrict__ WtHH,
    const float* __restrict__ bih, const float* __restrict__ bhh,
    TO* __restrict__ Out, int R, int relu_out)
{
  __shared__ __attribute__((aligned(16))) short Xs[128 * 32];
  __shared__ __attribute__((aligned(16))) short Hs[128 * 32];
  __shared__ __attribute__((aligned(16))) short Ws[192 * 32];
  int nrowt = (R + 127) >> 7;
  int grp = blockIdx.x / 56, rem = blockIdx.x % 56;
  int rowt = grp * 8 + (rem & 7), colt = rem >> 3;
  if (rowt >= nrowt) return;
  int row0 = rowt * 128, col0 = colt * 32;
  int tid = threadIdx.x;
  int w = tid >> 6, lane = tid & 63, quad = lane >> 4, l15 = lane & 15;

  f32x4 zero4 = {0.f, 0.f, 0.f, 0.f};
  f32x4 acc[6][2][2];
#pragma unroll
  for (int g = 0; g < 6; ++g)
#pragma unroll
    for (int r = 0; r < 2; ++r)
#pragma unroll
      for (int c = 0; c < 2; ++c) acc[g][r][c] = zero4;

  for (int k0 = 0; k0 < GG; k0 += 32) {
    {
      int row = tid >> 1, half = tid & 1;
      int r = row0 + row;
      short tx[16], th[16];
      stage16<TI>(X + (size_t)r * GG + k0 + half * 16, k0 + half * 16, GG, r < R, tx);
      stage16<TI>(H + (size_t)r * GG + k0 + half * 16, k0 + half * 16, GG, r < R, th);
      *(bf16x8*)&Xs[sw(row, 2 * half)]     = *(bf16x8*)&tx[0];
      *(bf16x8*)&Xs[sw(row, 2 * half + 1)] = *(bf16x8*)&tx[8];
      *(bf16x8*)&Hs[sw(row, 2 * half)]     = *(bf16x8*)&th[0];
      *(bf16x8*)&Hs[sw(row, 2 * half + 1)] = *(bf16x8*)&th[8];
    }
    for (int task = tid; task < 768; task += 256) {
      int rw = task >> 2, seg = task & 3;
      int g = rw >> 5, cc = rw & 31;
      int n = col0 + cc, k = k0 + seg * 8;
      const unsigned short* wp = (g < 3)
          ? WtIH + (size_t)(g * GG + n) * GG + k
          : WtHH + (size_t)((g - 3) * GG + n) * GG + k;
      short t8[8];
      if (n < GG && k + 8 <= GG) {
        *(bf16x8*)&t8[0] = *(const bf16x8*)wp;
      } else {
#pragma unroll
        for (int j = 0; j < 8; ++j)
          t8[j] = (n < GG && k + j < GG) ? (short)wp[j] : (short)0;
      }
      *(bf16x8*)&Ws[sw(rw, seg)] = *(bf16x8*)&t8[0];
    }
    __syncthreads();
    bf16x8 ax[2], ah[2];
#pragma unroll
    for (int r = 0; r < 2; ++r) {
      ax[r] = *(const bf16x8*)&Xs[sw(w * 32 + r * 16 + l15, quad)];
      ah[r] = *(const bf16x8*)&Hs[sw(w * 32 + r * 16 + l15, quad)];
    }
#pragma unroll
    for (int g = 0; g < 6; ++g) {
      bf16x8 b[2];
#pragma unroll
      for (int c = 0; c < 2; ++c)
        b[c] = *(const bf16x8*)&Ws[sw(g * 32 + c * 16 + l15, quad)];
#pragma unroll
      for (int r = 0; r < 2; ++r)
#pragma unroll
        for (int c = 0; c < 2; ++c)
          acc[g][r][c] = __builtin_amdgcn_mfma_f32_16x16x32_bf16(
              (g < 3) ? ax[r] : ah[r], b[c], acc[g][r][c], 0, 0, 0);
    }
    __syncthreads();
  }
#pragma unroll
  for (int r = 0; r < 2; ++r) {
#pragma unroll
    for (int c = 0; c < 2; ++c) {
      int col = col0 + c * 16 + l15;
      if (col >= GG) continue;
      float br = bih[col],       bhr = bhh[col];
      float bz = bih[200 + col], bhz = bhh[200 + col];
      float bn = bih[400 + col], bhn = bhh[400 + col];
#pragma unroll
      for (int i = 0; i < 4; ++i) {
        int row = row0 + w * 32 + r * 16 + quad * 4 + i;
        if (row >= R) continue;
        float rr = sigmf(acc[0][r][c][i] + br + acc[3][r][c][i] + bhr);
        float zz = sigmf(acc[1][r][c][i] + bz + acc[4][r][c][i] + bhz);
        float nn = tanhf(acc[2][r][c][i] + bn + rr * (acc[5][r][c][i] + bhn));
        float hval = ldv<TI>(H + (size_t)row * GG + col);
        float o = (1.f - zz) * nn + zz * hval;
        if (relu_out) o = fmaxf(o, 0.f);
        if constexpr (sizeof(TO) == 2) Out[(size_t)row * GG + col] = f2bf(o);
        else Out[(size_t)row * GG + col] = o;
      }
    }
  }
}

// ---------------- fp32 tiled GEMM (small readout shapes) ----------------
#define Bb 64
#define Bn 64
#define Bk 16
__global__ __launch_bounds__(256) void gemm_kernel(
    const float* __restrict__ A, const float* __restrict__ W,
    const float* __restrict__ bias, const float* __restrict__ rowmask,
    float* __restrict__ Cf, void* __restrict__ Oout, const int* __restrict__ oflag,
    int Mr, int Nc, int K, int act)
{
  __shared__ float As[Bk][Bb + 1];
  __shared__ float Ws[Bk][Bn];
  int row0 = blockIdx.x * Bb, col0 = blockIdx.y * Bn;
  int tid = threadIdx.x;
  int ty = tid >> 4, tx = tid & 15;
  float acc[4][4] = {};
  for (int k0 = 0; k0 < K; k0 += Bk) {
    for (int l = tid; l < Bb * Bk; l += 256) {
      int m = l >> 4, kk = l & 15;
      int r = row0 + m, k = k0 + kk;
      As[kk][m] = (r < Mr && k < K) ? A[(size_t)r * K + k] : 0.f;
    }
    for (int l = tid; l < Bk * Bn; l += 256) {
      int kk = l >> 6, nn = l & 63;
      int k = k0 + kk, c = col0 + nn;
      Ws[kk][nn] = (k < K && c < Nc) ? W[(size_t)k * Nc + c] : 0.f;
    }
    __syncthreads();
#pragma unroll
    for (int kk = 0; kk < Bk; ++kk) {
      float av[4], bv[4];
#pragma unroll
      for (int i = 0; i < 4; ++i) av[i] = As[kk][ty * 4 + i];
#pragma unroll
      for (int j = 0; j < 4; ++j) bv[j] = Ws[kk][tx * 4 + j];
#pragma unroll
      for (int i = 0; i < 4; ++i)
#pragma unroll
        for (int j = 0; j < 4; ++j) acc[i][j] += av[i] * bv[j];
    }
    __syncthreads();
  }
  int isbf = (oflag != nullptr) ? *oflag : 0;
#pragma unroll
  for (int i = 0; i < 4; ++i) {
    int r = row0 + ty * 4 + i;
    if (r >= Mr) continue;
    bool valid = (rowmask == nullptr) || (rowmask[r] > 0.f);
#pragma unroll
    for (int j = 0; j < 4; ++j) {
      int c = col0 + tx * 4 + j;
      if (c >= Nc) continue;
      float v = valid ? (acc[i][j] + (bias ? bias[c] : 0.f)) : 0.f;
      if (act == 1) v = leakyf(v);
      else if (act == 2) v = eluf(v);
      else if (act == 3) v = fmaxf(v, 0.f);
      size_t idx = (size_t)r * Nc + c;
      if (Oout) {
        if (isbf) ((__hip_bfloat16*)Oout)[idx] = __float2bfloat16(v);
        else      ((float*)Oout)[idx] = v;
      } else {
        Cf[idx] = v;
      }
    }
  }
}

// ---------------- per-node dot(s), bf16 input ----------------
__global__ __launch_bounds__(256) void node_dot2(
    const unsigned short* __restrict__ X, const float* __restrict__ w1,
    const float* __restrict__ w2,
    float* __restrict__ o1, float* __restrict__ o2, int N)
{
  int v = (blockIdx.x * 256 + threadIdx.x) >> 6;
  int lane = threadIdx.x & 63;
  if (v >= N) return;
  float d1 = 0.f, d2 = 0.f;
  for (int k = lane; k < GG; k += 64) {
    float x = bf2f(X[(size_t)v * GG + k]);
    d1 += x * w1[k];
    if (w2) d2 += x * w2[k];
  }
  for (int off = 32; off; off >>= 1) {
    d1 += __shfl_down(d1, off);
    if (w2) d2 += __shfl_down(d2, off);
  }
  if (lane == 0) { o1[v] = d1; if (w2) o2[v] = d2; }
}

__global__ __launch_bounds__(256) void graph_sum(
    const unsigned short* __restrict__ h, float* __restrict__ g)
{
  int b = blockIdx.x, k = threadIdx.x;
  if (k < GG) {
    float a = 0.f;
    for (int i = 0; i < 50; ++i) a += bf2f(h[((size_t)b * 50 + i) * GG + k]);
    g[(size_t)b * GG + k] = a;
  }
}

__global__ __launch_bounds__(256) void attn_kernel(
    const float* __restrict__ g, const unsigned short* __restrict__ h2,
    const float* __restrict__ w1, const float* __restrict__ dh,
    const float* __restrict__ rb, float* __restrict__ weighted)
{
  int b = blockIdx.x;
  __shared__ float red[256];
  __shared__ float zs[50];
  __shared__ float as_[50];
  __shared__ float dgs;
  int tid = threadIdx.x;
  float p = 0.f;
  if (tid < GG) p = fmaxf(g[(size_t)b * GG + tid], 0.f) * w1[tid];
  red[tid] = p;
  __syncthreads();
  for (int s = 128; s; s >>= 1) { if (tid < s) red[tid] += red[tid + s]; __syncthreads(); }
  if (tid == 0) dgs = red[0];
  __syncthreads();
  if (tid < 50) zs[tid] = leakyf(dgs + dh[b * 50 + tid] + rb[0]);
  __syncthreads();
  if (tid == 0) {
    float m = -1e30f;
    for (int i = 0; i < 50; ++i) m = fmaxf(m, zs[i]);
    float s = 0.f;
    for (int i = 0; i < 50; ++i) { float e = expf(zs[i] - m); as_[i] = e; s += e; }
    float inv = 1.f / s;
    for (int i = 0; i < 50; ++i) as_[i] *= inv;
  }
  __syncthreads();
  if (tid < GG) {
    float a = 0.f;
    for (int i = 0; i < 50; ++i) a += as_[i] * bf2f(h2[((size_t)b * 50 + i) * GG + tid]);
    weighted[(size_t)b * GG + tid] = a;
  }
}

// ---------------- host ----------------
static inline int gemm_grid(int Mr, int Nc) {
  int nrow = (Mr + 127) / 128, ncol = (Nc + 63) / 64;
  return ((nrow + 7) / 8) * 8 * ncol;
}
static inline int gru_grid(int R) {
  int nrow = (R + 127) / 128;
  return ((nrow + 7) / 8) * 56;
}

extern "C" void kernel_launch(void* const* d_in, const int* in_sizes, int n_in,
                              void* d_out, int out_size, void* d_ws, size_t ws_size,
                              hipStream_t stream)
{
  (void)n_in; (void)out_size; (void)ws_size;
  const int N = NN, M = MM, B = BB, F = FF, G = GG, P = PP;
  float* ws = (float*)d_ws;
  size_t off = 0;
  auto alloc = [&](size_t n) { size_t o = off; off += (n + 63) & ~(size_t)63; return o; };

  size_t o_flag = alloc(16);
  size_t o_pn_w = alloc(F * G), o_pn_b = alloc(G);
  size_t o_pe1_w = alloc((F + EE) * G), o_pe1_b = alloc(G);
  size_t o_pe2_w = alloc(2 * G), o_pe2_b = alloc(1);
  size_t o_et_w = alloc(G * G), o_et_b = alloc(G);
  size_t o_g0_wih = alloc(G * 3 * G), o_g0_whh = alloc(G * 3 * G);
  size_t o_g0_bih = alloc(3 * G), o_g0_bhh = alloc(3 * G);
  size_t o_lpe_w = alloc(2 * G), o_lpe_b = alloc(1);
  size_t o_lpn_w = alloc(G * G), o_lpn_b = alloc(G);
  size_t o_g1_wih = alloc(G * 3 * G), o_g1_whh = alloc(G * 3 * G);
  size_t o_g1_bih = alloc(3 * G), o_g1_bhh = alloc(3 * G);
  size_t o_rl_w = alloc(2 * 2 * G), o_rl_b = alloc(2);
  size_t o_rp_w = alloc(2 * G * G), o_rp_b = alloc(2 * G);
  size_t o_rg_wih = alloc(2 * G * 3 * G), o_rg_whh = alloc(2 * G * 3 * G);
  size_t o_rg_bih = alloc(2 * 3 * G), o_rg_bhh = alloc(2 * 3 * G);
  size_t o_t_w = alloc(G * P), o_t_b = alloc(P);
  size_t o_Xn = alloc((size_t)N * F);
  size_t o_Xe = alloc((size_t)M * EE);
  size_t o_B1 = alloc((size_t)N * G);
  size_t o_B2 = alloc((size_t)N * G);
  size_t o_B3 = alloc((size_t)N * G);
  size_t o_ssum = alloc(N);
  size_t o_gd = alloc(N), o_gs = alloc(N), o_dh = alloc(N);
  size_t o_gv0 = alloc((size_t)B * G), o_gwt = alloc((size_t)B * G), o_grep = alloc((size_t)B * G);
  size_t o_gv1 = alloc((size_t)B * G), o_gv2 = alloc((size_t)B * G);
  size_t o_etT  = alloc(G * G / 2), o_lpnT = alloc(G * G / 2);
  size_t o_g0ihT = alloc(G * 3 * G / 2), o_g0hhT = alloc(G * 3 * G / 2);
  size_t o_g1ihT = alloc(G * 3 * G / 2), o_g1hhT = alloc(G * 3 * G / 2);
  size_t o_rg0ihT = alloc(G * 3 * G / 2), o_rg0hhT = alloc(G * 3 * G / 2);
  size_t o_rg1ihT = alloc(G * 3 * G / 2), o_rg1hhT = alloc(G * 3 * G / 2);
  size_t o_pnT = alloc(G * F / 2 + 64), o_pe1T = alloc(G * F / 2 + 64);
  size_t o_cnt = alloc(N), o_off = alloc(N), o_cur = alloc(N);
  size_t o_elist = alloc(M), o_bsum = alloc(64), o_incl = alloc(N);

  int* flag = (int*)(ws + o_flag);
  int* cntA = (int*)(ws + o_cnt);
  int* offA = (int*)(ws + o_off);
  int* curA = (int*)(ws + o_cur);
  int* elist = (int*)(ws + o_elist);
  int* bsum = (int*)(ws + o_bsum);
  int* incl = (int*)(ws + o_incl);
  unsigned short* B1b = (unsigned short*)(ws + o_B1);
  unsigned short* B2b = (unsigned short*)(ws + o_B2);
  unsigned short* B3b = (unsigned short*)(ws + o_B3);

  CvtJobs32 jobs;
  int ji = 0;
  auto push = [&](int idx, size_t dsto) {
    jobs.j[ji].s = d_in[idx];
    jobs.j[ji].d = ws + dsto;
    jobs.j[ji].n = in_sizes[idx];
    jobs.j[ji].pad = 0;
    ++ji;
  };
  push(0, o_Xn);
  push(1, o_Xe);
  push(2, o_pn_w);  push(3, o_pn_b);
  push(4, o_pe1_w); push(5, o_pe1_b);
  push(6, o_pe2_w); push(7, o_pe2_b);
  push(8, o_et_w);  push(9, o_et_b);
  push(10, o_g0_wih); push(11, o_g0_whh); push(12, o_g0_bih); push(13, o_g0_bhh);
  push(14, o_lpe_w);  push(15, o_lpe_b);
  push(16, o_lpn_w);  push(17, o_lpn_b);
  push(18, o_g1_wih); push(19, o_g1_whh); push(20, o_g1_bih); push(21, o_g1_bhh);
  push(22, o_rl_w);   push(23, o_rl_b);
  push(24, o_rp_w);   push(25, o_rp_b);
  push(26, o_rg_wih); push(27, o_rg_whh); push(28, o_rg_bih); push(29, o_rg_bhh);
  push(30, o_t_w);    push(31, o_t_b);

  const int* src = (const int*)d_in[32];
  const int* dst = (const int*)d_in[33];

  dim3 blk(256);
  detect_dtype<<<dim3(1), blk, 0, stream>>>((const unsigned int*)d_in[0], flag);
  cvt_any<<<dim3(512, 32), blk, 0, stream>>>(jobs, flag);

  // ---- CSR build (by dst) ----
  hipMemsetAsync(cntA, 0, (size_t)N * 4, stream);
  hist_kernel<<<dim3((M + 255) / 256), blk, 0, stream>>>(dst, cntA, M);
  int nscb = (N + SCHUNK - 1) / SCHUNK;
  scan1_kernel<<<dim3(nscb), blk, 0, stream>>>(cntA, incl, bsum, N);
  scan2_kernel<<<dim3(1), dim3(64), 0, stream>>>(bsum, nscb);
  scan3_kernel<<<dim3((N + 255) / 256), blk, 0, stream>>>(incl, cntA, bsum, offA, curA, N);
  fill_kernel<<<dim3((M + 255) / 256), blk, 0, stream>>>(dst, curA, elist, M);

  // ---- weight transposes ----
  TJobs12 tj;
  auto tpush = [&](int slot, size_t srcO, size_t dstO, int K, int Nc) {
    tj.j[slot].s = ws + srcO;
    tj.j[slot].d = (unsigned short*)(ws + dstO);
    tj.j[slot].K = K; tj.j[slot].N = Nc;
  };
  tpush(0, o_et_w,  o_etT,  G, G);
  tpush(1, o_lpn_w, o_lpnT, G, G);
  tpush(2, o_g0_wih, o_g0ihT, G, 3 * G);
  tpush(3, o_g0_whh, o_g0hhT, G, 3 * G);
  tpush(4, o_g1_wih, o_g1ihT, G, 3 * G);
  tpush(5, o_g1_whh, o_g1hhT, G, 3 * G);
  tpush(6, o_rg_wih, o_rg0ihT, G, 3 * G);
  tpush(7, o_rg_whh, o_rg0hhT, G, 3 * G);
  tpush(8, o_rg_wih + (size_t)G * 3 * G, o_rg1ihT, G, 3 * G);
  tpush(9, o_rg_whh + (size_t)G * 3 * G, o_rg1hhT, G, 3 * G);
  tpush(10, o_pn_w,  o_pnT,  F, G);
  tpush(11, o_pe1_w, o_pe1T, F, G);
  transpose_bf16<<<dim3(128, 12), blk, 0, stream>>>(tj);

  dim3 gWave((N + 3) / 4);

  // hv_new = leaky(Xn@pn_w + pn_b) -> B1 bf16
  mfma_gemm<float><<<dim3(gemm_grid(N, G)), blk, 0, stream>>>(
      ws + o_Xn, (const unsigned short*)(ws + o_pnT), ws + o_pn_b, nullptr,
      B1b, N, G, F, 1);
  // xa = Xn @ pe1_w[:39] -> B2 bf16
  mfma_gemm<float><<<dim3(gemm_grid(N, G)), blk, 0, stream>>>(
      ws + o_Xn, (const unsigned short*)(ws + o_pe1T), nullptr, nullptr,
      B2b, N, G, F, 0);
  // fused layer-1 agg (alpha computed inline from B1b)
  l1_agg<<<gWave, blk, 0, stream>>>(ws + o_Xe, B2b, B1b,
                                    ws + o_pe1_w + (size_t)F * G, ws + o_pe1_b,
                                    ws + o_pe2_w, ws + o_pe2_w + G, ws + o_pe2_b,
                                    src, offA, cntA, elist,
                                    B3b, ws + o_ssum, N);
  // c = elu(mask(B3@et_w + et_b)) -> B2 bf16
  mfma_gemm<unsigned short><<<dim3(gemm_grid(N, G)), blk, 0, stream>>>(
      B3b, (const unsigned short*)(ws + o_etT), ws + o_et_b, ws + o_ssum,
      B2b, N, G, G, 2);
  // h = relu(GRU0(x=B2, h=B1)) -> B3 bf16
  mfma_gru<unsigned short, unsigned short><<<dim3(gru_grid(N)), blk, 0, stream>>>(
      B2b, B1b,
      (const unsigned short*)(ws + o_g0ihT), (const unsigned short*)(ws + o_g0hhT),
      ws + o_g0_bih, ws + o_g0_bhh, B3b, N, 1);

  // ---- layer 2 ----
  node_dot2<<<gWave, blk, 0, stream>>>(B3b, ws + o_lpe_w, ws + o_lpe_w + G,
                                       ws + o_gd, ws + o_gs, N);
  // hv_proj = h@lpn_w + lpn_b -> B1 bf16
  mfma_gemm<unsigned short><<<dim3(gemm_grid(N, G)), blk, 0, stream>>>(
      B3b, (const unsigned short*)(ws + o_lpnT), ws + o_lpn_b, nullptr,
      B1b, N, G, G, 0);
  l2_agg<<<gWave, blk, 0, stream>>>(B1b, ws + o_gd, ws + o_gs, ws + o_lpe_b,
                                    src, offA, cntA, elist, B2b, N);
  // h2 = relu(GRU1(x=B2, h=B3)) -> B1 bf16
  mfma_gru<unsigned short, unsigned short><<<dim3(gru_grid(N)), blk, 0, stream>>>(
      B2b, B3b,
      (const unsigned short*)(ws + o_g1ihT), (const unsigned short*)(ws + o_g1hhT),
      ws + o_g1_bih, ws + o_g1_bhh, B1b, N, 1);

  // ---- readout ----
  graph_sum<<<dim3(B), blk, 0, stream>>>(B1b, ws + o_gv0);
  dim3 gBG((B + Bb - 1) / Bb, (G + Bn - 1) / Bn);
  size_t gcur = o_gv0, gnext = o_gv1;
  for (int t = 0; t < 2; ++t) {
    node_dot2<<<gWave, blk, 0, stream>>>(B1b, ws + o_rl_w + t * 2 * G + G,
                                         nullptr, ws + o_dh, nullptr, N);
    attn_kernel<<<dim3(B), blk, 0, stream>>>(ws + gcur, B1b, ws + o_rl_w + t * 2 * G,
                                             ws + o_dh, ws + o_rl_b + t, ws + o_gwt);
    gemm_kernel<<<gBG, blk, 0, stream>>>(ws + o_gwt, ws + o_rp_w + (size_t)t * G * G,
                                         ws + o_rp_b + t * G, nullptr,
                                         ws + o_grep, nullptr, nullptr, B, G, G, 2);
    mfma_gru<float, float><<<dim3(gru_grid(B)), blk, 0, stream>>>(
        ws + o_grep, ws + gcur,
        (const unsigned short*)(ws + (t == 0 ? o_rg0ihT : o_rg1ihT)),
        (const unsigned short*)(ws + (t == 0 ? o_rg0hhT : o_rg1hhT)),
        ws + o_rg_bih + t * 3 * G, ws + o_rg_bhh + t * 3 * G,
        ws + gnext, B, 0);
    gcur = gnext;
    gnext = o_gv2;
  }
  dim3 gOut((B + Bb - 1) / Bb, (P + Bn - 1) / Bn);
  gemm_kernel<<<gOut, blk, 0, stream>>>(ws + gcur, ws + o_t_w, ws + o_t_b, nullptr,
                                        nullptr, d_out, flag, B, P, G, 0);
}

// Round 8
// 948.809 us; speedup vs baseline: 4.2837x; 1.0506x over previous
//
#include <hip/hip_runtime.h>
#include <hip/hip_bf16.h>

// ---------------- constants ----------------
#define NN 50000
#define MM 400000
#define BB 1000
#define FF 39
#define EE 11
#define GG 200
#define PP 128

typedef __attribute__((ext_vector_type(8))) short bf16x8;
typedef __attribute__((ext_vector_type(4))) float f32x4;
struct us4 { unsigned short x, y, z, w; };

// ---------------- helpers ----------------
__device__ __forceinline__ float bf2f(unsigned short u) {
  return __uint_as_float(((unsigned int)u) << 16);
}
__device__ __forceinline__ unsigned short f2bf(float x) {
  union { __hip_bfloat16 b; unsigned short u; } v;
  v.b = __float2bfloat16(x);
  return v.u;
}
__device__ __forceinline__ float leakyf(float x) { return x > 0.f ? x : 0.01f * x; }
__device__ __forceinline__ float eluf(float x)   { return x > 0.f ? x : (expf(x) - 1.f); }
__device__ __forceinline__ float sigmf(float x)  { return 1.f / (1.f + expf(-x)); }
__device__ __forceinline__ int sw(int row, int seg) {
  return row * 32 + ((seg ^ ((row >> 1) & 3)) << 3);
}
template <typename T> __device__ __forceinline__ float ldv(const T* p);
template <> __device__ __forceinline__ float ldv<float>(const float* p) { return *p; }
template <> __device__ __forceinline__ float ldv<unsigned short>(const unsigned short* p) { return bf2f(*p); }

template <typename T>
__device__ __forceinline__ void stage16(const T* ap, int kbase, int K, bool rowok, short* tmp) {
  if (rowok && kbase + 16 <= K) {
    if constexpr (sizeof(T) == 2) {
      *(bf16x8*)&tmp[0] = *(const bf16x8*)(ap);
      *(bf16x8*)&tmp[8] = *(const bf16x8*)(ap + 8);
    } else {
#pragma unroll
      for (int j = 0; j < 16; ++j) tmp[j] = (short)f2bf(ap[j]);
    }
  } else if (rowok) {
#pragma unroll
    for (int j = 0; j < 16; ++j) {
      if (kbase + j < K) {
        if constexpr (sizeof(T) == 2) tmp[j] = (short)ap[j];
        else tmp[j] = (short)f2bf(ap[j]);
      } else tmp[j] = 0;
    }
  } else {
#pragma unroll
    for (int j = 0; j < 16; ++j) tmp[j] = 0;
  }
}

// ---------------- runtime dtype detection ----------------
__global__ __launch_bounds__(256) void detect_dtype(const unsigned int* __restrict__ w,
                                                    int* __restrict__ flag) {
  __shared__ int cnt[256];
  int c = 0;
  for (int i = threadIdx.x; i < 2048; i += 256) {
    unsigned int e = (w[i] >> 8) & 0x7F;
    c += (e >= 60 && e <= 64) ? 1 : 0;
  }
  cnt[threadIdx.x] = c;
  __syncthreads();
  for (int s = 128; s; s >>= 1) {
    if (threadIdx.x < s) cnt[threadIdx.x] += cnt[threadIdx.x + s];
    __syncthreads();
  }
  if (threadIdx.x == 0) *flag = (cnt[0] >= 1024) ? 1 : 0;
}

// ---------------- batched conversion to f32 ----------------
struct CvtJob { const void* s; float* d; int n; int pad; };
struct CvtJobs32 { CvtJob j[32]; };

__global__ __launch_bounds__(256) void cvt_any(CvtJobs32 jobs, const int* __restrict__ flag) {
  CvtJob job = jobs.j[blockIdx.y];
  int isbf = *flag;
  if (isbf) {
    const unsigned short* s = (const unsigned short*)job.s;
    for (int i = blockIdx.x * 256 + threadIdx.x; i < job.n; i += gridDim.x * 256)
      job.d[i] = bf2f(s[i]);
  } else {
    const float* s = (const float*)job.s;
    for (int i = blockIdx.x * 256 + threadIdx.x; i < job.n; i += gridDim.x * 256)
      job.d[i] = s[i];
  }
}

// ---------------- weight transpose+cvt ----------------
struct TJob { const float* s; unsigned short* d; int K; int N; };
struct TJobs12 { TJob j[12]; };

__global__ __launch_bounds__(256) void transpose_bf16(TJobs12 jobs) {
  TJob job = jobs.j[blockIdx.y];
  int total = job.K * job.N;
  for (int idx = blockIdx.x * 256 + threadIdx.x; idx < total; idx += gridDim.x * 256) {
    int n = idx / job.K, k = idx - n * job.K;
    job.d[idx] = f2bf(job.s[(size_t)k * job.N + n]);
  }
}

// ---------------- CSR build ----------------
__global__ __launch_bounds__(256) void hist_kernel(const int* __restrict__ dst,
                                                   int* __restrict__ cnt, int M) {
  int e = blockIdx.x * 256 + threadIdx.x;
  if (e < M) atomicAdd(&cnt[dst[e]], 1);
}

#define SCHUNK 2048
__global__ __launch_bounds__(256) void scan1_kernel(const int* __restrict__ cnt,
                                                    int* __restrict__ incl,
                                                    int* __restrict__ bsum, int n) {
  __shared__ int lds[256];
  int b = blockIdx.x, tid = threadIdx.x;
  int base = b * SCHUNK + tid * 8;
  int v[8], s = 0;
#pragma unroll
  for (int j = 0; j < 8; ++j) { int i = base + j; v[j] = (i < n) ? cnt[i] : 0; s += v[j]; }
  lds[tid] = s;
  __syncthreads();
  for (int o = 1; o < 256; o <<= 1) {
    int t = (tid >= o) ? lds[tid - o] : 0;
    __syncthreads();
    lds[tid] += t;
    __syncthreads();
  }
  int run = lds[tid] - s;
#pragma unroll
  for (int j = 0; j < 8; ++j) {
    run += v[j];
    int i = base + j;
    if (i < n) incl[i] = run;
  }
  if (tid == 255) bsum[b] = lds[255];
}

__global__ void scan2_kernel(int* __restrict__ bsum, int nb) {
  if (threadIdx.x == 0 && blockIdx.x == 0) {
    int run = 0;
    for (int i = 0; i < nb; ++i) { int t = bsum[i]; bsum[i] = run; run += t; }
  }
}

__global__ __launch_bounds__(256) void scan3_kernel(const int* __restrict__ incl,
                                                    const int* __restrict__ cnt,
                                                    const int* __restrict__ bsum,
                                                    int* __restrict__ offA,
                                                    int* __restrict__ cur, int n) {
  int i = blockIdx.x * 256 + threadIdx.x;
  if (i >= n) return;
  int o = incl[i] - cnt[i] + bsum[i / SCHUNK];
  offA[i] = o;
  cur[i] = o;
}

__global__ __launch_bounds__(256) void fill_kernel(const int* __restrict__ dst,
                                                   int* __restrict__ cur,
                                                   int* __restrict__ elist, int M) {
  int e = blockIdx.x * 256 + threadIdx.x;
  if (e >= M) return;
  int pos = atomicAdd(&cur[dst[e]], 1);
  elist[pos] = e;
}

// ---------------- layer-1 fused aggregation: one wave per block ----------------
// unroll x4: 4 gathers + 4 interleaved shuffle-reduction chains in flight.
__global__ __launch_bounds__(64) void l1_agg(
    const float* __restrict__ Xe, const unsigned short* __restrict__ xa,
    const unsigned short* __restrict__ hvnew,
    const float* __restrict__ pe1w_e, const float* __restrict__ pe1b,
    const float* __restrict__ pe2w_n, const float* __restrict__ pe2w_e,
    const float* __restrict__ pe2b, const int* __restrict__ srcA,
    const int* __restrict__ offA, const int* __restrict__ cntA, const int* __restrict__ elist,
    unsigned short* __restrict__ S, float* __restrict__ ssumOut, int N)
{
  int v = blockIdx.x;
  int lane = threadIdx.x;
  if (v >= N) return;
  int begin = offA[v], cnt = cntA[v];
  bool act = lane < 50;
  int kb = act ? 4 * lane : 0;
  float b[4], p[4], pn[4];
  float pw[EE][4];
#pragma unroll
  for (int j = 0; j < 4; ++j) {
    b[j]  = pe1b[kb + j];
    p[j]  = act ? pe2w_e[kb + j] : 0.f;
    pn[j] = act ? pe2w_n[kb + j] : 0.f;
  }
#pragma unroll
  for (int jj = 0; jj < EE; ++jj)
#pragma unroll
    for (int j = 0; j < 4; ++j) pw[jj][j] = pe1w_e[jj * GG + kb + j];

  // alpha = hv_new[v] . pe2w_n
  us4 hv = *(const us4*)(hvnew + (size_t)v * GG + kb);
  float da = bf2f(hv.x) * pn[0] + bf2f(hv.y) * pn[1] + bf2f(hv.z) * pn[2] + bf2f(hv.w) * pn[3];
#pragma unroll
  for (int o = 32; o; o >>= 1) da += __shfl_down(da, o);
  float alv = __shfl(da, 0) + pe2b[0];

  float ss = 0.f;
  float a0 = 0.f, a1 = 0.f, a2 = 0.f, a3 = 0.f;
  int t = 0;
  for (; t + 4 <= cnt; t += 4) {
    int e[4], s[4];
#pragma unroll
    for (int u = 0; u < 4; ++u) {
      e[u] = __builtin_amdgcn_readfirstlane(elist[begin + t + u]);
      s[u] = __builtin_amdgcn_readfirstlane(srcA[e[u]]);
    }
    us4 g[4];
#pragma unroll
    for (int u = 0; u < 4; ++u) g[u] = *(const us4*)(xa + (size_t)s[u] * GG + kb);
    float h[4][4];
#pragma unroll
    for (int u = 0; u < 4; ++u) {
      h[u][0] = bf2f(g[u].x) + b[0];
      h[u][1] = bf2f(g[u].y) + b[1];
      h[u][2] = bf2f(g[u].z) + b[2];
      h[u][3] = bf2f(g[u].w) + b[3];
    }
#pragma unroll
    for (int jj = 0; jj < EE; ++jj) {
#pragma unroll
      for (int u = 0; u < 4; ++u) {
        float x = Xe[(size_t)e[u] * EE + jj];
        h[u][0] += x * pw[jj][0]; h[u][1] += x * pw[jj][1];
        h[u][2] += x * pw[jj][2]; h[u][3] += x * pw[jj][3];
      }
    }
    float bp[4];
#pragma unroll
    for (int u = 0; u < 4; ++u) {
#pragma unroll
      for (int j = 0; j < 4; ++j) h[u][j] = leakyf(h[u][j]);
      bp[u] = h[u][0] * p[0] + h[u][1] * p[1] + h[u][2] * p[2] + h[u][3] * p[3];
    }
#pragma unroll
    for (int o = 32; o; o >>= 1) {
#pragma unroll
      for (int u = 0; u < 4; ++u) bp[u] += __shfl_down(bp[u], o);
    }
#pragma unroll
    for (int u = 0; u < 4; ++u) {
      float w = __expf(fminf(leakyf(alv + __shfl(bp[u], 0)), 60.f));
      ss += w;
      a0 += w * h[u][0]; a1 += w * h[u][1]; a2 += w * h[u][2]; a3 += w * h[u][3];
    }
  }
  for (; t < cnt; ++t) {
    int e0 = __builtin_amdgcn_readfirstlane(elist[begin + t]);
    int s0 = __builtin_amdgcn_readfirstlane(srcA[e0]);
    us4 g0 = *(const us4*)(xa + (size_t)s0 * GG + kb);
    float h0 = bf2f(g0.x) + b[0], h1 = bf2f(g0.y) + b[1];
    float h2 = bf2f(g0.z) + b[2], h3 = bf2f(g0.w) + b[3];
#pragma unroll
    for (int jj = 0; jj < EE; ++jj) {
      float x = Xe[(size_t)e0 * EE + jj];
      h0 += x * pw[jj][0]; h1 += x * pw[jj][1];
      h2 += x * pw[jj][2]; h3 += x * pw[jj][3];
    }
    h0 = leakyf(h0); h1 = leakyf(h1); h2 = leakyf(h2); h3 = leakyf(h3);
    float bp = h0 * p[0] + h1 * p[1] + h2 * p[2] + h3 * p[3];
#pragma unroll
    for (int o = 32; o; o >>= 1) bp += __shfl_down(bp, o);
    float w = __expf(fminf(leakyf(alv + __shfl(bp, 0)), 60.f));
    ss += w;
    a0 += w * h0; a1 += w * h1; a2 += w * h2; a3 += w * h3;
  }
  float inv = (cnt > 0) ? 1.f / ss : 0.f;
  if (act) {
    us4 o4;
    o4.x = f2bf(a0 * inv); o4.y = f2bf(a1 * inv);
    o4.z = f2bf(a2 * inv); o4.w = f2bf(a3 * inv);
    *(us4*)(S + (size_t)v * GG + kb) = o4;
  }
  if (lane == 0) ssumOut[v] = (cnt > 0) ? ss : 0.f;
}

// ---------------- layer-2 fused aggregation: one wave per block ----------------
__global__ __launch_bounds__(64) void l2_agg(
    const unsigned short* __restrict__ hvp, const float* __restrict__ gd,
    const float* __restrict__ gs, const float* __restrict__ lpeb,
    const int* __restrict__ srcA,
    const int* __restrict__ offA, const int* __restrict__ cntA, const int* __restrict__ elist,
    unsigned short* __restrict__ S2, int N)
{
  int v = blockIdx.x;
  int lane = threadIdx.x;
  if (v >= N) return;
  int begin = offA[v], cnt = cntA[v];
  bool act = lane < 50;
  int kb = act ? 4 * lane : 0;
  float gdv = gd[v] + lpeb[0];
  float ss = 0.f;
  float a0 = 0.f, a1 = 0.f, a2 = 0.f, a3 = 0.f;
  int t = 0;
  for (; t + 4 <= cnt; t += 4) {
    int e[4], s[4];
#pragma unroll
    for (int u = 0; u < 4; ++u) {
      e[u] = __builtin_amdgcn_readfirstlane(elist[begin + t + u]);
      s[u] = __builtin_amdgcn_readfirstlane(srcA[e[u]]);
    }
    us4 g0 = *(const us4*)(hvp + (size_t)s[0] * GG + kb);
    us4 g1 = *(const us4*)(hvp + (size_t)s[1] * GG + kb);
    us4 g2 = *(const us4*)(hvp + (size_t)s[2] * GG + kb);
    us4 g3 = *(const us4*)(hvp + (size_t)s[3] * GG + kb);
    float w0 = __expf(fminf(leakyf(gdv + gs[s[0]]), 60.f));
    float w1 = __expf(fminf(leakyf(gdv + gs[s[1]]), 60.f));
    float w2 = __expf(fminf(leakyf(gdv + gs[s[2]]), 60.f));
    float w3 = __expf(fminf(leakyf(gdv + gs[s[3]]), 60.f));
    ss += w0 + w1 + w2 + w3;
    a0 += w0 * bf2f(g0.x) + w1 * bf2f(g1.x) + w2 * bf2f(g2.x) + w3 * bf2f(g3.x);
    a1 += w0 * bf2f(g0.y) + w1 * bf2f(g1.y) + w2 * bf2f(g2.y) + w3 * bf2f(g3.y);
    a2 += w0 * bf2f(g0.z) + w1 * bf2f(g1.z) + w2 * bf2f(g2.z) + w3 * bf2f(g3.z);
    a3 += w0 * bf2f(g0.w) + w1 * bf2f(g1.w) + w2 * bf2f(g2.w) + w3 * bf2f(g3.w);
  }
  for (; t < cnt; ++t) {
    int e = __builtin_amdgcn_readfirstlane(elist[begin + t]);
    int s = __builtin_amdgcn_readfirstlane(srcA[e]);
    us4 g = *(const us4*)(hvp + (size_t)s * GG + kb);
    float w = __expf(fminf(leakyf(gdv + gs[s]), 60.f));
    ss += w;
    a0 += w * bf2f(g.x); a1 += w * bf2f(g.y);
    a2 += w * bf2f(g.z); a3 += w * bf2f(g.w);
  }
  float inv = (cnt > 0) ? 1.f / ss : 0.f;
  if (act) {
    us4 o4;
    o4.x = f2bf((cnt > 0) ? eluf(a0 * inv) : 0.f);
    o4.y = f2bf((cnt > 0) ? eluf(a1 * inv) : 0.f);
    o4.z = f2bf((cnt > 0) ? eluf(a2 * inv) : 0.f);
    o4.w = f2bf((cnt > 0) ? eluf(a3 * inv) : 0.f);
    *(us4*)(S2 + (size_t)v * GG + kb) = o4;
  }
}

// ================= MFMA GEMM (bf16 out) =================
template <typename TA>
__global__ __launch_bounds__(256) void mfma_gemm(
    const TA* __restrict__ A, const unsigned short* __restrict__ Wt,
    const float* __restrict__ bias, const float* __restrict__ rowmask,
    unsigned short* __restrict__ Cb, int Mr, int Nc, int K, int act)
{
  __shared__ __attribute__((aligned(16))) short As[128 * 32];
  __shared__ __attribute__((aligned(16))) short Bs[64 * 32];
  int ncol = (Nc + 63) >> 6;
  int nrowt = (Mr + 127) >> 7;
  int per = 8 * ncol;
  int grp = blockIdx.x / per, rem = blockIdx.x % per;
  int rowt = grp * 8 + (rem & 7), colt = rem >> 3;
  if (rowt >= nrowt) return;
  int row0 = rowt * 128, col0 = colt * 64;
  int tid = threadIdx.x;
  int w = tid >> 6, lane = tid & 63, quad = lane >> 4, l15 = lane & 15;

  f32x4 zero4 = {0.f, 0.f, 0.f, 0.f};
  f32x4 acc[2][4];
#pragma unroll
  for (int r = 0; r < 2; ++r)
#pragma unroll
    for (int c = 0; c < 4; ++c) acc[r][c] = zero4;

  for (int k0 = 0; k0 < K; k0 += 32) {
    {
      int row = tid >> 1, half = tid & 1;
      int r = row0 + row;
      short tmp[16];
      stage16<TA>(A + (size_t)r * K + k0 + half * 16, k0 + half * 16, K, r < Mr, tmp);
      *(bf16x8*)&As[sw(row, 2 * half)]     = *(bf16x8*)&tmp[0];
      *(bf16x8*)&As[sw(row, 2 * half + 1)] = *(bf16x8*)&tmp[8];
    }
    {
      int col = tid & 63, seg = tid >> 6;
      int n = col0 + col, k = k0 + seg * 8;
      short t8[8];
      const unsigned short* wp = Wt + (size_t)n * K + k;
      if (n < Nc && k + 8 <= K) {
        *(bf16x8*)&t8[0] = *(const bf16x8*)wp;
      } else {
#pragma unroll
        for (int j = 0; j < 8; ++j)
          t8[j] = (n < Nc && k + j < K) ? (short)wp[j] : (short)0;
      }
      *(bf16x8*)&Bs[sw(col, seg)] = *(bf16x8*)&t8[0];
    }
    __syncthreads();
    bf16x8 a[2], b[4];
#pragma unroll
    for (int r = 0; r < 2; ++r)
      a[r] = *(const bf16x8*)&As[sw(w * 32 + r * 16 + l15, quad)];
#pragma unroll
    for (int c = 0; c < 4; ++c)
      b[c] = *(const bf16x8*)&Bs[sw(c * 16 + l15, quad)];
#pragma unroll
    for (int r = 0; r < 2; ++r)
#pragma unroll
      for (int c = 0; c < 4; ++c)
        acc[r][c] = __builtin_amdgcn_mfma_f32_16x16x32_bf16(a[r], b[c], acc[r][c], 0, 0, 0);
    __syncthreads();
  }
#pragma unroll
  for (int r = 0; r < 2; ++r) {
#pragma unroll
    for (int c = 0; c < 4; ++c) {
      int col = col0 + c * 16 + l15;
      if (col >= Nc) continue;
#pragma unroll
      for (int i = 0; i < 4; ++i) {
        int row = row0 + w * 32 + r * 16 + quad * 4 + i;
        if (row >= Mr) continue;
        bool valid = (rowmask == nullptr) || (rowmask[row] > 0.f);
        float v = valid ? (acc[r][c][i] + (bias ? bias[col] : 0.f)) : 0.f;
        if (act == 1) v = leakyf(v);
        else if (act == 2) v = eluf(v);
        Cb[(size_t)row * Nc + col] = f2bf(v);
      }
    }
  }
}

// ================= fused MFMA GRU =================
template <typename TI, typename TO>
__global__ __launch_bounds__(256) void mfma_gru(
    const TI* __restrict__ X, const TI* __restrict__ H,
    const unsigned short* __restrict__ WtIH, const unsigned short* __restrict__ WtHH,
    const float* __restrict__ bih, const float* __restrict__ bhh,
    TO* __restrict__ Out, int R, int relu_out)
{
  __shared__ __attribute__((aligned(16))) short Xs[128 * 32];
  __shared__ __attribute__((aligned(16))) short Hs[128 * 32];
  __shared__ __attribute__((aligned(16))) short Ws[192 * 32];
  int nrowt = (R + 127) >> 7;
  int grp = blockIdx.x / 56, rem = blockIdx.x % 56;
  int rowt = grp * 8 + (rem & 7), colt = rem >> 3;
  if (rowt >= nrowt) return;
  int row0 = rowt * 128, col0 = colt * 32;
  int tid = threadIdx.x;
  int w = tid >> 6, lane = tid & 63, quad = lane >> 4, l15 = lane & 15;

  f32x4 zero4 = {0.f, 0.f, 0.f, 0.f};
  f32x4 acc[6][2][2];
#pragma unroll
  for (int g = 0; g < 6; ++g)
#pragma unroll
    for (int r = 0; r < 2; ++r)
#pragma unroll
      for (int c = 0; c < 2; ++c) acc[g][r][c] = zero4;

  for (int k0 = 0; k0 < GG; k0 += 32) {
    {
      int row = tid >> 1, half = tid & 1;
      int r = row0 + row;
      short tx[16], th[16];
      stage16<TI>(X + (size_t)r * GG + k0 + half * 16, k0 + half * 16, GG, r < R, tx);
      stage16<TI>(H + (size_t)r * GG + k0 + half * 16, k0 + half * 16, GG, r < R, th);
      *(bf16x8*)&Xs[sw(row, 2 * half)]     = *(bf16x8*)&tx[0];
      *(bf16x8*)&Xs[sw(row, 2 * half + 1)] = *(bf16x8*)&tx[8];
      *(bf16x8*)&Hs[sw(row, 2 * half)]     = *(bf16x8*)&th[0];
      *(bf16x8*)&Hs[sw(row, 2 * half + 1)] = *(bf16x8*)&th[8];
    }
    for (int task = tid; task < 768; task += 256) {
      int rw = task >> 2, seg = task & 3;
      int g = rw >> 5, cc = rw & 31;
      int n = col0 + cc, k = k0 + seg * 8;
      const unsigned short* wp = (g < 3)
          ? WtIH + (size_t)(g * GG + n) * GG + k
          : WtHH + (size_t)((g - 3) * GG + n) * GG + k;
      short t8[8];
      if (n < GG && k + 8 <= GG) {
        *(bf16x8*)&t8[0] = *(const bf16x8*)wp;
      } else {
#pragma unroll
        for (int j = 0; j < 8; ++j)
          t8[j] = (n < GG && k + j < GG) ? (short)wp[j] : (short)0;
      }
      *(bf16x8*)&Ws[sw(rw, seg)] = *(bf16x8*)&t8[0];
    }
    __syncthreads();
    bf16x8 ax[2], ah[2];
#pragma unroll
    for (int r = 0; r < 2; ++r) {
      ax[r] = *(const bf16x8*)&Xs[sw(w * 32 + r * 16 + l15, quad)];
      ah[r] = *(const bf16x8*)&Hs[sw(w * 32 + r * 16 + l15, quad)];
    }
#pragma unroll
    for (int g = 0; g < 6; ++g) {
      bf16x8 b[2];
#pragma unroll
      for (int c = 0; c < 2; ++c)
        b[c] = *(const bf16x8*)&Ws[sw(g * 32 + c * 16 + l15, quad)];
#pragma unroll
      for (int r = 0; r < 2; ++r)
#pragma unroll
        for (int c = 0; c < 2; ++c)
          acc[g][r][c] = __builtin_amdgcn_mfma_f32_16x16x32_bf16(
              (g < 3) ? ax[r] : ah[r], b[c], acc[g][r][c], 0, 0, 0);
    }
    __syncthreads();
  }
#pragma unroll
  for (int r = 0; r < 2; ++r) {
#pragma unroll
    for (int c = 0; c < 2; ++c) {
      int col = col0 + c * 16 + l15;
      if (col >= GG) continue;
      float br = bih[col],       bhr = bhh[col];
      float bz = bih[200 + col], bhz = bhh[200 + col];
      float bn = bih[400 + col], bhn = bhh[400 + col];
#pragma unroll
      for (int i = 0; i < 4; ++i) {
        int row = row0 + w * 32 + r * 16 + quad * 4 + i;
        if (row >= R) continue;
        float rr = sigmf(acc[0][r][c][i] + br + acc[3][r][c][i] + bhr);
        float zz = sigmf(acc[1][r][c][i] + bz + acc[4][r][c][i] + bhz);
        float nn = tanhf(acc[2][r][c][i] + bn + rr * (acc[5][r][c][i] + bhn));
        float hval = ldv<TI>(H + (size_t)row * GG + col);
        float o = (1.f - zz) * nn + zz * hval;
        if (relu_out) o = fmaxf(o, 0.f);
        if constexpr (sizeof(TO) == 2) Out[(size_t)row * GG + col] = f2bf(o);
        else Out[(size_t)row * GG + col] = o;
      }
    }
  }
}

// ---------------- fp32 tiled GEMM (small readout shapes) ----------------
#define Bb 64
#define Bn 64
#define Bk 16
__global__ __launch_bounds__(256) void gemm_kernel(
    const float* __restrict__ A, const float* __restrict__ W,
    const float* __restrict__ bias, const float* __restrict__ rowmask,
    float* __restrict__ Cf, void* __restrict__ Oout, const int* __restrict__ oflag,
    int Mr, int Nc, int K, int act)
{
  __shared__ float As[Bk][Bb + 1];
  __shared__ float Ws[Bk][Bn];
  int row0 = blockIdx.x * Bb, col0 = blockIdx.y * Bn;
  int tid = threadIdx.x;
  int ty = tid >> 4, tx = tid & 15;
  float acc[4][4] = {};
  for (int k0 = 0; k0 < K; k0 += Bk) {
    for (int l = tid; l < Bb * Bk; l += 256) {
      int m = l >> 4, kk = l & 15;
      int r = row0 + m, k = k0 + kk;
      As[kk][m] = (r < Mr && k < K) ? A[(size_t)r * K + k] : 0.f;
    }
    for (int l = tid; l < Bk * Bn; l += 256) {
      int kk = l >> 6, nn = l & 63;
      int k = k0 + kk, c = col0 + nn;
      Ws[kk][nn] = (k < K && c < Nc) ? W[(size_t)k * Nc + c] : 0.f;
    }
    __syncthreads();
#pragma unroll
    for (int kk = 0; kk < Bk; ++kk) {
      float av[4], bv[4];
#pragma unroll
      for (int i = 0; i < 4; ++i) av[i] = As[kk][ty * 4 + i];
#pragma unroll
      for (int j = 0; j < 4; ++j) bv[j] = Ws[kk][tx * 4 + j];
#pragma unroll
      for (int i = 0; i < 4; ++i)
#pragma unroll
        for (int j = 0; j < 4; ++j) acc[i][j] += av[i] * bv[j];
    }
    __syncthreads();
  }
  int isbf = (oflag != nullptr) ? *oflag : 0;
#pragma unroll
  for (int i = 0; i < 4; ++i) {
    int r = row0 + ty * 4 + i;
    if (r >= Mr) continue;
    bool valid = (rowmask == nullptr) || (rowmask[r] > 0.f);
#pragma unroll
    for (int j = 0; j < 4; ++j) {
      int c = col0 + tx * 4 + j;
      if (c >= Nc) continue;
      float v = valid ? (acc[i][j] + (bias ? bias[c] : 0.f)) : 0.f;
      if (act == 1) v = leakyf(v);
      else if (act == 2) v = eluf(v);
      else if (act == 3) v = fmaxf(v, 0.f);
      size_t idx = (size_t)r * Nc + c;
      if (Oout) {
        if (isbf) ((__hip_bfloat16*)Oout)[idx] = __float2bfloat16(v);
        else      ((float*)Oout)[idx] = v;
      } else {
        Cf[idx] = v;
      }
    }
  }
}

// ---------------- per-node dot(s), bf16 input ----------------
__global__ __launch_bounds__(256) void node_dot2(
    const unsigned short* __restrict__ X, const float* __restrict__ w1,
    const float* __restrict__ w2,
    float* __restrict__ o1, float* __restrict__ o2, int N)
{
  int v = (blockIdx.x * 256 + threadIdx.x) >> 6;
  int lane = threadIdx.x & 63;
  if (v >= N) return;
  float d1 = 0.f, d2 = 0.f;
  for (int k = lane; k < GG; k += 64) {
    float x = bf2f(X[(size_t)v * GG + k]);
    d1 += x * w1[k];
    if (w2) d2 += x * w2[k];
  }
  for (int off = 32; off; off >>= 1) {
    d1 += __shfl_down(d1, off);
    if (w2) d2 += __shfl_down(d2, off);
  }
  if (lane == 0) { o1[v] = d1; if (w2) o2[v] = d2; }
}

__global__ __launch_bounds__(256) void graph_sum(
    const unsigned short* __restrict__ h, float* __restrict__ g)
{
  int b = blockIdx.x, k = threadIdx.x;
  if (k < GG) {
    float a = 0.f;
    for (int i = 0; i < 50; ++i) a += bf2f(h[((size_t)b * 50 + i) * GG + k]);
    g[(size_t)b * GG + k] = a;
  }
}

__global__ __launch_bounds__(256) void attn_kernel(
    const float* __restrict__ g, const unsigned short* __restrict__ h2,
    const float* __restrict__ w1, const float* __restrict__ dh,
    const float* __restrict__ rb, float* __restrict__ weighted)
{
  int b = blockIdx.x;
  __shared__ float red[256];
  __shared__ float zs[50];
  __shared__ float as_[50];
  __shared__ float dgs;
  int tid = threadIdx.x;
  float p = 0.f;
  if (tid < GG) p = fmaxf(g[(size_t)b * GG + tid], 0.f) * w1[tid];
  red[tid] = p;
  __syncthreads();
  for (int s = 128; s; s >>= 1) { if (tid < s) red[tid] += red[tid + s]; __syncthreads(); }
  if (tid == 0) dgs = red[0];
  __syncthreads();
  if (tid < 50) zs[tid] = leakyf(dgs + dh[b * 50 + tid] + rb[0]);
  __syncthreads();
  if (tid == 0) {
    float m = -1e30f;
    for (int i = 0; i < 50; ++i) m = fmaxf(m, zs[i]);
    float s = 0.f;
    for (int i = 0; i < 50; ++i) { float e = expf(zs[i] - m); as_[i] = e; s += e; }
    float inv = 1.f / s;
    for (int i = 0; i < 50; ++i) as_[i] *= inv;
  }
  __syncthreads();
  if (tid < GG) {
    float a = 0.f;
    for (int i = 0; i < 50; ++i) a += as_[i] * bf2f(h2[((size_t)b * 50 + i) * GG + tid]);
    weighted[(size_t)b * GG + tid] = a;
  }
}

// ---------------- host ----------------
static inline int gemm_grid(int Mr, int Nc) {
  int nrow = (Mr + 127) / 128, ncol = (Nc + 63) / 64;
  return ((nrow + 7) / 8) * 8 * ncol;
}
static inline int gru_grid(int R) {
  int nrow = (R + 127) / 128;
  return ((nrow + 7) / 8) * 56;
}

extern "C" void kernel_launch(void* const* d_in, const int* in_sizes, int n_in,
                              void* d_out, int out_size, void* d_ws, size_t ws_size,
                              hipStream_t stream)
{
  (void)n_in; (void)out_size; (void)ws_size;
  const int N = NN, M = MM, B = BB, F = FF, G = GG, P = PP;
  float* ws = (float*)d_ws;
  size_t off = 0;
  auto alloc = [&](size_t n) { size_t o = off; off += (n + 63) & ~(size_t)63; return o; };

  size_t o_flag = alloc(16);
  size_t o_pn_w = alloc(F * G), o_pn_b = alloc(G);
  size_t o_pe1_w = alloc((F + EE) * G), o_pe1_b = alloc(G);
  size_t o_pe2_w = alloc(2 * G), o_pe2_b = alloc(1);
  size_t o_et_w = alloc(G * G), o_et_b = alloc(G);
  size_t o_g0_wih = alloc(G * 3 * G), o_g0_whh = alloc(G * 3 * G);
  size_t o_g0_bih = alloc(3 * G), o_g0_bhh = alloc(3 * G);
  size_t o_lpe_w = alloc(2 * G), o_lpe_b = alloc(1);
  size_t o_lpn_w = alloc(G * G), o_lpn_b = alloc(G);
  size_t o_g1_wih = alloc(G * 3 * G), o_g1_whh = alloc(G * 3 * G);
  size_t o_g1_bih = alloc(3 * G), o_g1_bhh = alloc(3 * G);
  size_t o_rl_w = alloc(2 * 2 * G), o_rl_b = alloc(2);
  size_t o_rp_w = alloc(2 * G * G), o_rp_b = alloc(2 * G);
  size_t o_rg_wih = alloc(2 * G * 3 * G), o_rg_whh = alloc(2 * G * 3 * G);
  size_t o_rg_bih = alloc(2 * 3 * G), o_rg_bhh = alloc(2 * 3 * G);
  size_t o_t_w = alloc(G * P), o_t_b = alloc(P);
  size_t o_Xn = alloc((size_t)N * F);
  size_t o_Xe = alloc((size_t)M * EE);
  size_t o_B1 = alloc((size_t)N * G);
  size_t o_B2 = alloc((size_t)N * G);
  size_t o_B3 = alloc((size_t)N * G);
  size_t o_ssum = alloc(N);
  size_t o_gd = alloc(N), o_gs = alloc(N), o_dh = alloc(N);
  size_t o_gv0 = alloc((size_t)B * G), o_gwt = alloc((size_t)B * G), o_grep = alloc((size_t)B * G);
  size_t o_gv1 = alloc((size_t)B * G), o_gv2 = alloc((size_t)B * G);
  size_t o_etT  = alloc(G * G / 2), o_lpnT = alloc(G * G / 2);
  size_t o_g0ihT = alloc(G * 3 * G / 2), o_g0hhT = alloc(G * 3 * G / 2);
  size_t o_g1ihT = alloc(G * 3 * G / 2), o_g1hhT = alloc(G * 3 * G / 2);
  size_t o_rg0ihT = alloc(G * 3 * G / 2), o_rg0hhT = alloc(G * 3 * G / 2);
  size_t o_rg1ihT = alloc(G * 3 * G / 2), o_rg1hhT = alloc(G * 3 * G / 2);
  size_t o_pnT = alloc(G * F / 2 + 64), o_pe1T = alloc(G * F / 2 + 64);
  size_t o_cnt = alloc(N), o_off = alloc(N), o_cur = alloc(N);
  size_t o_elist = alloc(M), o_bsum = alloc(64), o_incl = alloc(N);

  int* flag = (int*)(ws + o_flag);
  int* cntA = (int*)(ws + o_cnt);
  int* offA = (int*)(ws + o_off);
  int* curA = (int*)(ws + o_cur);
  int* elist = (int*)(ws + o_elist);
  int* bsum = (int*)(ws + o_bsum);
  int* incl = (int*)(ws + o_incl);
  unsigned short* B1b = (unsigned short*)(ws + o_B1);
  unsigned short* B2b = (unsigned short*)(ws + o_B2);
  unsigned short* B3b = (unsigned short*)(ws + o_B3);

  CvtJobs32 jobs;
  int ji = 0;
  auto push = [&](int idx, size_t dsto) {
    jobs.j[ji].s = d_in[idx];
    jobs.j[ji].d = ws + dsto;
    jobs.j[ji].n = in_sizes[idx];
    jobs.j[ji].pad = 0;
    ++ji;
  };
  push(0, o_Xn);
  push(1, o_Xe);
  push(2, o_pn_w);  push(3, o_pn_b);
  push(4, o_pe1_w); push(5, o_pe1_b);
  push(6, o_pe2_w); push(7, o_pe2_b);
  push(8, o_et_w);  push(9, o_et_b);
  push(10, o_g0_wih); push(11, o_g0_whh); push(12, o_g0_bih); push(13, o_g0_bhh);
  push(14, o_lpe_w);  push(15, o_lpe_b);
  push(16, o_lpn_w);  push(17, o_lpn_b);
  push(18, o_g1_wih); push(19, o_g1_whh); push(20, o_g1_bih); push(21, o_g1_bhh);
  push(22, o_rl_w);   push(23, o_rl_b);
  push(24, o_rp_w);   push(25, o_rp_b);
  push(26, o_rg_wih); push(27, o_rg_whh); push(28, o_rg_bih); push(29, o_rg_bhh);
  push(30, o_t_w);    push(31, o_t_b);

  const int* src = (const int*)d_in[32];
  const int* dst = (const int*)d_in[33];

  dim3 blk(256);
  detect_dtype<<<dim3(1), blk, 0, stream>>>((const unsigned int*)d_in[0], flag);
  cvt_any<<<dim3(512, 32), blk, 0, stream>>>(jobs, flag);

  // ---- CSR build (by dst) ----
  hipMemsetAsync(cntA, 0, (size_t)N * 4, stream);
  hist_kernel<<<dim3((M + 255) / 256), blk, 0, stream>>>(dst, cntA, M);
  int nscb = (N + SCHUNK - 1) / SCHUNK;
  scan1_kernel<<<dim3(nscb), blk, 0, stream>>>(cntA, incl, bsum, N);
  scan2_kernel<<<dim3(1), dim3(64), 0, stream>>>(bsum, nscb);
  scan3_kernel<<<dim3((N + 255) / 256), blk, 0, stream>>>(incl, cntA, bsum, offA, curA, N);
  fill_kernel<<<dim3((M + 255) / 256), blk, 0, stream>>>(dst, curA, elist, M);

  // ---- weight transposes ----
  TJobs12 tj;
  auto tpush = [&](int slot, size_t srcO, size_t dstO, int K, int Nc) {
    tj.j[slot].s = ws + srcO;
    tj.j[slot].d = (unsigned short*)(ws + dstO);
    tj.j[slot].K = K; tj.j[slot].N = Nc;
  };
  tpush(0, o_et_w,  o_etT,  G, G);
  tpush(1, o_lpn_w, o_lpnT, G, G);
  tpush(2, o_g0_wih, o_g0ihT, G, 3 * G);
  tpush(3, o_g0_whh, o_g0hhT, G, 3 * G);
  tpush(4, o_g1_wih, o_g1ihT, G, 3 * G);
  tpush(5, o_g1_whh, o_g1hhT, G, 3 * G);
  tpush(6, o_rg_wih, o_rg0ihT, G, 3 * G);
  tpush(7, o_rg_whh, o_rg0hhT, G, 3 * G);
  tpush(8, o_rg_wih + (size_t)G * 3 * G, o_rg1ihT, G, 3 * G);
  tpush(9, o_rg_whh + (size_t)G * 3 * G, o_rg1hhT, G, 3 * G);
  tpush(10, o_pn_w,  o_pnT,  F, G);
  tpush(11, o_pe1_w, o_pe1T, F, G);
  transpose_bf16<<<dim3(128, 12), blk, 0, stream>>>(tj);

  // hv_new = leaky(Xn@pn_w + pn_b) -> B1 bf16
  mfma_gemm<float><<<dim3(gemm_grid(N, G)), blk, 0, stream>>>(
      ws + o_Xn, (const unsigned short*)(ws + o_pnT), ws + o_pn_b, nullptr,
      B1b, N, G, F, 1);
  // xa = Xn @ pe1_w[:39] -> B2 bf16
  mfma_gemm<float><<<dim3(gemm_grid(N, G)), blk, 0, stream>>>(
      ws + o_Xn, (const unsigned short*)(ws + o_pe1T), nullptr, nullptr,
      B2b, N, G, F, 0);
  // fused layer-1 agg (alpha computed inline from B1b); one wave per node
  l1_agg<<<dim3(N), dim3(64), 0, stream>>>(ws + o_Xe, B2b, B1b,
                                           ws + o_pe1_w + (size_t)F * G, ws + o_pe1_b,
                                           ws + o_pe2_w, ws + o_pe2_w + G, ws + o_pe2_b,
                                           src, offA, cntA, elist,
                                           B3b, ws + o_ssum, N);
  // c = elu(mask(B3@et_w + et_b)) -> B2 bf16
  mfma_gemm<unsigned short><<<dim3(gemm_grid(N, G)), blk, 0, stream>>>(
      B3b, (const unsigned short*)(ws + o_etT), ws + o_et_b, ws + o_ssum,
      B2b, N, G, G, 2);
  // h = relu(GRU0(x=B2, h=B1)) -> B3 bf16
  mfma_gru<unsigned short, unsigned short><<<dim3(gru_grid(N)), blk, 0, stream>>>(
      B2b, B1b,
      (const unsigned short*)(ws + o_g0ihT), (const unsigned short*)(ws + o_g0hhT),
      ws + o_g0_bih, ws + o_g0_bhh, B3b, N, 1);

  // ---- layer 2 ----
  dim3 gWave((N + 3) / 4);
  node_dot2<<<gWave, blk, 0, stream>>>(B3b, ws + o_lpe_w, ws + o_lpe_w + G,
                                       ws + o_gd, ws + o_gs, N);
  // hv_proj = h@lpn_w + lpn_b -> B1 bf16
  mfma_gemm<unsigned short><<<dim3(gemm_grid(N, G)), blk, 0, stream>>>(
      B3b, (const unsigned short*)(ws + o_lpnT), ws + o_lpn_b, nullptr,
      B1b, N, G, G, 0);
  l2_agg<<<dim3(N), dim3(64), 0, stream>>>(B1b, ws + o_gd, ws + o_gs, ws + o_lpe_b,
                                           src, offA, cntA, elist, B2b, N);
  // h2 = relu(GRU1(x=B2, h=B3)) -> B1 bf16
  mfma_gru<unsigned short, unsigned short><<<dim3(gru_grid(N)), blk, 0, stream>>>(
      B2b, B3b,
      (const unsigned short*)(ws + o_g1ihT), (const unsigned short*)(ws + o_g1hhT),
      ws + o_g1_bih, ws + o_g1_bhh, B1b, N, 1);

  // ---- readout ----
  graph_sum<<<dim3(B), blk, 0, stream>>>(B1b, ws + o_gv0);
  dim3 gBG((B + Bb - 1) / Bb, (G + Bn - 1) / Bn);
  size_t gcur = o_gv0, gnext = o_gv1;
  for (int t = 0; t < 2; ++t) {
    node_dot2<<<gWave, blk, 0, stream>>>(B1b, ws + o_rl_w + t * 2 * G + G,
                                         nullptr, ws + o_dh, nullptr, N);
    attn_kernel<<<dim3(B), blk, 0, stream>>>(ws + gcur, B1b, ws + o_rl_w + t * 2 * G,
                                             ws + o_dh, ws + o_rl_b + t, ws + o_gwt);
    gemm_kernel<<<gBG, blk, 0, stream>>>(ws + o_gwt, ws + o_rp_w + (size_t)t * G * G,
                                         ws + o_rp_b + t * G, nullptr,
                                         ws + o_grep, nullptr, nullptr, B, G, G, 2);
    mfma_gru<float, float><<<dim3(gru_grid(B)), blk, 0, stream>>>(
        ws + o_grep, ws + gcur,
        (const unsigned short*)(ws + (t == 0 ? o_rg0ihT : o_rg1ihT)),
        (const unsigned short*)(ws + (t == 0 ? o_rg0hhT : o_rg1hhT)),
        ws + o_rg_bih + t * 3 * G, ws + o_rg_bhh + t * 3 * G,
        ws + gnext, B, 0);
    gcur = gnext;
    gnext = o_gv2;
  }
  dim3 gOut((B + Bb - 1) / Bb, (P + Bn - 1) / Bn);
  gemm_kernel<<<gOut, blk, 0, stream>>>(ws + gcur, ws + o_t_w, ws + o_t_b, nullptr,
                                        nullptr, d_out, flag, B, P, G, 0);
}

// Round 9
// 910.839 us; speedup vs baseline: 4.4623x; 1.0417x over previous
//
#include <hip/hip_runtime.h>
#include <hip/hip_bf16.h>

// ---------------- constants ----------------
#define NN 50000
#define MM 400000
#define BB 1000
#define FF 39
#define EE 11
#define GG 200
#define PP 128

typedef __attribute__((ext_vector_type(8))) short bf16x8;
typedef __attribute__((ext_vector_type(4))) float f32x4;
struct us4 { unsigned short x, y, z, w; };

// ---------------- helpers ----------------
__device__ __forceinline__ float bf2f(unsigned short u) {
  return __uint_as_float(((unsigned int)u) << 16);
}
__device__ __forceinline__ unsigned short f2bf(float x) {
  union { __hip_bfloat16 b; unsigned short u; } v;
  v.b = __float2bfloat16(x);
  return v.u;
}
__device__ __forceinline__ float leakyf(float x) { return x > 0.f ? x : 0.01f * x; }
__device__ __forceinline__ float eluf(float x)   { return x > 0.f ? x : (expf(x) - 1.f); }
__device__ __forceinline__ float sigmf(float x)  { return 1.f / (1.f + expf(-x)); }
template <typename T> __device__ __forceinline__ float ldv(const T* p);
template <> __device__ __forceinline__ float ldv<float>(const float* p) { return *p; }
template <> __device__ __forceinline__ float ldv<unsigned short>(const unsigned short* p) { return bf2f(*p); }

// direct global A-fragment load: 8 consecutive elements at base+off (16B aligned)
template <typename T>
__device__ __forceinline__ bf16x8 afrag(const T* base, size_t off) {
  if constexpr (sizeof(T) == 2) {
    return *(const bf16x8*)(base + off);
  } else {
    float4 f0 = *(const float4*)(base + off);
    float4 f1 = *(const float4*)(base + off + 4);
    short t[8];
    t[0] = (short)f2bf(f0.x); t[1] = (short)f2bf(f0.y);
    t[2] = (short)f2bf(f0.z); t[3] = (short)f2bf(f0.w);
    t[4] = (short)f2bf(f1.x); t[5] = (short)f2bf(f1.y);
    t[6] = (short)f2bf(f1.z); t[7] = (short)f2bf(f1.w);
    return *(bf16x8*)t;
  }
}

// ---------------- runtime dtype detection ----------------
__global__ __launch_bounds__(256) void detect_dtype(const unsigned int* __restrict__ w,
                                                    int* __restrict__ flag) {
  __shared__ int cnt[256];
  int c = 0;
  for (int i = threadIdx.x; i < 2048; i += 256) {
    unsigned int e = (w[i] >> 8) & 0x7F;
    c += (e >= 60 && e <= 64) ? 1 : 0;
  }
  cnt[threadIdx.x] = c;
  __syncthreads();
  for (int s = 128; s; s >>= 1) {
    if (threadIdx.x < s) cnt[threadIdx.x] += cnt[threadIdx.x + s];
    __syncthreads();
  }
  if (threadIdx.x == 0) *flag = (cnt[0] >= 1024) ? 1 : 0;
}

// ---------------- batched conversion to f32 ----------------
struct CvtJob { const void* s; float* d; int n; int pad; };
struct CvtJobs32 { CvtJob j[32]; };

__global__ __launch_bounds__(256) void cvt_any(CvtJobs32 jobs, const int* __restrict__ flag) {
  CvtJob job = jobs.j[blockIdx.y];
  int isbf = *flag;
  if (isbf) {
    const unsigned short* s = (const unsigned short*)job.s;
    for (int i = blockIdx.x * 256 + threadIdx.x; i < job.n; i += gridDim.x * 256)
      job.d[i] = bf2f(s[i]);
  } else {
    const float* s = (const float*)job.s;
    for (int i = blockIdx.x * 256 + threadIdx.x; i < job.n; i += gridDim.x * 256)
      job.d[i] = s[i];
  }
}

// Xn -> bf16 padded [N][40]
__global__ __launch_bounds__(256) void cvt_xn(const void* __restrict__ src,
                                              unsigned short* __restrict__ dstb,
                                              const int* __restrict__ flag, int N) {
  int isbf = *flag;
  int total = N * 40;
  for (int i = blockIdx.x * 256 + threadIdx.x; i < total; i += gridDim.x * 256) {
    int n = i / 40, k = i - n * 40;
    unsigned short v = 0;
    if (k < FF) {
      if (isbf) v = ((const unsigned short*)src)[n * FF + k];
      else      v = f2bf(((const float*)src)[n * FF + k]);
    }
    dstb[i] = v;
  }
}

// ---------------- weight transpose+cvt: W f32 [K][N] -> Wt bf16 [N][KP] (k-padded) ----------------
struct TJob { const float* s; unsigned short* d; int K; int N; int KP; int pad; };
struct TJobs12 { TJob j[12]; };

__global__ __launch_bounds__(256) void transpose_bf16(TJobs12 jobs) {
  TJob job = jobs.j[blockIdx.y];
  int total = job.N * job.KP;
  for (int idx = blockIdx.x * 256 + threadIdx.x; idx < total; idx += gridDim.x * 256) {
    int n = idx / job.KP, k = idx - n * job.KP;
    job.d[idx] = (k < job.K) ? f2bf(job.s[(size_t)k * job.N + n]) : (unsigned short)0;
  }
}

// ---------------- CSR build ----------------
__global__ __launch_bounds__(256) void hist_kernel(const int* __restrict__ dst,
                                                   int* __restrict__ cnt, int M) {
  int e = blockIdx.x * 256 + threadIdx.x;
  if (e < M) atomicAdd(&cnt[dst[e]], 1);
}

#define SCHUNK 2048
__global__ __launch_bounds__(256) void scan1_kernel(const int* __restrict__ cnt,
                                                    int* __restrict__ incl,
                                                    int* __restrict__ bsum, int n) {
  __shared__ int lds[256];
  int b = blockIdx.x, tid = threadIdx.x;
  int base = b * SCHUNK + tid * 8;
  int v[8], s = 0;
#pragma unroll
  for (int j = 0; j < 8; ++j) { int i = base + j; v[j] = (i < n) ? cnt[i] : 0; s += v[j]; }
  lds[tid] = s;
  __syncthreads();
  for (int o = 1; o < 256; o <<= 1) {
    int t = (tid >= o) ? lds[tid - o] : 0;
    __syncthreads();
    lds[tid] += t;
    __syncthreads();
  }
  int run = lds[tid] - s;
#pragma unroll
  for (int j = 0; j < 8; ++j) {
    run += v[j];
    int i = base + j;
    if (i < n) incl[i] = run;
  }
  if (tid == 255) bsum[b] = lds[255];
}

__global__ void scan2_kernel(int* __restrict__ bsum, int nb) {
  if (threadIdx.x == 0 && blockIdx.x == 0) {
    int run = 0;
    for (int i = 0; i < nb; ++i) { int t = bsum[i]; bsum[i] = run; run += t; }
  }
}

__global__ __launch_bounds__(256) void scan3_kernel(const int* __restrict__ incl,
                                                    const int* __restrict__ cnt,
                                                    const int* __restrict__ bsum,
                                                    int* __restrict__ offA,
                                                    int* __restrict__ cur, int n) {
  int i = blockIdx.x * 256 + threadIdx.x;
  if (i >= n) return;
  int o = incl[i] - cnt[i] + bsum[i / SCHUNK];
  offA[i] = o;
  cur[i] = o;
}

__global__ __launch_bounds__(256) void fill_kernel(const int* __restrict__ dst,
                                                   int* __restrict__ cur,
                                                   int* __restrict__ elist, int M) {
  int e = blockIdx.x * 256 + threadIdx.x;
  if (e >= M) return;
  int pos = atomicAdd(&cur[dst[e]], 1);
  elist[pos] = e;
}

// ---------------- layer-1 fused aggregation: one wave per block ----------------
__global__ __launch_bounds__(64) void l1_agg(
    const float* __restrict__ Xe, const unsigned short* __restrict__ xa,
    const unsigned short* __restrict__ hvnew,
    const float* __restrict__ pe1w_e, const float* __restrict__ pe1b,
    const float* __restrict__ pe2w_n, const float* __restrict__ pe2w_e,
    const float* __restrict__ pe2b, const int* __restrict__ srcA,
    const int* __restrict__ offA, const int* __restrict__ cntA, const int* __restrict__ elist,
    unsigned short* __restrict__ S, float* __restrict__ ssumOut, int N)
{
  int v = blockIdx.x;
  int lane = threadIdx.x;
  if (v >= N) return;
  int begin = offA[v], cnt = cntA[v];
  bool act = lane < 50;
  int kb = act ? 4 * lane : 0;
  float b[4], p[4], pn[4];
  float pw[EE][4];
#pragma unroll
  for (int j = 0; j < 4; ++j) {
    b[j]  = pe1b[kb + j];
    p[j]  = act ? pe2w_e[kb + j] : 0.f;
    pn[j] = act ? pe2w_n[kb + j] : 0.f;
  }
#pragma unroll
  for (int jj = 0; jj < EE; ++jj)
#pragma unroll
    for (int j = 0; j < 4; ++j) pw[jj][j] = pe1w_e[jj * GG + kb + j];

  us4 hv = *(const us4*)(hvnew + (size_t)v * GG + kb);
  float da = bf2f(hv.x) * pn[0] + bf2f(hv.y) * pn[1] + bf2f(hv.z) * pn[2] + bf2f(hv.w) * pn[3];
#pragma unroll
  for (int o = 32; o; o >>= 1) da += __shfl_down(da, o);
  float alv = __shfl(da, 0) + pe2b[0];

  float ss = 0.f;
  float a0 = 0.f, a1 = 0.f, a2 = 0.f, a3 = 0.f;
  int t = 0;
  for (; t + 4 <= cnt; t += 4) {
    int e[4], s[4];
#pragma unroll
    for (int u = 0; u < 4; ++u) {
      e[u] = __builtin_amdgcn_readfirstlane(elist[begin + t + u]);
      s[u] = __builtin_amdgcn_readfirstlane(srcA[e[u]]);
    }
    us4 g[4];
#pragma unroll
    for (int u = 0; u < 4; ++u) g[u] = *(const us4*)(xa + (size_t)s[u] * GG + kb);
    float h[4][4];
#pragma unroll
    for (int u = 0; u < 4; ++u) {
      h[u][0] = bf2f(g[u].x) + b[0];
      h[u][1] = bf2f(g[u].y) + b[1];
      h[u][2] = bf2f(g[u].z) + b[2];
      h[u][3] = bf2f(g[u].w) + b[3];
    }
#pragma unroll
    for (int jj = 0; jj < EE; ++jj) {
#pragma unroll
      for (int u = 0; u < 4; ++u) {
        float x = Xe[(size_t)e[u] * EE + jj];
        h[u][0] += x * pw[jj][0]; h[u][1] += x * pw[jj][1];
        h[u][2] += x * pw[jj][2]; h[u][3] += x * pw[jj][3];
      }
    }
    float bp[4];
#pragma unroll
    for (int u = 0; u < 4; ++u) {
#pragma unroll
      for (int j = 0; j < 4; ++j) h[u][j] = leakyf(h[u][j]);
      bp[u] = h[u][0] * p[0] + h[u][1] * p[1] + h[u][2] * p[2] + h[u][3] * p[3];
    }
#pragma unroll
    for (int o = 32; o; o >>= 1) {
#pragma unroll
      for (int u = 0; u < 4; ++u) bp[u] += __shfl_down(bp[u], o);
    }
#pragma unroll
    for (int u = 0; u < 4; ++u) {
      float w = __expf(fminf(leakyf(alv + __shfl(bp[u], 0)), 60.f));
      ss += w;
      a0 += w * h[u][0]; a1 += w * h[u][1]; a2 += w * h[u][2]; a3 += w * h[u][3];
    }
  }
  for (; t < cnt; ++t) {
    int e0 = __builtin_amdgcn_readfirstlane(elist[begin + t]);
    int s0 = __builtin_amdgcn_readfirstlane(srcA[e0]);
    us4 g0 = *(const us4*)(xa + (size_t)s0 * GG + kb);
    float h0 = bf2f(g0.x) + b[0], h1 = bf2f(g0.y) + b[1];
    float h2 = bf2f(g0.z) + b[2], h3 = bf2f(g0.w) + b[3];
#pragma unroll
    for (int jj = 0; jj < EE; ++jj) {
      float x = Xe[(size_t)e0 * EE + jj];
      h0 += x * pw[jj][0]; h1 += x * pw[jj][1];
      h2 += x * pw[jj][2]; h3 += x * pw[jj][3];
    }
    h0 = leakyf(h0); h1 = leakyf(h1); h2 = leakyf(h2); h3 = leakyf(h3);
    float bp = h0 * p[0] + h1 * p[1] + h2 * p[2] + h3 * p[3];
#pragma unroll
    for (int o = 32; o; o >>= 1) bp += __shfl_down(bp, o);
    float w = __expf(fminf(leakyf(alv + __shfl(bp, 0)), 60.f));
    ss += w;
    a0 += w * h0; a1 += w * h1; a2 += w * h2; a3 += w * h3;
  }
  float inv = (cnt > 0) ? 1.f / ss : 0.f;
  if (act) {
    us4 o4;
    o4.x = f2bf(a0 * inv); o4.y = f2bf(a1 * inv);
    o4.z = f2bf(a2 * inv); o4.w = f2bf(a3 * inv);
    *(us4*)(S + (size_t)v * GG + kb) = o4;
  }
  if (lane == 0) ssumOut[v] = (cnt > 0) ? ss : 0.f;
}

// ---------------- layer-2 fused aggregation: one wave per block ----------------
__global__ __launch_bounds__(64) void l2_agg(
    const unsigned short* __restrict__ hvp, const float* __restrict__ gd,
    const float* __restrict__ gs, const float* __restrict__ lpeb,
    const int* __restrict__ srcA,
    const int* __restrict__ offA, const int* __restrict__ cntA, const int* __restrict__ elist,
    unsigned short* __restrict__ S2, int N)
{
  int v = blockIdx.x;
  int lane = threadIdx.x;
  if (v >= N) return;
  int begin = offA[v], cnt = cntA[v];
  bool act = lane < 50;
  int kb = act ? 4 * lane : 0;
  float gdv = gd[v] + lpeb[0];
  float ss = 0.f;
  float a0 = 0.f, a1 = 0.f, a2 = 0.f, a3 = 0.f;
  int t = 0;
  for (; t + 4 <= cnt; t += 4) {
    int e[4], s[4];
#pragma unroll
    for (int u = 0; u < 4; ++u) {
      e[u] = __builtin_amdgcn_readfirstlane(elist[begin + t + u]);
      s[u] = __builtin_amdgcn_readfirstlane(srcA[e[u]]);
    }
    us4 g0 = *(const us4*)(hvp + (size_t)s[0] * GG + kb);
    us4 g1 = *(const us4*)(hvp + (size_t)s[1] * GG + kb);
    us4 g2 = *(const us4*)(hvp + (size_t)s[2] * GG + kb);
    us4 g3 = *(const us4*)(hvp + (size_t)s[3] * GG + kb);
    float w0 = __expf(fminf(leakyf(gdv + gs[s[0]]), 60.f));
    float w1 = __expf(fminf(leakyf(gdv + gs[s[1]]), 60.f));
    float w2 = __expf(fminf(leakyf(gdv + gs[s[2]]), 60.f));
    float w3 = __expf(fminf(leakyf(gdv + gs[s[3]]), 60.f));
    ss += w0 + w1 + w2 + w3;
    a0 += w0 * bf2f(g0.x) + w1 * bf2f(g1.x) + w2 * bf2f(g2.x) + w3 * bf2f(g3.x);
    a1 += w0 * bf2f(g0.y) + w1 * bf2f(g1.y) + w2 * bf2f(g2.y) + w3 * bf2f(g3.y);
    a2 += w0 * bf2f(g0.z) + w1 * bf2f(g1.z) + w2 * bf2f(g2.z) + w3 * bf2f(g3.z);
    a3 += w0 * bf2f(g0.w) + w1 * bf2f(g1.w) + w2 * bf2f(g2.w) + w3 * bf2f(g3.w);
  }
  for (; t < cnt; ++t) {
    int e = __builtin_amdgcn_readfirstlane(elist[begin + t]);
    int s = __builtin_amdgcn_readfirstlane(srcA[e]);
    us4 g = *(const us4*)(hvp + (size_t)s * GG + kb);
    float w = __expf(fminf(leakyf(gdv + gs[s]), 60.f));
    ss += w;
    a0 += w * bf2f(g.x); a1 += w * bf2f(g.y);
    a2 += w * bf2f(g.z); a3 += w * bf2f(g.w);
  }
  float inv = (cnt > 0) ? 1.f / ss : 0.f;
  if (act) {
    us4 o4;
    o4.x = f2bf((cnt > 0) ? eluf(a0 * inv) : 0.f);
    o4.y = f2bf((cnt > 0) ? eluf(a1 * inv) : 0.f);
    o4.z = f2bf((cnt > 0) ? eluf(a2 * inv) : 0.f);
    o4.w = f2bf((cnt > 0) ? eluf(a3 * inv) : 0.f);
    *(us4*)(S2 + (size_t)v * GG + kb) = o4;
  }
}

// ================= direct-from-L2 MFMA GEMM (no LDS, no barriers) =================
// A: [Mr][strideA] (bf16); Wt: [Nc][KP] bf16, zero-padded k>=K.
__global__ __launch_bounds__(256) void mfma_gemm_d(
    const unsigned short* __restrict__ A, int strideA,
    const unsigned short* __restrict__ Wt, int KP,
    const float* __restrict__ bias, const float* __restrict__ rowmask,
    unsigned short* __restrict__ Cb, int Mr, int Nc, int act)
{
  int ncol = (Nc + 63) >> 6;
  int nrowt = (Mr + 127) >> 7;
  int per = 8 * ncol;
  int grp = blockIdx.x / per, rem = blockIdx.x % per;
  int rowt = grp * 8 + (rem & 7), colt = rem >> 3;
  if (rowt >= nrowt) return;
  int row0 = rowt * 128, col0 = colt * 64;
  int tid = threadIdx.x;
  int w = tid >> 6, lane = tid & 63, quad = lane >> 4, l15 = lane & 15;

  int rA0 = min(row0 + w * 32 + l15, Mr - 1);
  int rA1 = min(row0 + w * 32 + 16 + l15, Mr - 1);
  int nB[4];
#pragma unroll
  for (int c = 0; c < 4; ++c) nB[c] = min(col0 + c * 16 + l15, Nc - 1);

  f32x4 zero4 = {0.f, 0.f, 0.f, 0.f};
  f32x4 acc[2][4];
#pragma unroll
  for (int r = 0; r < 2; ++r)
#pragma unroll
    for (int c = 0; c < 4; ++c) acc[r][c] = zero4;

  for (int k0 = 0; k0 < KP; k0 += 32) {
    int kq = k0 + quad * 8;
    bf16x8 a0 = afrag(A, (size_t)rA0 * strideA + kq);
    bf16x8 a1 = afrag(A, (size_t)rA1 * strideA + kq);
    bf16x8 b[4];
#pragma unroll
    for (int c = 0; c < 4; ++c) b[c] = afrag(Wt, (size_t)nB[c] * KP + kq);
#pragma unroll
    for (int c = 0; c < 4; ++c) {
      acc[0][c] = __builtin_amdgcn_mfma_f32_16x16x32_bf16(a0, b[c], acc[0][c], 0, 0, 0);
      acc[1][c] = __builtin_amdgcn_mfma_f32_16x16x32_bf16(a1, b[c], acc[1][c], 0, 0, 0);
    }
  }
#pragma unroll
  for (int r = 0; r < 2; ++r) {
#pragma unroll
    for (int c = 0; c < 4; ++c) {
      int col = col0 + c * 16 + l15;
      if (col >= Nc) continue;
#pragma unroll
      for (int i = 0; i < 4; ++i) {
        int row = row0 + w * 32 + r * 16 + quad * 4 + i;
        if (row >= Mr) continue;
        bool valid = (rowmask == nullptr) || (rowmask[row] > 0.f);
        float v = valid ? (acc[r][c][i] + (bias ? bias[col] : 0.f)) : 0.f;
        if (act == 1) v = leakyf(v);
        else if (act == 2) v = eluf(v);
        Cb[(size_t)row * Nc + col] = f2bf(v);
      }
    }
  }
}

// ================= direct-from-L2 fused MFMA GRU (no LDS, no barriers) =================
// X,H: [R][200] (TI); WtIH/WtHH: [600][KP] bf16, zero-padded.
template <typename TI, typename TO>
__global__ __launch_bounds__(256) void mfma_gru_d(
    const TI* __restrict__ X, const TI* __restrict__ H,
    const unsigned short* __restrict__ WtIH, const unsigned short* __restrict__ WtHH,
    int KP, const float* __restrict__ bih, const float* __restrict__ bhh,
    TO* __restrict__ Out, int R, int relu_out)
{
  int nrowt = (R + 127) >> 7;
  int grp = blockIdx.x / 56, rem = blockIdx.x % 56;
  int rowt = grp * 8 + (rem & 7), colt = rem >> 3;
  if (rowt >= nrowt) return;
  int row0 = rowt * 128, col0 = colt * 32;
  int tid = threadIdx.x;
  int w = tid >> 6, lane = tid & 63, quad = lane >> 4, l15 = lane & 15;

  int rA0 = min(row0 + w * 32 + l15, R - 1);
  int rA1 = min(row0 + w * 32 + 16 + l15, R - 1);
  int nB0 = min(col0 + l15, GG - 1);
  int nB1 = min(col0 + 16 + l15, GG - 1);

  f32x4 zero4 = {0.f, 0.f, 0.f, 0.f};
  f32x4 acc[6][2][2];
#pragma unroll
  for (int g = 0; g < 6; ++g)
#pragma unroll
    for (int r = 0; r < 2; ++r)
#pragma unroll
      for (int c = 0; c < 2; ++c) acc[g][r][c] = zero4;

  for (int k0 = 0; k0 < KP; k0 += 32) {
    int kq = k0 + quad * 8;
    bf16x8 ax0 = afrag(X, (size_t)rA0 * GG + kq);
    bf16x8 ax1 = afrag(X, (size_t)rA1 * GG + kq);
    bf16x8 ah0 = afrag(H, (size_t)rA0 * GG + kq);
    bf16x8 ah1 = afrag(H, (size_t)rA1 * GG + kq);
#pragma unroll
    for (int g = 0; g < 3; ++g) {
      bf16x8 bi0 = afrag(WtIH, (size_t)(g * GG + nB0) * KP + kq);
      bf16x8 bi1 = afrag(WtIH, (size_t)(g * GG + nB1) * KP + kq);
      bf16x8 bh0 = afrag(WtHH, (size_t)(g * GG + nB0) * KP + kq);
      bf16x8 bh1 = afrag(WtHH, (size_t)(g * GG + nB1) * KP + kq);
      acc[g][0][0] = __builtin_amdgcn_mfma_f32_16x16x32_bf16(ax0, bi0, acc[g][0][0], 0, 0, 0);
      acc[g][0][1] = __builtin_amdgcn_mfma_f32_16x16x32_bf16(ax0, bi1, acc[g][0][1], 0, 0, 0);
      acc[g][1][0] = __builtin_amdgcn_mfma_f32_16x16x32_bf16(ax1, bi0, acc[g][1][0], 0, 0, 0);
      acc[g][1][1] = __builtin_amdgcn_mfma_f32_16x16x32_bf16(ax1, bi1, acc[g][1][1], 0, 0, 0);
      acc[g + 3][0][0] = __builtin_amdgcn_mfma_f32_16x16x32_bf16(ah0, bh0, acc[g + 3][0][0], 0, 0, 0);
      acc[g + 3][0][1] = __builtin_amdgcn_mfma_f32_16x16x32_bf16(ah0, bh1, acc[g + 3][0][1], 0, 0, 0);
      acc[g + 3][1][0] = __builtin_amdgcn_mfma_f32_16x16x32_bf16(ah1, bh0, acc[g + 3][1][0], 0, 0, 0);
      acc[g + 3][1][1] = __builtin_amdgcn_mfma_f32_16x16x32_bf16(ah1, bh1, acc[g + 3][1][1], 0, 0, 0);
    }
  }
#pragma unroll
  for (int r = 0; r < 2; ++r) {
#pragma unroll
    for (int c = 0; c < 2; ++c) {
      int col = col0 + c * 16 + l15;
      if (col >= GG) continue;
      float br = bih[col],       bhr = bhh[col];
      float bz = bih[200 + col], bhz = bhh[200 + col];
      float bn = bih[400 + col], bhn = bhh[400 + col];
#pragma unroll
      for (int i = 0; i < 4; ++i) {
        int row = row0 + w * 32 + r * 16 + quad * 4 + i;
        if (row >= R) continue;
        float rr = sigmf(acc[0][r][c][i] + br + acc[3][r][c][i] + bhr);
        float zz = sigmf(acc[1][r][c][i] + bz + acc[4][r][c][i] + bhz);
        float nn = tanhf(acc[2][r][c][i] + bn + rr * (acc[5][r][c][i] + bhn));
        float hval = ldv<TI>(H + (size_t)row * GG + col);
        float o = (1.f - zz) * nn + zz * hval;
        if (relu_out) o = fmaxf(o, 0.f);
        if constexpr (sizeof(TO) == 2) Out[(size_t)row * GG + col] = f2bf(o);
        else Out[(size_t)row * GG + col] = o;
      }
    }
  }
}

// ---------------- fp32 tiled GEMM (small readout shapes) ----------------
#define Bb 64
#define Bn 64
#define Bk 16
__global__ __launch_bounds__(256) void gemm_kernel(
    const float* __restrict__ A, const float* __restrict__ W,
    const float* __restrict__ bias, const float* __restrict__ rowmask,
    float* __restrict__ Cf, void* __restrict__ Oout, const int* __restrict__ oflag,
    int Mr, int Nc, int K, int act)
{
  __shared__ float As[Bk][Bb + 1];
  __shared__ float Ws[Bk][Bn];
  int row0 = blockIdx.x * Bb, col0 = blockIdx.y * Bn;
  int tid = threadIdx.x;
  int ty = tid >> 4, tx = tid & 15;
  float acc[4][4] = {};
  for (int k0 = 0; k0 < K; k0 += Bk) {
    for (int l = tid; l < Bb * Bk; l += 256) {
      int m = l >> 4, kk = l & 15;
      int r = row0 + m, k = k0 + kk;
      As[kk][m] = (r < Mr && k < K) ? A[(size_t)r * K + k] : 0.f;
    }
    for (int l = tid; l < Bk * Bn; l += 256) {
      int kk = l >> 6, nn = l & 63;
      int k = k0 + kk, c = col0 + nn;
      Ws[kk][nn] = (k < K && c < Nc) ? W[(size_t)k * Nc + c] : 0.f;
    }
    __syncthreads();
#pragma unroll
    for (int kk = 0; kk < Bk; ++kk) {
      float av[4], bv[4];
#pragma unroll
      for (int i = 0; i < 4; ++i) av[i] = As[kk][ty * 4 + i];
#pragma unroll
      for (int j = 0; j < 4; ++j) bv[j] = Ws[kk][tx * 4 + j];
#pragma unroll
      for (int i = 0; i < 4; ++i)
#pragma unroll
        for (int j = 0; j < 4; ++j) acc[i][j] += av[i] * bv[j];
    }
    __syncthreads();
  }
  int isbf = (oflag != nullptr) ? *oflag : 0;
#pragma unroll
  for (int i = 0; i < 4; ++i) {
    int r = row0 + ty * 4 + i;
    if (r >= Mr) continue;
    bool valid = (rowmask == nullptr) || (rowmask[r] > 0.f);
#pragma unroll
    for (int j = 0; j < 4; ++j) {
      int c = col0 + tx * 4 + j;
      if (c >= Nc) continue;
      float v = valid ? (acc[i][j] + (bias ? bias[c] : 0.f)) : 0.f;
      if (act == 1) v = leakyf(v);
      else if (act == 2) v = eluf(v);
      else if (act == 3) v = fmaxf(v, 0.f);
      size_t idx = (size_t)r * Nc + c;
      if (Oout) {
        if (isbf) ((__hip_bfloat16*)Oout)[idx] = __float2bfloat16(v);
        else      ((float*)Oout)[idx] = v;
      } else {
        Cf[idx] = v;
      }
    }
  }
}

// ---------------- per-node dot(s), bf16 input ----------------
__global__ __launch_bounds__(256) void node_dot2(
    const unsigned short* __restrict__ X, const float* __restrict__ w1,
    const float* __restrict__ w2,
    float* __restrict__ o1, float* __restrict__ o2, int N)
{
  int v = (blockIdx.x * 256 + threadIdx.x) >> 6;
  int lane = threadIdx.x & 63;
  if (v >= N) return;
  float d1 = 0.f, d2 = 0.f;
  for (int k = lane; k < GG; k += 64) {
    float x = bf2f(X[(size_t)v * GG + k]);
    d1 += x * w1[k];
    if (w2) d2 += x * w2[k];
  }
  for (int off = 32; off; off >>= 1) {
    d1 += __shfl_down(d1, off);
    if (w2) d2 += __shfl_down(d2, off);
  }
  if (lane == 0) { o1[v] = d1; if (w2) o2[v] = d2; }
}

__global__ __launch_bounds__(256) void graph_sum(
    const unsigned short* __restrict__ h, float* __restrict__ g)
{
  int b = blockIdx.x, k = threadIdx.x;
  if (k < GG) {
    float a = 0.f;
    for (int i = 0; i < 50; ++i) a += bf2f(h[((size_t)b * 50 + i) * GG + k]);
    g[(size_t)b * GG + k] = a;
  }
}

__global__ __launch_bounds__(256) void attn_kernel(
    const float* __restrict__ g, const unsigned short* __restrict__ h2,
    const float* __restrict__ w1, const float* __restrict__ dh,
    const float* __restrict__ rb, float* __restrict__ weighted)
{
  int b = blockIdx.x;
  __shared__ float red[256];
  __shared__ float zs[50];
  __shared__ float as_[50];
  __shared__ float dgs;
  int tid = threadIdx.x;
  float p = 0.f;
  if (tid < GG) p = fmaxf(g[(size_t)b * GG + tid], 0.f) * w1[tid];
  red[tid] = p;
  __syncthreads();
  for (int s = 128; s; s >>= 1) { if (tid < s) red[tid] += red[tid + s]; __syncthreads(); }
  if (tid == 0) dgs = red[0];
  __syncthreads();
  if (tid < 50) zs[tid] = leakyf(dgs + dh[b * 50 + tid] + rb[0]);
  __syncthreads();
  if (tid == 0) {
    float m = -1e30f;
    for (int i = 0; i < 50; ++i) m = fmaxf(m, zs[i]);
    float s = 0.f;
    for (int i = 0; i < 50; ++i) { float e = expf(zs[i] - m); as_[i] = e; s += e; }
    float inv = 1.f / s;
    for (int i = 0; i < 50; ++i) as_[i] *= inv;
  }
  __syncthreads();
  if (tid < GG) {
    float a = 0.f;
    for (int i = 0; i < 50; ++i) a += as_[i] * bf2f(h2[((size_t)b * 50 + i) * GG + tid]);
    weighted[(size_t)b * GG + tid] = a;
  }
}

// ---------------- host ----------------
static inline int gemm_grid(int Mr, int Nc) {
  int nrow = (Mr + 127) / 128, ncol = (Nc + 63) / 64;
  return ((nrow + 7) / 8) * 8 * ncol;
}
static inline int gru_grid(int R) {
  int nrow = (R + 127) / 128;
  return ((nrow + 7) / 8) * 56;
}

extern "C" void kernel_launch(void* const* d_in, const int* in_sizes, int n_in,
                              void* d_out, int out_size, void* d_ws, size_t ws_size,
                              hipStream_t stream)
{
  (void)n_in; (void)out_size; (void)ws_size;
  const int N = NN, M = MM, B = BB, F = FF, G = GG, P = PP;
  const int KP200 = 224, KP39 = 64;
  float* ws = (float*)d_ws;
  size_t off = 0;
  auto alloc = [&](size_t n) { size_t o = off; off += (n + 63) & ~(size_t)63; return o; };

  size_t o_flag = alloc(16);
  size_t o_pn_w = alloc(F * G), o_pn_b = alloc(G);
  size_t o_pe1_w = alloc((F + EE) * G), o_pe1_b = alloc(G);
  size_t o_pe2_w = alloc(2 * G), o_pe2_b = alloc(1);
  size_t o_et_w = alloc(G * G), o_et_b = alloc(G);
  size_t o_g0_wih = alloc(G * 3 * G), o_g0_whh = alloc(G * 3 * G);
  size_t o_g0_bih = alloc(3 * G), o_g0_bhh = alloc(3 * G);
  size_t o_lpe_w = alloc(2 * G), o_lpe_b = alloc(1);
  size_t o_lpn_w = alloc(G * G), o_lpn_b = alloc(G);
  size_t o_g1_wih = alloc(G * 3 * G), o_g1_whh = alloc(G * 3 * G);
  size_t o_g1_bih = alloc(3 * G), o_g1_bhh = alloc(3 * G);
  size_t o_rl_w = alloc(2 * 2 * G), o_rl_b = alloc(2);
  size_t o_rp_w = alloc(2 * G * G), o_rp_b = alloc(2 * G);
  size_t o_rg_wih = alloc(2 * G * 3 * G), o_rg_whh = alloc(2 * G * 3 * G);
  size_t o_rg_bih = alloc(2 * 3 * G), o_rg_bhh = alloc(2 * 3 * G);
  size_t o_t_w = alloc(G * P), o_t_b = alloc(P);
  size_t o_Xnb = alloc((size_t)N * 40 / 2 + 64);      // bf16 [N][40]
  size_t o_Xe = alloc((size_t)M * EE);
  size_t o_B1 = alloc((size_t)N * G);                 // bf16 buffers (half used)
  size_t o_B2 = alloc((size_t)N * G);
  size_t o_B3 = alloc((size_t)N * G);
  size_t o_ssum = alloc(N);
  size_t o_gd = alloc(N), o_gs = alloc(N), o_dh = alloc(N);
  size_t o_gv0 = alloc((size_t)B * G), o_gwt = alloc((size_t)B * G), o_grep = alloc((size_t)B * G);
  size_t o_gv1 = alloc((size_t)B * G), o_gv2 = alloc((size_t)B * G);
  // bf16 transposed k-padded weights (float-unit sizes = shorts/2)
  size_t o_etT  = alloc(G * KP200 / 2 + 64), o_lpnT = alloc(G * KP200 / 2 + 64);
  size_t o_g0ihT = alloc(3 * G * KP200 / 2 + 64), o_g0hhT = alloc(3 * G * KP200 / 2 + 64);
  size_t o_g1ihT = alloc(3 * G * KP200 / 2 + 64), o_g1hhT = alloc(3 * G * KP200 / 2 + 64);
  size_t o_rg0ihT = alloc(3 * G * KP200 / 2 + 64), o_rg0hhT = alloc(3 * G * KP200 / 2 + 64);
  size_t o_rg1ihT = alloc(3 * G * KP200 / 2 + 64), o_rg1hhT = alloc(3 * G * KP200 / 2 + 64);
  size_t o_pnT = alloc(G * KP39 / 2 + 64), o_pe1T = alloc(G * KP39 / 2 + 64);
  size_t o_cnt = alloc(N), o_off = alloc(N), o_cur = alloc(N);
  size_t o_elist = alloc(M), o_bsum = alloc(64), o_incl = alloc(N);

  int* flag = (int*)(ws + o_flag);
  int* cntA = (int*)(ws + o_cnt);
  int* offA = (int*)(ws + o_off);
  int* curA = (int*)(ws + o_cur);
  int* elist = (int*)(ws + o_elist);
  int* bsum = (int*)(ws + o_bsum);
  int* incl = (int*)(ws + o_incl);
  unsigned short* Xnb = (unsigned short*)(ws + o_Xnb);
  unsigned short* B1b = (unsigned short*)(ws + o_B1);
  unsigned short* B2b = (unsigned short*)(ws + o_B2);
  unsigned short* B3b = (unsigned short*)(ws + o_B3);

  CvtJobs32 jobs;
  int ji = 0;
  auto push = [&](int idx, size_t dsto) {
    jobs.j[ji].s = d_in[idx];
    jobs.j[ji].d = ws + dsto;
    jobs.j[ji].n = in_sizes[idx];
    jobs.j[ji].pad = 0;
    ++ji;
  };
  push(1, o_Xe);
  push(2, o_pn_w);  push(3, o_pn_b);
  push(4, o_pe1_w); push(5, o_pe1_b);
  push(6, o_pe2_w); push(7, o_pe2_b);
  push(8, o_et_w);  push(9, o_et_b);
  push(10, o_g0_wih); push(11, o_g0_whh); push(12, o_g0_bih); push(13, o_g0_bhh);
  push(14, o_lpe_w);  push(15, o_lpe_b);
  push(16, o_lpn_w);  push(17, o_lpn_b);
  push(18, o_g1_wih); push(19, o_g1_whh); push(20, o_g1_bih); push(21, o_g1_bhh);
  push(22, o_rl_w);   push(23, o_rl_b);
  push(24, o_rp_w);   push(25, o_rp_b);
  push(26, o_rg_wih); push(27, o_rg_whh); push(28, o_rg_bih); push(29, o_rg_bhh);
  push(30, o_t_w);    push(31, o_t_b);
  // ji == 31

  const int* src = (const int*)d_in[32];
  const int* dst = (const int*)d_in[33];

  dim3 blk(256);
  detect_dtype<<<dim3(1), blk, 0, stream>>>((const unsigned int*)d_in[0], flag);
  cvt_any<<<dim3(512, 31), blk, 0, stream>>>(jobs, flag);
  cvt_xn<<<dim3((N * 40 + 255) / 256), blk, 0, stream>>>(d_in[0], Xnb, flag, N);

  // ---- CSR build (by dst) ----
  hipMemsetAsync(cntA, 0, (size_t)N * 4, stream);
  hist_kernel<<<dim3((M + 255) / 256), blk, 0, stream>>>(dst, cntA, M);
  int nscb = (N + SCHUNK - 1) / SCHUNK;
  scan1_kernel<<<dim3(nscb), blk, 0, stream>>>(cntA, incl, bsum, N);
  scan2_kernel<<<dim3(1), dim3(64), 0, stream>>>(bsum, nscb);
  scan3_kernel<<<dim3((N + 255) / 256), blk, 0, stream>>>(incl, cntA, bsum, offA, curA, N);
  fill_kernel<<<dim3((M + 255) / 256), blk, 0, stream>>>(dst, curA, elist, M);

  // ---- weight transposes (k-padded) ----
  TJobs12 tj;
  auto tpush = [&](int slot, size_t srcO, size_t dstO, int K, int Nc, int KPv) {
    tj.j[slot].s = ws + srcO;
    tj.j[slot].d = (unsigned short*)(ws + dstO);
    tj.j[slot].K = K; tj.j[slot].N = Nc; tj.j[slot].KP = KPv; tj.j[slot].pad = 0;
  };
  tpush(0, o_et_w,  o_etT,  G, G, KP200);
  tpush(1, o_lpn_w, o_lpnT, G, G, KP200);
  tpush(2, o_g0_wih, o_g0ihT, G, 3 * G, KP200);
  tpush(3, o_g0_whh, o_g0hhT, G, 3 * G, KP200);
  tpush(4, o_g1_wih, o_g1ihT, G, 3 * G, KP200);
  tpush(5, o_g1_whh, o_g1hhT, G, 3 * G, KP200);
  tpush(6, o_rg_wih, o_rg0ihT, G, 3 * G, KP200);
  tpush(7, o_rg_whh, o_rg0hhT, G, 3 * G, KP200);
  tpush(8, o_rg_wih + (size_t)G * 3 * G, o_rg1ihT, G, 3 * G, KP200);
  tpush(9, o_rg_whh + (size_t)G * 3 * G, o_rg1hhT, G, 3 * G, KP200);
  tpush(10, o_pn_w,  o_pnT,  F, G, KP39);
  tpush(11, o_pe1_w, o_pe1T, F, G, KP39);
  transpose_bf16<<<dim3(128, 12), blk, 0, stream>>>(tj);

  int gg = gemm_grid(N, G);
  // hv_new = leaky(Xnb@pn_w + pn_b) -> B1 bf16
  mfma_gemm_d<<<dim3(gg), blk, 0, stream>>>(
      Xnb, 40, (const unsigned short*)(ws + o_pnT), KP39,
      ws + o_pn_b, nullptr, B1b, N, G, 1);
  // xa = Xnb @ pe1_w[:39] -> B2 bf16
  mfma_gemm_d<<<dim3(gg), blk, 0, stream>>>(
      Xnb, 40, (const unsigned short*)(ws + o_pe1T), KP39,
      nullptr, nullptr, B2b, N, G, 0);
  // fused layer-1 agg (alpha computed inline from B1b); one wave per node
  l1_agg<<<dim3(N), dim3(64), 0, stream>>>(ws + o_Xe, B2b, B1b,
                                           ws + o_pe1_w + (size_t)F * G, ws + o_pe1_b,
                                           ws + o_pe2_w, ws + o_pe2_w + G, ws + o_pe2_b,
                                           src, offA, cntA, elist,
                                           B3b, ws + o_ssum, N);
  // c = elu(mask(B3@et_w + et_b)) -> B2 bf16
  mfma_gemm_d<<<dim3(gg), blk, 0, stream>>>(
      B3b, G, (const unsigned short*)(ws + o_etT), KP200,
      ws + o_et_b, ws + o_ssum, B2b, N, G, 2);
  // h = relu(GRU0(x=B2, h=B1)) -> B3 bf16
  mfma_gru_d<unsigned short, unsigned short><<<dim3(gru_grid(N)), blk, 0, stream>>>(
      B2b, B1b,
      (const unsigned short*)(ws + o_g0ihT), (const unsigned short*)(ws + o_g0hhT), KP200,
      ws + o_g0_bih, ws + o_g0_bhh, B3b, N, 1);

  // ---- layer 2 ----
  dim3 gWave((N + 3) / 4);
  node_dot2<<<gWave, blk, 0, stream>>>(B3b, ws + o_lpe_w, ws + o_lpe_w + G,
                                       ws + o_gd, ws + o_gs, N);
  // hv_proj = h@lpn_w + lpn_b -> B1 bf16
  mfma_gemm_d<<<dim3(gg), blk, 0, stream>>>(
      B3b, G, (const unsigned short*)(ws + o_lpnT), KP200,
      ws + o_lpn_b, nullptr, B1b, N, G, 0);
  l2_agg<<<dim3(N), dim3(64), 0, stream>>>(B1b, ws + o_gd, ws + o_gs, ws + o_lpe_b,
                                           src, offA, cntA, elist, B2b, N);
  // h2 = relu(GRU1(x=B2, h=B3)) -> B1 bf16
  mfma_gru_d<unsigned short, unsigned short><<<dim3(gru_grid(N)), blk, 0, stream>>>(
      B2b, B3b,
      (const unsigned short*)(ws + o_g1ihT), (const unsigned short*)(ws + o_g1hhT), KP200,
      ws + o_g1_bih, ws + o_g1_bhh, B1b, N, 1);

  // ---- readout ----
  graph_sum<<<dim3(B), blk, 0, stream>>>(B1b, ws + o_gv0);
  dim3 gBG((B + Bb - 1) / Bb, (G + Bn - 1) / Bn);
  size_t gcur = o_gv0, gnext = o_gv1;
  for (int t = 0; t < 2; ++t) {
    node_dot2<<<gWave, blk, 0, stream>>>(B1b, ws + o_rl_w + t * 2 * G + G,
                                         nullptr, ws + o_dh, nullptr, N);
    attn_kernel<<<dim3(B), blk, 0, stream>>>(ws + gcur, B1b, ws + o_rl_w + t * 2 * G,
                                             ws + o_dh, ws + o_rl_b + t, ws + o_gwt);
    gemm_kernel<<<gBG, blk, 0, stream>>>(ws + o_gwt, ws + o_rp_w + (size_t)t * G * G,
                                         ws + o_rp_b + t * G, nullptr,
                                         ws + o_grep, nullptr, nullptr, B, G, G, 2);
    mfma_gru_d<float, float><<<dim3(gru_grid(B)), blk, 0, stream>>>(
        ws + o_grep, ws + gcur,
        (const unsigned short*)(ws + (t == 0 ? o_rg0ihT : o_rg1ihT)),
        (const unsigned short*)(ws + (t == 0 ? o_rg0hhT : o_rg1hhT)), KP200,
        ws + o_rg_bih + t * 3 * G, ws + o_rg_bhh + t * 3 * G,
        ws + gnext, B, 0);
    gcur = gnext;
    gnext = o_gv2;
  }
  dim3 gOut((B + Bb - 1) / Bb, (P + Bn - 1) / Bn);
  gemm_kernel<<<gOut, blk, 0, stream>>>(ws + gcur, ws + o_t_w, ws + o_t_b, nullptr,
                                        nullptr, d_out, flag, B, P, G, 0);
}

// Round 10
// 891.252 us; speedup vs baseline: 4.5603x; 1.0220x over previous
//
#include <hip/hip_runtime.h>
#include <hip/hip_bf16.h>

// ---------------- constants ----------------
#define NN 50000
#define MM 400000
#define BB 1000
#define FF 39
#define EE 11
#define GG 200
#define PP 128

typedef __attribute__((ext_vector_type(8))) short bf16x8;
typedef __attribute__((ext_vector_type(4))) float f32x4;
struct us4 { unsigned short x, y, z, w; };

// ---------------- helpers ----------------
__device__ __forceinline__ float bf2f(unsigned short u) {
  return __uint_as_float(((unsigned int)u) << 16);
}
__device__ __forceinline__ unsigned short f2bf(float x) {
  union { __hip_bfloat16 b; unsigned short u; } v;
  v.b = __float2bfloat16(x);
  return v.u;
}
__device__ __forceinline__ float rcp_f(float x) { return __builtin_amdgcn_rcpf(x); }
__device__ __forceinline__ float leakyf(float x) { return x > 0.f ? x : 0.01f * x; }
__device__ __forceinline__ float elu_fast(float x)  { return x > 0.f ? x : __expf(x) - 1.f; }
__device__ __forceinline__ float sigm_fast(float x) { return rcp_f(1.f + __expf(-x)); }
__device__ __forceinline__ float tanh_fast(float x) { return 1.f - 2.f * rcp_f(1.f + __expf(2.f * x)); }
template <typename T> __device__ __forceinline__ float ldv(const T* p);
template <> __device__ __forceinline__ float ldv<float>(const float* p) { return *p; }
template <> __device__ __forceinline__ float ldv<unsigned short>(const unsigned short* p) { return bf2f(*p); }

// direct global A-fragment load: 8 consecutive elements at base+off (dword aligned)
template <typename T>
__device__ __forceinline__ bf16x8 afrag(const T* base, size_t off) {
  if constexpr (sizeof(T) == 2) {
    return *(const bf16x8*)(base + off);
  } else {
    float4 f0 = *(const float4*)(base + off);
    float4 f1 = *(const float4*)(base + off + 4);
    short t[8];
    t[0] = (short)f2bf(f0.x); t[1] = (short)f2bf(f0.y);
    t[2] = (short)f2bf(f0.z); t[3] = (short)f2bf(f0.w);
    t[4] = (short)f2bf(f1.x); t[5] = (short)f2bf(f1.y);
    t[6] = (short)f2bf(f1.z); t[7] = (short)f2bf(f1.w);
    return *(bf16x8*)t;
  }
}

// ---------------- runtime dtype detection ----------------
__global__ __launch_bounds__(256) void detect_dtype(const unsigned int* __restrict__ w,
                                                    int* __restrict__ flag) {
  __shared__ int cnt[256];
  int c = 0;
  for (int i = threadIdx.x; i < 2048; i += 256) {
    unsigned int e = (w[i] >> 8) & 0x7F;
    c += (e >= 60 && e <= 64) ? 1 : 0;
  }
  cnt[threadIdx.x] = c;
  __syncthreads();
  for (int s = 128; s; s >>= 1) {
    if (threadIdx.x < s) cnt[threadIdx.x] += cnt[threadIdx.x + s];
    __syncthreads();
  }
  if (threadIdx.x == 0) *flag = (cnt[0] >= 1024) ? 1 : 0;
}

// ---------------- batched conversion to f32 ----------------
struct CvtJob { const void* s; float* d; int n; int pad; };
struct CvtJobs32 { CvtJob j[32]; };

__global__ __launch_bounds__(256) void cvt_any(CvtJobs32 jobs, const int* __restrict__ flag) {
  CvtJob job = jobs.j[blockIdx.y];
  int isbf = *flag;
  if (isbf) {
    const unsigned short* s = (const unsigned short*)job.s;
    for (int i = blockIdx.x * 256 + threadIdx.x; i < job.n; i += gridDim.x * 256)
      job.d[i] = bf2f(s[i]);
  } else {
    const float* s = (const float*)job.s;
    for (int i = blockIdx.x * 256 + threadIdx.x; i < job.n; i += gridDim.x * 256)
      job.d[i] = s[i];
  }
}

// Xn -> bf16 padded [N][40]
__global__ __launch_bounds__(256) void cvt_xn(const void* __restrict__ src,
                                              unsigned short* __restrict__ dstb,
                                              const int* __restrict__ flag, int N) {
  int isbf = *flag;
  int total = N * 40;
  for (int i = blockIdx.x * 256 + threadIdx.x; i < total; i += gridDim.x * 256) {
    int n = i / 40, k = i - n * 40;
    unsigned short v = 0;
    if (k < FF) {
      if (isbf) v = ((const unsigned short*)src)[n * FF + k];
      else      v = f2bf(((const float*)src)[n * FF + k]);
    }
    dstb[i] = v;
  }
}

// ---------------- weight transpose+cvt: W f32 [K][N] -> Wt bf16 [N][KP] ----------------
struct TJob { const float* s; unsigned short* d; int K; int N; int KP; int pad; };
struct TJobs12 { TJob j[12]; };

__global__ __launch_bounds__(256) void transpose_bf16(TJobs12 jobs) {
  TJob job = jobs.j[blockIdx.y];
  int total = job.N * job.KP;
  for (int idx = blockIdx.x * 256 + threadIdx.x; idx < total; idx += gridDim.x * 256) {
    int n = idx / job.KP, k = idx - n * job.KP;
    job.d[idx] = (k < job.K) ? f2bf(job.s[(size_t)k * job.N + n]) : (unsigned short)0;
  }
}

// ---------------- CSR build ----------------
__global__ __launch_bounds__(256) void hist_kernel(const int* __restrict__ dst,
                                                   int* __restrict__ cnt, int M) {
  int e = blockIdx.x * 256 + threadIdx.x;
  if (e < M) atomicAdd(&cnt[dst[e]], 1);
}

#define SCHUNK 2048
__global__ __launch_bounds__(256) void scan1_kernel(const int* __restrict__ cnt,
                                                    int* __restrict__ incl,
                                                    int* __restrict__ bsum, int n) {
  __shared__ int lds[256];
  int b = blockIdx.x, tid = threadIdx.x;
  int base = b * SCHUNK + tid * 8;
  int v[8], s = 0;
#pragma unroll
  for (int j = 0; j < 8; ++j) { int i = base + j; v[j] = (i < n) ? cnt[i] : 0; s += v[j]; }
  lds[tid] = s;
  __syncthreads();
  for (int o = 1; o < 256; o <<= 1) {
    int t = (tid >= o) ? lds[tid - o] : 0;
    __syncthreads();
    lds[tid] += t;
    __syncthreads();
  }
  int run = lds[tid] - s;
#pragma unroll
  for (int j = 0; j < 8; ++j) {
    run += v[j];
    int i = base + j;
    if (i < n) incl[i] = run;
  }
  if (tid == 255) bsum[b] = lds[255];
}

__global__ void scan2_kernel(int* __restrict__ bsum, int nb) {
  if (threadIdx.x == 0 && blockIdx.x == 0) {
    int run = 0;
    for (int i = 0; i < nb; ++i) { int t = bsum[i]; bsum[i] = run; run += t; }
  }
}

__global__ __launch_bounds__(256) void scan3_kernel(const int* __restrict__ incl,
                                                    const int* __restrict__ cnt,
                                                    const int* __restrict__ bsum,
                                                    int* __restrict__ offA,
                                                    int* __restrict__ cur, int n) {
  int i = blockIdx.x * 256 + threadIdx.x;
  if (i >= n) return;
  int o = incl[i] - cnt[i] + bsum[i / SCHUNK];
  offA[i] = o;
  cur[i] = o;
}

__global__ __launch_bounds__(256) void fill_kernel(const int* __restrict__ dst,
                                                   int* __restrict__ cur,
                                                   int* __restrict__ elist, int M) {
  int e = blockIdx.x * 256 + threadIdx.x;
  if (e >= M) return;
  int pos = atomicAdd(&cur[dst[e]], 1);
  elist[pos] = e;
}

// ---------------- layer-1 fused aggregation: one wave per block ----------------
__global__ __launch_bounds__(64) void l1_agg(
    const float* __restrict__ Xe, const unsigned short* __restrict__ xa,
    const unsigned short* __restrict__ hvnew,
    const float* __restrict__ pe1w_e, const float* __restrict__ pe1b,
    const float* __restrict__ pe2w_n, const float* __restrict__ pe2w_e,
    const float* __restrict__ pe2b, const int* __restrict__ srcA,
    const int* __restrict__ offA, const int* __restrict__ cntA, const int* __restrict__ elist,
    unsigned short* __restrict__ S, float* __restrict__ ssumOut, int N)
{
  int v = blockIdx.x;
  int lane = threadIdx.x;
  if (v >= N) return;
  int begin = offA[v], cnt = cntA[v];
  bool act = lane < 50;
  int kb = act ? 4 * lane : 0;
  float b[4], p[4], pn[4];
  float pw[EE][4];
#pragma unroll
  for (int j = 0; j < 4; ++j) {
    b[j]  = pe1b[kb + j];
    p[j]  = act ? pe2w_e[kb + j] : 0.f;
    pn[j] = act ? pe2w_n[kb + j] : 0.f;
  }
#pragma unroll
  for (int jj = 0; jj < EE; ++jj)
#pragma unroll
    for (int j = 0; j < 4; ++j) pw[jj][j] = pe1w_e[jj * GG + kb + j];

  us4 hv = *(const us4*)(hvnew + (size_t)v * GG + kb);
  float da = bf2f(hv.x) * pn[0] + bf2f(hv.y) * pn[1] + bf2f(hv.z) * pn[2] + bf2f(hv.w) * pn[3];
#pragma unroll
  for (int o = 32; o; o >>= 1) da += __shfl_down(da, o);
  float alv = __shfl(da, 0) + pe2b[0];

  float ss = 0.f;
  float a0 = 0.f, a1 = 0.f, a2 = 0.f, a3 = 0.f;
  int t = 0;
  for (; t + 4 <= cnt; t += 4) {
    int e[4], s[4];
#pragma unroll
    for (int u = 0; u < 4; ++u) {
      e[u] = __builtin_amdgcn_readfirstlane(elist[begin + t + u]);
      s[u] = __builtin_amdgcn_readfirstlane(srcA[e[u]]);
    }
    us4 g[4];
#pragma unroll
    for (int u = 0; u < 4; ++u) g[u] = *(const us4*)(xa + (size_t)s[u] * GG + kb);
    float h[4][4];
#pragma unroll
    for (int u = 0; u < 4; ++u) {
      h[u][0] = bf2f(g[u].x) + b[0];
      h[u][1] = bf2f(g[u].y) + b[1];
      h[u][2] = bf2f(g[u].z) + b[2];
      h[u][3] = bf2f(g[u].w) + b[3];
    }
#pragma unroll
    for (int jj = 0; jj < EE; ++jj) {
#pragma unroll
      for (int u = 0; u < 4; ++u) {
        float x = Xe[(size_t)e[u] * EE + jj];
        h[u][0] += x * pw[jj][0]; h[u][1] += x * pw[jj][1];
        h[u][2] += x * pw[jj][2]; h[u][3] += x * pw[jj][3];
      }
    }
    float bp[4];
#pragma unroll
    for (int u = 0; u < 4; ++u) {
#pragma unroll
      for (int j = 0; j < 4; ++j) h[u][j] = leakyf(h[u][j]);
      bp[u] = h[u][0] * p[0] + h[u][1] * p[1] + h[u][2] * p[2] + h[u][3] * p[3];
    }
#pragma unroll
    for (int o = 32; o; o >>= 1) {
#pragma unroll
      for (int u = 0; u < 4; ++u) bp[u] += __shfl_down(bp[u], o);
    }
#pragma unroll
    for (int u = 0; u < 4; ++u) {
      float w = __expf(fminf(leakyf(alv + __shfl(bp[u], 0)), 60.f));
      ss += w;
      a0 += w * h[u][0]; a1 += w * h[u][1]; a2 += w * h[u][2]; a3 += w * h[u][3];
    }
  }
  for (; t < cnt; ++t) {
    int e0 = __builtin_amdgcn_readfirstlane(elist[begin + t]);
    int s0 = __builtin_amdgcn_readfirstlane(srcA[e0]);
    us4 g0 = *(const us4*)(xa + (size_t)s0 * GG + kb);
    float h0 = bf2f(g0.x) + b[0], h1 = bf2f(g0.y) + b[1];
    float h2 = bf2f(g0.z) + b[2], h3 = bf2f(g0.w) + b[3];
#pragma unroll
    for (int jj = 0; jj < EE; ++jj) {
      float x = Xe[(size_t)e0 * EE + jj];
      h0 += x * pw[jj][0]; h1 += x * pw[jj][1];
      h2 += x * pw[jj][2]; h3 += x * pw[jj][3];
    }
    h0 = leakyf(h0); h1 = leakyf(h1); h2 = leakyf(h2); h3 = leakyf(h3);
    float bp = h0 * p[0] + h1 * p[1] + h2 * p[2] + h3 * p[3];
#pragma unroll
    for (int o = 32; o; o >>= 1) bp += __shfl_down(bp, o);
    float w = __expf(fminf(leakyf(alv + __shfl(bp, 0)), 60.f));
    ss += w;
    a0 += w * h0; a1 += w * h1; a2 += w * h2; a3 += w * h3;
  }
  float inv = (cnt > 0) ? rcp_f(ss) : 0.f;
  if (act) {
    us4 o4;
    o4.x = f2bf(a0 * inv); o4.y = f2bf(a1 * inv);
    o4.z = f2bf(a2 * inv); o4.w = f2bf(a3 * inv);
    *(us4*)(S + (size_t)v * GG + kb) = o4;
  }
  if (lane == 0) ssumOut[v] = (cnt > 0) ? ss : 0.f;
}

// ---------------- layer-2 fused aggregation: one wave per block ----------------
__global__ __launch_bounds__(64) void l2_agg(
    const unsigned short* __restrict__ hvp, const float* __restrict__ gd,
    const float* __restrict__ gs, const float* __restrict__ lpeb,
    const int* __restrict__ srcA,
    const int* __restrict__ offA, const int* __restrict__ cntA, const int* __restrict__ elist,
    unsigned short* __restrict__ S2, int N)
{
  int v = blockIdx.x;
  int lane = threadIdx.x;
  if (v >= N) return;
  int begin = offA[v], cnt = cntA[v];
  bool act = lane < 50;
  int kb = act ? 4 * lane : 0;
  float gdv = gd[v] + lpeb[0];
  float ss = 0.f;
  float a0 = 0.f, a1 = 0.f, a2 = 0.f, a3 = 0.f;
  int t = 0;
  for (; t + 4 <= cnt; t += 4) {
    int e[4], s[4];
#pragma unroll
    for (int u = 0; u < 4; ++u) {
      e[u] = __builtin_amdgcn_readfirstlane(elist[begin + t + u]);
      s[u] = __builtin_amdgcn_readfirstlane(srcA[e[u]]);
    }
    us4 g0 = *(const us4*)(hvp + (size_t)s[0] * GG + kb);
    us4 g1 = *(const us4*)(hvp + (size_t)s[1] * GG + kb);
    us4 g2 = *(const us4*)(hvp + (size_t)s[2] * GG + kb);
    us4 g3 = *(const us4*)(hvp + (size_t)s[3] * GG + kb);
    float w0 = __expf(fminf(leakyf(gdv + gs[s[0]]), 60.f));
    float w1 = __expf(fminf(leakyf(gdv + gs[s[1]]), 60.f));
    float w2 = __expf(fminf(leakyf(gdv + gs[s[2]]), 60.f));
    float w3 = __expf(fminf(leakyf(gdv + gs[s[3]]), 60.f));
    ss += w0 + w1 + w2 + w3;
    a0 += w0 * bf2f(g0.x) + w1 * bf2f(g1.x) + w2 * bf2f(g2.x) + w3 * bf2f(g3.x);
    a1 += w0 * bf2f(g0.y) + w1 * bf2f(g1.y) + w2 * bf2f(g2.y) + w3 * bf2f(g3.y);
    a2 += w0 * bf2f(g0.z) + w1 * bf2f(g1.z) + w2 * bf2f(g2.z) + w3 * bf2f(g3.z);
    a3 += w0 * bf2f(g0.w) + w1 * bf2f(g1.w) + w2 * bf2f(g2.w) + w3 * bf2f(g3.w);
  }
  for (; t < cnt; ++t) {
    int e = __builtin_amdgcn_readfirstlane(elist[begin + t]);
    int s = __builtin_amdgcn_readfirstlane(srcA[e]);
    us4 g = *(const us4*)(hvp + (size_t)s * GG + kb);
    float w = __expf(fminf(leakyf(gdv + gs[s]), 60.f));
    ss += w;
    a0 += w * bf2f(g.x); a1 += w * bf2f(g.y);
    a2 += w * bf2f(g.z); a3 += w * bf2f(g.w);
  }
  float inv = (cnt > 0) ? rcp_f(ss) : 0.f;
  if (act) {
    us4 o4;
    o4.x = f2bf((cnt > 0) ? elu_fast(a0 * inv) : 0.f);
    o4.y = f2bf((cnt > 0) ? elu_fast(a1 * inv) : 0.f);
    o4.z = f2bf((cnt > 0) ? elu_fast(a2 * inv) : 0.f);
    o4.w = f2bf((cnt > 0) ? elu_fast(a3 * inv) : 0.f);
    *(us4*)(S2 + (size_t)v * GG + kb) = o4;
  }
}

// ================= direct-from-L2 MFMA GEMM (no LDS, no barriers) =================
template <int KPT>
__global__ __launch_bounds__(256, 2) void mfma_gemm_d(
    const unsigned short* __restrict__ A, int strideA,
    const unsigned short* __restrict__ Wt,
    const float* __restrict__ bias, const float* __restrict__ rowmask,
    unsigned short* __restrict__ Cb, int Mr, int Nc, int act)
{
  int ncol = (Nc + 63) >> 6;
  int nrowt = (Mr + 127) >> 7;
  int per = 8 * ncol;
  int grp = blockIdx.x / per, rem = blockIdx.x % per;
  int rowt = grp * 8 + (rem & 7), colt = rem >> 3;
  if (rowt >= nrowt) return;
  int row0 = rowt * 128, col0 = colt * 64;
  int tid = threadIdx.x;
  int w = tid >> 6, lane = tid & 63, quad = lane >> 4, l15 = lane & 15;

  int rA0 = min(row0 + w * 32 + l15, Mr - 1);
  int rA1 = min(row0 + w * 32 + 16 + l15, Mr - 1);
  int nB[4];
#pragma unroll
  for (int c = 0; c < 4; ++c) nB[c] = min(col0 + c * 16 + l15, Nc - 1);
  const unsigned short* pA0 = A + (size_t)rA0 * strideA + quad * 8;
  const unsigned short* pA1 = A + (size_t)rA1 * strideA + quad * 8;
  const unsigned short* pB[4];
#pragma unroll
  for (int c = 0; c < 4; ++c) pB[c] = Wt + (size_t)nB[c] * KPT + quad * 8;

  f32x4 zero4 = {0.f, 0.f, 0.f, 0.f};
  f32x4 acc[2][4];
#pragma unroll
  for (int r = 0; r < 2; ++r)
#pragma unroll
    for (int c = 0; c < 4; ++c) acc[r][c] = zero4;

#pragma unroll
  for (int k0 = 0; k0 < KPT; k0 += 32) {
    bf16x8 a0 = *(const bf16x8*)(pA0 + k0);
    bf16x8 a1 = *(const bf16x8*)(pA1 + k0);
    bf16x8 b[4];
#pragma unroll
    for (int c = 0; c < 4; ++c) b[c] = *(const bf16x8*)(pB[c] + k0);
#pragma unroll
    for (int c = 0; c < 4; ++c) {
      acc[0][c] = __builtin_amdgcn_mfma_f32_16x16x32_bf16(a0, b[c], acc[0][c], 0, 0, 0);
      acc[1][c] = __builtin_amdgcn_mfma_f32_16x16x32_bf16(a1, b[c], acc[1][c], 0, 0, 0);
    }
  }
#pragma unroll
  for (int r = 0; r < 2; ++r) {
#pragma unroll
    for (int c = 0; c < 4; ++c) {
      int col = col0 + c * 16 + l15;
      if (col >= Nc) continue;
#pragma unroll
      for (int i = 0; i < 4; ++i) {
        int row = row0 + w * 32 + r * 16 + quad * 4 + i;
        if (row >= Mr) continue;
        bool valid = (rowmask == nullptr) || (rowmask[row] > 0.f);
        float v = valid ? (acc[r][c][i] + (bias ? bias[col] : 0.f)) : 0.f;
        if (act == 1) v = leakyf(v);
        else if (act == 2) v = elu_fast(v);
        Cb[(size_t)row * Nc + col] = f2bf(v);
      }
    }
  }
}

// ================= direct-from-L2 fused MFMA GRU (no LDS, no barriers) =================
#define KPG 224
template <typename TI, typename TO>
__global__ __launch_bounds__(256, 2) void mfma_gru_d(
    const TI* __restrict__ X, const TI* __restrict__ H,
    const unsigned short* __restrict__ WtIH, const unsigned short* __restrict__ WtHH,
    const float* __restrict__ bih, const float* __restrict__ bhh,
    TO* __restrict__ Out, int R, int relu_out)
{
  int nrowt = (R + 127) >> 7;
  int grp = blockIdx.x / 56, rem = blockIdx.x % 56;
  int rowt = grp * 8 + (rem & 7), colt = rem >> 3;
  if (rowt >= nrowt) return;
  int row0 = rowt * 128, col0 = colt * 32;
  int tid = threadIdx.x;
  int w = tid >> 6, lane = tid & 63, quad = lane >> 4, l15 = lane & 15;

  int rA0 = min(row0 + w * 32 + l15, R - 1);
  int rA1 = min(row0 + w * 32 + 16 + l15, R - 1);
  int nB0 = min(col0 + l15, GG - 1);
  int nB1 = min(col0 + 16 + l15, GG - 1);
  const TI* pX0 = X + (size_t)rA0 * GG + quad * 8;
  const TI* pX1 = X + (size_t)rA1 * GG + quad * 8;
  const TI* pH0 = H + (size_t)rA0 * GG + quad * 8;
  const TI* pH1 = H + (size_t)rA1 * GG + quad * 8;
  const unsigned short* pBi0[3];
  const unsigned short* pBi1[3];
  const unsigned short* pBh0[3];
  const unsigned short* pBh1[3];
#pragma unroll
  for (int g = 0; g < 3; ++g) {
    pBi0[g] = WtIH + (size_t)(g * GG + nB0) * KPG + quad * 8;
    pBi1[g] = WtIH + (size_t)(g * GG + nB1) * KPG + quad * 8;
    pBh0[g] = WtHH + (size_t)(g * GG + nB0) * KPG + quad * 8;
    pBh1[g] = WtHH + (size_t)(g * GG + nB1) * KPG + quad * 8;
  }

  f32x4 zero4 = {0.f, 0.f, 0.f, 0.f};
  f32x4 acc[6][2][2];
#pragma unroll
  for (int g = 0; g < 6; ++g)
#pragma unroll
    for (int r = 0; r < 2; ++r)
#pragma unroll
      for (int c = 0; c < 2; ++c) acc[g][r][c] = zero4;

#pragma unroll
  for (int k0 = 0; k0 < KPG; k0 += 32) {
    bf16x8 ax0 = afrag(pX0, k0);
    bf16x8 ax1 = afrag(pX1, k0);
    bf16x8 ah0 = afrag(pH0, k0);
    bf16x8 ah1 = afrag(pH1, k0);
#pragma unroll
    for (int g = 0; g < 3; ++g) {
      bf16x8 bi0 = *(const bf16x8*)(pBi0[g] + k0);
      bf16x8 bi1 = *(const bf16x8*)(pBi1[g] + k0);
      bf16x8 bh0 = *(const bf16x8*)(pBh0[g] + k0);
      bf16x8 bh1 = *(const bf16x8*)(pBh1[g] + k0);
      acc[g][0][0] = __builtin_amdgcn_mfma_f32_16x16x32_bf16(ax0, bi0, acc[g][0][0], 0, 0, 0);
      acc[g][0][1] = __builtin_amdgcn_mfma_f32_16x16x32_bf16(ax0, bi1, acc[g][0][1], 0, 0, 0);
      acc[g][1][0] = __builtin_amdgcn_mfma_f32_16x16x32_bf16(ax1, bi0, acc[g][1][0], 0, 0, 0);
      acc[g][1][1] = __builtin_amdgcn_mfma_f32_16x16x32_bf16(ax1, bi1, acc[g][1][1], 0, 0, 0);
      acc[g + 3][0][0] = __builtin_amdgcn_mfma_f32_16x16x32_bf16(ah0, bh0, acc[g + 3][0][0], 0, 0, 0);
      acc[g + 3][0][1] = __builtin_amdgcn_mfma_f32_16x16x32_bf16(ah0, bh1, acc[g + 3][0][1], 0, 0, 0);
      acc[g + 3][1][0] = __builtin_amdgcn_mfma_f32_16x16x32_bf16(ah1, bh0, acc[g + 3][1][0], 0, 0, 0);
      acc[g + 3][1][1] = __builtin_amdgcn_mfma_f32_16x16x32_bf16(ah1, bh1, acc[g + 3][1][1], 0, 0, 0);
    }
  }
#pragma unroll
  for (int r = 0; r < 2; ++r) {
#pragma unroll
    for (int c = 0; c < 2; ++c) {
      int col = col0 + c * 16 + l15;
      if (col >= GG) continue;
      float br = bih[col],       bhr = bhh[col];
      float bz = bih[200 + col], bhz = bhh[200 + col];
      float bn = bih[400 + col], bhn = bhh[400 + col];
#pragma unroll
      for (int i = 0; i < 4; ++i) {
        int row = row0 + w * 32 + r * 16 + quad * 4 + i;
        if (row >= R) continue;
        float rr = sigm_fast(acc[0][r][c][i] + br + acc[3][r][c][i] + bhr);
        float zz = sigm_fast(acc[1][r][c][i] + bz + acc[4][r][c][i] + bhz);
        float nn = tanh_fast(acc[2][r][c][i] + bn + rr * (acc[5][r][c][i] + bhn));
        float hval = ldv<TI>(H + (size_t)row * GG + col);
        float o = (1.f - zz) * nn + zz * hval;
        if (relu_out) o = fmaxf(o, 0.f);
        if constexpr (sizeof(TO) == 2) Out[(size_t)row * GG + col] = f2bf(o);
        else Out[(size_t)row * GG + col] = o;
      }
    }
  }
}

// ---------------- fp32 tiled GEMM (small readout shapes) ----------------
#define Bb 64
#define Bn 64
#define Bk 16
__global__ __launch_bounds__(256) void gemm_kernel(
    const float* __restrict__ A, const float* __restrict__ W,
    const float* __restrict__ bias, const float* __restrict__ rowmask,
    float* __restrict__ Cf, void* __restrict__ Oout, const int* __restrict__ oflag,
    int Mr, int Nc, int K, int act)
{
  __shared__ float As[Bk][Bb + 1];
  __shared__ float Ws[Bk][Bn];
  int row0 = blockIdx.x * Bb, col0 = blockIdx.y * Bn;
  int tid = threadIdx.x;
  int ty = tid >> 4, tx = tid & 15;
  float acc[4][4] = {};
  for (int k0 = 0; k0 < K; k0 += Bk) {
    for (int l = tid; l < Bb * Bk; l += 256) {
      int m = l >> 4, kk = l & 15;
      int r = row0 + m, k = k0 + kk;
      As[kk][m] = (r < Mr && k < K) ? A[(size_t)r * K + k] : 0.f;
    }
    for (int l = tid; l < Bk * Bn; l += 256) {
      int kk = l >> 6, nn = l & 63;
      int k = k0 + kk, c = col0 + nn;
      Ws[kk][nn] = (k < K && c < Nc) ? W[(size_t)k * Nc + c] : 0.f;
    }
    __syncthreads();
#pragma unroll
    for (int kk = 0; kk < Bk; ++kk) {
      float av[4], bv[4];
#pragma unroll
      for (int i = 0; i < 4; ++i) av[i] = As[kk][ty * 4 + i];
#pragma unroll
      for (int j = 0; j < 4; ++j) bv[j] = Ws[kk][tx * 4 + j];
#pragma unroll
      for (int i = 0; i < 4; ++i)
#pragma unroll
        for (int j = 0; j < 4; ++j) acc[i][j] += av[i] * bv[j];
    }
    __syncthreads();
  }
  int isbf = (oflag != nullptr) ? *oflag : 0;
#pragma unroll
  for (int i = 0; i < 4; ++i) {
    int r = row0 + ty * 4 + i;
    if (r >= Mr) continue;
    bool valid = (rowmask == nullptr) || (rowmask[r] > 0.f);
#pragma unroll
    for (int j = 0; j < 4; ++j) {
      int c = col0 + tx * 4 + j;
      if (c >= Nc) continue;
      float v = valid ? (acc[i][j] + (bias ? bias[c] : 0.f)) : 0.f;
      if (act == 1) v = leakyf(v);
      else if (act == 2) v = elu_fast(v);
      else if (act == 3) v = fmaxf(v, 0.f);
      size_t idx = (size_t)r * Nc + c;
      if (Oout) {
        if (isbf) ((__hip_bfloat16*)Oout)[idx] = __float2bfloat16(v);
        else      ((float*)Oout)[idx] = v;
      } else {
        Cf[idx] = v;
      }
    }
  }
}

// ---------------- per-node dot(s), bf16 input ----------------
__global__ __launch_bounds__(256) void node_dot2(
    const unsigned short* __restrict__ X, const float* __restrict__ w1,
    const float* __restrict__ w2,
    float* __restrict__ o1, float* __restrict__ o2, int N)
{
  int v = (blockIdx.x * 256 + threadIdx.x) >> 6;
  int lane = threadIdx.x & 63;
  if (v >= N) return;
  float d1 = 0.f, d2 = 0.f;
  for (int k = lane; k < GG; k += 64) {
    float x = bf2f(X[(size_t)v * GG + k]);
    d1 += x * w1[k];
    if (w2) d2 += x * w2[k];
  }
  for (int off = 32; off; off >>= 1) {
    d1 += __shfl_down(d1, off);
    if (w2) d2 += __shfl_down(d2, off);
  }
  if (lane == 0) { o1[v] = d1; if (w2) o2[v] = d2; }
}

__global__ __launch_bounds__(256) void graph_sum(
    const unsigned short* __restrict__ h, float* __restrict__ g)
{
  int b = blockIdx.x, k = threadIdx.x;
  if (k < GG) {
    float a = 0.f;
    for (int i = 0; i < 50; ++i) a += bf2f(h[((size_t)b * 50 + i) * GG + k]);
    g[(size_t)b * GG + k] = a;
  }
}

__global__ __launch_bounds__(256) void attn_kernel(
    const float* __restrict__ g, const unsigned short* __restrict__ h2,
    const float* __restrict__ w1, const float* __restrict__ dh,
    const float* __restrict__ rb, float* __restrict__ weighted)
{
  int b = blockIdx.x;
  __shared__ float red[256];
  __shared__ float zs[50];
  __shared__ float as_[50];
  __shared__ float dgs;
  int tid = threadIdx.x;
  float p = 0.f;
  if (tid < GG) p = fmaxf(g[(size_t)b * GG + tid], 0.f) * w1[tid];
  red[tid] = p;
  __syncthreads();
  for (int s = 128; s; s >>= 1) { if (tid < s) red[tid] += red[tid + s]; __syncthreads(); }
  if (tid == 0) dgs = red[0];
  __syncthreads();
  if (tid < 50) zs[tid] = leakyf(dgs + dh[b * 50 + tid] + rb[0]);
  __syncthreads();
  if (tid == 0) {
    float m = -1e30f;
    for (int i = 0; i < 50; ++i) m = fmaxf(m, zs[i]);
    float s = 0.f;
    for (int i = 0; i < 50; ++i) { float e = __expf(zs[i] - m); as_[i] = e; s += e; }
    float inv = 1.f / s;
    for (int i = 0; i < 50; ++i) as_[i] *= inv;
  }
  __syncthreads();
  if (tid < GG) {
    float a = 0.f;
    for (int i = 0; i < 50; ++i) a += as_[i] * bf2f(h2[((size_t)b * 50 + i) * GG + tid]);
    weighted[(size_t)b * GG + tid] = a;
  }
}

// ---------------- host ----------------
static inline int gemm_grid(int Mr, int Nc) {
  int nrow = (Mr + 127) / 128, ncol = (Nc + 63) / 64;
  return ((nrow + 7) / 8) * 8 * ncol;
}
static inline int gru_grid(int R) {
  int nrow = (R + 127) / 128;
  return ((nrow + 7) / 8) * 56;
}

extern "C" void kernel_launch(void* const* d_in, const int* in_sizes, int n_in,
                              void* d_out, int out_size, void* d_ws, size_t ws_size,
                              hipStream_t stream)
{
  (void)n_in; (void)out_size; (void)ws_size;
  const int N = NN, M = MM, B = BB, F = FF, G = GG, P = PP;
  const int KP200 = 224, KP39 = 64;
  float* ws = (float*)d_ws;
  size_t off = 0;
  auto alloc = [&](size_t n) { size_t o = off; off += (n + 63) & ~(size_t)63; return o; };

  size_t o_flag = alloc(16);
  size_t o_pn_w = alloc(F * G), o_pn_b = alloc(G);
  size_t o_pe1_w = alloc((F + EE) * G), o_pe1_b = alloc(G);
  size_t o_pe2_w = alloc(2 * G), o_pe2_b = alloc(1);
  size_t o_et_w = alloc(G * G), o_et_b = alloc(G);
  size_t o_g0_wih = alloc(G * 3 * G), o_g0_whh = alloc(G * 3 * G);
  size_t o_g0_bih = alloc(3 * G), o_g0_bhh = alloc(3 * G);
  size_t o_lpe_w = alloc(2 * G), o_lpe_b = alloc(1);
  size_t o_lpn_w = alloc(G * G), o_lpn_b = alloc(G);
  size_t o_g1_wih = alloc(G * 3 * G), o_g1_whh = alloc(G * 3 * G);
  size_t o_g1_bih = alloc(3 * G), o_g1_bhh = alloc(3 * G);
  size_t o_rl_w = alloc(2 * 2 * G), o_rl_b = alloc(2);
  size_t o_rp_w = alloc(2 * G * G), o_rp_b = alloc(2 * G);
  size_t o_rg_wih = alloc(2 * G * 3 * G), o_rg_whh = alloc(2 * G * 3 * G);
  size_t o_rg_bih = alloc(2 * 3 * G), o_rg_bhh = alloc(2 * 3 * G);
  size_t o_t_w = alloc(G * P), o_t_b = alloc(P);
  size_t o_Xnb = alloc((size_t)N * 40 / 2 + 64);
  size_t o_Xe = alloc((size_t)M * EE);
  size_t o_B1 = alloc((size_t)N * G);
  size_t o_B2 = alloc((size_t)N * G);
  size_t o_B3 = alloc((size_t)N * G);
  size_t o_ssum = alloc(N);
  size_t o_gd = alloc(N), o_gs = alloc(N), o_dh = alloc(N);
  size_t o_gv0 = alloc((size_t)B * G), o_gwt = alloc((size_t)B * G), o_grep = alloc((size_t)B * G + 64);
  size_t o_gv1 = alloc((size_t)B * G + 64), o_gv2 = alloc((size_t)B * G + 64);
  size_t o_etT  = alloc(G * KP200 / 2 + 64), o_lpnT = alloc(G * KP200 / 2 + 64);
  size_t o_g0ihT = alloc(3 * G * KP200 / 2 + 64), o_g0hhT = alloc(3 * G * KP200 / 2 + 64);
  size_t o_g1ihT = alloc(3 * G * KP200 / 2 + 64), o_g1hhT = alloc(3 * G * KP200 / 2 + 64);
  size_t o_rg0ihT = alloc(3 * G * KP200 / 2 + 64), o_rg0hhT = alloc(3 * G * KP200 / 2 + 64);
  size_t o_rg1ihT = alloc(3 * G * KP200 / 2 + 64), o_rg1hhT = alloc(3 * G * KP200 / 2 + 64);
  size_t o_pnT = alloc(G * KP39 / 2 + 64), o_pe1T = alloc(G * KP39 / 2 + 64);
  size_t o_cnt = alloc(N), o_off = alloc(N), o_cur = alloc(N);
  size_t o_elist = alloc(M), o_bsum = alloc(64), o_incl = alloc(N);

  int* flag = (int*)(ws + o_flag);
  int* cntA = (int*)(ws + o_cnt);
  int* offA = (int*)(ws + o_off);
  int* curA = (int*)(ws + o_cur);
  int* elist = (int*)(ws + o_elist);
  int* bsum = (int*)(ws + o_bsum);
  int* incl = (int*)(ws + o_incl);
  unsigned short* Xnb = (unsigned short*)(ws + o_Xnb);
  unsigned short* B1b = (unsigned short*)(ws + o_B1);
  unsigned short* B2b = (unsigned short*)(ws + o_B2);
  unsigned short* B3b = (unsigned short*)(ws + o_B3);

  CvtJobs32 jobs;
  int ji = 0;
  auto push = [&](int idx, size_t dsto) {
    jobs.j[ji].s = d_in[idx];
    jobs.j[ji].d = ws + dsto;
    jobs.j[ji].n = in_sizes[idx];
    jobs.j[ji].pad = 0;
    ++ji;
  };
  push(1, o_Xe);
  push(2, o_pn_w);  push(3, o_pn_b);
  push(4, o_pe1_w); push(5, o_pe1_b);
  push(6, o_pe2_w); push(7, o_pe2_b);
  push(8, o_et_w);  push(9, o_et_b);
  push(10, o_g0_wih); push(11, o_g0_whh); push(12, o_g0_bih); push(13, o_g0_bhh);
  push(14, o_lpe_w);  push(15, o_lpe_b);
  push(16, o_lpn_w);  push(17, o_lpn_b);
  push(18, o_g1_wih); push(19, o_g1_whh); push(20, o_g1_bih); push(21, o_g1_bhh);
  push(22, o_rl_w);   push(23, o_rl_b);
  push(24, o_rp_w);   push(25, o_rp_b);
  push(26, o_rg_wih); push(27, o_rg_whh); push(28, o_rg_bih); push(29, o_rg_bhh);
  push(30, o_t_w);    push(31, o_t_b);

  const int* src = (const int*)d_in[32];
  const int* dst = (const int*)d_in[33];

  dim3 blk(256);
  detect_dtype<<<dim3(1), blk, 0, stream>>>((const unsigned int*)d_in[0], flag);
  cvt_any<<<dim3(512, 31), blk, 0, stream>>>(jobs, flag);
  cvt_xn<<<dim3((N * 40 + 255) / 256), blk, 0, stream>>>(d_in[0], Xnb, flag, N);

  // ---- CSR build (by dst) ----
  hipMemsetAsync(cntA, 0, (size_t)N * 4, stream);
  hist_kernel<<<dim3((M + 255) / 256), blk, 0, stream>>>(dst, cntA, M);
  int nscb = (N + SCHUNK - 1) / SCHUNK;
  scan1_kernel<<<dim3(nscb), blk, 0, stream>>>(cntA, incl, bsum, N);
  scan2_kernel<<<dim3(1), dim3(64), 0, stream>>>(bsum, nscb);
  scan3_kernel<<<dim3((N + 255) / 256), blk, 0, stream>>>(incl, cntA, bsum, offA, curA, N);
  fill_kernel<<<dim3((M + 255) / 256), blk, 0, stream>>>(dst, curA, elist, M);

  // ---- weight transposes (k-padded) ----
  TJobs12 tj;
  auto tpush = [&](int slot, size_t srcO, size_t dstO, int K, int Nc, int KPv) {
    tj.j[slot].s = ws + srcO;
    tj.j[slot].d = (unsigned short*)(ws + dstO);
    tj.j[slot].K = K; tj.j[slot].N = Nc; tj.j[slot].KP = KPv; tj.j[slot].pad = 0;
  };
  tpush(0, o_et_w,  o_etT,  G, G, KP200);
  tpush(1, o_lpn_w, o_lpnT, G, G, KP200);
  tpush(2, o_g0_wih, o_g0ihT, G, 3 * G, KP200);
  tpush(3, o_g0_whh, o_g0hhT, G, 3 * G, KP200);
  tpush(4, o_g1_wih, o_g1ihT, G, 3 * G, KP200);
  tpush(5, o_g1_whh, o_g1hhT, G, 3 * G, KP200);
  tpush(6, o_rg_wih, o_rg0ihT, G, 3 * G, KP200);
  tpush(7, o_rg_whh, o_rg0hhT, G, 3 * G, KP200);
  tpush(8, o_rg_wih + (size_t)G * 3 * G, o_rg1ihT, G, 3 * G, KP200);
  tpush(9, o_rg_whh + (size_t)G * 3 * G, o_rg1hhT, G, 3 * G, KP200);
  tpush(10, o_pn_w,  o_pnT,  F, G, KP39);
  tpush(11, o_pe1_w, o_pe1T, F, G, KP39);
  transpose_bf16<<<dim3(128, 12), blk, 0, stream>>>(tj);

  int gg = gemm_grid(N, G);
  // hv_new = leaky(Xnb@pn_w + pn_b) -> B1 bf16
  mfma_gemm_d<64><<<dim3(gg), blk, 0, stream>>>(
      Xnb, 40, (const unsigned short*)(ws + o_pnT),
      ws + o_pn_b, nullptr, B1b, N, G, 1);
  // xa = Xnb @ pe1_w[:39] -> B2 bf16
  mfma_gemm_d<64><<<dim3(gg), blk, 0, stream>>>(
      Xnb, 40, (const unsigned short*)(ws + o_pe1T),
      nullptr, nullptr, B2b, N, G, 0);
  // fused layer-1 agg; one wave per node
  l1_agg<<<dim3(N), dim3(64), 0, stream>>>(ws + o_Xe, B2b, B1b,
                                           ws + o_pe1_w + (size_t)F * G, ws + o_pe1_b,
                                           ws + o_pe2_w, ws + o_pe2_w + G, ws + o_pe2_b,
                                           src, offA, cntA, elist,
                                           B3b, ws + o_ssum, N);
  // c = elu(mask(B3@et_w + et_b)) -> B2 bf16
  mfma_gemm_d<224><<<dim3(gg), blk, 0, stream>>>(
      B3b, G, (const unsigned short*)(ws + o_etT),
      ws + o_et_b, ws + o_ssum, B2b, N, G, 2);
  // h = relu(GRU0(x=B2, h=B1)) -> B3 bf16
  mfma_gru_d<unsigned short, unsigned short><<<dim3(gru_grid(N)), blk, 0, stream>>>(
      B2b, B1b,
      (const unsigned short*)(ws + o_g0ihT), (const unsigned short*)(ws + o_g0hhT),
      ws + o_g0_bih, ws + o_g0_bhh, B3b, N, 1);

  // ---- layer 2 ----
  dim3 gWave((N + 3) / 4);
  node_dot2<<<gWave, blk, 0, stream>>>(B3b, ws + o_lpe_w, ws + o_lpe_w + G,
                                       ws + o_gd, ws + o_gs, N);
  // hv_proj = h@lpn_w + lpn_b -> B1 bf16
  mfma_gemm_d<224><<<dim3(gg), blk, 0, stream>>>(
      B3b, G, (const unsigned short*)(ws + o_lpnT),
      ws + o_lpn_b, nullptr, B1b, N, G, 0);
  l2_agg<<<dim3(N), dim3(64), 0, stream>>>(B1b, ws + o_gd, ws + o_gs, ws + o_lpe_b,
                                           src, offA, cntA, elist, B2b, N);
  // h2 = relu(GRU1(x=B2, h=B3)) -> B1 bf16
  mfma_gru_d<unsigned short, unsigned short><<<dim3(gru_grid(N)), blk, 0, stream>>>(
      B2b, B3b,
      (const unsigned short*)(ws + o_g1ihT), (const unsigned short*)(ws + o_g1hhT),
      ws + o_g1_bih, ws + o_g1_bhh, B1b, N, 1);

  // ---- readout ----
  graph_sum<<<dim3(B), blk, 0, stream>>>(B1b, ws + o_gv0);
  dim3 gBG((B + Bb - 1) / Bb, (G + Bn - 1) / Bn);
  size_t gcur = o_gv0, gnext = o_gv1;
  for (int t = 0; t < 2; ++t) {
    node_dot2<<<gWave, blk, 0, stream>>>(B1b, ws + o_rl_w + t * 2 * G + G,
                                         nullptr, ws + o_dh, nullptr, N);
    attn_kernel<<<dim3(B), blk, 0, stream>>>(ws + gcur, B1b, ws + o_rl_w + t * 2 * G,
                                             ws + o_dh, ws + o_rl_b + t, ws + o_gwt);
    gemm_kernel<<<gBG, blk, 0, stream>>>(ws + o_gwt, ws + o_rp_w + (size_t)t * G * G,
                                         ws + o_rp_b + t * G, nullptr,
                                         ws + o_grep, nullptr, nullptr, B, G, G, 2);
    mfma_gru_d<float, float><<<dim3(gru_grid(B)), blk, 0, stream>>>(
        ws + o_grep, ws + gcur,
        (const unsigned short*)(ws + (t == 0 ? o_rg0ihT : o_rg1ihT)),
        (const unsigned short*)(ws + (t == 0 ? o_rg0hhT : o_rg1hhT)),
        ws + o_rg_bih + t * 3 * G, ws + o_rg_bhh + t * 3 * G,
        ws + gnext, B, 0);
    gcur = gnext;
    gnext = o_gv2;
  }
  dim3 gOut((B + Bb - 1) / Bb, (P + Bn - 1) / Bn);
  gemm_kernel<<<gOut, blk, 0, stream>>>(ws + gcur, ws + o_t_w, ws + o_t_b, nullptr,
                                        nullptr, d_out, flag, B, P, G, 0);
}

// Round 11
// 805.513 us; speedup vs baseline: 5.0457x; 1.1064x over previous
//
#include <hip/hip_runtime.h>
#include <hip/hip_bf16.h>

// ---------------- constants ----------------
#define NN 50000
#define MM 400000
#define BB 1000
#define FF 39
#define EE 11
#define GG 200
#define PP 128

typedef __attribute__((ext_vector_type(8))) short bf16x8;
typedef __attribute__((ext_vector_type(4))) float f32x4;
struct us4 { unsigned short x, y, z, w; };

// ---------------- helpers ----------------
__device__ __forceinline__ float bf2f(unsigned short u) {
  return __uint_as_float(((unsigned int)u) << 16);
}
__device__ __forceinline__ unsigned short f2bf(float x) {
  union { __hip_bfloat16 b; unsigned short u; } v;
  v.b = __float2bfloat16(x);
  return v.u;
}
__device__ __forceinline__ float rcp_f(float x) { return __builtin_amdgcn_rcpf(x); }
__device__ __forceinline__ float leakyf(float x) { return x > 0.f ? x : 0.01f * x; }
__device__ __forceinline__ float elu_fast(float x)  { return x > 0.f ? x : __expf(x) - 1.f; }
__device__ __forceinline__ float sigm_fast(float x) { return rcp_f(1.f + __expf(-x)); }
__device__ __forceinline__ float tanh_fast(float x) { return 1.f - 2.f * rcp_f(1.f + __expf(2.f * x)); }
template <typename T> __device__ __forceinline__ float ldv(const T* p);
template <> __device__ __forceinline__ float ldv<float>(const float* p) { return *p; }
template <> __device__ __forceinline__ float ldv<unsigned short>(const unsigned short* p) { return bf2f(*p); }

// direct global A-fragment load: 8 consecutive elements (row layout)
template <typename T>
__device__ __forceinline__ bf16x8 afrag(const T* base, size_t off) {
  if constexpr (sizeof(T) == 2) {
    return *(const bf16x8*)(base + off);
  } else {
    float4 f0 = *(const float4*)(base + off);
    float4 f1 = *(const float4*)(base + off + 4);
    short t[8];
    t[0] = (short)f2bf(f0.x); t[1] = (short)f2bf(f0.y);
    t[2] = (short)f2bf(f0.z); t[3] = (short)f2bf(f0.w);
    t[4] = (short)f2bf(f1.x); t[5] = (short)f2bf(f1.y);
    t[6] = (short)f2bf(f1.z); t[7] = (short)f2bf(f1.w);
    return *(bf16x8*)t;
  }
}

// ---------------- runtime dtype detection ----------------
__global__ __launch_bounds__(256) void detect_dtype(const unsigned int* __restrict__ w,
                                                    int* __restrict__ flag) {
  __shared__ int cnt[256];
  int c = 0;
  for (int i = threadIdx.x; i < 2048; i += 256) {
    unsigned int e = (w[i] >> 8) & 0x7F;
    c += (e >= 60 && e <= 64) ? 1 : 0;
  }
  cnt[threadIdx.x] = c;
  __syncthreads();
  for (int s = 128; s; s >>= 1) {
    if (threadIdx.x < s) cnt[threadIdx.x] += cnt[threadIdx.x + s];
    __syncthreads();
  }
  if (threadIdx.x == 0) *flag = (cnt[0] >= 1024) ? 1 : 0;
}

// ---------------- batched conversion to f32 ----------------
struct CvtJob { const void* s; float* d; int n; int pad; };
struct CvtJobs32 { CvtJob j[32]; };

__global__ __launch_bounds__(256) void cvt_any(CvtJobs32 jobs, const int* __restrict__ flag) {
  CvtJob job = jobs.j[blockIdx.y];
  int isbf = *flag;
  if (isbf) {
    const unsigned short* s = (const unsigned short*)job.s;
    for (int i = blockIdx.x * 256 + threadIdx.x; i < job.n; i += gridDim.x * 256)
      job.d[i] = bf2f(s[i]);
  } else {
    const float* s = (const float*)job.s;
    for (int i = blockIdx.x * 256 + threadIdx.x; i < job.n; i += gridDim.x * 256)
      job.d[i] = s[i];
  }
}

// Xn -> bf16 padded [N][40]
__global__ __launch_bounds__(256) void cvt_xn(const void* __restrict__ src,
                                              unsigned short* __restrict__ dstb,
                                              const int* __restrict__ flag, int N) {
  int isbf = *flag;
  int total = N * 40;
  for (int i = blockIdx.x * 256 + threadIdx.x; i < total; i += gridDim.x * 256) {
    int n = i / 40, k = i - n * 40;
    unsigned short v = 0;
    if (k < FF) {
      if (isbf) v = ((const unsigned short*)src)[n * FF + k];
      else      v = f2bf(((const float*)src)[n * FF + k]);
    }
    dstb[i] = v;
  }
}

// ---------------- fragment-major weight pack ----------------
// src f32 [K rows][Ns cols], use cols [coff, coff+200). Output: 14 col-tiles of 16,
// nkc k-chunks of 32; element order [ct][kc][lane][j]: n=ct*16+(lane&15),
// k=kc*32+(lane>>4)*8+j. Each (ct,kc) fragment is a contiguous 1KB block.
struct PJob { const float* s; unsigned short* d; int K; int Ns; int coff; int nkc; };
struct PJobs28 { PJob j[28]; };

__global__ __launch_bounds__(256) void pack_bf16(PJobs28 jobs) {
  PJob job = jobs.j[blockIdx.y];
  int per = job.nkc * 512;
  int total = 14 * per;
  for (int idx = blockIdx.x * 256 + threadIdx.x; idx < total; idx += gridDim.x * 256) {
    int ct = idx / per, r = idx - ct * per;
    int kc = r >> 9, e = r & 511;
    int lane = e >> 3, j = e & 7;
    int n = ct * 16 + (lane & 15);
    int k = kc * 32 + (lane >> 4) * 8 + j;
    job.d[idx] = (k < job.K && n < GG)
        ? f2bf(job.s[(size_t)k * job.Ns + job.coff + n]) : (unsigned short)0;
  }
}

// ---------------- CSR build ----------------
__global__ __launch_bounds__(256) void hist_kernel(const int* __restrict__ dst,
                                                   int* __restrict__ cnt, int M) {
  int e = blockIdx.x * 256 + threadIdx.x;
  if (e < M) atomicAdd(&cnt[dst[e]], 1);
}

#define SCHUNK 2048
__global__ __launch_bounds__(256) void scan1_kernel(const int* __restrict__ cnt,
                                                    int* __restrict__ incl,
                                                    int* __restrict__ bsum, int n) {
  __shared__ int lds[256];
  int b = blockIdx.x, tid = threadIdx.x;
  int base = b * SCHUNK + tid * 8;
  int v[8], s = 0;
#pragma unroll
  for (int j = 0; j < 8; ++j) { int i = base + j; v[j] = (i < n) ? cnt[i] : 0; s += v[j]; }
  lds[tid] = s;
  __syncthreads();
  for (int o = 1; o < 256; o <<= 1) {
    int t = (tid >= o) ? lds[tid - o] : 0;
    __syncthreads();
    lds[tid] += t;
    __syncthreads();
  }
  int run = lds[tid] - s;
#pragma unroll
  for (int j = 0; j < 8; ++j) {
    run += v[j];
    int i = base + j;
    if (i < n) incl[i] = run;
  }
  if (tid == 255) bsum[b] = lds[255];
}

__global__ void scan2_kernel(int* __restrict__ bsum, int nb) {
  if (threadIdx.x == 0 && blockIdx.x == 0) {
    int run = 0;
    for (int i = 0; i < nb; ++i) { int t = bsum[i]; bsum[i] = run; run += t; }
  }
}

__global__ __launch_bounds__(256) void scan3_kernel(const int* __restrict__ incl,
                                                    const int* __restrict__ cnt,
                                                    const int* __restrict__ bsum,
                                                    int* __restrict__ offA,
                                                    int* __restrict__ cur, int n) {
  int i = blockIdx.x * 256 + threadIdx.x;
  if (i >= n) return;
  int o = incl[i] - cnt[i] + bsum[i / SCHUNK];
  offA[i] = o;
  cur[i] = o;
}

__global__ __launch_bounds__(256) void fill_kernel(const int* __restrict__ dst,
                                                   int* __restrict__ cur,
                                                   int* __restrict__ elist, int M) {
  int e = blockIdx.x * 256 + threadIdx.x;
  if (e >= M) return;
  int pos = atomicAdd(&cur[dst[e]], 1);
  elist[pos] = e;
}

// ---------------- layer-1 fused aggregation: one wave per block ----------------
__global__ __launch_bounds__(64) void l1_agg(
    const float* __restrict__ Xe, const unsigned short* __restrict__ xa,
    const unsigned short* __restrict__ hvnew,
    const float* __restrict__ pe1w_e, const float* __restrict__ pe1b,
    const float* __restrict__ pe2w_n, const float* __restrict__ pe2w_e,
    const float* __restrict__ pe2b, const int* __restrict__ srcA,
    const int* __restrict__ offA, const int* __restrict__ cntA, const int* __restrict__ elist,
    unsigned short* __restrict__ S, float* __restrict__ ssumOut, int N)
{
  int v = blockIdx.x;
  int lane = threadIdx.x;
  if (v >= N) return;
  int begin = offA[v], cnt = cntA[v];
  bool act = lane < 50;
  int kb = act ? 4 * lane : 0;
  float b[4], p[4], pn[4];
  float pw[EE][4];
#pragma unroll
  for (int j = 0; j < 4; ++j) {
    b[j]  = pe1b[kb + j];
    p[j]  = act ? pe2w_e[kb + j] : 0.f;
    pn[j] = act ? pe2w_n[kb + j] : 0.f;
  }
#pragma unroll
  for (int jj = 0; jj < EE; ++jj)
#pragma unroll
    for (int j = 0; j < 4; ++j) pw[jj][j] = pe1w_e[jj * GG + kb + j];

  us4 hv = *(const us4*)(hvnew + (size_t)v * GG + kb);
  float da = bf2f(hv.x) * pn[0] + bf2f(hv.y) * pn[1] + bf2f(hv.z) * pn[2] + bf2f(hv.w) * pn[3];
#pragma unroll
  for (int o = 32; o; o >>= 1) da += __shfl_down(da, o);
  float alv = __shfl(da, 0) + pe2b[0];

  float ss = 0.f;
  float a0 = 0.f, a1 = 0.f, a2 = 0.f, a3 = 0.f;
  int t = 0;
  for (; t + 4 <= cnt; t += 4) {
    int e[4], s[4];
#pragma unroll
    for (int u = 0; u < 4; ++u) {
      e[u] = __builtin_amdgcn_readfirstlane(elist[begin + t + u]);
      s[u] = __builtin_amdgcn_readfirstlane(srcA[e[u]]);
    }
    us4 g[4];
#pragma unroll
    for (int u = 0; u < 4; ++u) g[u] = *(const us4*)(xa + (size_t)s[u] * GG + kb);
    float h[4][4];
#pragma unroll
    for (int u = 0; u < 4; ++u) {
      h[u][0] = bf2f(g[u].x) + b[0];
      h[u][1] = bf2f(g[u].y) + b[1];
      h[u][2] = bf2f(g[u].z) + b[2];
      h[u][3] = bf2f(g[u].w) + b[3];
    }
#pragma unroll
    for (int jj = 0; jj < EE; ++jj) {
#pragma unroll
      for (int u = 0; u < 4; ++u) {
        float x = Xe[(size_t)e[u] * EE + jj];
        h[u][0] += x * pw[jj][0]; h[u][1] += x * pw[jj][1];
        h[u][2] += x * pw[jj][2]; h[u][3] += x * pw[jj][3];
      }
    }
    float bp[4];
#pragma unroll
    for (int u = 0; u < 4; ++u) {
#pragma unroll
      for (int j = 0; j < 4; ++j) h[u][j] = leakyf(h[u][j]);
      bp[u] = h[u][0] * p[0] + h[u][1] * p[1] + h[u][2] * p[2] + h[u][3] * p[3];
    }
#pragma unroll
    for (int o = 32; o; o >>= 1) {
#pragma unroll
      for (int u = 0; u < 4; ++u) bp[u] += __shfl_down(bp[u], o);
    }
#pragma unroll
    for (int u = 0; u < 4; ++u) {
      float w = __expf(fminf(leakyf(alv + __shfl(bp[u], 0)), 60.f));
      ss += w;
      a0 += w * h[u][0]; a1 += w * h[u][1]; a2 += w * h[u][2]; a3 += w * h[u][3];
    }
  }
  for (; t < cnt; ++t) {
    int e0 = __builtin_amdgcn_readfirstlane(elist[begin + t]);
    int s0 = __builtin_amdgcn_readfirstlane(srcA[e0]);
    us4 g0 = *(const us4*)(xa + (size_t)s0 * GG + kb);
    float h0 = bf2f(g0.x) + b[0], h1 = bf2f(g0.y) + b[1];
    float h2 = bf2f(g0.z) + b[2], h3 = bf2f(g0.w) + b[3];
#pragma unroll
    for (int jj = 0; jj < EE; ++jj) {
      float x = Xe[(size_t)e0 * EE + jj];
      h0 += x * pw[jj][0]; h1 += x * pw[jj][1];
      h2 += x * pw[jj][2]; h3 += x * pw[jj][3];
    }
    h0 = leakyf(h0); h1 = leakyf(h1); h2 = leakyf(h2); h3 = leakyf(h3);
    float bp = h0 * p[0] + h1 * p[1] + h2 * p[2] + h3 * p[3];
#pragma unroll
    for (int o = 32; o; o >>= 1) bp += __shfl_down(bp, o);
    float w = __expf(fminf(leakyf(alv + __shfl(bp, 0)), 60.f));
    ss += w;
    a0 += w * h0; a1 += w * h1; a2 += w * h2; a3 += w * h3;
  }
  float inv = (cnt > 0) ? rcp_f(ss) : 0.f;
  if (act) {
    us4 o4;
    o4.x = f2bf(a0 * inv); o4.y = f2bf(a1 * inv);
    o4.z = f2bf(a2 * inv); o4.w = f2bf(a3 * inv);
    *(us4*)(S + (size_t)v * GG + kb) = o4;
  }
  if (lane == 0) ssumOut[v] = (cnt > 0) ? ss : 0.f;
}

// ---------------- layer-2 fused aggregation: one wave per block ----------------
__global__ __launch_bounds__(64) void l2_agg(
    const unsigned short* __restrict__ hvp, const float* __restrict__ gd,
    const float* __restrict__ gs, const float* __restrict__ lpeb,
    const int* __restrict__ srcA,
    const int* __restrict__ offA, const int* __restrict__ cntA, const int* __restrict__ elist,
    unsigned short* __restrict__ S2, int N)
{
  int v = blockIdx.x;
  int lane = threadIdx.x;
  if (v >= N) return;
  int begin = offA[v], cnt = cntA[v];
  bool act = lane < 50;
  int kb = act ? 4 * lane : 0;
  float gdv = gd[v] + lpeb[0];
  float ss = 0.f;
  float a0 = 0.f, a1 = 0.f, a2 = 0.f, a3 = 0.f;
  int t = 0;
  for (; t + 4 <= cnt; t += 4) {
    int e[4], s[4];
#pragma unroll
    for (int u = 0; u < 4; ++u) {
      e[u] = __builtin_amdgcn_readfirstlane(elist[begin + t + u]);
      s[u] = __builtin_amdgcn_readfirstlane(srcA[e[u]]);
    }
    us4 g0 = *(const us4*)(hvp + (size_t)s[0] * GG + kb);
    us4 g1 = *(const us4*)(hvp + (size_t)s[1] * GG + kb);
    us4 g2 = *(const us4*)(hvp + (size_t)s[2] * GG + kb);
    us4 g3 = *(const us4*)(hvp + (size_t)s[3] * GG + kb);
    float w0 = __expf(fminf(leakyf(gdv + gs[s[0]]), 60.f));
    float w1 = __expf(fminf(leakyf(gdv + gs[s[1]]), 60.f));
    float w2 = __expf(fminf(leakyf(gdv + gs[s[2]]), 60.f));
    float w3 = __expf(fminf(leakyf(gdv + gs[s[3]]), 60.f));
    ss += w0 + w1 + w2 + w3;
    a0 += w0 * bf2f(g0.x) + w1 * bf2f(g1.x) + w2 * bf2f(g2.x) + w3 * bf2f(g3.x);
    a1 += w0 * bf2f(g0.y) + w1 * bf2f(g1.y) + w2 * bf2f(g2.y) + w3 * bf2f(g3.y);
    a2 += w0 * bf2f(g0.z) + w1 * bf2f(g1.z) + w2 * bf2f(g2.z) + w3 * bf2f(g3.z);
    a3 += w0 * bf2f(g0.w) + w1 * bf2f(g1.w) + w2 * bf2f(g2.w) + w3 * bf2f(g3.w);
  }
  for (; t < cnt; ++t) {
    int e = __builtin_amdgcn_readfirstlane(elist[begin + t]);
    int s = __builtin_amdgcn_readfirstlane(srcA[e]);
    us4 g = *(const us4*)(hvp + (size_t)s * GG + kb);
    float w = __expf(fminf(leakyf(gdv + gs[s]), 60.f));
    ss += w;
    a0 += w * bf2f(g.x); a1 += w * bf2f(g.y);
    a2 += w * bf2f(g.z); a3 += w * bf2f(g.w);
  }
  float inv = (cnt > 0) ? rcp_f(ss) : 0.f;
  if (act) {
    us4 o4;
    o4.x = f2bf((cnt > 0) ? elu_fast(a0 * inv) : 0.f);
    o4.y = f2bf((cnt > 0) ? elu_fast(a1 * inv) : 0.f);
    o4.z = f2bf((cnt > 0) ? elu_fast(a2 * inv) : 0.f);
    o4.w = f2bf((cnt > 0) ? elu_fast(a3 * inv) : 0.f);
    *(us4*)(S2 + (size_t)v * GG + kb) = o4;
  }
}

// ================= direct-from-L2 MFMA GEMM, packed-B =================
// A: [Mr][strideA] row layout; Wp: packed [14 tiles][NKC chunks][64][8].
template <int NKC>
__global__ __launch_bounds__(256, 2) void mfma_gemm_d(
    const unsigned short* __restrict__ A, int strideA,
    const unsigned short* __restrict__ Wp,
    const float* __restrict__ bias, const float* __restrict__ rowmask,
    unsigned short* __restrict__ Cb, int Mr, int Nc, int act)
{
  int ncol = (Nc + 63) >> 6;
  int nrowt = (Mr + 127) >> 7;
  int per = 8 * ncol;
  int grp = blockIdx.x / per, rem = blockIdx.x % per;
  int rowt = grp * 8 + (rem & 7), colt = rem >> 3;
  if (rowt >= nrowt) return;
  int row0 = rowt * 128, col0 = colt * 64;
  int tid = threadIdx.x;
  int w = tid >> 6, lane = tid & 63, quad = lane >> 4, l15 = lane & 15;

  int rA0 = min(row0 + w * 32 + l15, Mr - 1);
  int rA1 = min(row0 + w * 32 + 16 + l15, Mr - 1);
  const unsigned short* pA0 = A + (size_t)rA0 * strideA + quad * 8;
  const unsigned short* pA1 = A + (size_t)rA1 * strideA + quad * 8;
  const unsigned short* pB[4];
#pragma unroll
  for (int c = 0; c < 4; ++c)
    pB[c] = Wp + ((size_t)(colt * 4 + c) * NKC) * 512 + lane * 8;

  f32x4 zero4 = {0.f, 0.f, 0.f, 0.f};
  f32x4 acc[2][4];
#pragma unroll
  for (int r = 0; r < 2; ++r)
#pragma unroll
    for (int c = 0; c < 4; ++c) acc[r][c] = zero4;

#pragma unroll
  for (int kc = 0; kc < NKC; ++kc) {
    bf16x8 a0 = *(const bf16x8*)(pA0 + kc * 32);
    bf16x8 a1 = *(const bf16x8*)(pA1 + kc * 32);
    bf16x8 b[4];
#pragma unroll
    for (int c = 0; c < 4; ++c) b[c] = *(const bf16x8*)(pB[c] + kc * 512);
#pragma unroll
    for (int c = 0; c < 4; ++c) {
      acc[0][c] = __builtin_amdgcn_mfma_f32_16x16x32_bf16(a0, b[c], acc[0][c], 0, 0, 0);
      acc[1][c] = __builtin_amdgcn_mfma_f32_16x16x32_bf16(a1, b[c], acc[1][c], 0, 0, 0);
    }
  }
#pragma unroll
  for (int r = 0; r < 2; ++r) {
#pragma unroll
    for (int c = 0; c < 4; ++c) {
      int col = col0 + c * 16 + l15;
      if (col >= Nc) continue;
#pragma unroll
      for (int i = 0; i < 4; ++i) {
        int row = row0 + w * 32 + r * 16 + quad * 4 + i;
        if (row >= Mr) continue;
        bool valid = (rowmask == nullptr) || (rowmask[row] > 0.f);
        float v = valid ? (acc[r][c][i] + (bias ? bias[col] : 0.f)) : 0.f;
        if (act == 1) v = leakyf(v);
        else if (act == 2) v = elu_fast(v);
        Cb[(size_t)row * Nc + col] = f2bf(v);
      }
    }
  }
}

// ================= direct-from-L2 fused MFMA GRU, packed-B =================
// WIHp/WHHp: packed per gate: [gate][14 tiles][7 chunks][64][8].
template <typename TI, typename TO>
__global__ __launch_bounds__(256, 2) void mfma_gru_d(
    const TI* __restrict__ X, const TI* __restrict__ H,
    const unsigned short* __restrict__ WIHp, const unsigned short* __restrict__ WHHp,
    const float* __restrict__ bih, const float* __restrict__ bhh,
    TO* __restrict__ Out, int R, int relu_out)
{
  int nrowt = (R + 127) >> 7;
  int grp = blockIdx.x / 56, rem = blockIdx.x % 56;
  int rowt = grp * 8 + (rem & 7), colt = rem >> 3;
  if (rowt >= nrowt) return;
  int row0 = rowt * 128, col0 = colt * 32;
  int tid = threadIdx.x;
  int w = tid >> 6, lane = tid & 63, quad = lane >> 4, l15 = lane & 15;

  int rA0 = min(row0 + w * 32 + l15, R - 1);
  int rA1 = min(row0 + w * 32 + 16 + l15, R - 1);
  const TI* pX0 = X + (size_t)rA0 * GG + quad * 8;
  const TI* pX1 = X + (size_t)rA1 * GG + quad * 8;
  const TI* pH0 = H + (size_t)rA0 * GG + quad * 8;
  const TI* pH1 = H + (size_t)rA1 * GG + quad * 8;
  const unsigned short* pBi[3][2];
  const unsigned short* pBh[3][2];
#pragma unroll
  for (int g = 0; g < 3; ++g)
#pragma unroll
    for (int c = 0; c < 2; ++c) {
      size_t tileoff = ((size_t)(g * 14 + colt * 2 + c) * 7) * 512 + lane * 8;
      pBi[g][c] = WIHp + tileoff;
      pBh[g][c] = WHHp + tileoff;
    }

  f32x4 zero4 = {0.f, 0.f, 0.f, 0.f};
  f32x4 acc[6][2][2];
#pragma unroll
  for (int g = 0; g < 6; ++g)
#pragma unroll
    for (int r = 0; r < 2; ++r)
#pragma unroll
      for (int c = 0; c < 2; ++c) acc[g][r][c] = zero4;

#pragma unroll
  for (int kc = 0; kc < 7; ++kc) {
    bf16x8 ax0 = afrag(pX0, kc * 32);
    bf16x8 ax1 = afrag(pX1, kc * 32);
    bf16x8 ah0 = afrag(pH0, kc * 32);
    bf16x8 ah1 = afrag(pH1, kc * 32);
#pragma unroll
    for (int g = 0; g < 3; ++g) {
      bf16x8 bi0 = *(const bf16x8*)(pBi[g][0] + kc * 512);
      bf16x8 bi1 = *(const bf16x8*)(pBi[g][1] + kc * 512);
      bf16x8 bh0 = *(const bf16x8*)(pBh[g][0] + kc * 512);
      bf16x8 bh1 = *(const bf16x8*)(pBh[g][1] + kc * 512);
      acc[g][0][0] = __builtin_amdgcn_mfma_f32_16x16x32_bf16(ax0, bi0, acc[g][0][0], 0, 0, 0);
      acc[g][0][1] = __builtin_amdgcn_mfma_f32_16x16x32_bf16(ax0, bi1, acc[g][0][1], 0, 0, 0);
      acc[g][1][0] = __builtin_amdgcn_mfma_f32_16x16x32_bf16(ax1, bi0, acc[g][1][0], 0, 0, 0);
      acc[g][1][1] = __builtin_amdgcn_mfma_f32_16x16x32_bf16(ax1, bi1, acc[g][1][1], 0, 0, 0);
      acc[g + 3][0][0] = __builtin_amdgcn_mfma_f32_16x16x32_bf16(ah0, bh0, acc[g + 3][0][0], 0, 0, 0);
      acc[g + 3][0][1] = __builtin_amdgcn_mfma_f32_16x16x32_bf16(ah0, bh1, acc[g + 3][0][1], 0, 0, 0);
      acc[g + 3][1][0] = __builtin_amdgcn_mfma_f32_16x16x32_bf16(ah1, bh0, acc[g + 3][1][0], 0, 0, 0);
      acc[g + 3][1][1] = __builtin_amdgcn_mfma_f32_16x16x32_bf16(ah1, bh1, acc[g + 3][1][1], 0, 0, 0);
    }
  }
#pragma unroll
  for (int r = 0; r < 2; ++r) {
#pragma unroll
    for (int c = 0; c < 2; ++c) {
      int col = col0 + c * 16 + l15;
      if (col >= GG) continue;
      float br = bih[col],       bhr = bhh[col];
      float bz = bih[200 + col], bhz = bhh[200 + col];
      float bn = bih[400 + col], bhn = bhh[400 + col];
#pragma unroll
      for (int i = 0; i < 4; ++i) {
        int row = row0 + w * 32 + r * 16 + quad * 4 + i;
        if (row >= R) continue;
        float rr = sigm_fast(acc[0][r][c][i] + br + acc[3][r][c][i] + bhr);
        float zz = sigm_fast(acc[1][r][c][i] + bz + acc[4][r][c][i] + bhz);
        float nn = tanh_fast(acc[2][r][c][i] + bn + rr * (acc[5][r][c][i] + bhn));
        float hval = ldv<TI>(H + (size_t)row * GG + col);
        float o = (1.f - zz) * nn + zz * hval;
        if (relu_out) o = fmaxf(o, 0.f);
        if constexpr (sizeof(TO) == 2) Out[(size_t)row * GG + col] = f2bf(o);
        else Out[(size_t)row * GG + col] = o;
      }
    }
  }
}

// ---------------- fp32 tiled GEMM (small readout shapes) ----------------
#define Bb 64
#define Bn 64
#define Bk 16
__global__ __launch_bounds__(256) void gemm_kernel(
    const float* __restrict__ A, const float* __restrict__ W,
    const float* __restrict__ bias, const float* __restrict__ rowmask,
    float* __restrict__ Cf, void* __restrict__ Oout, const int* __restrict__ oflag,
    int Mr, int Nc, int K, int act)
{
  __shared__ float As[Bk][Bb + 1];
  __shared__ float Ws[Bk][Bn];
  int row0 = blockIdx.x * Bb, col0 = blockIdx.y * Bn;
  int tid = threadIdx.x;
  int ty = tid >> 4, tx = tid & 15;
  float acc[4][4] = {};
  for (int k0 = 0; k0 < K; k0 += Bk) {
    for (int l = tid; l < Bb * Bk; l += 256) {
      int m = l >> 4, kk = l & 15;
      int r = row0 + m, k = k0 + kk;
      As[kk][m] = (r < Mr && k < K) ? A[(size_t)r * K + k] : 0.f;
    }
    for (int l = tid; l < Bk * Bn; l += 256) {
      int kk = l >> 6, nn = l & 63;
      int k = k0 + kk, c = col0 + nn;
      Ws[kk][nn] = (k < K && c < Nc) ? W[(size_t)k * Nc + c] : 0.f;
    }
    __syncthreads();
#pragma unroll
    for (int kk = 0; kk < Bk; ++kk) {
      float av[4], bv[4];
#pragma unroll
      for (int i = 0; i < 4; ++i) av[i] = As[kk][ty * 4 + i];
#pragma unroll
      for (int j = 0; j < 4; ++j) bv[j] = Ws[kk][tx * 4 + j];
#pragma unroll
      for (int i = 0; i < 4; ++i)
#pragma unroll
        for (int j = 0; j < 4; ++j) acc[i][j] += av[i] * bv[j];
    }
    __syncthreads();
  }
  int isbf = (oflag != nullptr) ? *oflag : 0;
#pragma unroll
  for (int i = 0; i < 4; ++i) {
    int r = row0 + ty * 4 + i;
    if (r >= Mr) continue;
    bool valid = (rowmask == nullptr) || (rowmask[r] > 0.f);
#pragma unroll
    for (int j = 0; j < 4; ++j) {
      int c = col0 + tx * 4 + j;
      if (c >= Nc) continue;
      float v = valid ? (acc[i][j] + (bias ? bias[c] : 0.f)) : 0.f;
      if (act == 1) v = leakyf(v);
      else if (act == 2) v = elu_fast(v);
      else if (act == 3) v = fmaxf(v, 0.f);
      size_t idx = (size_t)r * Nc + c;
      if (Oout) {
        if (isbf) ((__hip_bfloat16*)Oout)[idx] = __float2bfloat16(v);
        else      ((float*)Oout)[idx] = v;
      } else {
        Cf[idx] = v;
      }
    }
  }
}

// ---------------- per-node dot(s), bf16 input ----------------
__global__ __launch_bounds__(256) void node_dot2(
    const unsigned short* __restrict__ X, const float* __restrict__ w1,
    const float* __restrict__ w2,
    float* __restrict__ o1, float* __restrict__ o2, int N)
{
  int v = (blockIdx.x * 256 + threadIdx.x) >> 6;
  int lane = threadIdx.x & 63;
  if (v >= N) return;
  float d1 = 0.f, d2 = 0.f;
  for (int k = lane; k < GG; k += 64) {
    float x = bf2f(X[(size_t)v * GG + k]);
    d1 += x * w1[k];
    if (w2) d2 += x * w2[k];
  }
  for (int off = 32; off; off >>= 1) {
    d1 += __shfl_down(d1, off);
    if (w2) d2 += __shfl_down(d2, off);
  }
  if (lane == 0) { o1[v] = d1; if (w2) o2[v] = d2; }
}

__global__ __launch_bounds__(256) void graph_sum(
    const unsigned short* __restrict__ h, float* __restrict__ g)
{
  int b = blockIdx.x, k = threadIdx.x;
  if (k < GG) {
    float a = 0.f;
    for (int i = 0; i < 50; ++i) a += bf2f(h[((size_t)b * 50 + i) * GG + k]);
    g[(size_t)b * GG + k] = a;
  }
}

__global__ __launch_bounds__(256) void attn_kernel(
    const float* __restrict__ g, const unsigned short* __restrict__ h2,
    const float* __restrict__ w1, const float* __restrict__ dh,
    const float* __restrict__ rb, float* __restrict__ weighted)
{
  int b = blockIdx.x;
  __shared__ float red[256];
  __shared__ float zs[50];
  __shared__ float as_[50];
  __shared__ float dgs;
  int tid = threadIdx.x;
  float p = 0.f;
  if (tid < GG) p = fmaxf(g[(size_t)b * GG + tid], 0.f) * w1[tid];
  red[tid] = p;
  __syncthreads();
  for (int s = 128; s; s >>= 1) { if (tid < s) red[tid] += red[tid + s]; __syncthreads(); }
  if (tid == 0) dgs = red[0];
  __syncthreads();
  if (tid < 50) zs[tid] = leakyf(dgs + dh[b * 50 + tid] + rb[0]);
  __syncthreads();
  if (tid == 0) {
    float m = -1e30f;
    for (int i = 0; i < 50; ++i) m = fmaxf(m, zs[i]);
    float s = 0.f;
    for (int i = 0; i < 50; ++i) { float e = __expf(zs[i] - m); as_[i] = e; s += e; }
    float inv = 1.f / s;
    for (int i = 0; i < 50; ++i) as_[i] *= inv;
  }
  __syncthreads();
  if (tid < GG) {
    float a = 0.f;
    for (int i = 0; i < 50; ++i) a += as_[i] * bf2f(h2[((size_t)b * 50 + i) * GG + tid]);
    weighted[(size_t)b * GG + tid] = a;
  }
}

// ---------------- host ----------------
static inline int gemm_grid(int Mr, int Nc) {
  int nrow = (Mr + 127) / 128, ncol = (Nc + 63) / 64;
  return ((nrow + 7) / 8) * 8 * ncol;
}
static inline int gru_grid(int R) {
  int nrow = (R + 127) / 128;
  return ((nrow + 7) / 8) * 56;
}

extern "C" void kernel_launch(void* const* d_in, const int* in_sizes, int n_in,
                              void* d_out, int out_size, void* d_ws, size_t ws_size,
                              hipStream_t stream)
{
  (void)n_in; (void)out_size; (void)ws_size;
  const int N = NN, M = MM, B = BB, F = FF, G = GG, P = PP;
  // packed sizes (shorts): gate matrix 14*7*512 = 50176; nkc=2: 14*2*512 = 14336
  const int PK7 = 14 * 7 * 512, PK2 = 14 * 2 * 512;
  float* ws = (float*)d_ws;
  size_t off = 0;
  auto alloc = [&](size_t n) { size_t o = off; off += (n + 63) & ~(size_t)63; return o; };

  size_t o_flag = alloc(16);
  size_t o_pn_w = alloc(F * G), o_pn_b = alloc(G);
  size_t o_pe1_w = alloc((F + EE) * G), o_pe1_b = alloc(G);
  size_t o_pe2_w = alloc(2 * G), o_pe2_b = alloc(1);
  size_t o_et_w = alloc(G * G), o_et_b = alloc(G);
  size_t o_g0_wih = alloc(G * 3 * G), o_g0_whh = alloc(G * 3 * G);
  size_t o_g0_bih = alloc(3 * G), o_g0_bhh = alloc(3 * G);
  size_t o_lpe_w = alloc(2 * G), o_lpe_b = alloc(1);
  size_t o_lpn_w = alloc(G * G), o_lpn_b = alloc(G);
  size_t o_g1_wih = alloc(G * 3 * G), o_g1_whh = alloc(G * 3 * G);
  size_t o_g1_bih = alloc(3 * G), o_g1_bhh = alloc(3 * G);
  size_t o_rl_w = alloc(2 * 2 * G), o_rl_b = alloc(2);
  size_t o_rp_w = alloc(2 * G * G), o_rp_b = alloc(2 * G);
  size_t o_rg_wih = alloc(2 * G * 3 * G), o_rg_whh = alloc(2 * G * 3 * G);
  size_t o_rg_bih = alloc(2 * 3 * G), o_rg_bhh = alloc(2 * 3 * G);
  size_t o_t_w = alloc(G * P), o_t_b = alloc(P);
  size_t o_Xnb = alloc((size_t)N * 40 / 2 + 64);
  size_t o_Xe = alloc((size_t)M * EE);
  size_t o_B1 = alloc((size_t)N * G);
  size_t o_B2 = alloc((size_t)N * G);
  size_t o_B3 = alloc((size_t)N * G);
  size_t o_ssum = alloc(N);
  size_t o_gd = alloc(N), o_gs = alloc(N), o_dh = alloc(N);
  size_t o_gv0 = alloc((size_t)B * G), o_gwt = alloc((size_t)B * G), o_grep = alloc((size_t)B * G + 64);
  size_t o_gv1 = alloc((size_t)B * G + 64), o_gv2 = alloc((size_t)B * G + 64);
  // packed weights (float-unit sizes = shorts/2)
  size_t o_etP  = alloc(PK7 / 2 + 64), o_lpnP = alloc(PK7 / 2 + 64);
  size_t o_g0ihP = alloc(3 * PK7 / 2 + 64), o_g0hhP = alloc(3 * PK7 / 2 + 64);
  size_t o_g1ihP = alloc(3 * PK7 / 2 + 64), o_g1hhP = alloc(3 * PK7 / 2 + 64);
  size_t o_rg0ihP = alloc(3 * PK7 / 2 + 64), o_rg0hhP = alloc(3 * PK7 / 2 + 64);
  size_t o_rg1ihP = alloc(3 * PK7 / 2 + 64), o_rg1hhP = alloc(3 * PK7 / 2 + 64);
  size_t o_pnP = alloc(PK2 / 2 + 64), o_pe1P = alloc(PK2 / 2 + 64);
  size_t o_cnt = alloc(N), o_off = alloc(N), o_cur = alloc(N);
  size_t o_elist = alloc(M), o_bsum = alloc(64), o_incl = alloc(N);

  int* flag = (int*)(ws + o_flag);
  int* cntA = (int*)(ws + o_cnt);
  int* offA = (int*)(ws + o_off);
  int* curA = (int*)(ws + o_cur);
  int* elist = (int*)(ws + o_elist);
  int* bsum = (int*)(ws + o_bsum);
  int* incl = (int*)(ws + o_incl);
  unsigned short* Xnb = (unsigned short*)(ws + o_Xnb);
  unsigned short* B1b = (unsigned short*)(ws + o_B1);
  unsigned short* B2b = (unsigned short*)(ws + o_B2);
  unsigned short* B3b = (unsigned short*)(ws + o_B3);

  CvtJobs32 jobs;
  int ji = 0;
  auto push = [&](int idx, size_t dsto) {
    jobs.j[ji].s = d_in[idx];
    jobs.j[ji].d = ws + dsto;
    jobs.j[ji].n = in_sizes[idx];
    jobs.j[ji].pad = 0;
    ++ji;
  };
  push(1, o_Xe);
  push(2, o_pn_w);  push(3, o_pn_b);
  push(4, o_pe1_w); push(5, o_pe1_b);
  push(6, o_pe2_w); push(7, o_pe2_b);
  push(8, o_et_w);  push(9, o_et_b);
  push(10, o_g0_wih); push(11, o_g0_whh); push(12, o_g0_bih); push(13, o_g0_bhh);
  push(14, o_lpe_w);  push(15, o_lpe_b);
  push(16, o_lpn_w);  push(17, o_lpn_b);
  push(18, o_g1_wih); push(19, o_g1_whh); push(20, o_g1_bih); push(21, o_g1_bhh);
  push(22, o_rl_w);   push(23, o_rl_b);
  push(24, o_rp_w);   push(25, o_rp_b);
  push(26, o_rg_wih); push(27, o_rg_whh); push(28, o_rg_bih); push(29, o_rg_bhh);
  push(30, o_t_w);    push(31, o_t_b);

  const int* src = (const int*)d_in[32];
  const int* dst = (const int*)d_in[33];

  dim3 blk(256);
  detect_dtype<<<dim3(1), blk, 0, stream>>>((const unsigned int*)d_in[0], flag);
  cvt_any<<<dim3(512, 31), blk, 0, stream>>>(jobs, flag);
  cvt_xn<<<dim3((N * 40 + 255) / 256), blk, 0, stream>>>(d_in[0], Xnb, flag, N);

  // ---- CSR build (by dst) ----
  hipMemsetAsync(cntA, 0, (size_t)N * 4, stream);
  hist_kernel<<<dim3((M + 255) / 256), blk, 0, stream>>>(dst, cntA, M);
  int nscb = (N + SCHUNK - 1) / SCHUNK;
  scan1_kernel<<<dim3(nscb), blk, 0, stream>>>(cntA, incl, bsum, N);
  scan2_kernel<<<dim3(1), dim3(64), 0, stream>>>(bsum, nscb);
  scan3_kernel<<<dim3((N + 255) / 256), blk, 0, stream>>>(incl, cntA, bsum, offA, curA, N);
  fill_kernel<<<dim3((M + 255) / 256), blk, 0, stream>>>(dst, curA, elist, M);

  // ---- weight packing (fragment-major) ----
  PJobs28 pj;
  int pi = 0;
  auto ppush = [&](size_t srcO, size_t dstOshorts_base, int slot_shorts, int K, int Ns, int coff, int nkc) {
    pj.j[pi].s = ws + srcO;
    pj.j[pi].d = (unsigned short*)(ws + dstOshorts_base) + slot_shorts;
    pj.j[pi].K = K; pj.j[pi].Ns = Ns; pj.j[pi].coff = coff; pj.j[pi].nkc = nkc;
    ++pi;
  };
  ppush(o_et_w,  o_etP,  0, G, G, 0, 7);
  ppush(o_lpn_w, o_lpnP, 0, G, G, 0, 7);
  for (int g = 0; g < 3; ++g) {
    ppush(o_g0_wih, o_g0ihP, g * PK7, G, 3 * G, g * G, 7);
    ppush(o_g0_whh, o_g0hhP, g * PK7, G, 3 * G, g * G, 7);
    ppush(o_g1_wih, o_g1ihP, g * PK7, G, 3 * G, g * G, 7);
    ppush(o_g1_whh, o_g1hhP, g * PK7, G, 3 * G, g * G, 7);
    ppush(o_rg_wih, o_rg0ihP, g * PK7, G, 3 * G, g * G, 7);
    ppush(o_rg_whh, o_rg0hhP, g * PK7, G, 3 * G, g * G, 7);
    ppush(o_rg_wih + (size_t)G * 3 * G, o_rg1ihP, g * PK7, G, 3 * G, g * G, 7);
    ppush(o_rg_whh + (size_t)G * 3 * G, o_rg1hhP, g * PK7, G, 3 * G, g * G, 7);
  }
  ppush(o_pn_w,  o_pnP,  0, F, G, 0, 2);
  ppush(o_pe1_w, o_pe1P, 0, F, G, 0, 2);  // first 39 rows (node part)
  pack_bf16<<<dim3(64, 28), blk, 0, stream>>>(pj);

  int gg = gemm_grid(N, G);
  // hv_new = leaky(Xnb@pn_w + pn_b) -> B1 bf16
  mfma_gemm_d<2><<<dim3(gg), blk, 0, stream>>>(
      Xnb, 40, (const unsigned short*)(ws + o_pnP),
      ws + o_pn_b, nullptr, B1b, N, G, 1);
  // xa = Xnb @ pe1_w[:39] -> B2 bf16
  mfma_gemm_d<2><<<dim3(gg), blk, 0, stream>>>(
      Xnb, 40, (const unsigned short*)(ws + o_pe1P),
      nullptr, nullptr, B2b, N, G, 0);
  // fused layer-1 agg; one wave per node
  l1_agg<<<dim3(N), dim3(64), 0, stream>>>(ws + o_Xe, B2b, B1b,
                                           ws + o_pe1_w + (size_t)F * G, ws + o_pe1_b,
                                           ws + o_pe2_w, ws + o_pe2_w + G, ws + o_pe2_b,
                                           src, offA, cntA, elist,
                                           B3b, ws + o_ssum, N);
  // c = elu(mask(B3@et_w + et_b)) -> B2 bf16
  mfma_gemm_d<7><<<dim3(gg), blk, 0, stream>>>(
      B3b, G, (const unsigned short*)(ws + o_etP),
      ws + o_et_b, ws + o_ssum, B2b, N, G, 2);
  // h = relu(GRU0(x=B2, h=B1)) -> B3 bf16
  mfma_gru_d<unsigned short, unsigned short><<<dim3(gru_grid(N)), blk, 0, stream>>>(
      B2b, B1b,
      (const unsigned short*)(ws + o_g0ihP), (const unsigned short*)(ws + o_g0hhP),
      ws + o_g0_bih, ws + o_g0_bhh, B3b, N, 1);

  // ---- layer 2 ----
  dim3 gWave((N + 3) / 4);
  node_dot2<<<gWave, blk, 0, stream>>>(B3b, ws + o_lpe_w, ws + o_lpe_w + G,
                                       ws + o_gd, ws + o_gs, N);
  // hv_proj = h@lpn_w + lpn_b -> B1 bf16
  mfma_gemm_d<7><<<dim3(gg), blk, 0, stream>>>(
      B3b, G, (const unsigned short*)(ws + o_lpnP),
      ws + o_lpn_b, nullptr, B1b, N, G, 0);
  l2_agg<<<dim3(N), dim3(64), 0, stream>>>(B1b, ws + o_gd, ws + o_gs, ws + o_lpe_b,
                                           src, offA, cntA, elist, B2b, N);
  // h2 = relu(GRU1(x=B2, h=B3)) -> B1 bf16
  mfma_gru_d<unsigned short, unsigned short><<<dim3(gru_grid(N)), blk, 0, stream>>>(
      B2b, B3b,
      (const unsigned short*)(ws + o_g1ihP), (const unsigned short*)(ws + o_g1hhP),
      ws + o_g1_bih, ws + o_g1_bhh, B1b, N, 1);

  // ---- readout ----
  graph_sum<<<dim3(B), blk, 0, stream>>>(B1b, ws + o_gv0);
  dim3 gBG((B + Bb - 1) / Bb, (G + Bn - 1) / Bn);
  size_t gcur = o_gv0, gnext = o_gv1;
  for (int t = 0; t < 2; ++t) {
    node_dot2<<<gWave, blk, 0, stream>>>(B1b, ws + o_rl_w + t * 2 * G + G,
                                         nullptr, ws + o_dh, nullptr, N);
    attn_kernel<<<dim3(B), blk, 0, stream>>>(ws + gcur, B1b, ws + o_rl_w + t * 2 * G,
                                             ws + o_dh, ws + o_rl_b + t, ws + o_gwt);
    gemm_kernel<<<gBG, blk, 0, stream>>>(ws + o_gwt, ws + o_rp_w + (size_t)t * G * G,
                                         ws + o_rp_b + t * G, nullptr,
                                         ws + o_grep, nullptr, nullptr, B, G, G, 2);
    mfma_gru_d<float, float><<<dim3(gru_grid(B)), blk, 0, stream>>>(
        ws + o_grep, ws + gcur,
        (const unsigned short*)(ws + (t == 0 ? o_rg0ihP : o_rg1ihP)),
        (const unsigned short*)(ws + (t == 0 ? o_rg0hhP : o_rg1hhP)),
        ws + o_rg_bih + t * 3 * G, ws + o_rg_bhh + t * 3 * G,
        ws + gnext, B, 0);
    gcur = gnext;
    gnext = o_gv2;
  }
  dim3 gOut((B + Bb - 1) / Bb, (P + Bn - 1) / Bn);
  gemm_kernel<<<gOut, blk, 0, stream>>>(ws + gcur, ws + o_t_w, ws + o_t_b, nullptr,
                                        nullptr, d_out, flag, B, P, G, 0);
}